// Round 4
// baseline (807428.467 us; speedup 1.0000x reference)
//
#include <hip/hip_runtime.h>
#include <math.h>

#define NN 4096      // points
#define NC 768       // feature dim
#define KK 16        // knn k
#define SK 128       // spectral basis size
#define LM 1024      // Lanczos steps
#define NBLK 256     // cooperative grid blocks
#define LAMBDA_ 100.0f

typedef unsigned int u32;

__device__ __forceinline__ float hashf(u32 x) {
  x ^= x >> 16; x *= 0x7feb352dU; x ^= x >> 15; x *= 0x846ca68bU; x ^= x >> 16;
  return ((float)x) * (1.0f / 4294967296.0f);  // [0,1)
}

// ---- agent-scope (device-coherent) access helpers: bypass non-coherent L2 ----
__device__ __forceinline__ float agld(const float* p) {
  return __hip_atomic_load((float*)p, __ATOMIC_RELAXED, __HIP_MEMORY_SCOPE_AGENT);
}
__device__ __forceinline__ void agst(float* p, float v) {
  __hip_atomic_store(p, v, __ATOMIC_RELAXED, __HIP_MEMORY_SCOPE_AGENT);
}
__device__ __forceinline__ double agldd(const double* p) {
  return __hip_atomic_load((double*)p, __ATOMIC_RELAXED, __HIP_MEMORY_SCOPE_AGENT);
}
__device__ __forceinline__ void agstd(double* p, double v) {
  __hip_atomic_store(p, v, __ATOMIC_RELAXED, __HIP_MEMORY_SCOPE_AGENT);
}

// ---- flush-free grid barrier (co-resident cooperative grid required) ----
// All prior agent-scope stores are drained (vmcnt) by every wave before the
// block's representative arrives; counter lives at the coherence point.
__device__ __forceinline__ void gbar(unsigned* cnt, unsigned tgt) {
  asm volatile("s_waitcnt vmcnt(0)" ::: "memory");
  __syncthreads();
  if (threadIdx.x == 0) {
    __hip_atomic_fetch_add(cnt, 1u, __ATOMIC_RELEASE, __HIP_MEMORY_SCOPE_AGENT);
    while (__hip_atomic_load(cnt, __ATOMIC_ACQUIRE, __HIP_MEMORY_SCOPE_AGENT) < tgt)
      __builtin_amdgcn_s_sleep(1);
  }
  __syncthreads();
}

// ---------- row squared norms ----------
__global__ void k_sqnorm(const float* __restrict__ f, float* __restrict__ sq) {
  __shared__ float red[256];
  int i = blockIdx.x;
  float s = 0.f;
  for (int c = threadIdx.x; c < NC; c += 256) { float v = f[(size_t)i * NC + c]; s += v * v; }
  red[threadIdx.x] = s; __syncthreads();
  for (int o = 128; o > 0; o >>= 1) { if (threadIdx.x < o) red[threadIdx.x] += red[threadIdx.x + o]; __syncthreads(); }
  if (threadIdx.x == 0) sq[i] = red[0];
}

// ---------- d2 panel: pan[256][NN] for rows i0..i0+255 ----------
__global__ void __launch_bounds__(256) k_d2panel(const float* __restrict__ f, const float* __restrict__ sq,
                                                 float* __restrict__ pan, int i0) {
  __shared__ float As[16][65], Bs[16][65];
  int bj = blockIdx.x, bi = blockIdx.y;
  int row0 = i0 + bi * 64, col0 = bj * 64;
  int tx = threadIdx.x & 15, ty = threadIdx.x >> 4;
  float acc[4][4] = {};
  for (int k0 = 0; k0 < NC; k0 += 16) {
    for (int t2 = threadIdx.x; t2 < 1024; t2 += 256) {
      int kk = t2 & 15, rr = t2 >> 4;
      As[kk][rr] = f[(size_t)(row0 + rr) * NC + k0 + kk];
      Bs[kk][rr] = f[(size_t)(col0 + rr) * NC + k0 + kk];
    }
    __syncthreads();
#pragma unroll
    for (int kk = 0; kk < 16; kk++) {
      float av[4], bv[4];
#pragma unroll
      for (int a = 0; a < 4; a++) av[a] = As[kk][ty * 4 + a];
#pragma unroll
      for (int b = 0; b < 4; b++) bv[b] = Bs[kk][tx * 4 + b];
#pragma unroll
      for (int a = 0; a < 4; a++)
#pragma unroll
        for (int b = 0; b < 4; b++) acc[a][b] += av[a] * bv[b];
    }
    __syncthreads();
  }
#pragma unroll
  for (int a = 0; a < 4; a++) {
    int gr = row0 + ty * 4 + a;
    int pr = bi * 64 + ty * 4 + a;
    float sr = sq[gr];
#pragma unroll
    for (int b = 0; b < 4; b++) {
      int gc = col0 + tx * 4 + b;
      float v = sr + sq[gc] - 2.f * acc[a][b];
      v = fmaxf(v, 0.f);
      if (gr == gc) v += 1e10f;
      pan[(size_t)pr * NN + gc] = v;
    }
  }
}

// ---------- top-16 smallest per row ----------
__global__ void __launch_bounds__(256) k_topk(const float* __restrict__ pan, int i0,
                                              int* __restrict__ idx, float* __restrict__ dkv) {
  __shared__ float vals[NN];
  __shared__ float rv[256];
  __shared__ int ri[256];
  int r = blockIdx.x;
  const float* row = pan + (size_t)r * NN;
  for (int j = threadIdx.x; j < NN; j += 256) vals[j] = row[j];
  __syncthreads();
  for (int t3 = 0; t3 < KK; t3++) {
    float bv = 1e30f; int bi2 = NN;
    for (int j2 = threadIdx.x; j2 < NN; j2 += 256) {
      float v = vals[j2];
      if (v < bv || (v == bv && j2 < bi2)) { bv = v; bi2 = j2; }
    }
    rv[threadIdx.x] = bv; ri[threadIdx.x] = bi2;
    __syncthreads();
    for (int o = 128; o > 0; o >>= 1) {
      if (threadIdx.x < o) {
        float v2 = rv[threadIdx.x + o]; int i2 = ri[threadIdx.x + o];
        if (v2 < rv[threadIdx.x] || (v2 == rv[threadIdx.x] && i2 < ri[threadIdx.x])) {
          rv[threadIdx.x] = v2; ri[threadIdx.x] = i2;
        }
      }
      __syncthreads();
    }
    if (threadIdx.x == 0) {
      idx[(size_t)(i0 + r) * KK + t3] = ri[0];
      dkv[(size_t)(i0 + r) * KK + t3] = rv[0];
      vals[ri[0]] = 1e30f;
    }
    __syncthreads();
  }
}

// ---------- sigma2 = mean(dkv) + 1e-12 ----------
__global__ void k_partsum(const float* __restrict__ dkv, double* __restrict__ part) {
  __shared__ double red[256];
  double s = 0.0;
  for (int t2 = blockIdx.x * 256 + threadIdx.x; t2 < NN * KK; t2 += 64 * 256) s += (double)dkv[t2];
  red[threadIdx.x] = s; __syncthreads();
  for (int o = 128; o > 0; o >>= 1) { if (threadIdx.x < o) red[threadIdx.x] += red[threadIdx.x + o]; __syncthreads(); }
  if (threadIdx.x == 0) part[blockIdx.x] = red[0];
}
__global__ void k_sigma(const double* __restrict__ part, double* __restrict__ scal) {
  __shared__ double red[64];
  red[threadIdx.x] = part[threadIdx.x]; __syncthreads();
  for (int o = 32; o > 0; o >>= 1) { if (threadIdx.x < o) red[threadIdx.x] += red[threadIdx.x + o]; __syncthreads(); }
  if (threadIdx.x == 0) scal[0] = red[0] / (double)(NN * KK) + 1e-12;
}

// ---------- gaussian weights ----------
__global__ void k_wexp(const float* __restrict__ dkv, const double* __restrict__ scal,
                       float* __restrict__ wv) {
  int t = blockIdx.x * 256 + threadIdx.x;
  if (t >= NN * KK) return;
  float inv2s = (float)(0.5 / scal[0]);
  wv[t] = expf(-dkv[t] * inv2s);
}

// ---------- deterministic CSR transpose construction ----------
__global__ void k_count(const int* __restrict__ idx, int* __restrict__ cnt) {
  int t = blockIdx.x * 256 + threadIdx.x;
  if (t < NN * KK) atomicAdd(&cnt[idx[t]], 1);  // int atomics: order-invariant
}

__global__ void __launch_bounds__(1024) k_scan(const int* __restrict__ cnt,
                                               int* __restrict__ roff, int* __restrict__ rpos) {
  __shared__ int buf[1024];
  int t = threadIdx.x;
  int v[4]; int s = 0;
#pragma unroll
  for (int u = 0; u < 4; u++) { v[u] = cnt[t * 4 + u]; s += v[u]; }
  buf[t] = s; __syncthreads();
  for (int o = 1; o < 1024; o <<= 1) {
    int x = (t >= o) ? buf[t - o] : 0;
    __syncthreads();
    buf[t] += x;
    __syncthreads();
  }
  int run = (t == 0) ? 0 : buf[t - 1];
#pragma unroll
  for (int u = 0; u < 4; u++) { roff[t * 4 + u] = run; rpos[t * 4 + u] = run; run += v[u]; }
  if (t == 1023) roff[NN] = run;
}

__global__ void k_place(const int* __restrict__ idx, int* __restrict__ rpos, int* __restrict__ tsrc) {
  int i = blockIdx.x * 256 + threadIdx.x;
  if (i >= NN) return;
  for (int l = 0; l < KK; l++) {
    int j = idx[(size_t)i * KK + l];
    int e = atomicAdd(&rpos[j], 1);
    tsrc[e] = i * KK + l;
  }
}

__global__ void k_sortb(const int* __restrict__ roff, int* __restrict__ tsrc) {
  int i = blockIdx.x * 256 + threadIdx.x;
  if (i >= NN) return;
  int b = roff[i], e = roff[i + 1];
  for (int a = b + 1; a < e; a++) {
    int key = tsrc[a]; int c = a - 1;
    while (c >= b && tsrc[c] > key) { tsrc[c + 1] = tsrc[c]; c--; }
    tsrc[c + 1] = key;
  }
}

// ---------- degrees ----------
__global__ void k_deg(const float* __restrict__ wv, const int* __restrict__ roff,
                      const int* __restrict__ tsrc, float* __restrict__ deg) {
  int i = blockIdx.x * 256 + threadIdx.x;
  if (i >= NN) return;
  float s = 0.f;
  for (int l = 0; l < KK; l++) s += wv[(size_t)i * KK + l];
  float s2 = 0.f;
  for (int e = roff[i]; e < roff[i + 1]; e++) s2 += wv[tsrc[e]];
  deg[i] = 0.5f * (s + s2);
}

// ---------- normalized adjacency ----------
__global__ void k_wadj2(const float* __restrict__ wv, const int* __restrict__ idx,
                        const int* __restrict__ roff, const int* __restrict__ tsrc,
                        const float* __restrict__ deg,
                        float* __restrict__ wadjr, float* __restrict__ wadjt,
                        int* __restrict__ tcol) {
  int i = blockIdx.x * 256 + threadIdx.x;
  if (i >= NN) return;
  float di = 1.0f / sqrtf(deg[i] + 1e-8f);
  for (int l = 0; l < KK; l++) {
    int j = idx[(size_t)i * KK + l];
    float dj = 1.0f / sqrtf(deg[j] + 1e-8f);
    wadjr[(size_t)i * KK + l] = 0.5f * wv[(size_t)i * KK + l] * di * dj;
  }
  for (int e = roff[i]; e < roff[i + 1]; e++) {
    int s = tsrc[e];
    int sn = s / KK;
    float dj = 1.0f / sqrtf(deg[sn] + 1e-8f);
    wadjt[e] = 0.5f * wv[s] * di * dj;
    tcol[e] = sn;
  }
}

// ---------- fused cooperative Lanczos (full CGS2), flush-free barriers ----------
// Identical math / summation order to the grid.sync version (bit-identical),
// only the sync mechanism and load/store coherence pathways changed.
// Cross-block-fresh data (y, part, cvec, Ta, Tb, Q[it] row) uses agent-scope
// atomics (coherence-point access); older Q rows use normal cached loads
// (first in-kernel touch of each row is its agent write -> no stale L2 line).
__global__ void __launch_bounds__(256) k_lanczos(
    float* __restrict__ Q, float* __restrict__ y,
    const float* __restrict__ wadjr, const int* __restrict__ idx,
    const float* __restrict__ wadjt, const int* __restrict__ tcol,
    const int* __restrict__ roff,
    float* __restrict__ cvec, double* __restrict__ part,
    double* __restrict__ Ta, double* __restrict__ Tb,
    unsigned* __restrict__ gcnt, u32 seed) {
  const int b = blockIdx.x, t = threadIdx.x;
  const int n0 = b * 16;
  __shared__ double dred[256];
  __shared__ float fred[16][17];
  __shared__ float ysh[NN];
  __shared__ float cvsh[LM];
  unsigned gph = 0;

  // init residual + norm partials
  if (t < 16) {
    int n = n0 + t;
    agst(&y[n], hashf((u32)n * 2246822519u + seed) - 0.5f);
  }
  __syncthreads();
  if (t == 0) {
    double s = 0.0;
    for (int u = 0; u < 16; u++) { double v = (double)agld(&y[n0 + u]); s += v * v; }
    agstd(&part[b], s);
  }
  gbar(gcnt, ++gph * NBLK);

  for (int it = 0; it < LM; it++) {
    // ---- Phase A: norm, beta, q = y/||y|| ----
    dred[t] = agldd(&part[t]);
    __syncthreads();
    for (int o = 128; o > 0; o >>= 1) { if (t < o) dred[t] += dred[t + o]; __syncthreads(); }
    double nrm = sqrt(dred[0]);
    if (b == 0 && t == 0 && it > 0) agstd(&Tb[it - 1], nrm);
    float inv = (float)(1.0 / (nrm > 1e-300 ? nrm : 1e-300));
    if (t < 16) {
      int n = n0 + t;
      agst(&Q[(size_t)it * NN + n], agld(&y[n]) * inv);
    }
    gbar(gcnt, ++gph * NBLK);

    // ---- Phase B: SpMV y = M q_it (pure gather; q row read normal/cached) ----
    {
      int gid = b * 256 + t;
      if (gid < NN) {
        const float* q = Q + (size_t)it * NN;
        float acc = 0.f;
#pragma unroll
        for (int l = 0; l < KK; l++) acc += wadjr[(size_t)gid * KK + l] * q[idx[(size_t)gid * KK + l]];
        for (int e = roff[gid]; e < roff[gid + 1]; e++) acc += wadjt[e] * q[tcol[e]];
        agst(&y[gid], acc);
      }
    }
    gbar(gcnt, ++gph * NBLK);

    // ---- CGS2: two (dots, update) passes ----
    for (int pass = 0; pass < 2; pass++) {
      // stage y into LDS once (bit-identical values)
      for (int n = t; n < NN; n += 256) ysh[n] = agld(&y[n]);
      __syncthreads();
      // dots: block per j row
      for (int j = b; j <= it; j += 256) {
        const float* qj = Q + (size_t)j * NN;
        double s = 0.0;
        for (int n = t; n < NN; n += 256) s += (double)qj[n] * (double)ysh[n];
        dred[t] = s;
        __syncthreads();
        for (int o = 128; o > 0; o >>= 1) { if (t < o) dred[t] += dred[t + o]; __syncthreads(); }
        if (t == 0) {
          agst(&cvec[j], (float)dred[0]);
          if (pass == 0 && j == it) agstd(&Ta[it], dred[0]);
        }
        __syncthreads();
      }
      gbar(gcnt, ++gph * NBLK);
      // update: y[n0..n0+15] -= sum_j cvec[j] * Q[j][n]
      {
        for (int j2 = t; j2 <= it; j2 += 256) cvsh[j2] = agld(&cvec[j2]);
        __syncthreads();
        int g = t >> 4, nn = n0 + (t & 15);
        float s = 0.f;
        for (int j = g; j <= it; j += 16) s += cvsh[j] * Q[(size_t)j * NN + nn];
        fred[g][t & 15] = s;
        __syncthreads();
        for (int o = 8; o > 0; o >>= 1) {
          if (g < o) fred[g][t & 15] += fred[g + o][t & 15];
          __syncthreads();
        }
        if (t < 16) {
          int n = n0 + t;
          float ny = agld(&y[n]) - fred[0][t];
          agst(&y[n], ny);
          fred[0][t] = ny;  // stash for norm partial (avoids store->load race)
        }
        __syncthreads();
        if (pass == 1 && t == 0) {
          double s2 = 0.0;
          for (int u = 0; u < 16; u++) { double v = (double)fred[0][u]; s2 += v * v; }
          agstd(&part[b], s2);
        }
      }
      gbar(gcnt, ++gph * NBLK);
    }
  }
}

// ---------- bisection: top-SK eigenvalues of T ----------
__global__ void k_bisect(const double* __restrict__ Ta, const double* __restrict__ Tb,
                         double* __restrict__ theta, float* __restrict__ evL) {
  int j = threadIdx.x;
  if (j >= SK) return;
  int tgt = LM - j;
  double lo = -2.0, hi = 2.0;
  for (int iter = 0; iter < 60; iter++) {
    double mid = 0.5 * (lo + hi);
    int cnt = 0; double q = 1.0;
    for (int k = 0; k < LM; k++) {
      double off = (k > 0) ? Tb[k - 1] * Tb[k - 1] : 0.0;
      q = Ta[k] - mid - off / q;
      if (q < 0.0) cnt++;
      if (fabs(q) < 1e-280) q = -1e-280;
    }
    if (cnt >= tgt) hi = mid; else lo = mid;
  }
  theta[j] = 0.5 * (lo + hi);
  evL[j] = (float)(1.0 - theta[j]);
}

// ---------- inverse iteration for eigenvectors of T ----------
__global__ void k_invit(const double* __restrict__ Ta, const double* __restrict__ Tb,
                        const double* __restrict__ theta,
                        double* __restrict__ dws, double* __restrict__ ews,
                        double* __restrict__ fws, double* __restrict__ rws,
                        float* __restrict__ Ym) {
  int j = threadIdx.x;
  if (j >= SK) return;
  double sig = theta[j];
  for (int k = 0; k < LM; k++)
    rws[(size_t)k * SK + j] = (double)hashf((u32)k * 2654435761u + (u32)j * 40503u + 17u) - 0.5;
  for (int pass = 0; pass < 3; pass++) {
    double dk = Ta[0] - sig;
    double ek = Tb[0];
    double fk = 0.0;
    double rk = rws[j];
    for (int k = 0; k < LM - 1; k++) {
      double bk = Tb[k];
      double dn = Ta[k + 1] - sig;
      double en = (k + 2 < LM) ? Tb[k + 1] : 0.0;
      double rn = rws[(size_t)(k + 1) * SK + j];
      double dd, ee, ff, dk2, ek2, rkeep, rnext;
      if (fabs(dk) >= fabs(bk)) {
        double dsafe = (fabs(dk) > 1e-300) ? dk : 1e-300;
        double m = bk / dsafe;
        dd = dsafe; ee = ek; ff = fk;
        dk2 = dn - m * ek;
        ek2 = en - m * fk;
        rkeep = rk;
        rnext = rn - m * rk;
      } else {
        double m = dk / bk;
        dd = bk; ee = dn; ff = en;
        dk2 = ek - m * dn;
        ek2 = fk - m * en;
        rkeep = rn;
        rnext = rk - m * rn;
      }
      dws[(size_t)k * SK + j] = dd;
      ews[(size_t)k * SK + j] = ee;
      fws[(size_t)k * SK + j] = ff;
      rws[(size_t)k * SK + j] = rkeep;
      rk = rnext; dk = dk2; ek = ek2; fk = 0.0;
    }
    if (fabs(dk) < 1e-300) dk = 1e-300;
    dws[(size_t)(LM - 1) * SK + j] = dk;
    ews[(size_t)(LM - 1) * SK + j] = 0.0;
    fws[(size_t)(LM - 1) * SK + j] = 0.0;
    rws[(size_t)(LM - 1) * SK + j] = rk;
    double y1 = 0.0, y2 = 0.0, nr = 0.0;
    for (int k = LM - 1; k >= 0; k--) {
      double dv = dws[(size_t)k * SK + j];
      double yk = (rws[(size_t)k * SK + j] - ews[(size_t)k * SK + j] * y1 - fws[(size_t)k * SK + j] * y2) / dv;
      rws[(size_t)k * SK + j] = yk;
      y2 = y1; y1 = yk;
      nr += yk * yk;
    }
    double inv = 1.0 / sqrt(nr > 1e-300 ? nr : 1e-300);
    for (int k = 0; k < LM; k++) rws[(size_t)k * SK + j] *= inv;
  }
  for (int k = 0; k < LM; k++) Ym[(size_t)k * SK + j] = (float)rws[(size_t)k * SK + j];
}

// ---------- MGS on Ym columns ----------
__device__ __forceinline__ double wred64(double v) {
  for (int o = 32; o > 0; o >>= 1) v += __shfl_down(v, o, 64);
  return v;
}
__global__ void __launch_bounds__(256) k_mgsY(float* __restrict__ Ym) {
  __shared__ double lds[8];
  int t = threadIdx.x;
  for (int j = 0; j < SK; j++) {
    for (int jj = 0; jj < j; jj++) {
      double s = 0.0;
      for (int k = t; k < LM; k += 256) s += (double)Ym[(size_t)k * SK + jj] * (double)Ym[(size_t)k * SK + j];
      __syncthreads();
      s = wred64(s);
      if ((t & 63) == 0) lds[t >> 6] = s;
      __syncthreads();
      float cf = (float)(lds[0] + lds[1] + lds[2] + lds[3]);
      for (int k = t; k < LM; k += 256) Ym[(size_t)k * SK + j] -= cf * Ym[(size_t)k * SK + jj];
    }
    double s = 0.0;
    __syncthreads();
    for (int k = t; k < LM; k += 256) { double v = (double)Ym[(size_t)k * SK + j]; s += v * v; }
    s = wred64(s);
    if ((t & 63) == 0) lds[t >> 6] = s;
    __syncthreads();
    double nr = lds[0] + lds[1] + lds[2] + lds[3];
    float inv = (float)(1.0 / sqrt(nr > 1e-300 ? nr : 1e-300));
    for (int k = t; k < LM; k += 256) Ym[(size_t)k * SK + j] *= inv;
    __syncthreads();
  }
}

// ---------- generic tiled GEMMs ----------
__global__ void __launch_bounds__(256) k_gemm_tn(const float* __restrict__ A, const float* __restrict__ B,
                                                 float* __restrict__ Cm, int M, int P, int Kd) {
  __shared__ float As[16][65], Bs[16][65];
  int bm = blockIdx.x * 64, bp = blockIdx.y * 64;
  int tx = threadIdx.x & 15, ty = threadIdx.x >> 4;
  float acc[4][4] = {};
  for (int k0 = 0; k0 < Kd; k0 += 16) {
    for (int t2 = threadIdx.x; t2 < 1024; t2 += 256) {
      int mm = t2 & 63, kk = t2 >> 6;
      As[kk][mm] = A[(size_t)(k0 + kk) * M + bm + mm];
      Bs[kk][mm] = B[(size_t)(k0 + kk) * P + bp + mm];
    }
    __syncthreads();
#pragma unroll
    for (int kk = 0; kk < 16; kk++) {
      float av[4], bv[4];
#pragma unroll
      for (int a = 0; a < 4; a++) av[a] = As[kk][ty * 4 + a];
#pragma unroll
      for (int b = 0; b < 4; b++) bv[b] = Bs[kk][tx * 4 + b];
#pragma unroll
      for (int a = 0; a < 4; a++)
#pragma unroll
        for (int b = 0; b < 4; b++) acc[a][b] += av[a] * bv[b];
    }
    __syncthreads();
  }
#pragma unroll
  for (int a = 0; a < 4; a++)
#pragma unroll
    for (int b = 0; b < 4; b++)
      Cm[(size_t)(bm + ty * 4 + a) * P + bp + tx * 4 + b] = acc[a][b];
}

__global__ void __launch_bounds__(256) k_gemm_nt(const float* __restrict__ A, const float* __restrict__ B,
                                                 float* __restrict__ Cm, int M, int P, int Kd) {
  __shared__ float As[16][65], Bs[16][65];
  int bm = blockIdx.x * 64, bp = blockIdx.y * 64;
  int tx = threadIdx.x & 15, ty = threadIdx.x >> 4;
  float acc[4][4] = {};
  for (int k0 = 0; k0 < Kd; k0 += 16) {
    for (int t2 = threadIdx.x; t2 < 1024; t2 += 256) {
      int kk = t2 & 15, mm = t2 >> 4;
      As[kk][mm] = A[(size_t)(bm + mm) * Kd + k0 + kk];
      Bs[kk][mm] = B[(size_t)(bp + mm) * Kd + k0 + kk];
    }
    __syncthreads();
#pragma unroll
    for (int kk = 0; kk < 16; kk++) {
      float av[4], bv[4];
#pragma unroll
      for (int a = 0; a < 4; a++) av[a] = As[kk][ty * 4 + a];
#pragma unroll
      for (int b = 0; b < 4; b++) bv[b] = Bs[kk][tx * 4 + b];
#pragma unroll
      for (int a = 0; a < 4; a++)
#pragma unroll
        for (int b = 0; b < 4; b++) acc[a][b] += av[a] * bv[b];
    }
    __syncthreads();
  }
#pragma unroll
  for (int a = 0; a < 4; a++)
#pragma unroll
    for (int b = 0; b < 4; b++)
      Cm[(size_t)(bm + ty * 4 + a) * P + bp + tx * 4 + b] = acc[a][b];
}

__global__ void __launch_bounds__(256) k_gemm_nn(const float* __restrict__ A, const float* __restrict__ B,
                                                 float* __restrict__ Cm, int M, int P, int Kd) {
  __shared__ float As[16][65], Bs[16][65];
  int bm = blockIdx.x * 64, bp = blockIdx.y * 64;
  int tx = threadIdx.x & 15, ty = threadIdx.x >> 4;
  float acc[4][4] = {};
  for (int k0 = 0; k0 < Kd; k0 += 16) {
    for (int t2 = threadIdx.x; t2 < 1024; t2 += 256) {
      int kk = t2 & 15, mm = t2 >> 4;
      As[kk][mm] = A[(size_t)(bm + mm) * Kd + k0 + kk];
    }
    for (int t2 = threadIdx.x; t2 < 1024; t2 += 256) {
      int mm = t2 & 63, kk = t2 >> 6;
      Bs[kk][mm] = B[(size_t)(k0 + kk) * P + bp + mm];
    }
    __syncthreads();
#pragma unroll
    for (int kk = 0; kk < 16; kk++) {
      float av[4], bv[4];
#pragma unroll
      for (int a = 0; a < 4; a++) av[a] = As[kk][ty * 4 + a];
#pragma unroll
      for (int b = 0; b < 4; b++) bv[b] = Bs[kk][tx * 4 + b];
#pragma unroll
      for (int a = 0; a < 4; a++)
#pragma unroll
        for (int b = 0; b < 4; b++) acc[a][b] += av[a] * bv[b];
    }
    __syncthreads();
  }
#pragma unroll
  for (int a = 0; a < 4; a++)
#pragma unroll
    for (int b = 0; b < 4; b++)
      Cm[(size_t)(bm + ty * 4 + a) * P + bp + tx * 4 + b] = acc[a][b];
}

// ---------- s = max(max ev_a, max ev_b) ----------
__global__ void k_smax(const float* __restrict__ ea, const float* __restrict__ eb, double* __restrict__ scal) {
  __shared__ float red[128];
  int t = threadIdx.x;
  red[t] = fmaxf(ea[t], eb[t]);
  __syncthreads();
  for (int o = 64; o > 0; o >>= 1) { if (t < o) red[t] = fmaxf(red[t], red[t + o]); __syncthreads(); }
  if (t == 0) scal[1] = (double)red[0];
}

// ---------- resolvent mask ----------
__global__ void k_mask(const float* __restrict__ evr, const float* __restrict__ evc,
                       const double* __restrict__ scal, float* __restrict__ Dm) {
  int t = blockIdx.x * 256 + threadIdx.x;
  if (t >= SK * SK) return;
  int i = t / SK, j = t % SK;
  float s = (float)scal[1];
  float g1 = sqrtf(fmaxf(evc[j] / s, 0.f));
  float g2 = sqrtf(fmaxf(evr[i] / s, 0.f));
  float a2 = g2 * g2 + 1.f, a1 = g1 * g1 + 1.f;
  float re = g2 / a2 - g1 / a1;
  float im = 1.f / a2 - 1.f / a1;
  Dm[t] = re * re + im * im;
}

// ---------- per-row Cholesky solve ----------
__global__ void __launch_bounds__(128) k_cholsolve(const float* __restrict__ AAt, const float* __restrict__ BAt,
                                                   const float* __restrict__ Dm, float* __restrict__ Msg,
                                                   float* __restrict__ Cout) {
  __shared__ float xs[SK];
  int i = blockIdx.x;
  float* Ms = Msg + (size_t)i * SK * SK;
  for (int t2 = threadIdx.x; t2 < SK * SK; t2 += 128) {
    int r = t2 / SK, c2 = t2 % SK;
    float v = AAt[t2];
    if (r == c2) v += LAMBDA_ * Dm[(size_t)i * SK + r];
    Ms[t2] = v;
  }
  if (threadIdx.x < SK) xs[threadIdx.x] = BAt[(size_t)i * SK + threadIdx.x];
  __syncthreads();
  for (int k = 0; k < SK; k++) {
    if (threadIdx.x == 0) Ms[k * SK + k] = sqrtf(fmaxf(Ms[k * SK + k], 1e-20f));
    __syncthreads();
    float dk = Ms[k * SK + k];
    for (int r = k + 1 + threadIdx.x; r < SK; r += 128) Ms[r * SK + k] /= dk;
    __syncthreads();
    int rem = SK - k - 1;
    for (int t2 = threadIdx.x; t2 < rem * rem; t2 += 128) {
      int r = k + 1 + t2 / rem, c2 = k + 1 + t2 % rem;
      Ms[r * SK + c2] -= Ms[r * SK + k] * Ms[c2 * SK + k];
    }
    __syncthreads();
  }
  for (int k = 0; k < SK; k++) {
    if (threadIdx.x == 0) xs[k] /= Ms[k * SK + k];
    __syncthreads();
    float xv = xs[k];
    for (int r = k + 1 + threadIdx.x; r < SK; r += 128) xs[r] -= Ms[r * SK + k] * xv;
    __syncthreads();
  }
  for (int k = SK - 1; k >= 0; k--) {
    if (threadIdx.x == 0) xs[k] /= Ms[k * SK + k];
    __syncthreads();
    float xv = xs[k];
    for (int r = threadIdx.x; r < k; r += 128) xs[r] -= Ms[k * SK + r] * xv;
    __syncthreads();
  }
  for (int t2 = threadIdx.x; t2 < SK; t2 += 128) Cout[(size_t)i * SK + t2] = xs[t2];
}

// ---------- loss partials (deterministic) ----------
__global__ void k_frob_iden(const float* __restrict__ Mat, double* __restrict__ lpart, int slot) {
  __shared__ double red[256];
  double s = 0.0;
  for (int t2 = blockIdx.x * 256 + threadIdx.x; t2 < SK * SK; t2 += 32 * 256) {
    float v = Mat[t2] - ((t2 / SK == t2 % SK) ? 1.f : 0.f);
    s += (double)v * (double)v;
  }
  red[threadIdx.x] = s; __syncthreads();
  for (int o = 128; o > 0; o >>= 1) { if (threadIdx.x < o) red[threadIdx.x] += red[threadIdx.x + o]; __syncthreads(); }
  if (threadIdx.x == 0) lpart[slot * 32 + blockIdx.x] = red[0];
}
__global__ void k_lap(const float* __restrict__ Cm, const float* __restrict__ evc,
                      const float* __restrict__ evr, double* __restrict__ lpart, int slot) {
  __shared__ double red[256];
  double s = 0.0;
  for (int t2 = blockIdx.x * 256 + threadIdx.x; t2 < SK * SK; t2 += 32 * 256) {
    int i = t2 / SK, j = t2 % SK;
    float v = Cm[t2] * (evc[j] - evr[i]);
    s += (double)v * (double)v;
  }
  red[threadIdx.x] = s; __syncthreads();
  for (int o = 128; o > 0; o >>= 1) { if (threadIdx.x < o) red[threadIdx.x] += red[threadIdx.x + o]; __syncthreads(); }
  if (threadIdx.x == 0) lpart[slot * 32 + blockIdx.x] = red[0];
}
__global__ void k_writeout(const double* __restrict__ lpart, float* __restrict__ out) {
  if (threadIdx.x == 0) {
    double b = 0.0, o = 0.0, l = 0.0;
    for (int s = 0; s < 64; s++) b += lpart[s];
    for (int s = 64; s < 128; s++) o += lpart[s];
    for (int s = 128; s < 192; s++) l += lpart[s];
    out[0] = (float)b; out[1] = (float)o; out[2] = (float)l;
  }
}

extern "C" void kernel_launch(void* const* d_in, const int* in_sizes, int n_in,
                              void* d_out, int out_size, void* d_ws, size_t ws_size,
                              hipStream_t stream) {
  const float* feats[2] = {(const float*)d_in[0], (const float*)d_in[1]};
  char* p = (char*)d_ws;
  auto alloc = [&](size_t bytes) -> void* {
    char* r = p;
    p += (bytes + 255) & ~(size_t)255;
    return (void*)r;
  };
  float* pan   = (float*)alloc(sizeof(float) * 256 * NN);
  float* sq    = (float*)alloc(sizeof(float) * NN);
  int*   idx   = (int*)alloc(sizeof(int) * (size_t)NN * KK);
  float* dkv   = (float*)alloc(sizeof(float) * (size_t)NN * KK);
  float* wv    = (float*)alloc(sizeof(float) * (size_t)NN * KK);
  float* wadjr = (float*)alloc(sizeof(float) * (size_t)NN * KK);
  float* wadjt = (float*)alloc(sizeof(float) * (size_t)NN * KK);
  int*   cnt   = (int*)alloc(sizeof(int) * NN);
  int*   roff  = (int*)alloc(sizeof(int) * (NN + 1));
  int*   rpos  = (int*)alloc(sizeof(int) * NN);
  int*   tsrc  = (int*)alloc(sizeof(int) * (size_t)NN * KK);
  int*   tcol  = (int*)alloc(sizeof(int) * (size_t)NN * KK);
  float* deg   = (float*)alloc(sizeof(float) * NN);
  float* Q     = (float*)alloc(sizeof(float) * (size_t)LM * NN);
  float* yv    = (float*)alloc(sizeof(float) * NN);
  float* cv    = (float*)alloc(sizeof(float) * LM);
  double* part = (double*)alloc(sizeof(double) * 256);
  double* scal = (double*)alloc(sizeof(double) * 8);
  double* Ta   = (double*)alloc(sizeof(double) * LM);
  double* Tb   = (double*)alloc(sizeof(double) * LM);
  double* theta= (double*)alloc(sizeof(double) * SK);
  double* dws  = (double*)alloc(sizeof(double) * (size_t)LM * SK);
  double* ews  = (double*)alloc(sizeof(double) * (size_t)LM * SK);
  double* fws  = (double*)alloc(sizeof(double) * (size_t)LM * SK);
  double* rws  = (double*)alloc(sizeof(double) * (size_t)LM * SK);
  float* Ym    = (float*)alloc(sizeof(float) * (size_t)LM * SK);
  float* U0    = (float*)alloc(sizeof(float) * (size_t)NN * SK);
  float* U1    = (float*)alloc(sizeof(float) * (size_t)NN * SK);
  float* ev0   = (float*)alloc(sizeof(float) * SK);
  float* ev1   = (float*)alloc(sizeof(float) * SK);
  float* Ac    = (float*)alloc(sizeof(float) * (size_t)SK * NC);
  float* Bc    = (float*)alloc(sizeof(float) * (size_t)SK * NC);
  float* AAt   = (float*)alloc(sizeof(float) * SK * SK);
  float* BAt   = (float*)alloc(sizeof(float) * SK * SK);
  float* Dm    = (float*)alloc(sizeof(float) * SK * SK);
  float* Cxy   = (float*)alloc(sizeof(float) * SK * SK);
  float* Cyx   = (float*)alloc(sizeof(float) * SK * SK);
  float* P1    = (float*)alloc(sizeof(float) * SK * SK);
  float* Msg   = (float*)alloc(sizeof(float) * (size_t)SK * SK * SK);
  double* lpart= (double*)alloc(sizeof(double) * 192);
  unsigned* gcnt = (unsigned*)alloc(sizeof(unsigned) * 64);

  float* Us[2] = {U0, U1};
  float* evs[2] = {ev0, ev1};

  for (int s2 = 0; s2 < 2; s2++) {
    const float* f = feats[s2];
    k_sqnorm<<<NN, 256, 0, stream>>>(f, sq);
    for (int p2 = 0; p2 < 16; p2++) {
      k_d2panel<<<dim3(64, 4), 256, 0, stream>>>(f, sq, pan, p2 * 256);
      k_topk<<<256, 256, 0, stream>>>(pan, p2 * 256, idx, dkv);
    }
    k_partsum<<<64, 256, 0, stream>>>(dkv, part);
    k_sigma<<<1, 64, 0, stream>>>(part, scal);
    k_wexp<<<NN * KK / 256, 256, 0, stream>>>(dkv, scal, wv);
    // deterministic CSR transpose
    hipMemsetAsync(cnt, 0, sizeof(int) * NN, stream);
    k_count<<<NN * KK / 256, 256, 0, stream>>>(idx, cnt);
    k_scan<<<1, 1024, 0, stream>>>(cnt, roff, rpos);
    k_place<<<16, 256, 0, stream>>>(idx, rpos, tsrc);
    k_sortb<<<16, 256, 0, stream>>>(roff, tsrc);
    k_deg<<<16, 256, 0, stream>>>(wv, roff, tsrc, deg);
    k_wadj2<<<16, 256, 0, stream>>>(wv, idx, roff, tsrc, deg, wadjr, wadjt, tcol);
    // fused cooperative Lanczos (full CGS2) with flush-free barriers
    hipMemsetAsync(gcnt, 0, sizeof(unsigned), stream);
    {
      u32 seed = 1234567u + (u32)s2 * 77777u;
      void* args[] = {(void*)&Q, (void*)&yv, (void*)&wadjr, (void*)&idx,
                      (void*)&wadjt, (void*)&tcol, (void*)&roff,
                      (void*)&cv, (void*)&part, (void*)&Ta, (void*)&Tb,
                      (void*)&gcnt, (void*)&seed};
      hipLaunchCooperativeKernel((const void*)k_lanczos, dim3(NBLK), dim3(256), args, 0, stream);
    }
    k_bisect<<<1, 128, 0, stream>>>(Ta, Tb, theta, evs[s2]);
    k_invit<<<1, 128, 0, stream>>>(Ta, Tb, theta, dws, ews, fws, rws, Ym);
    k_mgsY<<<1, 256, 0, stream>>>(Ym);
    k_gemm_tn<<<dim3(NN / 64, SK / 64), 256, 0, stream>>>(Q, Ym, Us[s2], NN, SK, LM);
  }

  // spectral coefficients
  k_gemm_tn<<<dim3(SK / 64, NC / 64), 256, 0, stream>>>(U0, feats[0], Ac, SK, NC, NN);
  k_gemm_tn<<<dim3(SK / 64, NC / 64), 256, 0, stream>>>(U1, feats[1], Bc, SK, NC, NN);
  k_smax<<<1, 128, 0, stream>>>(ev0, ev1, scal);

  // Cxy: x = v(0), y = t(1)
  k_gemm_nt<<<dim3(2, 2), 256, 0, stream>>>(Ac, Ac, AAt, SK, SK, NC);
  k_gemm_nt<<<dim3(2, 2), 256, 0, stream>>>(Bc, Ac, BAt, SK, SK, NC);
  k_mask<<<64, 256, 0, stream>>>(ev1, ev0, scal, Dm);
  k_cholsolve<<<SK, 128, 0, stream>>>(AAt, BAt, Dm, Msg, Cxy);
  // Cyx: x = t(1), y = v(0)
  k_gemm_nt<<<dim3(2, 2), 256, 0, stream>>>(Bc, Bc, AAt, SK, SK, NC);
  k_gemm_nt<<<dim3(2, 2), 256, 0, stream>>>(Ac, Bc, BAt, SK, SK, NC);
  k_mask<<<64, 256, 0, stream>>>(ev0, ev1, scal, Dm);
  k_cholsolve<<<SK, 128, 0, stream>>>(AAt, BAt, Dm, Msg, Cyx);

  // losses
  k_gemm_nn<<<dim3(2, 2), 256, 0, stream>>>(Cxy, Cyx, P1, SK, SK, SK);
  k_frob_iden<<<32, 256, 0, stream>>>(P1, lpart, 0);
  k_gemm_nn<<<dim3(2, 2), 256, 0, stream>>>(Cyx, Cxy, P1, SK, SK, SK);
  k_frob_iden<<<32, 256, 0, stream>>>(P1, lpart, 1);
  k_gemm_tn<<<dim3(2, 2), 256, 0, stream>>>(Cxy, Cxy, P1, SK, SK, SK);
  k_frob_iden<<<32, 256, 0, stream>>>(P1, lpart, 2);
  k_gemm_tn<<<dim3(2, 2), 256, 0, stream>>>(Cyx, Cyx, P1, SK, SK, SK);
  k_frob_iden<<<32, 256, 0, stream>>>(P1, lpart, 3);
  k_lap<<<32, 256, 0, stream>>>(Cxy, ev0, ev1, lpart, 4);
  k_lap<<<32, 256, 0, stream>>>(Cyx, ev1, ev0, lpart, 5);
  k_writeout<<<1, 64, 0, stream>>>(lpart, (float*)d_out);
}

// Round 5
// 317745.288 us; speedup vs baseline: 2.5411x; 2.5411x over previous
//
#include <hip/hip_runtime.h>
#include <math.h>

#define NN 4096      // points
#define NC 768       // feature dim
#define KK 16        // knn k
#define SK 128       // spectral basis size
#define LM 1024      // Lanczos steps
#define NBLK 256     // cooperative grid blocks
#define LAMBDA_ 100.0f

typedef unsigned int u32;

__device__ __forceinline__ float hashf(u32 x) {
  x ^= x >> 16; x *= 0x7feb352dU; x ^= x >> 15; x *= 0x846ca68bU; x ^= x >> 16;
  return ((float)x) * (1.0f / 4294967296.0f);  // [0,1)
}

// ---- agent-scope (device-coherent) access helpers: bypass non-coherent L2 ----
__device__ __forceinline__ float agld(const float* p) {
  return __hip_atomic_load((float*)p, __ATOMIC_RELAXED, __HIP_MEMORY_SCOPE_AGENT);
}
__device__ __forceinline__ void agst(float* p, float v) {
  __hip_atomic_store(p, v, __ATOMIC_RELAXED, __HIP_MEMORY_SCOPE_AGENT);
}
__device__ __forceinline__ double agldd(const double* p) {
  return __hip_atomic_load((double*)p, __ATOMIC_RELAXED, __HIP_MEMORY_SCOPE_AGENT);
}
__device__ __forceinline__ void agstd(double* p, double v) {
  __hip_atomic_store(p, v, __ATOMIC_RELAXED, __HIP_MEMORY_SCOPE_AGENT);
}

// ---- flush-free grid barrier (co-resident cooperative grid required) ----
__device__ __forceinline__ void gbar(unsigned* cnt, unsigned tgt) {
  asm volatile("s_waitcnt vmcnt(0)" ::: "memory");
  __syncthreads();
  if (threadIdx.x == 0) {
    __hip_atomic_fetch_add(cnt, 1u, __ATOMIC_RELEASE, __HIP_MEMORY_SCOPE_AGENT);
    while (__hip_atomic_load(cnt, __ATOMIC_ACQUIRE, __HIP_MEMORY_SCOPE_AGENT) < tgt)
      __builtin_amdgcn_s_sleep(1);
  }
  __syncthreads();
}

// ---------- row squared norms ----------
__global__ void k_sqnorm(const float* __restrict__ f, float* __restrict__ sq) {
  __shared__ float red[256];
  int i = blockIdx.x;
  float s = 0.f;
  for (int c = threadIdx.x; c < NC; c += 256) { float v = f[(size_t)i * NC + c]; s += v * v; }
  red[threadIdx.x] = s; __syncthreads();
  for (int o = 128; o > 0; o >>= 1) { if (threadIdx.x < o) red[threadIdx.x] += red[threadIdx.x + o]; __syncthreads(); }
  if (threadIdx.x == 0) sq[i] = red[0];
}

// ---------- d2 panel: pan[256][NN] for rows i0..i0+255 ----------
__global__ void __launch_bounds__(256) k_d2panel(const float* __restrict__ f, const float* __restrict__ sq,
                                                 float* __restrict__ pan, int i0) {
  __shared__ float As[16][65], Bs[16][65];
  int bj = blockIdx.x, bi = blockIdx.y;
  int row0 = i0 + bi * 64, col0 = bj * 64;
  int tx = threadIdx.x & 15, ty = threadIdx.x >> 4;
  float acc[4][4] = {};
  for (int k0 = 0; k0 < NC; k0 += 16) {
    for (int t2 = threadIdx.x; t2 < 1024; t2 += 256) {
      int kk = t2 & 15, rr = t2 >> 4;
      As[kk][rr] = f[(size_t)(row0 + rr) * NC + k0 + kk];
      Bs[kk][rr] = f[(size_t)(col0 + rr) * NC + k0 + kk];
    }
    __syncthreads();
#pragma unroll
    for (int kk = 0; kk < 16; kk++) {
      float av[4], bv[4];
#pragma unroll
      for (int a = 0; a < 4; a++) av[a] = As[kk][ty * 4 + a];
#pragma unroll
      for (int b = 0; b < 4; b++) bv[b] = Bs[kk][tx * 4 + b];
#pragma unroll
      for (int a = 0; a < 4; a++)
#pragma unroll
        for (int b = 0; b < 4; b++) acc[a][b] += av[a] * bv[b];
    }
    __syncthreads();
  }
#pragma unroll
  for (int a = 0; a < 4; a++) {
    int gr = row0 + ty * 4 + a;
    int pr = bi * 64 + ty * 4 + a;
    float sr = sq[gr];
#pragma unroll
    for (int b = 0; b < 4; b++) {
      int gc = col0 + tx * 4 + b;
      float v = sr + sq[gc] - 2.f * acc[a][b];
      v = fmaxf(v, 0.f);
      if (gr == gc) v += 1e10f;
      pan[(size_t)pr * NN + gc] = v;
    }
  }
}

// ---------- top-16 smallest per row ----------
__global__ void __launch_bounds__(256) k_topk(const float* __restrict__ pan, int i0,
                                              int* __restrict__ idx, float* __restrict__ dkv) {
  __shared__ float vals[NN];
  __shared__ float rv[256];
  __shared__ int ri[256];
  int r = blockIdx.x;
  const float* row = pan + (size_t)r * NN;
  for (int j = threadIdx.x; j < NN; j += 256) vals[j] = row[j];
  __syncthreads();
  for (int t3 = 0; t3 < KK; t3++) {
    float bv = 1e30f; int bi2 = NN;
    for (int j2 = threadIdx.x; j2 < NN; j2 += 256) {
      float v = vals[j2];
      if (v < bv || (v == bv && j2 < bi2)) { bv = v; bi2 = j2; }
    }
    rv[threadIdx.x] = bv; ri[threadIdx.x] = bi2;
    __syncthreads();
    for (int o = 128; o > 0; o >>= 1) {
      if (threadIdx.x < o) {
        float v2 = rv[threadIdx.x + o]; int i2 = ri[threadIdx.x + o];
        if (v2 < rv[threadIdx.x] || (v2 == rv[threadIdx.x] && i2 < ri[threadIdx.x])) {
          rv[threadIdx.x] = v2; ri[threadIdx.x] = i2;
        }
      }
      __syncthreads();
    }
    if (threadIdx.x == 0) {
      idx[(size_t)(i0 + r) * KK + t3] = ri[0];
      dkv[(size_t)(i0 + r) * KK + t3] = rv[0];
      vals[ri[0]] = 1e30f;
    }
    __syncthreads();
  }
}

// ---------- sigma2 = mean(dkv) + 1e-12 ----------
__global__ void k_partsum(const float* __restrict__ dkv, double* __restrict__ part) {
  __shared__ double red[256];
  double s = 0.0;
  for (int t2 = blockIdx.x * 256 + threadIdx.x; t2 < NN * KK; t2 += 64 * 256) s += (double)dkv[t2];
  red[threadIdx.x] = s; __syncthreads();
  for (int o = 128; o > 0; o >>= 1) { if (threadIdx.x < o) red[threadIdx.x] += red[threadIdx.x + o]; __syncthreads(); }
  if (threadIdx.x == 0) part[blockIdx.x] = red[0];
}
__global__ void k_sigma(const double* __restrict__ part, double* __restrict__ scal) {
  __shared__ double red[64];
  red[threadIdx.x] = part[threadIdx.x]; __syncthreads();
  for (int o = 32; o > 0; o >>= 1) { if (threadIdx.x < o) red[threadIdx.x] += red[threadIdx.x + o]; __syncthreads(); }
  if (threadIdx.x == 0) scal[0] = red[0] / (double)(NN * KK) + 1e-12;
}

// ---------- gaussian weights ----------
__global__ void k_wexp(const float* __restrict__ dkv, const double* __restrict__ scal,
                       float* __restrict__ wv) {
  int t = blockIdx.x * 256 + threadIdx.x;
  if (t >= NN * KK) return;
  float inv2s = (float)(0.5 / scal[0]);
  wv[t] = expf(-dkv[t] * inv2s);
}

// ---------- deterministic CSR transpose construction ----------
__global__ void k_count(const int* __restrict__ idx, int* __restrict__ cnt) {
  int t = blockIdx.x * 256 + threadIdx.x;
  if (t < NN * KK) atomicAdd(&cnt[idx[t]], 1);
}

__global__ void __launch_bounds__(1024) k_scan(const int* __restrict__ cnt,
                                               int* __restrict__ roff, int* __restrict__ rpos) {
  __shared__ int buf[1024];
  int t = threadIdx.x;
  int v[4]; int s = 0;
#pragma unroll
  for (int u = 0; u < 4; u++) { v[u] = cnt[t * 4 + u]; s += v[u]; }
  buf[t] = s; __syncthreads();
  for (int o = 1; o < 1024; o <<= 1) {
    int x = (t >= o) ? buf[t - o] : 0;
    __syncthreads();
    buf[t] += x;
    __syncthreads();
  }
  int run = (t == 0) ? 0 : buf[t - 1];
#pragma unroll
  for (int u = 0; u < 4; u++) { roff[t * 4 + u] = run; rpos[t * 4 + u] = run; run += v[u]; }
  if (t == 1023) roff[NN] = run;
}

__global__ void k_place(const int* __restrict__ idx, int* __restrict__ rpos, int* __restrict__ tsrc) {
  int i = blockIdx.x * 256 + threadIdx.x;
  if (i >= NN) return;
  for (int l = 0; l < KK; l++) {
    int j = idx[(size_t)i * KK + l];
    int e = atomicAdd(&rpos[j], 1);
    tsrc[e] = i * KK + l;
  }
}

__global__ void k_sortb(const int* __restrict__ roff, int* __restrict__ tsrc) {
  int i = blockIdx.x * 256 + threadIdx.x;
  if (i >= NN) return;
  int b = roff[i], e = roff[i + 1];
  for (int a = b + 1; a < e; a++) {
    int key = tsrc[a]; int c = a - 1;
    while (c >= b && tsrc[c] > key) { tsrc[c + 1] = tsrc[c]; c--; }
    tsrc[c + 1] = key;
  }
}

// ---------- degrees ----------
__global__ void k_deg(const float* __restrict__ wv, const int* __restrict__ roff,
                      const int* __restrict__ tsrc, float* __restrict__ deg) {
  int i = blockIdx.x * 256 + threadIdx.x;
  if (i >= NN) return;
  float s = 0.f;
  for (int l = 0; l < KK; l++) s += wv[(size_t)i * KK + l];
  float s2 = 0.f;
  for (int e = roff[i]; e < roff[i + 1]; e++) s2 += wv[tsrc[e]];
  deg[i] = 0.5f * (s + s2);
}

// ---------- normalized adjacency ----------
__global__ void k_wadj2(const float* __restrict__ wv, const int* __restrict__ idx,
                        const int* __restrict__ roff, const int* __restrict__ tsrc,
                        const float* __restrict__ deg,
                        float* __restrict__ wadjr, float* __restrict__ wadjt,
                        int* __restrict__ tcol) {
  int i = blockIdx.x * 256 + threadIdx.x;
  if (i >= NN) return;
  float di = 1.0f / sqrtf(deg[i] + 1e-8f);
  for (int l = 0; l < KK; l++) {
    int j = idx[(size_t)i * KK + l];
    float dj = 1.0f / sqrtf(deg[j] + 1e-8f);
    wadjr[(size_t)i * KK + l] = 0.5f * wv[(size_t)i * KK + l] * di * dj;
  }
  for (int e = roff[i]; e < roff[i + 1]; e++) {
    int s = tsrc[e];
    int sn = s / KK;
    float dj = 1.0f / sqrtf(deg[sn] + 1e-8f);
    wadjt[e] = 0.5f * wv[s] * di * dj;
    tcol[e] = sn;
  }
}

// ---------- fused cooperative Lanczos, 1024 threads/block, 5 barriers/iter ----------
// Double-buffered residual (y0/y1). Phase B' = {norm from part, q-row write,
// SpMV with on-the-fly normalize}; then CGS2 = 2x {dots, update}. All
// reductions fixed-order -> call-deterministic. Q rows are write-once (agent
// store) then read via normal cached loads; residual/cvec/part always agent.
__global__ void __launch_bounds__(1024) k_lanczos(
    float* __restrict__ Q, float* __restrict__ y0v, float* __restrict__ y1v,
    const float* __restrict__ wadjr, const int* __restrict__ idx,
    const float* __restrict__ wadjt, const int* __restrict__ tcol,
    const int* __restrict__ roff,
    float* __restrict__ cvec, double* __restrict__ part,
    double* __restrict__ Ta, double* __restrict__ Tb,
    unsigned* __restrict__ gcnt, u32 seed) {
  const int b = blockIdx.x, t = threadIdx.x;
  const int n0 = b * 16;
  const int lane = t & 63, wvid = t >> 6;  // 16 waves
  __shared__ float ysh[NN];        // 16KB staged residual
  __shared__ float cvsh[LM];       // 4KB staged coefficients
  __shared__ double pd[256];       // norm partials
  __shared__ double wl[16];        // wave-leader partials
  __shared__ float fredu[64][17];  // update combine
  __shared__ float nyst[16];
  unsigned gph = 0;

  // init residual + norm partials
  if (t < 16) {
    int n = n0 + t;
    agst(&y0v[n], hashf((u32)n * 2246822519u + seed) - 0.5f);
  }
  __syncthreads();
  if (t == 0) {
    double s = 0.0;
    for (int u = 0; u < 16; u++) { double v = (double)agld(&y0v[n0 + u]); s += v * v; }
    agstd(&part[b], s);
  }
  gbar(gcnt, ++gph * NBLK);

  for (int it = 0; it < LM; it++) {
    float* r  = (it & 1) ? y1v : y0v;  // current residual (to normalize)
    float* r2 = (it & 1) ? y0v : y1v;  // SpMV target / working residual

    // ---- Phase B': norm + q-row write + SpMV (on-the-fly normalize) ----
    if (t < 256) pd[t] = agldd(&part[t]);
    __syncthreads();
    for (int o = 128; o > 0; o >>= 1) { if (t < o) pd[t] += pd[t + o]; __syncthreads(); }
    double nrm = sqrt(pd[0]);
    if (b == 0 && t == 0 && it > 0) agstd(&Tb[it - 1], nrm);
    float inv = (float)(1.0 / (nrm > 1e-300 ? nrm : 1e-300));
    if (t < 16) {
      int n = n0 + t;
      agst(&Q[(size_t)it * NN + n], agld(&r[n]) * inv);
    }
    {
      int n = n0 + wvid;                       // row per wave
      int rb = roff[n], re = roff[n + 1];
      int L = 16 + (re - rb);
      float acc = 0.f;
      for (int i = lane; i < L; i += 64) {
        float w, qv;
        if (i < 16) { w = wadjr[(size_t)n * KK + i]; qv = agld(&r[idx[(size_t)n * KK + i]]) * inv; }
        else        { int e = rb + i - 16; w = wadjt[e]; qv = agld(&r[tcol[e]]) * inv; }
        acc += w * qv;
      }
      for (int o = 32; o > 0; o >>= 1) acc += __shfl_down(acc, o, 64);
      if (lane == 0) agst(&r2[n], acc);
    }
    gbar(gcnt, ++gph * NBLK);

    // ---- CGS2: two (dots, update) passes on r2 ----
#pragma unroll
    for (int pass = 0; pass < 2; pass++) {
      // stage r2 -> LDS (agent loads, 4/thread)
      {
        int base = t * 4;
        float a0 = agld(&r2[base]), a1 = agld(&r2[base + 1]);
        float a2 = agld(&r2[base + 2]), a3 = agld(&r2[base + 3]);
        ysh[base] = a0; ysh[base + 1] = a1; ysh[base + 2] = a2; ysh[base + 3] = a3;
      }
      __syncthreads();
      // dots: up to 4 rows j == b (mod 256); compute all partials first (MLP)
      {
        float4 yv4 = *(const float4*)&ysh[t * 4];
        int j0 = b, j1 = b + 256, j2 = b + 512, j3 = b + 768;
        double s0 = 0.0, s1 = 0.0, s2 = 0.0, s3 = 0.0;
        if (j0 <= it) { float4 q4 = *(const float4*)&Q[(size_t)j0 * NN + t * 4];
          s0 = (double)q4.x * yv4.x; s0 += (double)q4.y * yv4.y; s0 += (double)q4.z * yv4.z; s0 += (double)q4.w * yv4.w; }
        if (j1 <= it) { float4 q4 = *(const float4*)&Q[(size_t)j1 * NN + t * 4];
          s1 = (double)q4.x * yv4.x; s1 += (double)q4.y * yv4.y; s1 += (double)q4.z * yv4.z; s1 += (double)q4.w * yv4.w; }
        if (j2 <= it) { float4 q4 = *(const float4*)&Q[(size_t)j2 * NN + t * 4];
          s2 = (double)q4.x * yv4.x; s2 += (double)q4.y * yv4.y; s2 += (double)q4.z * yv4.z; s2 += (double)q4.w * yv4.w; }
        if (j3 <= it) { float4 q4 = *(const float4*)&Q[(size_t)j3 * NN + t * 4];
          s3 = (double)q4.x * yv4.x; s3 += (double)q4.y * yv4.y; s3 += (double)q4.z * yv4.z; s3 += (double)q4.w * yv4.w; }
        // reduce+store each row (block-uniform conditions -> safe syncs)
        for (int rsel = 0; rsel < 4; rsel++) {
          int j = b + rsel * 256;
          if (j > it) break;
          double s = (rsel == 0) ? s0 : (rsel == 1) ? s1 : (rsel == 2) ? s2 : s3;
          for (int o = 32; o > 0; o >>= 1) s += __shfl_down(s, o, 64);
          if (lane == 0) wl[wvid] = s;
          __syncthreads();
          if (t == 0) {
            double tot = 0.0;
            for (int u = 0; u < 16; u++) tot += wl[u];
            agst(&cvec[j], (float)tot);
            if (pass == 0 && j == it) agstd(&Ta[it], tot);
          }
          __syncthreads();
        }
      }
      gbar(gcnt, ++gph * NBLK);
      // update: r2[n0..n0+15] -= sum_j cvec[j]*Q[j][n]
      {
        for (int j2s = t; j2s <= it; j2s += 1024) cvsh[j2s] = agld(&cvec[j2s]);
        __syncthreads();
        int g = t >> 4, i = t & 15;
        float s0 = 0.f, s1 = 0.f, s2 = 0.f, s3 = 0.f;
        int j = g;
        for (; j + 192 <= it; j += 256) {
          s0 += cvsh[j]       * Q[(size_t)j * NN + n0 + i];
          s1 += cvsh[j + 64]  * Q[(size_t)(j + 64) * NN + n0 + i];
          s2 += cvsh[j + 128] * Q[(size_t)(j + 128) * NN + n0 + i];
          s3 += cvsh[j + 192] * Q[(size_t)(j + 192) * NN + n0 + i];
        }
        for (; j <= it; j += 64) s0 += cvsh[j] * Q[(size_t)j * NN + n0 + i];
        fredu[g][i] = (s0 + s1) + (s2 + s3);
        __syncthreads();
        for (int o = 32; o > 0; o >>= 1) {
          if (g < o) fredu[g][i] += fredu[g + o][i];
          __syncthreads();
        }
        if (t < 16) {
          int n = n0 + t;
          float ny = agld(&r2[n]) - fredu[0][t];
          agst(&r2[n], ny);
          nyst[t] = ny;
        }
        __syncthreads();
        if (pass == 1 && t == 0) {
          double s2d = 0.0;
          for (int u = 0; u < 16; u++) { double v = (double)nyst[u]; s2d += v * v; }
          agstd(&part[b], s2d);
        }
      }
      gbar(gcnt, ++gph * NBLK);
    }
  }
}

// ---------- bisection: top-SK eigenvalues of T ----------
__global__ void k_bisect(const double* __restrict__ Ta, const double* __restrict__ Tb,
                         double* __restrict__ theta, float* __restrict__ evL) {
  int j = threadIdx.x;
  if (j >= SK) return;
  int tgt = LM - j;
  double lo = -2.0, hi = 2.0;
  for (int iter = 0; iter < 60; iter++) {
    double mid = 0.5 * (lo + hi);
    int cnt = 0; double q = 1.0;
    for (int k = 0; k < LM; k++) {
      double off = (k > 0) ? Tb[k - 1] * Tb[k - 1] : 0.0;
      q = Ta[k] - mid - off / q;
      if (q < 0.0) cnt++;
      if (fabs(q) < 1e-280) q = -1e-280;
    }
    if (cnt >= tgt) hi = mid; else lo = mid;
  }
  theta[j] = 0.5 * (lo + hi);
  evL[j] = (float)(1.0 - theta[j]);
}

// ---------- inverse iteration for eigenvectors of T ----------
__global__ void k_invit(const double* __restrict__ Ta, const double* __restrict__ Tb,
                        const double* __restrict__ theta,
                        double* __restrict__ dws, double* __restrict__ ews,
                        double* __restrict__ fws, double* __restrict__ rws,
                        float* __restrict__ Ym) {
  int j = threadIdx.x;
  if (j >= SK) return;
  double sig = theta[j];
  for (int k = 0; k < LM; k++)
    rws[(size_t)k * SK + j] = (double)hashf((u32)k * 2654435761u + (u32)j * 40503u + 17u) - 0.5;
  for (int pass = 0; pass < 3; pass++) {
    double dk = Ta[0] - sig;
    double ek = Tb[0];
    double fk = 0.0;
    double rk = rws[j];
    for (int k = 0; k < LM - 1; k++) {
      double bk = Tb[k];
      double dn = Ta[k + 1] - sig;
      double en = (k + 2 < LM) ? Tb[k + 1] : 0.0;
      double rn = rws[(size_t)(k + 1) * SK + j];
      double dd, ee, ff, dk2, ek2, rkeep, rnext;
      if (fabs(dk) >= fabs(bk)) {
        double dsafe = (fabs(dk) > 1e-300) ? dk : 1e-300;
        double m = bk / dsafe;
        dd = dsafe; ee = ek; ff = fk;
        dk2 = dn - m * ek;
        ek2 = en - m * fk;
        rkeep = rk;
        rnext = rn - m * rk;
      } else {
        double m = dk / bk;
        dd = bk; ee = dn; ff = en;
        dk2 = ek - m * dn;
        ek2 = fk - m * en;
        rkeep = rn;
        rnext = rk - m * rn;
      }
      dws[(size_t)k * SK + j] = dd;
      ews[(size_t)k * SK + j] = ee;
      fws[(size_t)k * SK + j] = ff;
      rws[(size_t)k * SK + j] = rkeep;
      rk = rnext; dk = dk2; ek = ek2; fk = 0.0;
    }
    if (fabs(dk) < 1e-300) dk = 1e-300;
    dws[(size_t)(LM - 1) * SK + j] = dk;
    ews[(size_t)(LM - 1) * SK + j] = 0.0;
    fws[(size_t)(LM - 1) * SK + j] = 0.0;
    rws[(size_t)(LM - 1) * SK + j] = rk;
    double y1 = 0.0, y2 = 0.0, nr = 0.0;
    for (int k = LM - 1; k >= 0; k--) {
      double dv = dws[(size_t)k * SK + j];
      double yk = (rws[(size_t)k * SK + j] - ews[(size_t)k * SK + j] * y1 - fws[(size_t)k * SK + j] * y2) / dv;
      rws[(size_t)k * SK + j] = yk;
      y2 = y1; y1 = yk;
      nr += yk * yk;
    }
    double inv = 1.0 / sqrt(nr > 1e-300 ? nr : 1e-300);
    for (int k = 0; k < LM; k++) rws[(size_t)k * SK + j] *= inv;
  }
  for (int k = 0; k < LM; k++) Ym[(size_t)k * SK + j] = (float)rws[(size_t)k * SK + j];
}

// ---------- MGS on Ym columns ----------
__device__ __forceinline__ double wred64(double v) {
  for (int o = 32; o > 0; o >>= 1) v += __shfl_down(v, o, 64);
  return v;
}
__global__ void __launch_bounds__(256) k_mgsY(float* __restrict__ Ym) {
  __shared__ double lds[8];
  int t = threadIdx.x;
  for (int j = 0; j < SK; j++) {
    for (int jj = 0; jj < j; jj++) {
      double s = 0.0;
      for (int k = t; k < LM; k += 256) s += (double)Ym[(size_t)k * SK + jj] * (double)Ym[(size_t)k * SK + j];
      __syncthreads();
      s = wred64(s);
      if ((t & 63) == 0) lds[t >> 6] = s;
      __syncthreads();
      float cf = (float)(lds[0] + lds[1] + lds[2] + lds[3]);
      for (int k = t; k < LM; k += 256) Ym[(size_t)k * SK + j] -= cf * Ym[(size_t)k * SK + jj];
    }
    double s = 0.0;
    __syncthreads();
    for (int k = t; k < LM; k += 256) { double v = (double)Ym[(size_t)k * SK + j]; s += v * v; }
    s = wred64(s);
    if ((t & 63) == 0) lds[t >> 6] = s;
    __syncthreads();
    double nr = lds[0] + lds[1] + lds[2] + lds[3];
    float inv = (float)(1.0 / sqrt(nr > 1e-300 ? nr : 1e-300));
    for (int k = t; k < LM; k += 256) Ym[(size_t)k * SK + j] *= inv;
    __syncthreads();
  }
}

// ---------- generic tiled GEMMs ----------
__global__ void __launch_bounds__(256) k_gemm_tn(const float* __restrict__ A, const float* __restrict__ B,
                                                 float* __restrict__ Cm, int M, int P, int Kd) {
  __shared__ float As[16][65], Bs[16][65];
  int bm = blockIdx.x * 64, bp = blockIdx.y * 64;
  int tx = threadIdx.x & 15, ty = threadIdx.x >> 4;
  float acc[4][4] = {};
  for (int k0 = 0; k0 < Kd; k0 += 16) {
    for (int t2 = threadIdx.x; t2 < 1024; t2 += 256) {
      int mm = t2 & 63, kk = t2 >> 6;
      As[kk][mm] = A[(size_t)(k0 + kk) * M + bm + mm];
      Bs[kk][mm] = B[(size_t)(k0 + kk) * P + bp + mm];
    }
    __syncthreads();
#pragma unroll
    for (int kk = 0; kk < 16; kk++) {
      float av[4], bv[4];
#pragma unroll
      for (int a = 0; a < 4; a++) av[a] = As[kk][ty * 4 + a];
#pragma unroll
      for (int b = 0; b < 4; b++) bv[b] = Bs[kk][tx * 4 + b];
#pragma unroll
      for (int a = 0; a < 4; a++)
#pragma unroll
        for (int b = 0; b < 4; b++) acc[a][b] += av[a] * bv[b];
    }
    __syncthreads();
  }
#pragma unroll
  for (int a = 0; a < 4; a++)
#pragma unroll
    for (int b = 0; b < 4; b++)
      Cm[(size_t)(bm + ty * 4 + a) * P + bp + tx * 4 + b] = acc[a][b];
}

__global__ void __launch_bounds__(256) k_gemm_nt(const float* __restrict__ A, const float* __restrict__ B,
                                                 float* __restrict__ Cm, int M, int P, int Kd) {
  __shared__ float As[16][65], Bs[16][65];
  int bm = blockIdx.x * 64, bp = blockIdx.y * 64;
  int tx = threadIdx.x & 15, ty = threadIdx.x >> 4;
  float acc[4][4] = {};
  for (int k0 = 0; k0 < Kd; k0 += 16) {
    for (int t2 = threadIdx.x; t2 < 1024; t2 += 256) {
      int kk = t2 & 15, mm = t2 >> 4;
      As[kk][mm] = A[(size_t)(bm + mm) * Kd + k0 + kk];
      Bs[kk][mm] = B[(size_t)(bp + mm) * Kd + k0 + kk];
    }
    __syncthreads();
#pragma unroll
    for (int kk = 0; kk < 16; kk++) {
      float av[4], bv[4];
#pragma unroll
      for (int a = 0; a < 4; a++) av[a] = As[kk][ty * 4 + a];
#pragma unroll
      for (int b = 0; b < 4; b++) bv[b] = Bs[kk][tx * 4 + b];
#pragma unroll
      for (int a = 0; a < 4; a++)
#pragma unroll
        for (int b = 0; b < 4; b++) acc[a][b] += av[a] * bv[b];
    }
    __syncthreads();
  }
#pragma unroll
  for (int a = 0; a < 4; a++)
#pragma unroll
    for (int b = 0; b < 4; b++)
      Cm[(size_t)(bm + ty * 4 + a) * P + bp + tx * 4 + b] = acc[a][b];
}

__global__ void __launch_bounds__(256) k_gemm_nn(const float* __restrict__ A, const float* __restrict__ B,
                                                 float* __restrict__ Cm, int M, int P, int Kd) {
  __shared__ float As[16][65], Bs[16][65];
  int bm = blockIdx.x * 64, bp = blockIdx.y * 64;
  int tx = threadIdx.x & 15, ty = threadIdx.x >> 4;
  float acc[4][4] = {};
  for (int k0 = 0; k0 < Kd; k0 += 16) {
    for (int t2 = threadIdx.x; t2 < 1024; t2 += 256) {
      int kk = t2 & 15, mm = t2 >> 4;
      As[kk][mm] = A[(size_t)(bm + mm) * Kd + k0 + kk];
    }
    for (int t2 = threadIdx.x; t2 < 1024; t2 += 256) {
      int mm = t2 & 63, kk = t2 >> 6;
      Bs[kk][mm] = B[(size_t)(k0 + kk) * P + bp + mm];
    }
    __syncthreads();
#pragma unroll
    for (int kk = 0; kk < 16; kk++) {
      float av[4], bv[4];
#pragma unroll
      for (int a = 0; a < 4; a++) av[a] = As[kk][ty * 4 + a];
#pragma unroll
      for (int b = 0; b < 4; b++) bv[b] = Bs[kk][tx * 4 + b];
#pragma unroll
      for (int a = 0; a < 4; a++)
#pragma unroll
        for (int b = 0; b < 4; b++) acc[a][b] += av[a] * bv[b];
    }
    __syncthreads();
  }
#pragma unroll
  for (int a = 0; a < 4; a++)
#pragma unroll
    for (int b = 0; b < 4; b++)
      Cm[(size_t)(bm + ty * 4 + a) * P + bp + tx * 4 + b] = acc[a][b];
}

// ---------- s = max(max ev_a, max ev_b) ----------
__global__ void k_smax(const float* __restrict__ ea, const float* __restrict__ eb, double* __restrict__ scal) {
  __shared__ float red[128];
  int t = threadIdx.x;
  red[t] = fmaxf(ea[t], eb[t]);
  __syncthreads();
  for (int o = 64; o > 0; o >>= 1) { if (t < o) red[t] = fmaxf(red[t], red[t + o]); __syncthreads(); }
  if (t == 0) scal[1] = (double)red[0];
}

// ---------- resolvent mask ----------
__global__ void k_mask(const float* __restrict__ evr, const float* __restrict__ evc,
                       const double* __restrict__ scal, float* __restrict__ Dm) {
  int t = blockIdx.x * 256 + threadIdx.x;
  if (t >= SK * SK) return;
  int i = t / SK, j = t % SK;
  float s = (float)scal[1];
  float g1 = sqrtf(fmaxf(evc[j] / s, 0.f));
  float g2 = sqrtf(fmaxf(evr[i] / s, 0.f));
  float a2 = g2 * g2 + 1.f, a1 = g1 * g1 + 1.f;
  float re = g2 / a2 - g1 / a1;
  float im = 1.f / a2 - 1.f / a1;
  Dm[t] = re * re + im * im;
}

// ---------- per-row Cholesky solve ----------
__global__ void __launch_bounds__(128) k_cholsolve(const float* __restrict__ AAt, const float* __restrict__ BAt,
                                                   const float* __restrict__ Dm, float* __restrict__ Msg,
                                                   float* __restrict__ Cout) {
  __shared__ float xs[SK];
  int i = blockIdx.x;
  float* Ms = Msg + (size_t)i * SK * SK;
  for (int t2 = threadIdx.x; t2 < SK * SK; t2 += 128) {
    int r = t2 / SK, c2 = t2 % SK;
    float v = AAt[t2];
    if (r == c2) v += LAMBDA_ * Dm[(size_t)i * SK + r];
    Ms[t2] = v;
  }
  if (threadIdx.x < SK) xs[threadIdx.x] = BAt[(size_t)i * SK + threadIdx.x];
  __syncthreads();
  for (int k = 0; k < SK; k++) {
    if (threadIdx.x == 0) Ms[k * SK + k] = sqrtf(fmaxf(Ms[k * SK + k], 1e-20f));
    __syncthreads();
    float dk = Ms[k * SK + k];
    for (int r = k + 1 + threadIdx.x; r < SK; r += 128) Ms[r * SK + k] /= dk;
    __syncthreads();
    int rem = SK - k - 1;
    for (int t2 = threadIdx.x; t2 < rem * rem; t2 += 128) {
      int r = k + 1 + t2 / rem, c2 = k + 1 + t2 % rem;
      Ms[r * SK + c2] -= Ms[r * SK + k] * Ms[c2 * SK + k];
    }
    __syncthreads();
  }
  for (int k = 0; k < SK; k++) {
    if (threadIdx.x == 0) xs[k] /= Ms[k * SK + k];
    __syncthreads();
    float xv = xs[k];
    for (int r = k + 1 + threadIdx.x; r < SK; r += 128) xs[r] -= Ms[r * SK + k] * xv;
    __syncthreads();
  }
  for (int k = SK - 1; k >= 0; k--) {
    if (threadIdx.x == 0) xs[k] /= Ms[k * SK + k];
    __syncthreads();
    float xv = xs[k];
    for (int r = threadIdx.x; r < k; r += 128) xs[r] -= Ms[k * SK + r] * xv;
    __syncthreads();
  }
  for (int t2 = threadIdx.x; t2 < SK; t2 += 128) Cout[(size_t)i * SK + t2] = xs[t2];
}

// ---------- loss partials (deterministic) ----------
__global__ void k_frob_iden(const float* __restrict__ Mat, double* __restrict__ lpart, int slot) {
  __shared__ double red[256];
  double s = 0.0;
  for (int t2 = blockIdx.x * 256 + threadIdx.x; t2 < SK * SK; t2 += 32 * 256) {
    float v = Mat[t2] - ((t2 / SK == t2 % SK) ? 1.f : 0.f);
    s += (double)v * (double)v;
  }
  red[threadIdx.x] = s; __syncthreads();
  for (int o = 128; o > 0; o >>= 1) { if (threadIdx.x < o) red[threadIdx.x] += red[threadIdx.x + o]; __syncthreads(); }
  if (threadIdx.x == 0) lpart[slot * 32 + blockIdx.x] = red[0];
}
__global__ void k_lap(const float* __restrict__ Cm, const float* __restrict__ evc,
                      const float* __restrict__ evr, double* __restrict__ lpart, int slot) {
  __shared__ double red[256];
  double s = 0.0;
  for (int t2 = blockIdx.x * 256 + threadIdx.x; t2 < SK * SK; t2 += 32 * 256) {
    int i = t2 / SK, j = t2 % SK;
    float v = Cm[t2] * (evc[j] - evr[i]);
    s += (double)v * (double)v;
  }
  red[threadIdx.x] = s; __syncthreads();
  for (int o = 128; o > 0; o >>= 1) { if (threadIdx.x < o) red[threadIdx.x] += red[threadIdx.x + o]; __syncthreads(); }
  if (threadIdx.x == 0) lpart[slot * 32 + blockIdx.x] = red[0];
}
__global__ void k_writeout(const double* __restrict__ lpart, float* __restrict__ out) {
  if (threadIdx.x == 0) {
    double b = 0.0, o = 0.0, l = 0.0;
    for (int s = 0; s < 64; s++) b += lpart[s];
    for (int s = 64; s < 128; s++) o += lpart[s];
    for (int s = 128; s < 192; s++) l += lpart[s];
    out[0] = (float)b; out[1] = (float)o; out[2] = (float)l;
  }
}

extern "C" void kernel_launch(void* const* d_in, const int* in_sizes, int n_in,
                              void* d_out, int out_size, void* d_ws, size_t ws_size,
                              hipStream_t stream) {
  const float* feats[2] = {(const float*)d_in[0], (const float*)d_in[1]};
  char* p = (char*)d_ws;
  auto alloc = [&](size_t bytes) -> void* {
    char* r = p;
    p += (bytes + 255) & ~(size_t)255;
    return (void*)r;
  };
  float* pan   = (float*)alloc(sizeof(float) * 256 * NN);
  float* sq    = (float*)alloc(sizeof(float) * NN);
  int*   idx   = (int*)alloc(sizeof(int) * (size_t)NN * KK);
  float* dkv   = (float*)alloc(sizeof(float) * (size_t)NN * KK);
  float* wv    = (float*)alloc(sizeof(float) * (size_t)NN * KK);
  float* wadjr = (float*)alloc(sizeof(float) * (size_t)NN * KK);
  float* wadjt = (float*)alloc(sizeof(float) * (size_t)NN * KK);
  int*   cnt   = (int*)alloc(sizeof(int) * NN);
  int*   roff  = (int*)alloc(sizeof(int) * (NN + 1));
  int*   rpos  = (int*)alloc(sizeof(int) * NN);
  int*   tsrc  = (int*)alloc(sizeof(int) * (size_t)NN * KK);
  int*   tcol  = (int*)alloc(sizeof(int) * (size_t)NN * KK);
  float* deg   = (float*)alloc(sizeof(float) * NN);
  float* Q     = (float*)alloc(sizeof(float) * (size_t)LM * NN);
  float* yv0   = (float*)alloc(sizeof(float) * NN);
  float* yv1   = (float*)alloc(sizeof(float) * NN);
  float* cv    = (float*)alloc(sizeof(float) * LM);
  double* part = (double*)alloc(sizeof(double) * 256);
  double* scal = (double*)alloc(sizeof(double) * 8);
  double* Ta   = (double*)alloc(sizeof(double) * LM);
  double* Tb   = (double*)alloc(sizeof(double) * LM);
  double* theta= (double*)alloc(sizeof(double) * SK);
  double* dws  = (double*)alloc(sizeof(double) * (size_t)LM * SK);
  double* ews  = (double*)alloc(sizeof(double) * (size_t)LM * SK);
  double* fws  = (double*)alloc(sizeof(double) * (size_t)LM * SK);
  double* rws  = (double*)alloc(sizeof(double) * (size_t)LM * SK);
  float* Ym    = (float*)alloc(sizeof(float) * (size_t)LM * SK);
  float* U0    = (float*)alloc(sizeof(float) * (size_t)NN * SK);
  float* U1    = (float*)alloc(sizeof(float) * (size_t)NN * SK);
  float* ev0   = (float*)alloc(sizeof(float) * SK);
  float* ev1   = (float*)alloc(sizeof(float) * SK);
  float* Ac    = (float*)alloc(sizeof(float) * (size_t)SK * NC);
  float* Bc    = (float*)alloc(sizeof(float) * (size_t)SK * NC);
  float* AAt   = (float*)alloc(sizeof(float) * SK * SK);
  float* BAt   = (float*)alloc(sizeof(float) * SK * SK);
  float* Dm    = (float*)alloc(sizeof(float) * SK * SK);
  float* Cxy   = (float*)alloc(sizeof(float) * SK * SK);
  float* Cyx   = (float*)alloc(sizeof(float) * SK * SK);
  float* P1    = (float*)alloc(sizeof(float) * SK * SK);
  float* Msg   = (float*)alloc(sizeof(float) * (size_t)SK * SK * SK);
  double* lpart= (double*)alloc(sizeof(double) * 192);
  unsigned* gcnt = (unsigned*)alloc(sizeof(unsigned) * 64);

  float* Us[2] = {U0, U1};
  float* evs[2] = {ev0, ev1};

  for (int s2 = 0; s2 < 2; s2++) {
    const float* f = feats[s2];
    k_sqnorm<<<NN, 256, 0, stream>>>(f, sq);
    for (int p2 = 0; p2 < 16; p2++) {
      k_d2panel<<<dim3(64, 4), 256, 0, stream>>>(f, sq, pan, p2 * 256);
      k_topk<<<256, 256, 0, stream>>>(pan, p2 * 256, idx, dkv);
    }
    k_partsum<<<64, 256, 0, stream>>>(dkv, part);
    k_sigma<<<1, 64, 0, stream>>>(part, scal);
    k_wexp<<<NN * KK / 256, 256, 0, stream>>>(dkv, scal, wv);
    // deterministic CSR transpose
    hipMemsetAsync(cnt, 0, sizeof(int) * NN, stream);
    k_count<<<NN * KK / 256, 256, 0, stream>>>(idx, cnt);
    k_scan<<<1, 1024, 0, stream>>>(cnt, roff, rpos);
    k_place<<<16, 256, 0, stream>>>(idx, rpos, tsrc);
    k_sortb<<<16, 256, 0, stream>>>(roff, tsrc);
    k_deg<<<16, 256, 0, stream>>>(wv, roff, tsrc, deg);
    k_wadj2<<<16, 256, 0, stream>>>(wv, idx, roff, tsrc, deg, wadjr, wadjt, tcol);
    // fused cooperative Lanczos (full CGS2), 1024 threads/block
    hipMemsetAsync(gcnt, 0, sizeof(unsigned), stream);
    {
      u32 seed = 1234567u + (u32)s2 * 77777u;
      void* args[] = {(void*)&Q, (void*)&yv0, (void*)&yv1, (void*)&wadjr, (void*)&idx,
                      (void*)&wadjt, (void*)&tcol, (void*)&roff,
                      (void*)&cv, (void*)&part, (void*)&Ta, (void*)&Tb,
                      (void*)&gcnt, (void*)&seed};
      hipLaunchCooperativeKernel((const void*)k_lanczos, dim3(NBLK), dim3(1024), args, 0, stream);
    }
    k_bisect<<<1, 128, 0, stream>>>(Ta, Tb, theta, evs[s2]);
    k_invit<<<1, 128, 0, stream>>>(Ta, Tb, theta, dws, ews, fws, rws, Ym);
    k_mgsY<<<1, 256, 0, stream>>>(Ym);
    k_gemm_tn<<<dim3(NN / 64, SK / 64), 256, 0, stream>>>(Q, Ym, Us[s2], NN, SK, LM);
  }

  // spectral coefficients
  k_gemm_tn<<<dim3(SK / 64, NC / 64), 256, 0, stream>>>(U0, feats[0], Ac, SK, NC, NN);
  k_gemm_tn<<<dim3(SK / 64, NC / 64), 256, 0, stream>>>(U1, feats[1], Bc, SK, NC, NN);
  k_smax<<<1, 128, 0, stream>>>(ev0, ev1, scal);

  // Cxy: x = v(0), y = t(1)
  k_gemm_nt<<<dim3(2, 2), 256, 0, stream>>>(Ac, Ac, AAt, SK, SK, NC);
  k_gemm_nt<<<dim3(2, 2), 256, 0, stream>>>(Bc, Ac, BAt, SK, SK, NC);
  k_mask<<<64, 256, 0, stream>>>(ev1, ev0, scal, Dm);
  k_cholsolve<<<SK, 128, 0, stream>>>(AAt, BAt, Dm, Msg, Cxy);
  // Cyx: x = t(1), y = v(0)
  k_gemm_nt<<<dim3(2, 2), 256, 0, stream>>>(Bc, Bc, AAt, SK, SK, NC);
  k_gemm_nt<<<dim3(2, 2), 256, 0, stream>>>(Ac, Bc, BAt, SK, SK, NC);
  k_mask<<<64, 256, 0, stream>>>(ev0, ev1, scal, Dm);
  k_cholsolve<<<SK, 128, 0, stream>>>(AAt, BAt, Dm, Msg, Cyx);

  // losses
  k_gemm_nn<<<dim3(2, 2), 256, 0, stream>>>(Cxy, Cyx, P1, SK, SK, SK);
  k_frob_iden<<<32, 256, 0, stream>>>(P1, lpart, 0);
  k_gemm_nn<<<dim3(2, 2), 256, 0, stream>>>(Cyx, Cxy, P1, SK, SK, SK);
  k_frob_iden<<<32, 256, 0, stream>>>(P1, lpart, 1);
  k_gemm_tn<<<dim3(2, 2), 256, 0, stream>>>(Cxy, Cxy, P1, SK, SK, SK);
  k_frob_iden<<<32, 256, 0, stream>>>(P1, lpart, 2);
  k_gemm_tn<<<dim3(2, 2), 256, 0, stream>>>(Cyx, Cyx, P1, SK, SK, SK);
  k_frob_iden<<<32, 256, 0, stream>>>(P1, lpart, 3);
  k_lap<<<32, 256, 0, stream>>>(Cxy, ev0, ev1, lpart, 4);
  k_lap<<<32, 256, 0, stream>>>(Cyx, ev1, ev0, lpart, 5);
  k_writeout<<<1, 64, 0, stream>>>(lpart, (float*)d_out);
}

// Round 6
// 236148.901 us; speedup vs baseline: 3.4191x; 1.3455x over previous
//
#include <hip/hip_runtime.h>
#include <math.h>

#define NN 4096      // points
#define NC 768       // feature dim
#define KK 16        // knn k
#define SK 128       // spectral basis size
#define LM 1024      // Lanczos steps
#define NBLK 256     // cooperative grid blocks
#define LAMBDA_ 100.0f

typedef unsigned int u32;

__device__ __forceinline__ float hashf(u32 x) {
  x ^= x >> 16; x *= 0x7feb352dU; x ^= x >> 15; x *= 0x846ca68bU; x ^= x >> 16;
  return ((float)x) * (1.0f / 4294967296.0f);  // [0,1)
}

// ---- agent-scope (device-coherent) access helpers: bypass non-coherent L2 ----
__device__ __forceinline__ float agld(const float* p) {
  return __hip_atomic_load((float*)p, __ATOMIC_RELAXED, __HIP_MEMORY_SCOPE_AGENT);
}
__device__ __forceinline__ void agst(float* p, float v) {
  __hip_atomic_store(p, v, __ATOMIC_RELAXED, __HIP_MEMORY_SCOPE_AGENT);
}
__device__ __forceinline__ double agldd(const double* p) {
  return __hip_atomic_load((double*)p, __ATOMIC_RELAXED, __HIP_MEMORY_SCOPE_AGENT);
}
__device__ __forceinline__ void agstd(double* p, double v) {
  __hip_atomic_store(p, v, __ATOMIC_RELAXED, __HIP_MEMORY_SCOPE_AGENT);
}

// ---- two-level flush-free grid barrier (cooperative co-residency required) ----
// sy layout (unsigned, 4B each): [grp*16] group counters (64B apart),
// [256] top counter, [512 + grp*16] per-group epoch go-flags.
// Relaxed polls (no per-poll cache invalidate) + single acquire fence at end.
// Data visibility: vmcnt(0) drains all agent stores to the coherence point
// BEFORE any counter add, so any later agent load observes them; Q-row
// normal-cached reads rely on the write-once fresh-address argument.
__device__ __forceinline__ void gbar(unsigned* sy, unsigned gph) {
  asm volatile("s_waitcnt vmcnt(0)" ::: "memory");
  __syncthreads();
  if (threadIdx.x == 0) {
    const int grp = blockIdx.x >> 4, mem = blockIdx.x & 15;
    unsigned* gc  = sy + grp * 16;
    unsigned* top = sy + 256;
    unsigned* fl  = sy + 512 + grp * 16;
    __hip_atomic_fetch_add(gc, 1u, __ATOMIC_RELEASE, __HIP_MEMORY_SCOPE_AGENT);
    if (mem == 0) {
      while (__hip_atomic_load(gc, __ATOMIC_RELAXED, __HIP_MEMORY_SCOPE_AGENT) < gph * 16u)
        __builtin_amdgcn_s_sleep(2);
      __hip_atomic_fetch_add(top, 1u, __ATOMIC_RELEASE, __HIP_MEMORY_SCOPE_AGENT);
      while (__hip_atomic_load(top, __ATOMIC_RELAXED, __HIP_MEMORY_SCOPE_AGENT) < gph * 16u)
        __builtin_amdgcn_s_sleep(2);
      __hip_atomic_store(fl, gph, __ATOMIC_RELEASE, __HIP_MEMORY_SCOPE_AGENT);
    } else {
      while (__hip_atomic_load(fl, __ATOMIC_RELAXED, __HIP_MEMORY_SCOPE_AGENT) < gph)
        __builtin_amdgcn_s_sleep(2);
    }
    __builtin_amdgcn_fence(__ATOMIC_ACQUIRE, "agent");
  }
  __syncthreads();
}

// ---------- row squared norms ----------
__global__ void k_sqnorm(const float* __restrict__ f, float* __restrict__ sq) {
  __shared__ float red[256];
  int i = blockIdx.x;
  float s = 0.f;
  for (int c = threadIdx.x; c < NC; c += 256) { float v = f[(size_t)i * NC + c]; s += v * v; }
  red[threadIdx.x] = s; __syncthreads();
  for (int o = 128; o > 0; o >>= 1) { if (threadIdx.x < o) red[threadIdx.x] += red[threadIdx.x + o]; __syncthreads(); }
  if (threadIdx.x == 0) sq[i] = red[0];
}

// ---------- d2 panel: pan[256][NN] for rows i0..i0+255 ----------
__global__ void __launch_bounds__(256) k_d2panel(const float* __restrict__ f, const float* __restrict__ sq,
                                                 float* __restrict__ pan, int i0) {
  __shared__ float As[16][65], Bs[16][65];
  int bj = blockIdx.x, bi = blockIdx.y;
  int row0 = i0 + bi * 64, col0 = bj * 64;
  int tx = threadIdx.x & 15, ty = threadIdx.x >> 4;
  float acc[4][4] = {};
  for (int k0 = 0; k0 < NC; k0 += 16) {
    for (int t2 = threadIdx.x; t2 < 1024; t2 += 256) {
      int kk = t2 & 15, rr = t2 >> 4;
      As[kk][rr] = f[(size_t)(row0 + rr) * NC + k0 + kk];
      Bs[kk][rr] = f[(size_t)(col0 + rr) * NC + k0 + kk];
    }
    __syncthreads();
#pragma unroll
    for (int kk = 0; kk < 16; kk++) {
      float av[4], bv[4];
#pragma unroll
      for (int a = 0; a < 4; a++) av[a] = As[kk][ty * 4 + a];
#pragma unroll
      for (int b = 0; b < 4; b++) bv[b] = Bs[kk][tx * 4 + b];
#pragma unroll
      for (int a = 0; a < 4; a++)
#pragma unroll
        for (int b = 0; b < 4; b++) acc[a][b] += av[a] * bv[b];
    }
    __syncthreads();
  }
#pragma unroll
  for (int a = 0; a < 4; a++) {
    int gr = row0 + ty * 4 + a;
    int pr = bi * 64 + ty * 4 + a;
    float sr = sq[gr];
#pragma unroll
    for (int b = 0; b < 4; b++) {
      int gc = col0 + tx * 4 + b;
      float v = sr + sq[gc] - 2.f * acc[a][b];
      v = fmaxf(v, 0.f);
      if (gr == gc) v += 1e10f;
      pan[(size_t)pr * NN + gc] = v;
    }
  }
}

// ---------- top-16 smallest per row ----------
__global__ void __launch_bounds__(256) k_topk(const float* __restrict__ pan, int i0,
                                              int* __restrict__ idx, float* __restrict__ dkv) {
  __shared__ float vals[NN];
  __shared__ float rv[256];
  __shared__ int ri[256];
  int r = blockIdx.x;
  const float* row = pan + (size_t)r * NN;
  for (int j = threadIdx.x; j < NN; j += 256) vals[j] = row[j];
  __syncthreads();
  for (int t3 = 0; t3 < KK; t3++) {
    float bv = 1e30f; int bi2 = NN;
    for (int j2 = threadIdx.x; j2 < NN; j2 += 256) {
      float v = vals[j2];
      if (v < bv || (v == bv && j2 < bi2)) { bv = v; bi2 = j2; }
    }
    rv[threadIdx.x] = bv; ri[threadIdx.x] = bi2;
    __syncthreads();
    for (int o = 128; o > 0; o >>= 1) {
      if (threadIdx.x < o) {
        float v2 = rv[threadIdx.x + o]; int i2 = ri[threadIdx.x + o];
        if (v2 < rv[threadIdx.x] || (v2 == rv[threadIdx.x] && i2 < ri[threadIdx.x])) {
          rv[threadIdx.x] = v2; ri[threadIdx.x] = i2;
        }
      }
      __syncthreads();
    }
    if (threadIdx.x == 0) {
      idx[(size_t)(i0 + r) * KK + t3] = ri[0];
      dkv[(size_t)(i0 + r) * KK + t3] = rv[0];
      vals[ri[0]] = 1e30f;
    }
    __syncthreads();
  }
}

// ---------- sigma2 = mean(dkv) + 1e-12 ----------
__global__ void k_partsum(const float* __restrict__ dkv, double* __restrict__ part) {
  __shared__ double red[256];
  double s = 0.0;
  for (int t2 = blockIdx.x * 256 + threadIdx.x; t2 < NN * KK; t2 += 64 * 256) s += (double)dkv[t2];
  red[threadIdx.x] = s; __syncthreads();
  for (int o = 128; o > 0; o >>= 1) { if (threadIdx.x < o) red[threadIdx.x] += red[threadIdx.x + o]; __syncthreads(); }
  if (threadIdx.x == 0) part[blockIdx.x] = red[0];
}
__global__ void k_sigma(const double* __restrict__ part, double* __restrict__ scal) {
  __shared__ double red[64];
  red[threadIdx.x] = part[threadIdx.x]; __syncthreads();
  for (int o = 32; o > 0; o >>= 1) { if (threadIdx.x < o) red[threadIdx.x] += red[threadIdx.x + o]; __syncthreads(); }
  if (threadIdx.x == 0) scal[0] = red[0] / (double)(NN * KK) + 1e-12;
}

// ---------- gaussian weights ----------
__global__ void k_wexp(const float* __restrict__ dkv, const double* __restrict__ scal,
                       float* __restrict__ wv) {
  int t = blockIdx.x * 256 + threadIdx.x;
  if (t >= NN * KK) return;
  float inv2s = (float)(0.5 / scal[0]);
  wv[t] = expf(-dkv[t] * inv2s);
}

// ---------- deterministic CSR transpose construction ----------
__global__ void k_count(const int* __restrict__ idx, int* __restrict__ cnt) {
  int t = blockIdx.x * 256 + threadIdx.x;
  if (t < NN * KK) atomicAdd(&cnt[idx[t]], 1);
}

__global__ void __launch_bounds__(1024) k_scan(const int* __restrict__ cnt,
                                               int* __restrict__ roff, int* __restrict__ rpos) {
  __shared__ int buf[1024];
  int t = threadIdx.x;
  int v[4]; int s = 0;
#pragma unroll
  for (int u = 0; u < 4; u++) { v[u] = cnt[t * 4 + u]; s += v[u]; }
  buf[t] = s; __syncthreads();
  for (int o = 1; o < 1024; o <<= 1) {
    int x = (t >= o) ? buf[t - o] : 0;
    __syncthreads();
    buf[t] += x;
    __syncthreads();
  }
  int run = (t == 0) ? 0 : buf[t - 1];
#pragma unroll
  for (int u = 0; u < 4; u++) { roff[t * 4 + u] = run; rpos[t * 4 + u] = run; run += v[u]; }
  if (t == 1023) roff[NN] = run;
}

__global__ void k_place(const int* __restrict__ idx, int* __restrict__ rpos, int* __restrict__ tsrc) {
  int i = blockIdx.x * 256 + threadIdx.x;
  if (i >= NN) return;
  for (int l = 0; l < KK; l++) {
    int j = idx[(size_t)i * KK + l];
    int e = atomicAdd(&rpos[j], 1);
    tsrc[e] = i * KK + l;
  }
}

__global__ void k_sortb(const int* __restrict__ roff, int* __restrict__ tsrc) {
  int i = blockIdx.x * 256 + threadIdx.x;
  if (i >= NN) return;
  int b = roff[i], e = roff[i + 1];
  for (int a = b + 1; a < e; a++) {
    int key = tsrc[a]; int c = a - 1;
    while (c >= b && tsrc[c] > key) { tsrc[c + 1] = tsrc[c]; c--; }
    tsrc[c + 1] = key;
  }
}

// ---------- degrees ----------
__global__ void k_deg(const float* __restrict__ wv, const int* __restrict__ roff,
                      const int* __restrict__ tsrc, float* __restrict__ deg) {
  int i = blockIdx.x * 256 + threadIdx.x;
  if (i >= NN) return;
  float s = 0.f;
  for (int l = 0; l < KK; l++) s += wv[(size_t)i * KK + l];
  float s2 = 0.f;
  for (int e = roff[i]; e < roff[i + 1]; e++) s2 += wv[tsrc[e]];
  deg[i] = 0.5f * (s + s2);
}

// ---------- normalized adjacency ----------
__global__ void k_wadj2(const float* __restrict__ wv, const int* __restrict__ idx,
                        const int* __restrict__ roff, const int* __restrict__ tsrc,
                        const float* __restrict__ deg,
                        float* __restrict__ wadjr, float* __restrict__ wadjt,
                        int* __restrict__ tcol) {
  int i = blockIdx.x * 256 + threadIdx.x;
  if (i >= NN) return;
  float di = 1.0f / sqrtf(deg[i] + 1e-8f);
  for (int l = 0; l < KK; l++) {
    int j = idx[(size_t)i * KK + l];
    float dj = 1.0f / sqrtf(deg[j] + 1e-8f);
    wadjr[(size_t)i * KK + l] = 0.5f * wv[(size_t)i * KK + l] * di * dj;
  }
  for (int e = roff[i]; e < roff[i + 1]; e++) {
    int s = tsrc[e];
    int sn = s / KK;
    float dj = 1.0f / sqrtf(deg[sn] + 1e-8f);
    wadjt[e] = 0.5f * wv[s] * di * dj;
    tcol[e] = sn;
  }
}

// ---------- fused cooperative Lanczos, 1024 threads/block, 5 barriers/iter ----------
// Arithmetic identical to round-5 kernel; only the barrier changed (tree).
__global__ void __launch_bounds__(1024) k_lanczos(
    float* __restrict__ Q, float* __restrict__ y0v, float* __restrict__ y1v,
    const float* __restrict__ wadjr, const int* __restrict__ idx,
    const float* __restrict__ wadjt, const int* __restrict__ tcol,
    const int* __restrict__ roff,
    float* __restrict__ cvec, double* __restrict__ part,
    double* __restrict__ Ta, double* __restrict__ Tb,
    unsigned* __restrict__ sy, u32 seed) {
  const int b = blockIdx.x, t = threadIdx.x;
  const int n0 = b * 16;
  const int lane = t & 63, wvid = t >> 6;  // 16 waves
  __shared__ float ysh[NN];        // 16KB staged residual
  __shared__ float cvsh[LM];       // 4KB staged coefficients
  __shared__ double pd[256];       // norm partials
  __shared__ double wl[16];        // wave-leader partials
  __shared__ float fredu[64][17];  // update combine
  __shared__ float nyst[16];
  unsigned gph = 0;

  // init residual + norm partials
  if (t < 16) {
    int n = n0 + t;
    agst(&y0v[n], hashf((u32)n * 2246822519u + seed) - 0.5f);
  }
  __syncthreads();
  if (t == 0) {
    double s = 0.0;
    for (int u = 0; u < 16; u++) { double v = (double)agld(&y0v[n0 + u]); s += v * v; }
    agstd(&part[b], s);
  }
  gbar(sy, ++gph);

  for (int it = 0; it < LM; it++) {
    float* r  = (it & 1) ? y1v : y0v;  // current residual (to normalize)
    float* r2 = (it & 1) ? y0v : y1v;  // SpMV target / working residual

    // ---- Phase B': norm + q-row write + SpMV (on-the-fly normalize) ----
    if (t < 256) pd[t] = agldd(&part[t]);
    __syncthreads();
    for (int o = 128; o > 0; o >>= 1) { if (t < o) pd[t] += pd[t + o]; __syncthreads(); }
    double nrm = sqrt(pd[0]);
    if (b == 0 && t == 0 && it > 0) agstd(&Tb[it - 1], nrm);
    float inv = (float)(1.0 / (nrm > 1e-300 ? nrm : 1e-300));
    if (t < 16) {
      int n = n0 + t;
      agst(&Q[(size_t)it * NN + n], agld(&r[n]) * inv);
    }
    {
      int n = n0 + wvid;                       // row per wave
      int rb = roff[n], re = roff[n + 1];
      int L = 16 + (re - rb);
      float acc = 0.f;
      for (int i = lane; i < L; i += 64) {
        float w, qv;
        if (i < 16) { w = wadjr[(size_t)n * KK + i]; qv = agld(&r[idx[(size_t)n * KK + i]]) * inv; }
        else        { int e = rb + i - 16; w = wadjt[e]; qv = agld(&r[tcol[e]]) * inv; }
        acc += w * qv;
      }
      for (int o = 32; o > 0; o >>= 1) acc += __shfl_down(acc, o, 64);
      if (lane == 0) agst(&r2[n], acc);
    }
    gbar(sy, ++gph);

    // ---- CGS2: two (dots, update) passes on r2 ----
#pragma unroll
    for (int pass = 0; pass < 2; pass++) {
      // stage r2 -> LDS (agent loads, 4/thread)
      {
        int base = t * 4;
        float a0 = agld(&r2[base]), a1 = agld(&r2[base + 1]);
        float a2 = agld(&r2[base + 2]), a3 = agld(&r2[base + 3]);
        ysh[base] = a0; ysh[base + 1] = a1; ysh[base + 2] = a2; ysh[base + 3] = a3;
      }
      __syncthreads();
      // dots: up to 4 rows j == b (mod 256); compute all partials first (MLP)
      {
        float4 yv4 = *(const float4*)&ysh[t * 4];
        int j0 = b, j1 = b + 256, j2 = b + 512, j3 = b + 768;
        double s0 = 0.0, s1 = 0.0, s2 = 0.0, s3 = 0.0;
        if (j0 <= it) { float4 q4 = *(const float4*)&Q[(size_t)j0 * NN + t * 4];
          s0 = (double)q4.x * yv4.x; s0 += (double)q4.y * yv4.y; s0 += (double)q4.z * yv4.z; s0 += (double)q4.w * yv4.w; }
        if (j1 <= it) { float4 q4 = *(const float4*)&Q[(size_t)j1 * NN + t * 4];
          s1 = (double)q4.x * yv4.x; s1 += (double)q4.y * yv4.y; s1 += (double)q4.z * yv4.z; s1 += (double)q4.w * yv4.w; }
        if (j2 <= it) { float4 q4 = *(const float4*)&Q[(size_t)j2 * NN + t * 4];
          s2 = (double)q4.x * yv4.x; s2 += (double)q4.y * yv4.y; s2 += (double)q4.z * yv4.z; s2 += (double)q4.w * yv4.w; }
        if (j3 <= it) { float4 q4 = *(const float4*)&Q[(size_t)j3 * NN + t * 4];
          s3 = (double)q4.x * yv4.x; s3 += (double)q4.y * yv4.y; s3 += (double)q4.z * yv4.z; s3 += (double)q4.w * yv4.w; }
        for (int rsel = 0; rsel < 4; rsel++) {
          int j = b + rsel * 256;
          if (j > it) break;
          double s = (rsel == 0) ? s0 : (rsel == 1) ? s1 : (rsel == 2) ? s2 : s3;
          for (int o = 32; o > 0; o >>= 1) s += __shfl_down(s, o, 64);
          if (lane == 0) wl[wvid] = s;
          __syncthreads();
          if (t == 0) {
            double tot = 0.0;
            for (int u = 0; u < 16; u++) tot += wl[u];
            agst(&cvec[j], (float)tot);
            if (pass == 0 && j == it) agstd(&Ta[it], tot);
          }
          __syncthreads();
        }
      }
      gbar(sy, ++gph);
      // update: r2[n0..n0+15] -= sum_j cvec[j]*Q[j][n]
      {
        for (int j2s = t; j2s <= it; j2s += 1024) cvsh[j2s] = agld(&cvec[j2s]);
        __syncthreads();
        int g = t >> 4, i = t & 15;
        float s0 = 0.f, s1 = 0.f, s2 = 0.f, s3 = 0.f;
        int j = g;
        for (; j + 192 <= it; j += 256) {
          s0 += cvsh[j]       * Q[(size_t)j * NN + n0 + i];
          s1 += cvsh[j + 64]  * Q[(size_t)(j + 64) * NN + n0 + i];
          s2 += cvsh[j + 128] * Q[(size_t)(j + 128) * NN + n0 + i];
          s3 += cvsh[j + 192] * Q[(size_t)(j + 192) * NN + n0 + i];
        }
        for (; j <= it; j += 64) s0 += cvsh[j] * Q[(size_t)j * NN + n0 + i];
        fredu[g][i] = (s0 + s1) + (s2 + s3);
        __syncthreads();
        for (int o = 32; o > 0; o >>= 1) {
          if (g < o) fredu[g][i] += fredu[g + o][i];
          __syncthreads();
        }
        if (t < 16) {
          int n = n0 + t;
          float ny = agld(&r2[n]) - fredu[0][t];
          agst(&r2[n], ny);
          nyst[t] = ny;
        }
        __syncthreads();
        if (pass == 1 && t == 0) {
          double s2d = 0.0;
          for (int u = 0; u < 16; u++) { double v = (double)nyst[u]; s2d += v * v; }
          agstd(&part[b], s2d);
        }
      }
      gbar(sy, ++gph);
    }
  }
}

// ---------- bisection: top-SK eigenvalues of T ----------
__global__ void k_bisect(const double* __restrict__ Ta, const double* __restrict__ Tb,
                         double* __restrict__ theta, float* __restrict__ evL) {
  int j = threadIdx.x;
  if (j >= SK) return;
  int tgt = LM - j;
  double lo = -2.0, hi = 2.0;
  for (int iter = 0; iter < 60; iter++) {
    double mid = 0.5 * (lo + hi);
    int cnt = 0; double q = 1.0;
    for (int k = 0; k < LM; k++) {
      double off = (k > 0) ? Tb[k - 1] * Tb[k - 1] : 0.0;
      q = Ta[k] - mid - off / q;
      if (q < 0.0) cnt++;
      if (fabs(q) < 1e-280) q = -1e-280;
    }
    if (cnt >= tgt) hi = mid; else lo = mid;
  }
  theta[j] = 0.5 * (lo + hi);
  evL[j] = (float)(1.0 - theta[j]);
}

// ---------- inverse iteration for eigenvectors of T ----------
__global__ void k_invit(const double* __restrict__ Ta, const double* __restrict__ Tb,
                        const double* __restrict__ theta,
                        double* __restrict__ dws, double* __restrict__ ews,
                        double* __restrict__ fws, double* __restrict__ rws,
                        float* __restrict__ Ym) {
  int j = threadIdx.x;
  if (j >= SK) return;
  double sig = theta[j];
  for (int k = 0; k < LM; k++)
    rws[(size_t)k * SK + j] = (double)hashf((u32)k * 2654435761u + (u32)j * 40503u + 17u) - 0.5;
  for (int pass = 0; pass < 3; pass++) {
    double dk = Ta[0] - sig;
    double ek = Tb[0];
    double fk = 0.0;
    double rk = rws[j];
    for (int k = 0; k < LM - 1; k++) {
      double bk = Tb[k];
      double dn = Ta[k + 1] - sig;
      double en = (k + 2 < LM) ? Tb[k + 1] : 0.0;
      double rn = rws[(size_t)(k + 1) * SK + j];
      double dd, ee, ff, dk2, ek2, rkeep, rnext;
      if (fabs(dk) >= fabs(bk)) {
        double dsafe = (fabs(dk) > 1e-300) ? dk : 1e-300;
        double m = bk / dsafe;
        dd = dsafe; ee = ek; ff = fk;
        dk2 = dn - m * ek;
        ek2 = en - m * fk;
        rkeep = rk;
        rnext = rn - m * rk;
      } else {
        double m = dk / bk;
        dd = bk; ee = dn; ff = en;
        dk2 = ek - m * dn;
        ek2 = fk - m * en;
        rkeep = rn;
        rnext = rk - m * rn;
      }
      dws[(size_t)k * SK + j] = dd;
      ews[(size_t)k * SK + j] = ee;
      fws[(size_t)k * SK + j] = ff;
      rws[(size_t)k * SK + j] = rkeep;
      rk = rnext; dk = dk2; ek = ek2; fk = 0.0;
    }
    if (fabs(dk) < 1e-300) dk = 1e-300;
    dws[(size_t)(LM - 1) * SK + j] = dk;
    ews[(size_t)(LM - 1) * SK + j] = 0.0;
    fws[(size_t)(LM - 1) * SK + j] = 0.0;
    rws[(size_t)(LM - 1) * SK + j] = rk;
    double y1 = 0.0, y2 = 0.0, nr = 0.0;
    for (int k = LM - 1; k >= 0; k--) {
      double dv = dws[(size_t)k * SK + j];
      double yk = (rws[(size_t)k * SK + j] - ews[(size_t)k * SK + j] * y1 - fws[(size_t)k * SK + j] * y2) / dv;
      rws[(size_t)k * SK + j] = yk;
      y2 = y1; y1 = yk;
      nr += yk * yk;
    }
    double inv = 1.0 / sqrt(nr > 1e-300 ? nr : 1e-300);
    for (int k = 0; k < LM; k++) rws[(size_t)k * SK + j] *= inv;
  }
  for (int k = 0; k < LM; k++) Ym[(size_t)k * SK + j] = (float)rws[(size_t)k * SK + j];
}

// ---------- MGS on Ym columns ----------
__device__ __forceinline__ double wred64(double v) {
  for (int o = 32; o > 0; o >>= 1) v += __shfl_down(v, o, 64);
  return v;
}
__global__ void __launch_bounds__(256) k_mgsY(float* __restrict__ Ym) {
  __shared__ double lds[8];
  int t = threadIdx.x;
  for (int j = 0; j < SK; j++) {
    for (int jj = 0; jj < j; jj++) {
      double s = 0.0;
      for (int k = t; k < LM; k += 256) s += (double)Ym[(size_t)k * SK + jj] * (double)Ym[(size_t)k * SK + j];
      __syncthreads();
      s = wred64(s);
      if ((t & 63) == 0) lds[t >> 6] = s;
      __syncthreads();
      float cf = (float)(lds[0] + lds[1] + lds[2] + lds[3]);
      for (int k = t; k < LM; k += 256) Ym[(size_t)k * SK + j] -= cf * Ym[(size_t)k * SK + jj];
    }
    double s = 0.0;
    __syncthreads();
    for (int k = t; k < LM; k += 256) { double v = (double)Ym[(size_t)k * SK + j]; s += v * v; }
    s = wred64(s);
    if ((t & 63) == 0) lds[t >> 6] = s;
    __syncthreads();
    double nr = lds[0] + lds[1] + lds[2] + lds[3];
    float inv = (float)(1.0 / sqrt(nr > 1e-300 ? nr : 1e-300));
    for (int k = t; k < LM; k += 256) Ym[(size_t)k * SK + j] *= inv;
    __syncthreads();
  }
}

// ---------- generic tiled GEMMs ----------
__global__ void __launch_bounds__(256) k_gemm_tn(const float* __restrict__ A, const float* __restrict__ B,
                                                 float* __restrict__ Cm, int M, int P, int Kd) {
  __shared__ float As[16][65], Bs[16][65];
  int bm = blockIdx.x * 64, bp = blockIdx.y * 64;
  int tx = threadIdx.x & 15, ty = threadIdx.x >> 4;
  float acc[4][4] = {};
  for (int k0 = 0; k0 < Kd; k0 += 16) {
    for (int t2 = threadIdx.x; t2 < 1024; t2 += 256) {
      int mm = t2 & 63, kk = t2 >> 6;
      As[kk][mm] = A[(size_t)(k0 + kk) * M + bm + mm];
      Bs[kk][mm] = B[(size_t)(k0 + kk) * P + bp + mm];
    }
    __syncthreads();
#pragma unroll
    for (int kk = 0; kk < 16; kk++) {
      float av[4], bv[4];
#pragma unroll
      for (int a = 0; a < 4; a++) av[a] = As[kk][ty * 4 + a];
#pragma unroll
      for (int b = 0; b < 4; b++) bv[b] = Bs[kk][tx * 4 + b];
#pragma unroll
      for (int a = 0; a < 4; a++)
#pragma unroll
        for (int b = 0; b < 4; b++) acc[a][b] += av[a] * bv[b];
    }
    __syncthreads();
  }
#pragma unroll
  for (int a = 0; a < 4; a++)
#pragma unroll
    for (int b = 0; b < 4; b++)
      Cm[(size_t)(bm + ty * 4 + a) * P + bp + tx * 4 + b] = acc[a][b];
}

__global__ void __launch_bounds__(256) k_gemm_nt(const float* __restrict__ A, const float* __restrict__ B,
                                                 float* __restrict__ Cm, int M, int P, int Kd) {
  __shared__ float As[16][65], Bs[16][65];
  int bm = blockIdx.x * 64, bp = blockIdx.y * 64;
  int tx = threadIdx.x & 15, ty = threadIdx.x >> 4;
  float acc[4][4] = {};
  for (int k0 = 0; k0 < Kd; k0 += 16) {
    for (int t2 = threadIdx.x; t2 < 1024; t2 += 256) {
      int kk = t2 & 15, mm = t2 >> 4;
      As[kk][mm] = A[(size_t)(bm + mm) * Kd + k0 + kk];
      Bs[kk][mm] = B[(size_t)(bp + mm) * Kd + k0 + kk];
    }
    __syncthreads();
#pragma unroll
    for (int kk = 0; kk < 16; kk++) {
      float av[4], bv[4];
#pragma unroll
      for (int a = 0; a < 4; a++) av[a] = As[kk][ty * 4 + a];
#pragma unroll
      for (int b = 0; b < 4; b++) bv[b] = Bs[kk][tx * 4 + b];
#pragma unroll
      for (int a = 0; a < 4; a++)
#pragma unroll
        for (int b = 0; b < 4; b++) acc[a][b] += av[a] * bv[b];
    }
    __syncthreads();
  }
#pragma unroll
  for (int a = 0; a < 4; a++)
#pragma unroll
    for (int b = 0; b < 4; b++)
      Cm[(size_t)(bm + ty * 4 + a) * P + bp + tx * 4 + b] = acc[a][b];
}

__global__ void __launch_bounds__(256) k_gemm_nn(const float* __restrict__ A, const float* __restrict__ B,
                                                 float* __restrict__ Cm, int M, int P, int Kd) {
  __shared__ float As[16][65], Bs[16][65];
  int bm = blockIdx.x * 64, bp = blockIdx.y * 64;
  int tx = threadIdx.x & 15, ty = threadIdx.x >> 4;
  float acc[4][4] = {};
  for (int k0 = 0; k0 < Kd; k0 += 16) {
    for (int t2 = threadIdx.x; t2 < 1024; t2 += 256) {
      int kk = t2 & 15, mm = t2 >> 4;
      As[kk][mm] = A[(size_t)(bm + mm) * Kd + k0 + kk];
    }
    for (int t2 = threadIdx.x; t2 < 1024; t2 += 256) {
      int mm = t2 & 63, kk = t2 >> 6;
      Bs[kk][mm] = B[(size_t)(k0 + kk) * P + bp + mm];
    }
    __syncthreads();
#pragma unroll
    for (int kk = 0; kk < 16; kk++) {
      float av[4], bv[4];
#pragma unroll
      for (int a = 0; a < 4; a++) av[a] = As[kk][ty * 4 + a];
#pragma unroll
      for (int b = 0; b < 4; b++) bv[b] = Bs[kk][tx * 4 + b];
#pragma unroll
      for (int a = 0; a < 4; a++)
#pragma unroll
        for (int b = 0; b < 4; b++) acc[a][b] += av[a] * bv[b];
    }
    __syncthreads();
  }
#pragma unroll
  for (int a = 0; a < 4; a++)
#pragma unroll
    for (int b = 0; b < 4; b++)
      Cm[(size_t)(bm + ty * 4 + a) * P + bp + tx * 4 + b] = acc[a][b];
}

// ---------- s = max(max ev_a, max ev_b) ----------
__global__ void k_smax(const float* __restrict__ ea, const float* __restrict__ eb, double* __restrict__ scal) {
  __shared__ float red[128];
  int t = threadIdx.x;
  red[t] = fmaxf(ea[t], eb[t]);
  __syncthreads();
  for (int o = 64; o > 0; o >>= 1) { if (t < o) red[t] = fmaxf(red[t], red[t + o]); __syncthreads(); }
  if (t == 0) scal[1] = (double)red[0];
}

// ---------- resolvent mask ----------
__global__ void k_mask(const float* __restrict__ evr, const float* __restrict__ evc,
                       const double* __restrict__ scal, float* __restrict__ Dm) {
  int t = blockIdx.x * 256 + threadIdx.x;
  if (t >= SK * SK) return;
  int i = t / SK, j = t % SK;
  float s = (float)scal[1];
  float g1 = sqrtf(fmaxf(evc[j] / s, 0.f));
  float g2 = sqrtf(fmaxf(evr[i] / s, 0.f));
  float a2 = g2 * g2 + 1.f, a1 = g1 * g1 + 1.f;
  float re = g2 / a2 - g1 / a1;
  float im = 1.f / a2 - 1.f / a1;
  Dm[t] = re * re + im * im;
}

// ---------- per-row Cholesky solve ----------
__global__ void __launch_bounds__(128) k_cholsolve(const float* __restrict__ AAt, const float* __restrict__ BAt,
                                                   const float* __restrict__ Dm, float* __restrict__ Msg,
                                                   float* __restrict__ Cout) {
  __shared__ float xs[SK];
  int i = blockIdx.x;
  float* Ms = Msg + (size_t)i * SK * SK;
  for (int t2 = threadIdx.x; t2 < SK * SK; t2 += 128) {
    int r = t2 / SK, c2 = t2 % SK;
    float v = AAt[t2];
    if (r == c2) v += LAMBDA_ * Dm[(size_t)i * SK + r];
    Ms[t2] = v;
  }
  if (threadIdx.x < SK) xs[threadIdx.x] = BAt[(size_t)i * SK + threadIdx.x];
  __syncthreads();
  for (int k = 0; k < SK; k++) {
    if (threadIdx.x == 0) Ms[k * SK + k] = sqrtf(fmaxf(Ms[k * SK + k], 1e-20f));
    __syncthreads();
    float dk = Ms[k * SK + k];
    for (int r = k + 1 + threadIdx.x; r < SK; r += 128) Ms[r * SK + k] /= dk;
    __syncthreads();
    int rem = SK - k - 1;
    for (int t2 = threadIdx.x; t2 < rem * rem; t2 += 128) {
      int r = k + 1 + t2 / rem, c2 = k + 1 + t2 % rem;
      Ms[r * SK + c2] -= Ms[r * SK + k] * Ms[c2 * SK + k];
    }
    __syncthreads();
  }
  for (int k = 0; k < SK; k++) {
    if (threadIdx.x == 0) xs[k] /= Ms[k * SK + k];
    __syncthreads();
    float xv = xs[k];
    for (int r = k + 1 + threadIdx.x; r < SK; r += 128) xs[r] -= Ms[r * SK + k] * xv;
    __syncthreads();
  }
  for (int k = SK - 1; k >= 0; k--) {
    if (threadIdx.x == 0) xs[k] /= Ms[k * SK + k];
    __syncthreads();
    float xv = xs[k];
    for (int r = threadIdx.x; r < k; r += 128) xs[r] -= Ms[k * SK + r] * xv;
    __syncthreads();
  }
  for (int t2 = threadIdx.x; t2 < SK; t2 += 128) Cout[(size_t)i * SK + t2] = xs[t2];
}

// ---------- loss partials (deterministic) ----------
__global__ void k_frob_iden(const float* __restrict__ Mat, double* __restrict__ lpart, int slot) {
  __shared__ double red[256];
  double s = 0.0;
  for (int t2 = blockIdx.x * 256 + threadIdx.x; t2 < SK * SK; t2 += 32 * 256) {
    float v = Mat[t2] - ((t2 / SK == t2 % SK) ? 1.f : 0.f);
    s += (double)v * (double)v;
  }
  red[threadIdx.x] = s; __syncthreads();
  for (int o = 128; o > 0; o >>= 1) { if (threadIdx.x < o) red[threadIdx.x] += red[threadIdx.x + o]; __syncthreads(); }
  if (threadIdx.x == 0) lpart[slot * 32 + blockIdx.x] = red[0];
}
__global__ void k_lap(const float* __restrict__ Cm, const float* __restrict__ evc,
                      const float* __restrict__ evr, double* __restrict__ lpart, int slot) {
  __shared__ double red[256];
  double s = 0.0;
  for (int t2 = blockIdx.x * 256 + threadIdx.x; t2 < SK * SK; t2 += 32 * 256) {
    int i = t2 / SK, j = t2 % SK;
    float v = Cm[t2] * (evc[j] - evr[i]);
    s += (double)v * (double)v;
  }
  red[threadIdx.x] = s; __syncthreads();
  for (int o = 128; o > 0; o >>= 1) { if (threadIdx.x < o) red[threadIdx.x] += red[threadIdx.x + o]; __syncthreads(); }
  if (threadIdx.x == 0) lpart[slot * 32 + blockIdx.x] = red[0];
}
__global__ void k_writeout(const double* __restrict__ lpart, float* __restrict__ out) {
  if (threadIdx.x == 0) {
    double b = 0.0, o = 0.0, l = 0.0;
    for (int s = 0; s < 64; s++) b += lpart[s];
    for (int s = 64; s < 128; s++) o += lpart[s];
    for (int s = 128; s < 192; s++) l += lpart[s];
    out[0] = (float)b; out[1] = (float)o; out[2] = (float)l;
  }
}

extern "C" void kernel_launch(void* const* d_in, const int* in_sizes, int n_in,
                              void* d_out, int out_size, void* d_ws, size_t ws_size,
                              hipStream_t stream) {
  const float* feats[2] = {(const float*)d_in[0], (const float*)d_in[1]};
  char* p = (char*)d_ws;
  auto alloc = [&](size_t bytes) -> void* {
    char* r = p;
    p += (bytes + 255) & ~(size_t)255;
    return (void*)r;
  };
  float* pan   = (float*)alloc(sizeof(float) * 256 * NN);
  float* sq    = (float*)alloc(sizeof(float) * NN);
  int*   idx   = (int*)alloc(sizeof(int) * (size_t)NN * KK);
  float* dkv   = (float*)alloc(sizeof(float) * (size_t)NN * KK);
  float* wv    = (float*)alloc(sizeof(float) * (size_t)NN * KK);
  float* wadjr = (float*)alloc(sizeof(float) * (size_t)NN * KK);
  float* wadjt = (float*)alloc(sizeof(float) * (size_t)NN * KK);
  int*   cnt   = (int*)alloc(sizeof(int) * NN);
  int*   roff  = (int*)alloc(sizeof(int) * (NN + 1));
  int*   rpos  = (int*)alloc(sizeof(int) * NN);
  int*   tsrc  = (int*)alloc(sizeof(int) * (size_t)NN * KK);
  int*   tcol  = (int*)alloc(sizeof(int) * (size_t)NN * KK);
  float* deg   = (float*)alloc(sizeof(float) * NN);
  float* Q     = (float*)alloc(sizeof(float) * (size_t)LM * NN);
  float* yv0   = (float*)alloc(sizeof(float) * NN);
  float* yv1   = (float*)alloc(sizeof(float) * NN);
  float* cv    = (float*)alloc(sizeof(float) * LM);
  double* part = (double*)alloc(sizeof(double) * 256);
  double* scal = (double*)alloc(sizeof(double) * 8);
  double* Ta   = (double*)alloc(sizeof(double) * LM);
  double* Tb   = (double*)alloc(sizeof(double) * LM);
  double* theta= (double*)alloc(sizeof(double) * SK);
  double* dws  = (double*)alloc(sizeof(double) * (size_t)LM * SK);
  double* ews  = (double*)alloc(sizeof(double) * (size_t)LM * SK);
  double* fws  = (double*)alloc(sizeof(double) * (size_t)LM * SK);
  double* rws  = (double*)alloc(sizeof(double) * (size_t)LM * SK);
  float* Ym    = (float*)alloc(sizeof(float) * (size_t)LM * SK);
  float* U0    = (float*)alloc(sizeof(float) * (size_t)NN * SK);
  float* U1    = (float*)alloc(sizeof(float) * (size_t)NN * SK);
  float* ev0   = (float*)alloc(sizeof(float) * SK);
  float* ev1   = (float*)alloc(sizeof(float) * SK);
  float* Ac    = (float*)alloc(sizeof(float) * (size_t)SK * NC);
  float* Bc    = (float*)alloc(sizeof(float) * (size_t)SK * NC);
  float* AAt   = (float*)alloc(sizeof(float) * SK * SK);
  float* BAt   = (float*)alloc(sizeof(float) * SK * SK);
  float* Dm    = (float*)alloc(sizeof(float) * SK * SK);
  float* Cxy   = (float*)alloc(sizeof(float) * SK * SK);
  float* Cyx   = (float*)alloc(sizeof(float) * SK * SK);
  float* P1    = (float*)alloc(sizeof(float) * SK * SK);
  float* Msg   = (float*)alloc(sizeof(float) * (size_t)SK * SK * SK);
  double* lpart= (double*)alloc(sizeof(double) * 192);
  unsigned* sy = (unsigned*)alloc(sizeof(unsigned) * 1024);

  float* Us[2] = {U0, U1};
  float* evs[2] = {ev0, ev1};

  for (int s2 = 0; s2 < 2; s2++) {
    const float* f = feats[s2];
    k_sqnorm<<<NN, 256, 0, stream>>>(f, sq);
    for (int p2 = 0; p2 < 16; p2++) {
      k_d2panel<<<dim3(64, 4), 256, 0, stream>>>(f, sq, pan, p2 * 256);
      k_topk<<<256, 256, 0, stream>>>(pan, p2 * 256, idx, dkv);
    }
    k_partsum<<<64, 256, 0, stream>>>(dkv, part);
    k_sigma<<<1, 64, 0, stream>>>(part, scal);
    k_wexp<<<NN * KK / 256, 256, 0, stream>>>(dkv, scal, wv);
    // deterministic CSR transpose
    hipMemsetAsync(cnt, 0, sizeof(int) * NN, stream);
    k_count<<<NN * KK / 256, 256, 0, stream>>>(idx, cnt);
    k_scan<<<1, 1024, 0, stream>>>(cnt, roff, rpos);
    k_place<<<16, 256, 0, stream>>>(idx, rpos, tsrc);
    k_sortb<<<16, 256, 0, stream>>>(roff, tsrc);
    k_deg<<<16, 256, 0, stream>>>(wv, roff, tsrc, deg);
    k_wadj2<<<16, 256, 0, stream>>>(wv, idx, roff, tsrc, deg, wadjr, wadjt, tcol);
    // fused cooperative Lanczos (full CGS2), 1024 threads/block, tree barrier
    hipMemsetAsync(sy, 0, sizeof(unsigned) * 1024, stream);
    {
      u32 seed = 1234567u + (u32)s2 * 77777u;
      void* args[] = {(void*)&Q, (void*)&yv0, (void*)&yv1, (void*)&wadjr, (void*)&idx,
                      (void*)&wadjt, (void*)&tcol, (void*)&roff,
                      (void*)&cv, (void*)&part, (void*)&Ta, (void*)&Tb,
                      (void*)&sy, (void*)&seed};
      hipLaunchCooperativeKernel((const void*)k_lanczos, dim3(NBLK), dim3(1024), args, 0, stream);
    }
    k_bisect<<<1, 128, 0, stream>>>(Ta, Tb, theta, evs[s2]);
    k_invit<<<1, 128, 0, stream>>>(Ta, Tb, theta, dws, ews, fws, rws, Ym);
    k_mgsY<<<1, 256, 0, stream>>>(Ym);
    k_gemm_tn<<<dim3(NN / 64, SK / 64), 256, 0, stream>>>(Q, Ym, Us[s2], NN, SK, LM);
  }

  // spectral coefficients
  k_gemm_tn<<<dim3(SK / 64, NC / 64), 256, 0, stream>>>(U0, feats[0], Ac, SK, NC, NN);
  k_gemm_tn<<<dim3(SK / 64, NC / 64), 256, 0, stream>>>(U1, feats[1], Bc, SK, NC, NN);
  k_smax<<<1, 128, 0, stream>>>(ev0, ev1, scal);

  // Cxy: x = v(0), y = t(1)
  k_gemm_nt<<<dim3(2, 2), 256, 0, stream>>>(Ac, Ac, AAt, SK, SK, NC);
  k_gemm_nt<<<dim3(2, 2), 256, 0, stream>>>(Bc, Ac, BAt, SK, SK, NC);
  k_mask<<<64, 256, 0, stream>>>(ev1, ev0, scal, Dm);
  k_cholsolve<<<SK, 128, 0, stream>>>(AAt, BAt, Dm, Msg, Cxy);
  // Cyx: x = t(1), y = v(0)
  k_gemm_nt<<<dim3(2, 2), 256, 0, stream>>>(Bc, Bc, AAt, SK, SK, NC);
  k_gemm_nt<<<dim3(2, 2), 256, 0, stream>>>(Ac, Bc, BAt, SK, SK, NC);
  k_mask<<<64, 256, 0, stream>>>(ev0, ev1, scal, Dm);
  k_cholsolve<<<SK, 128, 0, stream>>>(AAt, BAt, Dm, Msg, Cyx);

  // losses
  k_gemm_nn<<<dim3(2, 2), 256, 0, stream>>>(Cxy, Cyx, P1, SK, SK, SK);
  k_frob_iden<<<32, 256, 0, stream>>>(P1, lpart, 0);
  k_gemm_nn<<<dim3(2, 2), 256, 0, stream>>>(Cyx, Cxy, P1, SK, SK, SK);
  k_frob_iden<<<32, 256, 0, stream>>>(P1, lpart, 1);
  k_gemm_tn<<<dim3(2, 2), 256, 0, stream>>>(Cxy, Cxy, P1, SK, SK, SK);
  k_frob_iden<<<32, 256, 0, stream>>>(P1, lpart, 2);
  k_gemm_tn<<<dim3(2, 2), 256, 0, stream>>>(Cyx, Cyx, P1, SK, SK, SK);
  k_frob_iden<<<32, 256, 0, stream>>>(P1, lpart, 3);
  k_lap<<<32, 256, 0, stream>>>(Cxy, ev0, ev1, lpart, 4);
  k_lap<<<32, 256, 0, stream>>>(Cyx, ev1, ev0, lpart, 5);
  k_writeout<<<1, 64, 0, stream>>>(lpart, (float*)d_out);
}

// Round 7
// 133485.669 us; speedup vs baseline: 6.0488x; 1.7691x over previous
//
#include <hip/hip_runtime.h>
#include <math.h>

#define NN 4096      // points
#define NC 768       // feature dim
#define KK 16        // knn k
#define SK 128       // spectral basis size
#define LM 1024      // Lanczos steps
#define LAMBDA_ 100.0f

typedef unsigned int u32;

__device__ __forceinline__ float hashf(u32 x) {
  x ^= x >> 16; x *= 0x7feb352dU; x ^= x >> 15; x *= 0x846ca68bU; x ^= x >> 16;
  return ((float)x) * (1.0f / 4294967296.0f);  // [0,1)
}

// ---- agent-scope (device-coherent) access helpers ----
__device__ __forceinline__ float agld(const float* p) {
  return __hip_atomic_load((float*)p, __ATOMIC_RELAXED, __HIP_MEMORY_SCOPE_AGENT);
}
__device__ __forceinline__ void agst(float* p, float v) {
  __hip_atomic_store(p, v, __ATOMIC_RELAXED, __HIP_MEMORY_SCOPE_AGENT);
}
__device__ __forceinline__ double agldd(const double* p) {
  return __hip_atomic_load((double*)p, __ATOMIC_RELAXED, __HIP_MEMORY_SCOPE_AGENT);
}
__device__ __forceinline__ void agstd(double* p, double v) {
  __hip_atomic_store(p, v, __ATOMIC_RELAXED, __HIP_MEMORY_SCOPE_AGENT);
}

// ---- per-side two-level tree barrier (128 blocks: 8 groups x 16) ----
// syb layout (u32): [grp*16] group counters, [144] top counter, [256+grp*16] flags.
__device__ __forceinline__ void gbar2(unsigned* syb, int lb, unsigned gph) {
  asm volatile("s_waitcnt vmcnt(0)" ::: "memory");
  __syncthreads();
  if (threadIdx.x == 0) {
    const int grp = lb >> 4, mem = lb & 15;
    unsigned* gc  = syb + grp * 16;
    unsigned* top = syb + 144;
    unsigned* fl  = syb + 256 + grp * 16;
    __hip_atomic_fetch_add(gc, 1u, __ATOMIC_RELEASE, __HIP_MEMORY_SCOPE_AGENT);
    if (mem == 0) {
      while (__hip_atomic_load(gc, __ATOMIC_RELAXED, __HIP_MEMORY_SCOPE_AGENT) < gph * 16u)
        __builtin_amdgcn_s_sleep(2);
      __hip_atomic_fetch_add(top, 1u, __ATOMIC_RELEASE, __HIP_MEMORY_SCOPE_AGENT);
      while (__hip_atomic_load(top, __ATOMIC_RELAXED, __HIP_MEMORY_SCOPE_AGENT) < gph * 8u)
        __builtin_amdgcn_s_sleep(2);
      __hip_atomic_store(fl, gph, __ATOMIC_RELEASE, __HIP_MEMORY_SCOPE_AGENT);
    } else {
      while (__hip_atomic_load(fl, __ATOMIC_RELAXED, __HIP_MEMORY_SCOPE_AGENT) < gph)
        __builtin_amdgcn_s_sleep(2);
    }
    __builtin_amdgcn_fence(__ATOMIC_ACQUIRE, "agent");
  }
  __syncthreads();
}

// ---------- row squared norms ----------
__global__ void k_sqnorm(const float* __restrict__ f, float* __restrict__ sq) {
  __shared__ float red[256];
  int i = blockIdx.x;
  float s = 0.f;
  for (int c = threadIdx.x; c < NC; c += 256) { float v = f[(size_t)i * NC + c]; s += v * v; }
  red[threadIdx.x] = s; __syncthreads();
  for (int o = 128; o > 0; o >>= 1) { if (threadIdx.x < o) red[threadIdx.x] += red[threadIdx.x + o]; __syncthreads(); }
  if (threadIdx.x == 0) sq[i] = red[0];
}

// ---------- d2 panel ----------
__global__ void __launch_bounds__(256) k_d2panel(const float* __restrict__ f, const float* __restrict__ sq,
                                                 float* __restrict__ pan, int i0) {
  __shared__ float As[16][65], Bs[16][65];
  int bj = blockIdx.x, bi = blockIdx.y;
  int row0 = i0 + bi * 64, col0 = bj * 64;
  int tx = threadIdx.x & 15, ty = threadIdx.x >> 4;
  float acc[4][4] = {};
  for (int k0 = 0; k0 < NC; k0 += 16) {
    for (int t2 = threadIdx.x; t2 < 1024; t2 += 256) {
      int kk = t2 & 15, rr = t2 >> 4;
      As[kk][rr] = f[(size_t)(row0 + rr) * NC + k0 + kk];
      Bs[kk][rr] = f[(size_t)(col0 + rr) * NC + k0 + kk];
    }
    __syncthreads();
#pragma unroll
    for (int kk = 0; kk < 16; kk++) {
      float av[4], bv[4];
#pragma unroll
      for (int a = 0; a < 4; a++) av[a] = As[kk][ty * 4 + a];
#pragma unroll
      for (int b = 0; b < 4; b++) bv[b] = Bs[kk][tx * 4 + b];
#pragma unroll
      for (int a = 0; a < 4; a++)
#pragma unroll
        for (int b = 0; b < 4; b++) acc[a][b] += av[a] * bv[b];
    }
    __syncthreads();
  }
#pragma unroll
  for (int a = 0; a < 4; a++) {
    int gr = row0 + ty * 4 + a;
    int pr = bi * 64 + ty * 4 + a;
    float sr = sq[gr];
#pragma unroll
    for (int b = 0; b < 4; b++) {
      int gc = col0 + tx * 4 + b;
      float v = sr + sq[gc] - 2.f * acc[a][b];
      v = fmaxf(v, 0.f);
      if (gr == gc) v += 1e10f;
      pan[(size_t)pr * NN + gc] = v;
    }
  }
}

// ---------- top-16 smallest per row ----------
__global__ void __launch_bounds__(256) k_topk(const float* __restrict__ pan, int i0,
                                              int* __restrict__ idx, float* __restrict__ dkv) {
  __shared__ float vals[NN];
  __shared__ float rv[256];
  __shared__ int ri[256];
  int r = blockIdx.x;
  const float* row = pan + (size_t)r * NN;
  for (int j = threadIdx.x; j < NN; j += 256) vals[j] = row[j];
  __syncthreads();
  for (int t3 = 0; t3 < KK; t3++) {
    float bv = 1e30f; int bi2 = NN;
    for (int j2 = threadIdx.x; j2 < NN; j2 += 256) {
      float v = vals[j2];
      if (v < bv || (v == bv && j2 < bi2)) { bv = v; bi2 = j2; }
    }
    rv[threadIdx.x] = bv; ri[threadIdx.x] = bi2;
    __syncthreads();
    for (int o = 128; o > 0; o >>= 1) {
      if (threadIdx.x < o) {
        float v2 = rv[threadIdx.x + o]; int i2 = ri[threadIdx.x + o];
        if (v2 < rv[threadIdx.x] || (v2 == rv[threadIdx.x] && i2 < ri[threadIdx.x])) {
          rv[threadIdx.x] = v2; ri[threadIdx.x] = i2;
        }
      }
      __syncthreads();
    }
    if (threadIdx.x == 0) {
      idx[(size_t)(i0 + r) * KK + t3] = ri[0];
      dkv[(size_t)(i0 + r) * KK + t3] = rv[0];
      vals[ri[0]] = 1e30f;
    }
    __syncthreads();
  }
}

// ---------- sigma2 ----------
__global__ void k_partsum(const float* __restrict__ dkv, double* __restrict__ part) {
  __shared__ double red[256];
  double s = 0.0;
  for (int t2 = blockIdx.x * 256 + threadIdx.x; t2 < NN * KK; t2 += 64 * 256) s += (double)dkv[t2];
  red[threadIdx.x] = s; __syncthreads();
  for (int o = 128; o > 0; o >>= 1) { if (threadIdx.x < o) red[threadIdx.x] += red[threadIdx.x + o]; __syncthreads(); }
  if (threadIdx.x == 0) part[blockIdx.x] = red[0];
}
__global__ void k_sigma(const double* __restrict__ part, double* __restrict__ scal) {
  __shared__ double red[64];
  red[threadIdx.x] = part[threadIdx.x]; __syncthreads();
  for (int o = 32; o > 0; o >>= 1) { if (threadIdx.x < o) red[threadIdx.x] += red[threadIdx.x + o]; __syncthreads(); }
  if (threadIdx.x == 0) scal[0] = red[0] / (double)(NN * KK) + 1e-12;
}

// ---------- gaussian weights ----------
__global__ void k_wexp(const float* __restrict__ dkv, const double* __restrict__ scal,
                       float* __restrict__ wv) {
  int t = blockIdx.x * 256 + threadIdx.x;
  if (t >= NN * KK) return;
  float inv2s = (float)(0.5 / scal[0]);
  wv[t] = expf(-dkv[t] * inv2s);
}

// ---------- deterministic CSR transpose: counting-sort (no per-bucket sort) ----------
__global__ void k_count(const int* __restrict__ idx, int* __restrict__ cnt) {
  int t = blockIdx.x * 256 + threadIdx.x;
  if (t < NN * KK) atomicAdd(&cnt[idx[t]], 1);
}

__global__ void __launch_bounds__(1024) k_scan(const int* __restrict__ cnt,
                                               int* __restrict__ roff, int* __restrict__ rpos) {
  __shared__ int buf[1024];
  int t = threadIdx.x;
  int v[4]; int s = 0;
#pragma unroll
  for (int u = 0; u < 4; u++) { v[u] = cnt[t * 4 + u]; s += v[u]; }
  buf[t] = s; __syncthreads();
  for (int o = 1; o < 1024; o <<= 1) {
    int x = (t >= o) ? buf[t - o] : 0;
    __syncthreads();
    buf[t] += x;
    __syncthreads();
  }
  int run = (t == 0) ? 0 : buf[t - 1];
#pragma unroll
  for (int u = 0; u < 4; u++) { roff[t * 4 + u] = run; rpos[t * 4 + u] = run; run += v[u]; }
  if (t == 1023) roff[NN] = run;
}

// chunk c = edges [c*256,(c+1)*256); hist[c][j] counts (int atomics: order-invariant)
__global__ void k_hist(const int* __restrict__ idx, int* __restrict__ hist) {
  int e = blockIdx.x * 256 + threadIdx.x;
  atomicAdd(&hist[(e >> 8) * NN + idx[e]], 1);
}
// base[c][j] = roff[j] + sum_{c'<c} hist[c'][j]
__global__ void k_colscan(const int* __restrict__ hist, const int* __restrict__ roff,
                          int* __restrict__ baseb) {
  int j = blockIdx.x * 256 + threadIdx.x;
  if (j >= NN) return;
  int run = roff[j];
  for (int c = 0; c < 256; c++) { baseb[c * NN + j] = run; run += hist[c * NN + j]; }
}
// placement: within-chunk rank via LDS scan (stable => ascending e within bucket)
__global__ void __launch_bounds__(256) k_place2(const int* __restrict__ idx,
                                                const int* __restrict__ baseb,
                                                int* __restrict__ tsrc) {
  __shared__ int ish[256];
  int c = blockIdx.x;
  int e = c * 256 + threadIdx.x;
  ish[threadIdx.x] = idx[e];
  __syncthreads();
  int j = ish[threadIdx.x];
  int rank = 0;
  for (int p2 = 0; p2 < threadIdx.x; p2++) rank += (ish[p2] == j) ? 1 : 0;
  tsrc[baseb[c * NN + j] + rank] = e;
}

// ---------- degrees ----------
__global__ void k_deg(const float* __restrict__ wv, const int* __restrict__ roff,
                      const int* __restrict__ tsrc, float* __restrict__ deg) {
  int i = blockIdx.x * 256 + threadIdx.x;
  if (i >= NN) return;
  float s = 0.f;
  for (int l = 0; l < KK; l++) s += wv[(size_t)i * KK + l];
  float s2 = 0.f;
  for (int e = roff[i]; e < roff[i + 1]; e++) s2 += wv[tsrc[e]];
  deg[i] = 0.5f * (s + s2);
}

// ---------- normalized adjacency ----------
__global__ void k_wadj2(const float* __restrict__ wv, const int* __restrict__ idx,
                        const int* __restrict__ roff, const int* __restrict__ tsrc,
                        const float* __restrict__ deg,
                        float* __restrict__ wadjr, float* __restrict__ wadjt,
                        int* __restrict__ tcol) {
  int i = blockIdx.x * 256 + threadIdx.x;
  if (i >= NN) return;
  float di = 1.0f / sqrtf(deg[i] + 1e-8f);
  for (int l = 0; l < KK; l++) {
    int j = idx[(size_t)i * KK + l];
    float dj = 1.0f / sqrtf(deg[j] + 1e-8f);
    wadjr[(size_t)i * KK + l] = 0.5f * wv[(size_t)i * KK + l] * di * dj;
  }
  for (int e = roff[i]; e < roff[i + 1]; e++) {
    int s = tsrc[e];
    int sn = s / KK;
    float dj = 1.0f / sqrtf(deg[sn] + 1e-8f);
    wadjt[e] = 0.5f * wv[s] * di * dj;
    tcol[e] = sn;
  }
}

// ---------- DUAL-SIDE fused cooperative Lanczos ----------
// 256 blocks x 1024 threads; side s = b>>7 (independent), 128 blocks/side,
// each block owns 32 rows. 5 per-side tree barriers per iteration.
__global__ void __launch_bounds__(1024) k_lanczos2(
    float* __restrict__ Q0, float* __restrict__ Q1,
    float* __restrict__ ya0, float* __restrict__ ya1,
    float* __restrict__ yb0, float* __restrict__ yb1,
    const float* __restrict__ wadjr0, const int* __restrict__ idx0,
    const float* __restrict__ wadjt0, const int* __restrict__ tcol0, const int* __restrict__ roff0,
    const float* __restrict__ wadjr1, const int* __restrict__ idx1,
    const float* __restrict__ wadjt1, const int* __restrict__ tcol1, const int* __restrict__ roff1,
    float* __restrict__ cv0, float* __restrict__ cv1, double* __restrict__ part,
    double* __restrict__ Ta0, double* __restrict__ Tb0,
    double* __restrict__ Ta1, double* __restrict__ Tb1,
    unsigned* __restrict__ sy) {
  const int b = blockIdx.x, t = threadIdx.x;
  const int s = b >> 7, lb = b & 127;
  const int n0 = lb * 32;
  const int lane = t & 63, wvid = t >> 6;  // 16 waves
  float* Qs = s ? Q1 : Q0;
  float* ybuf0 = s ? yb0 : ya0;
  float* ybuf1 = s ? yb1 : ya1;
  const float* wadjr = s ? wadjr1 : wadjr0;
  const int* idx = s ? idx1 : idx0;
  const float* wadjt = s ? wadjt1 : wadjt0;
  const int* tcol = s ? tcol1 : tcol0;
  const int* roff = s ? roff1 : roff0;
  float* cvs = s ? cv1 : cv0;
  double* ps = part + s * 128;
  double* Ta = s ? Ta1 : Ta0;
  double* Tb = s ? Tb1 : Tb0;
  unsigned* syb = sy + s * 512;
  u32 seed = 1234567u + (u32)s * 77777u;

  __shared__ float ysh[NN];
  __shared__ float cvsh[LM];
  __shared__ double pd[128];
  __shared__ double wl[16];
  __shared__ float fredu[32][33];
  __shared__ float nyst[32];
  unsigned gph = 0;

  // init residual + norm partial
  if (t < 32) {
    int n = n0 + t;
    agst(&ybuf0[n], hashf((u32)n * 2246822519u + seed) - 0.5f);
  }
  __syncthreads();
  if (t == 0) {
    double ss = 0.0;
    for (int u = 0; u < 32; u++) { double v = (double)agld(&ybuf0[n0 + u]); ss += v * v; }
    agstd(&ps[lb], ss);
  }
  gbar2(syb, lb, ++gph);

  for (int it = 0; it < LM; it++) {
    float* r  = (it & 1) ? ybuf1 : ybuf0;
    float* r2 = (it & 1) ? ybuf0 : ybuf1;

    // ---- norm + q-row write + SpMV (on-the-fly normalize) ----
    if (t < 128) pd[t] = agldd(&ps[t]);
    __syncthreads();
    for (int o = 64; o > 0; o >>= 1) { if (t < o) pd[t] += pd[t + o]; __syncthreads(); }
    double nrm = sqrt(pd[0]);
    if (lb == 0 && t == 0 && it > 0) agstd(&Tb[it - 1], nrm);
    float inv = (float)(1.0 / (nrm > 1e-300 ? nrm : 1e-300));
    if (t < 32) {
      int n = n0 + t;
      agst(&Qs[(size_t)it * NN + n], agld(&r[n]) * inv);
    }
#pragma unroll
    for (int rr = 0; rr < 2; rr++) {
      int n = n0 + wvid + rr * 16;       // 2 rows per wave
      int rb = roff[n], re = roff[n + 1];
      int L = 16 + (re - rb);
      float acc = 0.f;
      for (int i = lane; i < L; i += 64) {
        float w, qv;
        if (i < 16) { w = wadjr[(size_t)n * KK + i]; qv = agld(&r[idx[(size_t)n * KK + i]]) * inv; }
        else        { int e = rb + i - 16; w = wadjt[e]; qv = agld(&r[tcol[e]]) * inv; }
        acc += w * qv;
      }
      for (int o = 32; o > 0; o >>= 1) acc += __shfl_down(acc, o, 64);
      if (lane == 0) agst(&r2[n], acc);
    }
    gbar2(syb, lb, ++gph);

    // ---- CGS2: two (dots, update) passes on r2 ----
#pragma unroll
    for (int pass = 0; pass < 2; pass++) {
      {
        int base2 = t * 4;
        float a0 = agld(&r2[base2]), a1 = agld(&r2[base2 + 1]);
        float a2 = agld(&r2[base2 + 2]), a3 = agld(&r2[base2 + 3]);
        ysh[base2] = a0; ysh[base2 + 1] = a1; ysh[base2 + 2] = a2; ysh[base2 + 3] = a3;
      }
      __syncthreads();
      // dots: rows j = lb + rsel*128 (up to 8)
      {
        float4 yv4 = *(const float4*)&ysh[t * 4];
        double sa[8];
#pragma unroll
        for (int rsel = 0; rsel < 8; rsel++) {
          int j = lb + rsel * 128;
          sa[rsel] = 0.0;
          if (j <= it) {
            float4 q4 = *(const float4*)&Qs[(size_t)j * NN + t * 4];
            double d = (double)q4.x * yv4.x; d += (double)q4.y * yv4.y;
            d += (double)q4.z * yv4.z; d += (double)q4.w * yv4.w;
            sa[rsel] = d;
          }
        }
#pragma unroll
        for (int rsel = 0; rsel < 8; rsel++) {
          int j = lb + rsel * 128;      // block-uniform condition -> safe syncs
          if (j <= it) {
            double sd = sa[rsel];
            for (int o = 32; o > 0; o >>= 1) sd += __shfl_down(sd, o, 64);
            if (lane == 0) wl[wvid] = sd;
            __syncthreads();
            if (t == 0) {
              double tot = 0.0;
              for (int u = 0; u < 16; u++) tot += wl[u];
              agst(&cvs[j], (float)tot);
              if (pass == 0 && j == it) agstd(&Ta[it], tot);
            }
            __syncthreads();
          }
        }
      }
      gbar2(syb, lb, ++gph);
      // update: r2[n0..n0+31] -= sum_j cvs[j]*Q[j][n]
      {
        for (int j2s = t; j2s <= it; j2s += 1024) cvsh[j2s] = agld(&cvs[j2s]);
        __syncthreads();
        int i2 = t & 31, g = t >> 5;     // 32 cols x 32 j-groups
        float s0 = 0.f, s1 = 0.f, s2 = 0.f, s3 = 0.f;
        int j = g;
        for (; j + 96 <= it; j += 128) {
          s0 += cvsh[j]      * Qs[(size_t)j * NN + n0 + i2];
          s1 += cvsh[j + 32] * Qs[(size_t)(j + 32) * NN + n0 + i2];
          s2 += cvsh[j + 64] * Qs[(size_t)(j + 64) * NN + n0 + i2];
          s3 += cvsh[j + 96] * Qs[(size_t)(j + 96) * NN + n0 + i2];
        }
        for (; j <= it; j += 32) s0 += cvsh[j] * Qs[(size_t)j * NN + n0 + i2];
        fredu[g][i2] = (s0 + s1) + (s2 + s3);
        __syncthreads();
        for (int o = 16; o > 0; o >>= 1) {
          if (g < o) fredu[g][i2] += fredu[g + o][i2];
          __syncthreads();
        }
        if (t < 32) {
          int n = n0 + t;
          float ny = agld(&r2[n]) - fredu[0][t];
          agst(&r2[n], ny);
          nyst[t] = ny;
        }
        __syncthreads();
        if (pass == 1 && t == 0) {
          double s2d = 0.0;
          for (int u = 0; u < 32; u++) { double v = (double)nyst[u]; s2d += v * v; }
          agstd(&ps[lb], s2d);
        }
      }
      gbar2(syb, lb, ++gph);
    }
  }
}

// ---------- bisection ----------
__global__ void k_bisect(const double* __restrict__ Ta, const double* __restrict__ Tb,
                         double* __restrict__ theta, float* __restrict__ evL) {
  int j = threadIdx.x;
  if (j >= SK) return;
  int tgt = LM - j;
  double lo = -2.0, hi = 2.0;
  for (int iter = 0; iter < 60; iter++) {
    double mid = 0.5 * (lo + hi);
    int cnt = 0; double q = 1.0;
    for (int k = 0; k < LM; k++) {
      double off = (k > 0) ? Tb[k - 1] * Tb[k - 1] : 0.0;
      q = Ta[k] - mid - off / q;
      if (q < 0.0) cnt++;
      if (fabs(q) < 1e-280) q = -1e-280;
    }
    if (cnt >= tgt) hi = mid; else lo = mid;
  }
  theta[j] = 0.5 * (lo + hi);
  evL[j] = (float)(1.0 - theta[j]);
}

// ---------- inverse iteration ----------
__global__ void k_invit(const double* __restrict__ Ta, const double* __restrict__ Tb,
                        const double* __restrict__ theta,
                        double* __restrict__ dws, double* __restrict__ ews,
                        double* __restrict__ fws, double* __restrict__ rws,
                        float* __restrict__ Ym) {
  int j = threadIdx.x;
  if (j >= SK) return;
  double sig = theta[j];
  for (int k = 0; k < LM; k++)
    rws[(size_t)k * SK + j] = (double)hashf((u32)k * 2654435761u + (u32)j * 40503u + 17u) - 0.5;
  for (int pass = 0; pass < 3; pass++) {
    double dk = Ta[0] - sig;
    double ek = Tb[0];
    double fk = 0.0;
    double rk = rws[j];
    for (int k = 0; k < LM - 1; k++) {
      double bk = Tb[k];
      double dn = Ta[k + 1] - sig;
      double en = (k + 2 < LM) ? Tb[k + 1] : 0.0;
      double rn = rws[(size_t)(k + 1) * SK + j];
      double dd, ee, ff, dk2, ek2, rkeep, rnext;
      if (fabs(dk) >= fabs(bk)) {
        double dsafe = (fabs(dk) > 1e-300) ? dk : 1e-300;
        double m = bk / dsafe;
        dd = dsafe; ee = ek; ff = fk;
        dk2 = dn - m * ek;
        ek2 = en - m * fk;
        rkeep = rk;
        rnext = rn - m * rk;
      } else {
        double m = dk / bk;
        dd = bk; ee = dn; ff = en;
        dk2 = ek - m * dn;
        ek2 = fk - m * en;
        rkeep = rn;
        rnext = rk - m * rn;
      }
      dws[(size_t)k * SK + j] = dd;
      ews[(size_t)k * SK + j] = ee;
      fws[(size_t)k * SK + j] = ff;
      rws[(size_t)k * SK + j] = rkeep;
      rk = rnext; dk = dk2; ek = ek2; fk = 0.0;
    }
    if (fabs(dk) < 1e-300) dk = 1e-300;
    dws[(size_t)(LM - 1) * SK + j] = dk;
    ews[(size_t)(LM - 1) * SK + j] = 0.0;
    fws[(size_t)(LM - 1) * SK + j] = 0.0;
    rws[(size_t)(LM - 1) * SK + j] = rk;
    double y1 = 0.0, y2 = 0.0, nr = 0.0;
    for (int k = LM - 1; k >= 0; k--) {
      double dv = dws[(size_t)k * SK + j];
      double yk = (rws[(size_t)k * SK + j] - ews[(size_t)k * SK + j] * y1 - fws[(size_t)k * SK + j] * y2) / dv;
      rws[(size_t)k * SK + j] = yk;
      y2 = y1; y1 = yk;
      nr += yk * yk;
    }
    double inv = 1.0 / sqrt(nr > 1e-300 ? nr : 1e-300);
    for (int k = 0; k < LM; k++) rws[(size_t)k * SK + j] *= inv;
  }
  for (int k = 0; k < LM; k++) Ym[(size_t)k * SK + j] = (float)rws[(size_t)k * SK + j];
}

// ---------- MGS on Ym columns ----------
__device__ __forceinline__ double wred64(double v) {
  for (int o = 32; o > 0; o >>= 1) v += __shfl_down(v, o, 64);
  return v;
}
__global__ void __launch_bounds__(256) k_mgsY(float* __restrict__ Ym) {
  __shared__ double lds[8];
  int t = threadIdx.x;
  for (int j = 0; j < SK; j++) {
    for (int jj = 0; jj < j; jj++) {
      double s = 0.0;
      for (int k = t; k < LM; k += 256) s += (double)Ym[(size_t)k * SK + jj] * (double)Ym[(size_t)k * SK + j];
      __syncthreads();
      s = wred64(s);
      if ((t & 63) == 0) lds[t >> 6] = s;
      __syncthreads();
      float cf = (float)(lds[0] + lds[1] + lds[2] + lds[3]);
      for (int k = t; k < LM; k += 256) Ym[(size_t)k * SK + j] -= cf * Ym[(size_t)k * SK + jj];
    }
    double s = 0.0;
    __syncthreads();
    for (int k = t; k < LM; k += 256) { double v = (double)Ym[(size_t)k * SK + j]; s += v * v; }
    s = wred64(s);
    if ((t & 63) == 0) lds[t >> 6] = s;
    __syncthreads();
    double nr = lds[0] + lds[1] + lds[2] + lds[3];
    float inv = (float)(1.0 / sqrt(nr > 1e-300 ? nr : 1e-300));
    for (int k = t; k < LM; k += 256) Ym[(size_t)k * SK + j] *= inv;
    __syncthreads();
  }
}

// ---------- generic tiled GEMMs ----------
__global__ void __launch_bounds__(256) k_gemm_tn(const float* __restrict__ A, const float* __restrict__ B,
                                                 float* __restrict__ Cm, int M, int P, int Kd) {
  __shared__ float As[16][65], Bs[16][65];
  int bm = blockIdx.x * 64, bp = blockIdx.y * 64;
  int tx = threadIdx.x & 15, ty = threadIdx.x >> 4;
  float acc[4][4] = {};
  for (int k0 = 0; k0 < Kd; k0 += 16) {
    for (int t2 = threadIdx.x; t2 < 1024; t2 += 256) {
      int mm = t2 & 63, kk = t2 >> 6;
      As[kk][mm] = A[(size_t)(k0 + kk) * M + bm + mm];
      Bs[kk][mm] = B[(size_t)(k0 + kk) * P + bp + mm];
    }
    __syncthreads();
#pragma unroll
    for (int kk = 0; kk < 16; kk++) {
      float av[4], bv[4];
#pragma unroll
      for (int a = 0; a < 4; a++) av[a] = As[kk][ty * 4 + a];
#pragma unroll
      for (int b = 0; b < 4; b++) bv[b] = Bs[kk][tx * 4 + b];
#pragma unroll
      for (int a = 0; a < 4; a++)
#pragma unroll
        for (int b = 0; b < 4; b++) acc[a][b] += av[a] * bv[b];
    }
    __syncthreads();
  }
#pragma unroll
  for (int a = 0; a < 4; a++)
#pragma unroll
    for (int b = 0; b < 4; b++)
      Cm[(size_t)(bm + ty * 4 + a) * P + bp + tx * 4 + b] = acc[a][b];
}

__global__ void __launch_bounds__(256) k_gemm_nt(const float* __restrict__ A, const float* __restrict__ B,
                                                 float* __restrict__ Cm, int M, int P, int Kd) {
  __shared__ float As[16][65], Bs[16][65];
  int bm = blockIdx.x * 64, bp = blockIdx.y * 64;
  int tx = threadIdx.x & 15, ty = threadIdx.x >> 4;
  float acc[4][4] = {};
  for (int k0 = 0; k0 < Kd; k0 += 16) {
    for (int t2 = threadIdx.x; t2 < 1024; t2 += 256) {
      int kk = t2 & 15, mm = t2 >> 4;
      As[kk][mm] = A[(size_t)(bm + mm) * Kd + k0 + kk];
      Bs[kk][mm] = B[(size_t)(bp + mm) * Kd + k0 + kk];
    }
    __syncthreads();
#pragma unroll
    for (int kk = 0; kk < 16; kk++) {
      float av[4], bv[4];
#pragma unroll
      for (int a = 0; a < 4; a++) av[a] = As[kk][ty * 4 + a];
#pragma unroll
      for (int b = 0; b < 4; b++) bv[b] = Bs[kk][tx * 4 + b];
#pragma unroll
      for (int a = 0; a < 4; a++)
#pragma unroll
        for (int b = 0; b < 4; b++) acc[a][b] += av[a] * bv[b];
    }
    __syncthreads();
  }
#pragma unroll
  for (int a = 0; a < 4; a++)
#pragma unroll
    for (int b = 0; b < 4; b++)
      Cm[(size_t)(bm + ty * 4 + a) * P + bp + tx * 4 + b] = acc[a][b];
}

__global__ void __launch_bounds__(256) k_gemm_nn(const float* __restrict__ A, const float* __restrict__ B,
                                                 float* __restrict__ Cm, int M, int P, int Kd) {
  __shared__ float As[16][65], Bs[16][65];
  int bm = blockIdx.x * 64, bp = blockIdx.y * 64;
  int tx = threadIdx.x & 15, ty = threadIdx.x >> 4;
  float acc[4][4] = {};
  for (int k0 = 0; k0 < Kd; k0 += 16) {
    for (int t2 = threadIdx.x; t2 < 1024; t2 += 256) {
      int kk = t2 & 15, mm = t2 >> 4;
      As[kk][mm] = A[(size_t)(bm + mm) * Kd + k0 + kk];
    }
    for (int t2 = threadIdx.x; t2 < 1024; t2 += 256) {
      int mm = t2 & 63, kk = t2 >> 6;
      Bs[kk][mm] = B[(size_t)(k0 + kk) * P + bp + mm];
    }
    __syncthreads();
#pragma unroll
    for (int kk = 0; kk < 16; kk++) {
      float av[4], bv[4];
#pragma unroll
      for (int a = 0; a < 4; a++) av[a] = As[kk][ty * 4 + a];
#pragma unroll
      for (int b = 0; b < 4; b++) bv[b] = Bs[kk][tx * 4 + b];
#pragma unroll
      for (int a = 0; a < 4; a++)
#pragma unroll
        for (int b = 0; b < 4; b++) acc[a][b] += av[a] * bv[b];
    }
    __syncthreads();
  }
#pragma unroll
  for (int a = 0; a < 4; a++)
#pragma unroll
    for (int b = 0; b < 4; b++)
      Cm[(size_t)(bm + ty * 4 + a) * P + bp + tx * 4 + b] = acc[a][b];
}

// ---------- s = max(max ev_a, max ev_b) ----------
__global__ void k_smax(const float* __restrict__ ea, const float* __restrict__ eb, double* __restrict__ scal) {
  __shared__ float red[128];
  int t = threadIdx.x;
  red[t] = fmaxf(ea[t], eb[t]);
  __syncthreads();
  for (int o = 64; o > 0; o >>= 1) { if (t < o) red[t] = fmaxf(red[t], red[t + o]); __syncthreads(); }
  if (t == 0) scal[1] = (double)red[0];
}

// ---------- resolvent mask ----------
__global__ void k_mask(const float* __restrict__ evr, const float* __restrict__ evc,
                       const double* __restrict__ scal, float* __restrict__ Dm) {
  int t = blockIdx.x * 256 + threadIdx.x;
  if (t >= SK * SK) return;
  int i = t / SK, j = t % SK;
  float s = (float)scal[1];
  float g1 = sqrtf(fmaxf(evc[j] / s, 0.f));
  float g2 = sqrtf(fmaxf(evr[i] / s, 0.f));
  float a2 = g2 * g2 + 1.f, a1 = g1 * g1 + 1.f;
  float re = g2 / a2 - g1 / a1;
  float im = 1.f / a2 - 1.f / a1;
  Dm[t] = re * re + im * im;
}

// ---------- per-row Cholesky solve ----------
__global__ void __launch_bounds__(128) k_cholsolve(const float* __restrict__ AAt, const float* __restrict__ BAt,
                                                   const float* __restrict__ Dm, float* __restrict__ Msg,
                                                   float* __restrict__ Cout) {
  __shared__ float xs[SK];
  int i = blockIdx.x;
  float* Ms = Msg + (size_t)i * SK * SK;
  for (int t2 = threadIdx.x; t2 < SK * SK; t2 += 128) {
    int r = t2 / SK, c2 = t2 % SK;
    float v = AAt[t2];
    if (r == c2) v += LAMBDA_ * Dm[(size_t)i * SK + r];
    Ms[t2] = v;
  }
  if (threadIdx.x < SK) xs[threadIdx.x] = BAt[(size_t)i * SK + threadIdx.x];
  __syncthreads();
  for (int k = 0; k < SK; k++) {
    if (threadIdx.x == 0) Ms[k * SK + k] = sqrtf(fmaxf(Ms[k * SK + k], 1e-20f));
    __syncthreads();
    float dk = Ms[k * SK + k];
    for (int r = k + 1 + threadIdx.x; r < SK; r += 128) Ms[r * SK + k] /= dk;
    __syncthreads();
    int rem = SK - k - 1;
    for (int t2 = threadIdx.x; t2 < rem * rem; t2 += 128) {
      int r = k + 1 + t2 / rem, c2 = k + 1 + t2 % rem;
      Ms[r * SK + c2] -= Ms[r * SK + k] * Ms[c2 * SK + k];
    }
    __syncthreads();
  }
  for (int k = 0; k < SK; k++) {
    if (threadIdx.x == 0) xs[k] /= Ms[k * SK + k];
    __syncthreads();
    float xv = xs[k];
    for (int r = k + 1 + threadIdx.x; r < SK; r += 128) xs[r] -= Ms[r * SK + k] * xv;
    __syncthreads();
  }
  for (int k = SK - 1; k >= 0; k--) {
    if (threadIdx.x == 0) xs[k] /= Ms[k * SK + k];
    __syncthreads();
    float xv = xs[k];
    for (int r = threadIdx.x; r < k; r += 128) xs[r] -= Ms[k * SK + r] * xv;
    __syncthreads();
  }
  for (int t2 = threadIdx.x; t2 < SK; t2 += 128) Cout[(size_t)i * SK + t2] = xs[t2];
}

// ---------- loss partials (deterministic) ----------
__global__ void k_frob_iden(const float* __restrict__ Mat, double* __restrict__ lpart, int slot) {
  __shared__ double red[256];
  double s = 0.0;
  for (int t2 = blockIdx.x * 256 + threadIdx.x; t2 < SK * SK; t2 += 32 * 256) {
    float v = Mat[t2] - ((t2 / SK == t2 % SK) ? 1.f : 0.f);
    s += (double)v * (double)v;
  }
  red[threadIdx.x] = s; __syncthreads();
  for (int o = 128; o > 0; o >>= 1) { if (threadIdx.x < o) red[threadIdx.x] += red[threadIdx.x + o]; __syncthreads(); }
  if (threadIdx.x == 0) lpart[slot * 32 + blockIdx.x] = red[0];
}
__global__ void k_lap(const float* __restrict__ Cm, const float* __restrict__ evc,
                      const float* __restrict__ evr, double* __restrict__ lpart, int slot) {
  __shared__ double red[256];
  double s = 0.0;
  for (int t2 = blockIdx.x * 256 + threadIdx.x; t2 < SK * SK; t2 += 32 * 256) {
    int i = t2 / SK, j = t2 % SK;
    float v = Cm[t2] * (evc[j] - evr[i]);
    s += (double)v * (double)v;
  }
  red[threadIdx.x] = s; __syncthreads();
  for (int o = 128; o > 0; o >>= 1) { if (threadIdx.x < o) red[threadIdx.x] += red[threadIdx.x + o]; __syncthreads(); }
  if (threadIdx.x == 0) lpart[slot * 32 + blockIdx.x] = red[0];
}
__global__ void k_writeout(const double* __restrict__ lpart, float* __restrict__ out) {
  if (threadIdx.x == 0) {
    double b = 0.0, o = 0.0, l = 0.0;
    for (int s = 0; s < 64; s++) b += lpart[s];
    for (int s = 64; s < 128; s++) o += lpart[s];
    for (int s = 128; s < 192; s++) l += lpart[s];
    out[0] = (float)b; out[1] = (float)o; out[2] = (float)l;
  }
}

extern "C" void kernel_launch(void* const* d_in, const int* in_sizes, int n_in,
                              void* d_out, int out_size, void* d_ws, size_t ws_size,
                              hipStream_t stream) {
  const float* feats[2] = {(const float*)d_in[0], (const float*)d_in[1]};
  char* p = (char*)d_ws;
  auto alloc = [&](size_t bytes) -> void* {
    char* r = p;
    p += (bytes + 255) & ~(size_t)255;
    return (void*)r;
  };
  float* pan   = (float*)alloc(sizeof(float) * 256 * NN);
  float* sq    = (float*)alloc(sizeof(float) * NN);
  float* dkv   = (float*)alloc(sizeof(float) * (size_t)NN * KK);
  float* wv    = (float*)alloc(sizeof(float) * (size_t)NN * KK);
  int*   cnt   = (int*)alloc(sizeof(int) * NN);
  int*   rpos  = (int*)alloc(sizeof(int) * NN);
  int*   tsrc  = (int*)alloc(sizeof(int) * (size_t)NN * KK);
  float* deg   = (float*)alloc(sizeof(float) * NN);
  int*   hist  = (int*)alloc(sizeof(int) * 256 * NN);
  int*   baseb = (int*)alloc(sizeof(int) * 256 * NN);
  // per-side graph arrays
  int*   idxs[2];  float* wadjrs[2]; float* wadjts[2]; int* tcols[2]; int* roffs[2];
  for (int s = 0; s < 2; s++) {
    idxs[s]   = (int*)alloc(sizeof(int) * (size_t)NN * KK);
    wadjrs[s] = (float*)alloc(sizeof(float) * (size_t)NN * KK);
    wadjts[s] = (float*)alloc(sizeof(float) * (size_t)NN * KK);
    tcols[s]  = (int*)alloc(sizeof(int) * (size_t)NN * KK);
    roffs[s]  = (int*)alloc(sizeof(int) * (NN + 1));
  }
  float* Q0    = (float*)alloc(sizeof(float) * (size_t)LM * NN);
  float* Q1    = (float*)alloc(sizeof(float) * (size_t)LM * NN);
  float* ya0   = (float*)alloc(sizeof(float) * NN);
  float* ya1   = (float*)alloc(sizeof(float) * NN);
  float* yb0   = (float*)alloc(sizeof(float) * NN);
  float* yb1   = (float*)alloc(sizeof(float) * NN);
  float* cv0   = (float*)alloc(sizeof(float) * LM);
  float* cv1   = (float*)alloc(sizeof(float) * LM);
  double* part = (double*)alloc(sizeof(double) * 256);
  double* scal = (double*)alloc(sizeof(double) * 8);
  double* Ta0  = (double*)alloc(sizeof(double) * LM);
  double* Tb0  = (double*)alloc(sizeof(double) * LM);
  double* Ta1  = (double*)alloc(sizeof(double) * LM);
  double* Tb1  = (double*)alloc(sizeof(double) * LM);
  double* theta= (double*)alloc(sizeof(double) * SK);
  double* dws  = (double*)alloc(sizeof(double) * (size_t)LM * SK);
  double* ews  = (double*)alloc(sizeof(double) * (size_t)LM * SK);
  double* fws  = (double*)alloc(sizeof(double) * (size_t)LM * SK);
  double* rws  = (double*)alloc(sizeof(double) * (size_t)LM * SK);
  float* Ym0   = (float*)alloc(sizeof(float) * (size_t)LM * SK);
  float* Ym1   = (float*)alloc(sizeof(float) * (size_t)LM * SK);
  float* U0    = (float*)alloc(sizeof(float) * (size_t)NN * SK);
  float* U1    = (float*)alloc(sizeof(float) * (size_t)NN * SK);
  float* ev0   = (float*)alloc(sizeof(float) * SK);
  float* ev1   = (float*)alloc(sizeof(float) * SK);
  float* Ac    = (float*)alloc(sizeof(float) * (size_t)SK * NC);
  float* Bc    = (float*)alloc(sizeof(float) * (size_t)SK * NC);
  float* AAt   = (float*)alloc(sizeof(float) * SK * SK);
  float* BAt   = (float*)alloc(sizeof(float) * SK * SK);
  float* Dm    = (float*)alloc(sizeof(float) * SK * SK);
  float* Cxy   = (float*)alloc(sizeof(float) * SK * SK);
  float* Cyx   = (float*)alloc(sizeof(float) * SK * SK);
  float* P1    = (float*)alloc(sizeof(float) * SK * SK);
  float* Msg   = (float*)alloc(sizeof(float) * (size_t)SK * SK * SK);
  double* lpart= (double*)alloc(sizeof(double) * 192);
  unsigned* sy = (unsigned*)alloc(sizeof(unsigned) * 1024);

  double* Tas[2] = {Ta0, Ta1};
  double* Tbs[2] = {Tb0, Tb1};
  float* Yms[2] = {Ym0, Ym1};
  float* Qs2[2] = {Q0, Q1};
  float* Us[2] = {U0, U1};
  float* evs[2] = {ev0, ev1};

  // ---- kNN graph construction for both sides ----
  for (int s2 = 0; s2 < 2; s2++) {
    const float* f = feats[s2];
    int* idx = idxs[s2];
    k_sqnorm<<<NN, 256, 0, stream>>>(f, sq);
    for (int p2 = 0; p2 < 16; p2++) {
      k_d2panel<<<dim3(64, 4), 256, 0, stream>>>(f, sq, pan, p2 * 256);
      k_topk<<<256, 256, 0, stream>>>(pan, p2 * 256, idx, dkv);
    }
    k_partsum<<<64, 256, 0, stream>>>(dkv, part);
    k_sigma<<<1, 64, 0, stream>>>(part, scal);
    k_wexp<<<NN * KK / 256, 256, 0, stream>>>(dkv, scal, wv);
    // deterministic counting-sort CSR transpose
    hipMemsetAsync(cnt, 0, sizeof(int) * NN, stream);
    k_count<<<NN * KK / 256, 256, 0, stream>>>(idx, cnt);
    k_scan<<<1, 1024, 0, stream>>>(cnt, roffs[s2], rpos);
    hipMemsetAsync(hist, 0, sizeof(int) * 256 * NN, stream);
    k_hist<<<256, 256, 0, stream>>>(idx, hist);
    k_colscan<<<16, 256, 0, stream>>>(hist, roffs[s2], baseb);
    k_place2<<<256, 256, 0, stream>>>(idx, baseb, tsrc);
    k_deg<<<16, 256, 0, stream>>>(wv, roffs[s2], tsrc, deg);
    k_wadj2<<<16, 256, 0, stream>>>(wv, idx, roffs[s2], tsrc, deg,
                                    wadjrs[s2], wadjts[s2], tcols[s2]);
  }

  // ---- dual-side fused cooperative Lanczos ----
  hipMemsetAsync(sy, 0, sizeof(unsigned) * 1024, stream);
  {
    void* args[] = {(void*)&Q0, (void*)&Q1,
                    (void*)&ya0, (void*)&ya1, (void*)&yb0, (void*)&yb1,
                    (void*)&wadjrs[0], (void*)&idxs[0], (void*)&wadjts[0], (void*)&tcols[0], (void*)&roffs[0],
                    (void*)&wadjrs[1], (void*)&idxs[1], (void*)&wadjts[1], (void*)&tcols[1], (void*)&roffs[1],
                    (void*)&cv0, (void*)&cv1, (void*)&part,
                    (void*)&Ta0, (void*)&Tb0, (void*)&Ta1, (void*)&Tb1,
                    (void*)&sy};
    hipLaunchCooperativeKernel((const void*)k_lanczos2, dim3(256), dim3(1024), args, 0, stream);
  }

  // ---- per-side spectral finish ----
  for (int s2 = 0; s2 < 2; s2++) {
    k_bisect<<<1, 128, 0, stream>>>(Tas[s2], Tbs[s2], theta, evs[s2]);
    k_invit<<<1, 128, 0, stream>>>(Tas[s2], Tbs[s2], theta, dws, ews, fws, rws, Yms[s2]);
    k_mgsY<<<1, 256, 0, stream>>>(Yms[s2]);
    k_gemm_tn<<<dim3(NN / 64, SK / 64), 256, 0, stream>>>(Qs2[s2], Yms[s2], Us[s2], NN, SK, LM);
  }

  // ---- spectral coefficients + FM solves + losses ----
  k_gemm_tn<<<dim3(SK / 64, NC / 64), 256, 0, stream>>>(U0, feats[0], Ac, SK, NC, NN);
  k_gemm_tn<<<dim3(SK / 64, NC / 64), 256, 0, stream>>>(U1, feats[1], Bc, SK, NC, NN);
  k_smax<<<1, 128, 0, stream>>>(ev0, ev1, scal);

  k_gemm_nt<<<dim3(2, 2), 256, 0, stream>>>(Ac, Ac, AAt, SK, SK, NC);
  k_gemm_nt<<<dim3(2, 2), 256, 0, stream>>>(Bc, Ac, BAt, SK, SK, NC);
  k_mask<<<64, 256, 0, stream>>>(ev1, ev0, scal, Dm);
  k_cholsolve<<<SK, 128, 0, stream>>>(AAt, BAt, Dm, Msg, Cxy);
  k_gemm_nt<<<dim3(2, 2), 256, 0, stream>>>(Bc, Bc, AAt, SK, SK, NC);
  k_gemm_nt<<<dim3(2, 2), 256, 0, stream>>>(Ac, Bc, BAt, SK, SK, NC);
  k_mask<<<64, 256, 0, stream>>>(ev0, ev1, scal, Dm);
  k_cholsolve<<<SK, 128, 0, stream>>>(AAt, BAt, Dm, Msg, Cyx);

  k_gemm_nn<<<dim3(2, 2), 256, 0, stream>>>(Cxy, Cyx, P1, SK, SK, SK);
  k_frob_iden<<<32, 256, 0, stream>>>(P1, lpart, 0);
  k_gemm_nn<<<dim3(2, 2), 256, 0, stream>>>(Cyx, Cxy, P1, SK, SK, SK);
  k_frob_iden<<<32, 256, 0, stream>>>(P1, lpart, 1);
  k_gemm_tn<<<dim3(2, 2), 256, 0, stream>>>(Cxy, Cxy, P1, SK, SK, SK);
  k_frob_iden<<<32, 256, 0, stream>>>(P1, lpart, 2);
  k_gemm_tn<<<dim3(2, 2), 256, 0, stream>>>(Cyx, Cyx, P1, SK, SK, SK);
  k_frob_iden<<<32, 256, 0, stream>>>(P1, lpart, 3);
  k_lap<<<32, 256, 0, stream>>>(Cxy, ev0, ev1, lpart, 4);
  k_lap<<<32, 256, 0, stream>>>(Cyx, ev1, ev0, lpart, 5);
  k_writeout<<<1, 64, 0, stream>>>(lpart, (float*)d_out);
}

// Round 8
// 122845.349 us; speedup vs baseline: 6.5727x; 1.0866x over previous
//
#include <hip/hip_runtime.h>
#include <math.h>

#define NN 4096      // points
#define NC 768       // feature dim
#define KK 16        // knn k
#define SK 128       // spectral basis size
#define LM 1024      // Lanczos steps
#define LAMBDA_ 100.0f
// dynamic LDS: slab[LM][32] + ysh[NN] + cvsh[LM]
#define DYNLDS (LM * 32 * 4 + NN * 4 + LM * 4)

typedef unsigned int u32;

__device__ __forceinline__ float hashf(u32 x) {
  x ^= x >> 16; x *= 0x7feb352dU; x ^= x >> 15; x *= 0x846ca68bU; x ^= x >> 16;
  return ((float)x) * (1.0f / 4294967296.0f);  // [0,1)
}

// ---- agent-scope (device-coherent) access helpers ----
__device__ __forceinline__ float agld(const float* p) {
  return __hip_atomic_load((float*)p, __ATOMIC_RELAXED, __HIP_MEMORY_SCOPE_AGENT);
}
__device__ __forceinline__ void agst(float* p, float v) {
  __hip_atomic_store(p, v, __ATOMIC_RELAXED, __HIP_MEMORY_SCOPE_AGENT);
}
__device__ __forceinline__ double agldd(const double* p) {
  return __hip_atomic_load((double*)p, __ATOMIC_RELAXED, __HIP_MEMORY_SCOPE_AGENT);
}
__device__ __forceinline__ void agstd(double* p, double v) {
  __hip_atomic_store(p, v, __ATOMIC_RELAXED, __HIP_MEMORY_SCOPE_AGENT);
}

// ---- per-side two-level tree barrier (128 blocks: 8 groups x 16) ----
__device__ __forceinline__ void gbar2(unsigned* syb, int lb, unsigned gph) {
  asm volatile("s_waitcnt vmcnt(0)" ::: "memory");
  __syncthreads();
  if (threadIdx.x == 0) {
    const int grp = lb >> 4, mem = lb & 15;
    unsigned* gc  = syb + grp * 16;
    unsigned* top = syb + 144;
    unsigned* fl  = syb + 256 + grp * 16;
    __hip_atomic_fetch_add(gc, 1u, __ATOMIC_RELEASE, __HIP_MEMORY_SCOPE_AGENT);
    if (mem == 0) {
      while (__hip_atomic_load(gc, __ATOMIC_RELAXED, __HIP_MEMORY_SCOPE_AGENT) < gph * 16u)
        __builtin_amdgcn_s_sleep(2);
      __hip_atomic_fetch_add(top, 1u, __ATOMIC_RELEASE, __HIP_MEMORY_SCOPE_AGENT);
      while (__hip_atomic_load(top, __ATOMIC_RELAXED, __HIP_MEMORY_SCOPE_AGENT) < gph * 8u)
        __builtin_amdgcn_s_sleep(2);
      __hip_atomic_store(fl, gph, __ATOMIC_RELEASE, __HIP_MEMORY_SCOPE_AGENT);
    } else {
      while (__hip_atomic_load(fl, __ATOMIC_RELAXED, __HIP_MEMORY_SCOPE_AGENT) < gph)
        __builtin_amdgcn_s_sleep(2);
    }
    __builtin_amdgcn_fence(__ATOMIC_ACQUIRE, "agent");
  }
  __syncthreads();
}

// ---------- row squared norms ----------
__global__ void k_sqnorm(const float* __restrict__ f, float* __restrict__ sq) {
  __shared__ float red[256];
  int i = blockIdx.x;
  float s = 0.f;
  for (int c = threadIdx.x; c < NC; c += 256) { float v = f[(size_t)i * NC + c]; s += v * v; }
  red[threadIdx.x] = s; __syncthreads();
  for (int o = 128; o > 0; o >>= 1) { if (threadIdx.x < o) red[threadIdx.x] += red[threadIdx.x + o]; __syncthreads(); }
  if (threadIdx.x == 0) sq[i] = red[0];
}

// ---------- d2 panel ----------
__global__ void __launch_bounds__(256) k_d2panel(const float* __restrict__ f, const float* __restrict__ sq,
                                                 float* __restrict__ pan, int i0) {
  __shared__ float As[16][65], Bs[16][65];
  int bj = blockIdx.x, bi = blockIdx.y;
  int row0 = i0 + bi * 64, col0 = bj * 64;
  int tx = threadIdx.x & 15, ty = threadIdx.x >> 4;
  float acc[4][4] = {};
  for (int k0 = 0; k0 < NC; k0 += 16) {
    for (int t2 = threadIdx.x; t2 < 1024; t2 += 256) {
      int kk = t2 & 15, rr = t2 >> 4;
      As[kk][rr] = f[(size_t)(row0 + rr) * NC + k0 + kk];
      Bs[kk][rr] = f[(size_t)(col0 + rr) * NC + k0 + kk];
    }
    __syncthreads();
#pragma unroll
    for (int kk = 0; kk < 16; kk++) {
      float av[4], bv[4];
#pragma unroll
      for (int a = 0; a < 4; a++) av[a] = As[kk][ty * 4 + a];
#pragma unroll
      for (int b = 0; b < 4; b++) bv[b] = Bs[kk][tx * 4 + b];
#pragma unroll
      for (int a = 0; a < 4; a++)
#pragma unroll
        for (int b = 0; b < 4; b++) acc[a][b] += av[a] * bv[b];
    }
    __syncthreads();
  }
#pragma unroll
  for (int a = 0; a < 4; a++) {
    int gr = row0 + ty * 4 + a;
    int pr = bi * 64 + ty * 4 + a;
    float sr = sq[gr];
#pragma unroll
    for (int b = 0; b < 4; b++) {
      int gc = col0 + tx * 4 + b;
      float v = sr + sq[gc] - 2.f * acc[a][b];
      v = fmaxf(v, 0.f);
      if (gr == gc) v += 1e10f;
      pan[(size_t)pr * NN + gc] = v;
    }
  }
}

// ---------- top-16 smallest per row ----------
__global__ void __launch_bounds__(256) k_topk(const float* __restrict__ pan, int i0,
                                              int* __restrict__ idx, float* __restrict__ dkv) {
  __shared__ float vals[NN];
  __shared__ float rv[256];
  __shared__ int ri[256];
  int r = blockIdx.x;
  const float* row = pan + (size_t)r * NN;
  for (int j = threadIdx.x; j < NN; j += 256) vals[j] = row[j];
  __syncthreads();
  for (int t3 = 0; t3 < KK; t3++) {
    float bv = 1e30f; int bi2 = NN;
    for (int j2 = threadIdx.x; j2 < NN; j2 += 256) {
      float v = vals[j2];
      if (v < bv || (v == bv && j2 < bi2)) { bv = v; bi2 = j2; }
    }
    rv[threadIdx.x] = bv; ri[threadIdx.x] = bi2;
    __syncthreads();
    for (int o = 128; o > 0; o >>= 1) {
      if (threadIdx.x < o) {
        float v2 = rv[threadIdx.x + o]; int i2 = ri[threadIdx.x + o];
        if (v2 < rv[threadIdx.x] || (v2 == rv[threadIdx.x] && i2 < ri[threadIdx.x])) {
          rv[threadIdx.x] = v2; ri[threadIdx.x] = i2;
        }
      }
      __syncthreads();
    }
    if (threadIdx.x == 0) {
      idx[(size_t)(i0 + r) * KK + t3] = ri[0];
      dkv[(size_t)(i0 + r) * KK + t3] = rv[0];
      vals[ri[0]] = 1e30f;
    }
    __syncthreads();
  }
}

// ---------- sigma2 ----------
__global__ void k_partsum(const float* __restrict__ dkv, double* __restrict__ part) {
  __shared__ double red[256];
  double s = 0.0;
  for (int t2 = blockIdx.x * 256 + threadIdx.x; t2 < NN * KK; t2 += 64 * 256) s += (double)dkv[t2];
  red[threadIdx.x] = s; __syncthreads();
  for (int o = 128; o > 0; o >>= 1) { if (threadIdx.x < o) red[threadIdx.x] += red[threadIdx.x + o]; __syncthreads(); }
  if (threadIdx.x == 0) part[blockIdx.x] = red[0];
}
__global__ void k_sigma(const double* __restrict__ part, double* __restrict__ scal) {
  __shared__ double red[64];
  red[threadIdx.x] = part[threadIdx.x]; __syncthreads();
  for (int o = 32; o > 0; o >>= 1) { if (threadIdx.x < o) red[threadIdx.x] += red[threadIdx.x + o]; __syncthreads(); }
  if (threadIdx.x == 0) scal[0] = red[0] / (double)(NN * KK) + 1e-12;
}

// ---------- gaussian weights ----------
__global__ void k_wexp(const float* __restrict__ dkv, const double* __restrict__ scal,
                       float* __restrict__ wv) {
  int t = blockIdx.x * 256 + threadIdx.x;
  if (t >= NN * KK) return;
  float inv2s = (float)(0.5 / scal[0]);
  wv[t] = expf(-dkv[t] * inv2s);
}

// ---------- deterministic CSR transpose: counting-sort ----------
__global__ void k_count(const int* __restrict__ idx, int* __restrict__ cnt) {
  int t = blockIdx.x * 256 + threadIdx.x;
  if (t < NN * KK) atomicAdd(&cnt[idx[t]], 1);
}

__global__ void __launch_bounds__(1024) k_scan(const int* __restrict__ cnt,
                                               int* __restrict__ roff, int* __restrict__ rpos) {
  __shared__ int buf[1024];
  int t = threadIdx.x;
  int v[4]; int s = 0;
#pragma unroll
  for (int u = 0; u < 4; u++) { v[u] = cnt[t * 4 + u]; s += v[u]; }
  buf[t] = s; __syncthreads();
  for (int o = 1; o < 1024; o <<= 1) {
    int x = (t >= o) ? buf[t - o] : 0;
    __syncthreads();
    buf[t] += x;
    __syncthreads();
  }
  int run = (t == 0) ? 0 : buf[t - 1];
#pragma unroll
  for (int u = 0; u < 4; u++) { roff[t * 4 + u] = run; rpos[t * 4 + u] = run; run += v[u]; }
  if (t == 1023) roff[NN] = run;
}

__global__ void k_hist(const int* __restrict__ idx, int* __restrict__ hist) {
  int e = blockIdx.x * 256 + threadIdx.x;
  atomicAdd(&hist[(e >> 8) * NN + idx[e]], 1);
}
__global__ void k_colscan(const int* __restrict__ hist, const int* __restrict__ roff,
                          int* __restrict__ baseb) {
  int j = blockIdx.x * 256 + threadIdx.x;
  if (j >= NN) return;
  int run = roff[j];
  for (int c = 0; c < 256; c++) { baseb[c * NN + j] = run; run += hist[c * NN + j]; }
}
__global__ void __launch_bounds__(256) k_place2(const int* __restrict__ idx,
                                                const int* __restrict__ baseb,
                                                int* __restrict__ tsrc) {
  __shared__ int ish[256];
  int c = blockIdx.x;
  int e = c * 256 + threadIdx.x;
  ish[threadIdx.x] = idx[e];
  __syncthreads();
  int j = ish[threadIdx.x];
  int rank = 0;
  for (int p2 = 0; p2 < threadIdx.x; p2++) rank += (ish[p2] == j) ? 1 : 0;
  tsrc[baseb[c * NN + j] + rank] = e;
}

// ---------- degrees ----------
__global__ void k_deg(const float* __restrict__ wv, const int* __restrict__ roff,
                      const int* __restrict__ tsrc, float* __restrict__ deg) {
  int i = blockIdx.x * 256 + threadIdx.x;
  if (i >= NN) return;
  float s = 0.f;
  for (int l = 0; l < KK; l++) s += wv[(size_t)i * KK + l];
  float s2 = 0.f;
  for (int e = roff[i]; e < roff[i + 1]; e++) s2 += wv[tsrc[e]];
  deg[i] = 0.5f * (s + s2);
}

// ---------- normalized adjacency ----------
__global__ void k_wadj2(const float* __restrict__ wv, const int* __restrict__ idx,
                        const int* __restrict__ roff, const int* __restrict__ tsrc,
                        const float* __restrict__ deg,
                        float* __restrict__ wadjr, float* __restrict__ wadjt,
                        int* __restrict__ tcol) {
  int i = blockIdx.x * 256 + threadIdx.x;
  if (i >= NN) return;
  float di = 1.0f / sqrtf(deg[i] + 1e-8f);
  for (int l = 0; l < KK; l++) {
    int j = idx[(size_t)i * KK + l];
    float dj = 1.0f / sqrtf(deg[j] + 1e-8f);
    wadjr[(size_t)i * KK + l] = 0.5f * wv[(size_t)i * KK + l] * di * dj;
  }
  for (int e = roff[i]; e < roff[i + 1]; e++) {
    int s = tsrc[e];
    int sn = s / KK;
    float dj = 1.0f / sqrtf(deg[sn] + 1e-8f);
    wadjt[e] = 0.5f * wv[s] * di * dj;
    tcol[e] = sn;
  }
}

// ---------- DUAL-SIDE fused cooperative Lanczos, LDS-cached slab ----------
// 256 blocks x 1024 threads; side s = b>>7, 128 blocks/side, 32 rows/block.
// Dynamic LDS: slabsh[LM][32] mirrors Q[j][n0..n0+31] (written by this block),
// ysh[NN] stages the residual each phase, cvsh[LM] stages coefficients.
// Values/summation orders identical to round-7 kernel -> bit-identical output.
__global__ void __launch_bounds__(1024) k_lanczos2(
    float* __restrict__ Q0, float* __restrict__ Q1,
    float* __restrict__ ya0, float* __restrict__ ya1,
    float* __restrict__ yb0, float* __restrict__ yb1,
    const float* __restrict__ wadjr0, const int* __restrict__ idx0,
    const float* __restrict__ wadjt0, const int* __restrict__ tcol0, const int* __restrict__ roff0,
    const float* __restrict__ wadjr1, const int* __restrict__ idx1,
    const float* __restrict__ wadjt1, const int* __restrict__ tcol1, const int* __restrict__ roff1,
    float* __restrict__ cv0, float* __restrict__ cv1, double* __restrict__ part,
    double* __restrict__ Ta0, double* __restrict__ Tb0,
    double* __restrict__ Ta1, double* __restrict__ Tb1,
    unsigned* __restrict__ sy) {
  const int b = blockIdx.x, t = threadIdx.x;
  const int s = b >> 7, lb = b & 127;
  const int n0 = lb * 32;
  const int lane = t & 63, wvid = t >> 6;  // 16 waves
  float* Qs = s ? Q1 : Q0;
  float* ybuf0 = s ? yb0 : ya0;
  float* ybuf1 = s ? yb1 : ya1;
  const float* wadjr = s ? wadjr1 : wadjr0;
  const int* idx = s ? idx1 : idx0;
  const float* wadjt = s ? wadjt1 : wadjt0;
  const int* tcol = s ? tcol1 : tcol0;
  const int* roff = s ? roff1 : roff0;
  float* cvs = s ? cv1 : cv0;
  double* ps = part + s * 128;
  double* Ta = s ? Ta1 : Ta0;
  double* Tb = s ? Tb1 : Tb0;
  unsigned* syb = sy + s * 512;
  u32 seed = 1234567u + (u32)s * 77777u;

  extern __shared__ char dynsh[];
  float* slabsh = (float*)dynsh;                      // [LM][32]
  float* ysh    = (float*)(dynsh + LM * 32 * 4);      // [NN]
  float* cvsh   = (float*)(dynsh + LM * 32 * 4 + NN * 4);  // [LM]
  __shared__ double pd[128];
  __shared__ double wl[16][8];
  __shared__ float fredu[32][33];
  __shared__ float r2loc[32];
  unsigned gph = 0;

  // init residual + norm partial
  if (t < 32) {
    int n = n0 + t;
    agst(&ybuf0[n], hashf((u32)n * 2246822519u + seed) - 0.5f);
  }
  __syncthreads();
  if (t == 0) {
    double ss = 0.0;
    for (int u = 0; u < 32; u++) { double v = (double)agld(&ybuf0[n0 + u]); ss += v * v; }
    agstd(&ps[lb], ss);
  }
  gbar2(syb, lb, ++gph);

  for (int it = 0; it < LM; it++) {
    float* r  = (it & 1) ? ybuf1 : ybuf0;
    float* r2 = (it & 1) ? ybuf0 : ybuf1;

    // ---- Phase A: stage r, norm, q-row write (+slab), SpMV from LDS ----
    {
      int b4 = t * 4;
      float a0 = agld(&r[b4]), a1 = agld(&r[b4 + 1]);
      float a2 = agld(&r[b4 + 2]), a3 = agld(&r[b4 + 3]);
      ysh[b4] = a0; ysh[b4 + 1] = a1; ysh[b4 + 2] = a2; ysh[b4 + 3] = a3;
    }
    if (t < 128) pd[t] = agldd(&ps[t]);
    __syncthreads();
    for (int o = 64; o > 0; o >>= 1) { if (t < o) pd[t] += pd[t + o]; __syncthreads(); }
    double nrm = sqrt(pd[0]);
    if (lb == 0 && t == 0 && it > 0) agstd(&Tb[it - 1], nrm);
    float inv = (float)(1.0 / (nrm > 1e-300 ? nrm : 1e-300));
    if (t < 32) {
      int n = n0 + t;
      float qv = ysh[n] * inv;
      agst(&Qs[(size_t)it * NN + n], qv);
      slabsh[it * 32 + t] = qv;
    }
#pragma unroll
    for (int rr = 0; rr < 2; rr++) {
      int n = n0 + wvid + rr * 16;       // 2 rows per wave
      int rb = roff[n], re = roff[n + 1];
      int L = 16 + (re - rb);
      float acc = 0.f;
      for (int i = lane; i < L; i += 64) {
        float w, qv;
        if (i < 16) { w = wadjr[(size_t)n * KK + i]; qv = ysh[idx[(size_t)n * KK + i]] * inv; }
        else        { int e = rb + i - 16; w = wadjt[e]; qv = ysh[tcol[e]] * inv; }
        acc += w * qv;
      }
      for (int o = 32; o > 0; o >>= 1) acc += __shfl_down(acc, o, 64);
      if (lane == 0) { agst(&r2[n], acc); r2loc[wvid + rr * 16] = acc; }
    }
    gbar2(syb, lb, ++gph);

    // ---- CGS2: two (dots, update) passes on r2 ----
#pragma unroll
    for (int pass = 0; pass < 2; pass++) {
      // stage r2 -> ysh (coalesced agent loads)
      {
        int b4 = t * 4;
        float a0 = agld(&r2[b4]), a1 = agld(&r2[b4 + 1]);
        float a2 = agld(&r2[b4 + 2]), a3 = agld(&r2[b4 + 3]);
        ysh[b4] = a0; ysh[b4 + 1] = a1; ysh[b4 + 2] = a2; ysh[b4 + 3] = a3;
      }
      __syncthreads();
      // dots: rows j = lb + rsel*128 (block-exclusive, L2-resident)
      {
        float4 yv4 = *(const float4*)&ysh[t * 4];
        double sa[8];
#pragma unroll
        for (int rsel = 0; rsel < 8; rsel++) {
          int j = lb + rsel * 128;
          sa[rsel] = 0.0;
          if (j <= it) {
            float4 q4 = *(const float4*)&Qs[(size_t)j * NN + t * 4];
            double d = (double)q4.x * yv4.x; d += (double)q4.y * yv4.y;
            d += (double)q4.z * yv4.z; d += (double)q4.w * yv4.w;
            sa[rsel] = d;
          }
        }
#pragma unroll
        for (int rsel = 0; rsel < 8; rsel++) {
          int j = lb + rsel * 128;
          if (j <= it) {
            double sd = sa[rsel];
            for (int o = 32; o > 0; o >>= 1) sd += __shfl_down(sd, o, 64);
            if (lane == 0) wl[wvid][rsel] = sd;
          }
        }
        __syncthreads();
        if (t < 8) {
          int j = lb + t * 128;
          if (j <= it) {
            double tot = 0.0;
            for (int u = 0; u < 16; u++) tot += wl[u][t];
            agst(&cvs[j], (float)tot);
            if (pass == 0 && j == it) agstd(&Ta[it], tot);
          }
        }
        __syncthreads();
      }
      gbar2(syb, lb, ++gph);
      // update: r2[n0..n0+31] -= sum_j cvs[j]*slab[j][col]  (slab in LDS)
      {
        for (int j2s = t; j2s <= it; j2s += 1024) cvsh[j2s] = agld(&cvs[j2s]);
        __syncthreads();
        int i2 = t & 31, g = t >> 5;     // 32 cols x 32 j-groups
        float s0 = 0.f, s1 = 0.f, s2 = 0.f, s3 = 0.f;
        int j = g;
        for (; j + 96 <= it; j += 128) {
          s0 += cvsh[j]      * slabsh[j * 32 + i2];
          s1 += cvsh[j + 32] * slabsh[(j + 32) * 32 + i2];
          s2 += cvsh[j + 64] * slabsh[(j + 64) * 32 + i2];
          s3 += cvsh[j + 96] * slabsh[(j + 96) * 32 + i2];
        }
        for (; j <= it; j += 32) s0 += cvsh[j] * slabsh[j * 32 + i2];
        fredu[g][i2] = (s0 + s1) + (s2 + s3);
        __syncthreads();
        for (int o = 16; o > 0; o >>= 1) {
          if (g < o) fredu[g][i2] += fredu[g + o][i2];
          __syncthreads();
        }
        if (t < 32) {
          int n = n0 + t;
          float ny = r2loc[t] - fredu[0][t];
          agst(&r2[n], ny);
          r2loc[t] = ny;
        }
        __syncthreads();
        if (pass == 1 && t == 0) {
          double s2d = 0.0;
          for (int u = 0; u < 32; u++) { double v = (double)r2loc[u]; s2d += v * v; }
          agstd(&ps[lb], s2d);
        }
      }
      gbar2(syb, lb, ++gph);
    }
  }
}

// ---------- bisection ----------
__global__ void k_bisect(const double* __restrict__ Ta, const double* __restrict__ Tb,
                         double* __restrict__ theta, float* __restrict__ evL) {
  int j = threadIdx.x;
  if (j >= SK) return;
  int tgt = LM - j;
  double lo = -2.0, hi = 2.0;
  for (int iter = 0; iter < 60; iter++) {
    double mid = 0.5 * (lo + hi);
    int cnt = 0; double q = 1.0;
    for (int k = 0; k < LM; k++) {
      double off = (k > 0) ? Tb[k - 1] * Tb[k - 1] : 0.0;
      q = Ta[k] - mid - off / q;
      if (q < 0.0) cnt++;
      if (fabs(q) < 1e-280) q = -1e-280;
    }
    if (cnt >= tgt) hi = mid; else lo = mid;
  }
  theta[j] = 0.5 * (lo + hi);
  evL[j] = (float)(1.0 - theta[j]);
}

// ---------- inverse iteration ----------
__global__ void k_invit(const double* __restrict__ Ta, const double* __restrict__ Tb,
                        const double* __restrict__ theta,
                        double* __restrict__ dws, double* __restrict__ ews,
                        double* __restrict__ fws, double* __restrict__ rws,
                        float* __restrict__ Ym) {
  int j = threadIdx.x;
  if (j >= SK) return;
  double sig = theta[j];
  for (int k = 0; k < LM; k++)
    rws[(size_t)k * SK + j] = (double)hashf((u32)k * 2654435761u + (u32)j * 40503u + 17u) - 0.5;
  for (int pass = 0; pass < 3; pass++) {
    double dk = Ta[0] - sig;
    double ek = Tb[0];
    double fk = 0.0;
    double rk = rws[j];
    for (int k = 0; k < LM - 1; k++) {
      double bk = Tb[k];
      double dn = Ta[k + 1] - sig;
      double en = (k + 2 < LM) ? Tb[k + 1] : 0.0;
      double rn = rws[(size_t)(k + 1) * SK + j];
      double dd, ee, ff, dk2, ek2, rkeep, rnext;
      if (fabs(dk) >= fabs(bk)) {
        double dsafe = (fabs(dk) > 1e-300) ? dk : 1e-300;
        double m = bk / dsafe;
        dd = dsafe; ee = ek; ff = fk;
        dk2 = dn - m * ek;
        ek2 = en - m * fk;
        rkeep = rk;
        rnext = rn - m * rk;
      } else {
        double m = dk / bk;
        dd = bk; ee = dn; ff = en;
        dk2 = ek - m * dn;
        ek2 = fk - m * en;
        rkeep = rn;
        rnext = rk - m * rn;
      }
      dws[(size_t)k * SK + j] = dd;
      ews[(size_t)k * SK + j] = ee;
      fws[(size_t)k * SK + j] = ff;
      rws[(size_t)k * SK + j] = rkeep;
      rk = rnext; dk = dk2; ek = ek2; fk = 0.0;
    }
    if (fabs(dk) < 1e-300) dk = 1e-300;
    dws[(size_t)(LM - 1) * SK + j] = dk;
    ews[(size_t)(LM - 1) * SK + j] = 0.0;
    fws[(size_t)(LM - 1) * SK + j] = 0.0;
    rws[(size_t)(LM - 1) * SK + j] = rk;
    double y1 = 0.0, y2 = 0.0, nr = 0.0;
    for (int k = LM - 1; k >= 0; k--) {
      double dv = dws[(size_t)k * SK + j];
      double yk = (rws[(size_t)k * SK + j] - ews[(size_t)k * SK + j] * y1 - fws[(size_t)k * SK + j] * y2) / dv;
      rws[(size_t)k * SK + j] = yk;
      y2 = y1; y1 = yk;
      nr += yk * yk;
    }
    double inv = 1.0 / sqrt(nr > 1e-300 ? nr : 1e-300);
    for (int k = 0; k < LM; k++) rws[(size_t)k * SK + j] *= inv;
  }
  for (int k = 0; k < LM; k++) Ym[(size_t)k * SK + j] = (float)rws[(size_t)k * SK + j];
}

// ---------- MGS on Ym columns ----------
__device__ __forceinline__ double wred64(double v) {
  for (int o = 32; o > 0; o >>= 1) v += __shfl_down(v, o, 64);
  return v;
}
__global__ void __launch_bounds__(256) k_mgsY(float* __restrict__ Ym) {
  __shared__ double lds[8];
  int t = threadIdx.x;
  for (int j = 0; j < SK; j++) {
    for (int jj = 0; jj < j; jj++) {
      double s = 0.0;
      for (int k = t; k < LM; k += 256) s += (double)Ym[(size_t)k * SK + jj] * (double)Ym[(size_t)k * SK + j];
      __syncthreads();
      s = wred64(s);
      if ((t & 63) == 0) lds[t >> 6] = s;
      __syncthreads();
      float cf = (float)(lds[0] + lds[1] + lds[2] + lds[3]);
      for (int k = t; k < LM; k += 256) Ym[(size_t)k * SK + j] -= cf * Ym[(size_t)k * SK + jj];
    }
    double s = 0.0;
    __syncthreads();
    for (int k = t; k < LM; k += 256) { double v = (double)Ym[(size_t)k * SK + j]; s += v * v; }
    s = wred64(s);
    if ((t & 63) == 0) lds[t >> 6] = s;
    __syncthreads();
    double nr = lds[0] + lds[1] + lds[2] + lds[3];
    float inv = (float)(1.0 / sqrt(nr > 1e-300 ? nr : 1e-300));
    for (int k = t; k < LM; k += 256) Ym[(size_t)k * SK + j] *= inv;
    __syncthreads();
  }
}

// ---------- generic tiled GEMMs ----------
__global__ void __launch_bounds__(256) k_gemm_tn(const float* __restrict__ A, const float* __restrict__ B,
                                                 float* __restrict__ Cm, int M, int P, int Kd) {
  __shared__ float As[16][65], Bs[16][65];
  int bm = blockIdx.x * 64, bp = blockIdx.y * 64;
  int tx = threadIdx.x & 15, ty = threadIdx.x >> 4;
  float acc[4][4] = {};
  for (int k0 = 0; k0 < Kd; k0 += 16) {
    for (int t2 = threadIdx.x; t2 < 1024; t2 += 256) {
      int mm = t2 & 63, kk = t2 >> 6;
      As[kk][mm] = A[(size_t)(k0 + kk) * M + bm + mm];
      Bs[kk][mm] = B[(size_t)(k0 + kk) * P + bp + mm];
    }
    __syncthreads();
#pragma unroll
    for (int kk = 0; kk < 16; kk++) {
      float av[4], bv[4];
#pragma unroll
      for (int a = 0; a < 4; a++) av[a] = As[kk][ty * 4 + a];
#pragma unroll
      for (int b = 0; b < 4; b++) bv[b] = Bs[kk][tx * 4 + b];
#pragma unroll
      for (int a = 0; a < 4; a++)
#pragma unroll
        for (int b = 0; b < 4; b++) acc[a][b] += av[a] * bv[b];
    }
    __syncthreads();
  }
#pragma unroll
  for (int a = 0; a < 4; a++)
#pragma unroll
    for (int b = 0; b < 4; b++)
      Cm[(size_t)(bm + ty * 4 + a) * P + bp + tx * 4 + b] = acc[a][b];
}

__global__ void __launch_bounds__(256) k_gemm_nt(const float* __restrict__ A, const float* __restrict__ B,
                                                 float* __restrict__ Cm, int M, int P, int Kd) {
  __shared__ float As[16][65], Bs[16][65];
  int bm = blockIdx.x * 64, bp = blockIdx.y * 64;
  int tx = threadIdx.x & 15, ty = threadIdx.x >> 4;
  float acc[4][4] = {};
  for (int k0 = 0; k0 < Kd; k0 += 16) {
    for (int t2 = threadIdx.x; t2 < 1024; t2 += 256) {
      int kk = t2 & 15, mm = t2 >> 4;
      As[kk][mm] = A[(size_t)(bm + mm) * Kd + k0 + kk];
      Bs[kk][mm] = B[(size_t)(bp + mm) * Kd + k0 + kk];
    }
    __syncthreads();
#pragma unroll
    for (int kk = 0; kk < 16; kk++) {
      float av[4], bv[4];
#pragma unroll
      for (int a = 0; a < 4; a++) av[a] = As[kk][ty * 4 + a];
#pragma unroll
      for (int b = 0; b < 4; b++) bv[b] = Bs[kk][tx * 4 + b];
#pragma unroll
      for (int a = 0; a < 4; a++)
#pragma unroll
        for (int b = 0; b < 4; b++) acc[a][b] += av[a] * bv[b];
    }
    __syncthreads();
  }
#pragma unroll
  for (int a = 0; a < 4; a++)
#pragma unroll
    for (int b = 0; b < 4; b++)
      Cm[(size_t)(bm + ty * 4 + a) * P + bp + tx * 4 + b] = acc[a][b];
}

__global__ void __launch_bounds__(256) k_gemm_nn(const float* __restrict__ A, const float* __restrict__ B,
                                                 float* __restrict__ Cm, int M, int P, int Kd) {
  __shared__ float As[16][65], Bs[16][65];
  int bm = blockIdx.x * 64, bp = blockIdx.y * 64;
  int tx = threadIdx.x & 15, ty = threadIdx.x >> 4;
  float acc[4][4] = {};
  for (int k0 = 0; k0 < Kd; k0 += 16) {
    for (int t2 = threadIdx.x; t2 < 1024; t2 += 256) {
      int kk = t2 & 15, mm = t2 >> 4;
      As[kk][mm] = A[(size_t)(bm + mm) * Kd + k0 + kk];
    }
    for (int t2 = threadIdx.x; t2 < 1024; t2 += 256) {
      int mm = t2 & 63, kk = t2 >> 6;
      Bs[kk][mm] = B[(size_t)(k0 + kk) * P + bp + mm];
    }
    __syncthreads();
#pragma unroll
    for (int kk = 0; kk < 16; kk++) {
      float av[4], bv[4];
#pragma unroll
      for (int a = 0; a < 4; a++) av[a] = As[kk][ty * 4 + a];
#pragma unroll
      for (int b = 0; b < 4; b++) bv[b] = Bs[kk][tx * 4 + b];
#pragma unroll
      for (int a = 0; a < 4; a++)
#pragma unroll
        for (int b = 0; b < 4; b++) acc[a][b] += av[a] * bv[b];
    }
    __syncthreads();
  }
#pragma unroll
  for (int a = 0; a < 4; a++)
#pragma unroll
    for (int b = 0; b < 4; b++)
      Cm[(size_t)(bm + ty * 4 + a) * P + bp + tx * 4 + b] = acc[a][b];
}

// ---------- s = max(max ev_a, max ev_b) ----------
__global__ void k_smax(const float* __restrict__ ea, const float* __restrict__ eb, double* __restrict__ scal) {
  __shared__ float red[128];
  int t = threadIdx.x;
  red[t] = fmaxf(ea[t], eb[t]);
  __syncthreads();
  for (int o = 64; o > 0; o >>= 1) { if (t < o) red[t] = fmaxf(red[t], red[t + o]); __syncthreads(); }
  if (t == 0) scal[1] = (double)red[0];
}

// ---------- resolvent mask ----------
__global__ void k_mask(const float* __restrict__ evr, const float* __restrict__ evc,
                       const double* __restrict__ scal, float* __restrict__ Dm) {
  int t = blockIdx.x * 256 + threadIdx.x;
  if (t >= SK * SK) return;
  int i = t / SK, j = t % SK;
  float s = (float)scal[1];
  float g1 = sqrtf(fmaxf(evc[j] / s, 0.f));
  float g2 = sqrtf(fmaxf(evr[i] / s, 0.f));
  float a2 = g2 * g2 + 1.f, a1 = g1 * g1 + 1.f;
  float re = g2 / a2 - g1 / a1;
  float im = 1.f / a2 - 1.f / a1;
  Dm[t] = re * re + im * im;
}

// ---------- per-row Cholesky solve ----------
__global__ void __launch_bounds__(128) k_cholsolve(const float* __restrict__ AAt, const float* __restrict__ BAt,
                                                   const float* __restrict__ Dm, float* __restrict__ Msg,
                                                   float* __restrict__ Cout) {
  __shared__ float xs[SK];
  int i = blockIdx.x;
  float* Ms = Msg + (size_t)i * SK * SK;
  for (int t2 = threadIdx.x; t2 < SK * SK; t2 += 128) {
    int r = t2 / SK, c2 = t2 % SK;
    float v = AAt[t2];
    if (r == c2) v += LAMBDA_ * Dm[(size_t)i * SK + r];
    Ms[t2] = v;
  }
  if (threadIdx.x < SK) xs[threadIdx.x] = BAt[(size_t)i * SK + threadIdx.x];
  __syncthreads();
  for (int k = 0; k < SK; k++) {
    if (threadIdx.x == 0) Ms[k * SK + k] = sqrtf(fmaxf(Ms[k * SK + k], 1e-20f));
    __syncthreads();
    float dk = Ms[k * SK + k];
    for (int r = k + 1 + threadIdx.x; r < SK; r += 128) Ms[r * SK + k] /= dk;
    __syncthreads();
    int rem = SK - k - 1;
    for (int t2 = threadIdx.x; t2 < rem * rem; t2 += 128) {
      int r = k + 1 + t2 / rem, c2 = k + 1 + t2 % rem;
      Ms[r * SK + c2] -= Ms[r * SK + k] * Ms[c2 * SK + k];
    }
    __syncthreads();
  }
  for (int k = 0; k < SK; k++) {
    if (threadIdx.x == 0) xs[k] /= Ms[k * SK + k];
    __syncthreads();
    float xv = xs[k];
    for (int r = k + 1 + threadIdx.x; r < SK; r += 128) xs[r] -= Ms[r * SK + k] * xv;
    __syncthreads();
  }
  for (int k = SK - 1; k >= 0; k--) {
    if (threadIdx.x == 0) xs[k] /= Ms[k * SK + k];
    __syncthreads();
    float xv = xs[k];
    for (int r = threadIdx.x; r < k; r += 128) xs[r] -= Ms[k * SK + r] * xv;
    __syncthreads();
  }
  for (int t2 = threadIdx.x; t2 < SK; t2 += 128) Cout[(size_t)i * SK + t2] = xs[t2];
}

// ---------- loss partials (deterministic) ----------
__global__ void k_frob_iden(const float* __restrict__ Mat, double* __restrict__ lpart, int slot) {
  __shared__ double red[256];
  double s = 0.0;
  for (int t2 = blockIdx.x * 256 + threadIdx.x; t2 < SK * SK; t2 += 32 * 256) {
    float v = Mat[t2] - ((t2 / SK == t2 % SK) ? 1.f : 0.f);
    s += (double)v * (double)v;
  }
  red[threadIdx.x] = s; __syncthreads();
  for (int o = 128; o > 0; o >>= 1) { if (threadIdx.x < o) red[threadIdx.x] += red[threadIdx.x + o]; __syncthreads(); }
  if (threadIdx.x == 0) lpart[slot * 32 + blockIdx.x] = red[0];
}
__global__ void k_lap(const float* __restrict__ Cm, const float* __restrict__ evc,
                      const float* __restrict__ evr, double* __restrict__ lpart, int slot) {
  __shared__ double red[256];
  double s = 0.0;
  for (int t2 = blockIdx.x * 256 + threadIdx.x; t2 < SK * SK; t2 += 32 * 256) {
    int i = t2 / SK, j = t2 % SK;
    float v = Cm[t2] * (evc[j] - evr[i]);
    s += (double)v * (double)v;
  }
  red[threadIdx.x] = s; __syncthreads();
  for (int o = 128; o > 0; o >>= 1) { if (threadIdx.x < o) red[threadIdx.x] += red[threadIdx.x + o]; __syncthreads(); }
  if (threadIdx.x == 0) lpart[slot * 32 + blockIdx.x] = red[0];
}
__global__ void k_writeout(const double* __restrict__ lpart, float* __restrict__ out) {
  if (threadIdx.x == 0) {
    double b = 0.0, o = 0.0, l = 0.0;
    for (int s = 0; s < 64; s++) b += lpart[s];
    for (int s = 64; s < 128; s++) o += lpart[s];
    for (int s = 128; s < 192; s++) l += lpart[s];
    out[0] = (float)b; out[1] = (float)o; out[2] = (float)l;
  }
}

extern "C" void kernel_launch(void* const* d_in, const int* in_sizes, int n_in,
                              void* d_out, int out_size, void* d_ws, size_t ws_size,
                              hipStream_t stream) {
  const float* feats[2] = {(const float*)d_in[0], (const float*)d_in[1]};
  char* p = (char*)d_ws;
  auto alloc = [&](size_t bytes) -> void* {
    char* r = p;
    p += (bytes + 255) & ~(size_t)255;
    return (void*)r;
  };
  float* pan   = (float*)alloc(sizeof(float) * 256 * NN);
  float* sq    = (float*)alloc(sizeof(float) * NN);
  float* dkv   = (float*)alloc(sizeof(float) * (size_t)NN * KK);
  float* wv    = (float*)alloc(sizeof(float) * (size_t)NN * KK);
  int*   cnt   = (int*)alloc(sizeof(int) * NN);
  int*   rpos  = (int*)alloc(sizeof(int) * NN);
  int*   tsrc  = (int*)alloc(sizeof(int) * (size_t)NN * KK);
  float* deg   = (float*)alloc(sizeof(float) * NN);
  int*   hist  = (int*)alloc(sizeof(int) * 256 * NN);
  int*   baseb = (int*)alloc(sizeof(int) * 256 * NN);
  int*   idxs[2];  float* wadjrs[2]; float* wadjts[2]; int* tcols[2]; int* roffs[2];
  for (int s = 0; s < 2; s++) {
    idxs[s]   = (int*)alloc(sizeof(int) * (size_t)NN * KK);
    wadjrs[s] = (float*)alloc(sizeof(float) * (size_t)NN * KK);
    wadjts[s] = (float*)alloc(sizeof(float) * (size_t)NN * KK);
    tcols[s]  = (int*)alloc(sizeof(int) * (size_t)NN * KK);
    roffs[s]  = (int*)alloc(sizeof(int) * (NN + 1));
  }
  float* Q0    = (float*)alloc(sizeof(float) * (size_t)LM * NN);
  float* Q1    = (float*)alloc(sizeof(float) * (size_t)LM * NN);
  float* ya0   = (float*)alloc(sizeof(float) * NN);
  float* ya1   = (float*)alloc(sizeof(float) * NN);
  float* yb0   = (float*)alloc(sizeof(float) * NN);
  float* yb1   = (float*)alloc(sizeof(float) * NN);
  float* cv0   = (float*)alloc(sizeof(float) * LM);
  float* cv1   = (float*)alloc(sizeof(float) * LM);
  double* part = (double*)alloc(sizeof(double) * 256);
  double* scal = (double*)alloc(sizeof(double) * 8);
  double* Ta0  = (double*)alloc(sizeof(double) * LM);
  double* Tb0  = (double*)alloc(sizeof(double) * LM);
  double* Ta1  = (double*)alloc(sizeof(double) * LM);
  double* Tb1  = (double*)alloc(sizeof(double) * LM);
  double* theta= (double*)alloc(sizeof(double) * SK);
  double* dws  = (double*)alloc(sizeof(double) * (size_t)LM * SK);
  double* ews  = (double*)alloc(sizeof(double) * (size_t)LM * SK);
  double* fws  = (double*)alloc(sizeof(double) * (size_t)LM * SK);
  double* rws  = (double*)alloc(sizeof(double) * (size_t)LM * SK);
  float* Ym0   = (float*)alloc(sizeof(float) * (size_t)LM * SK);
  float* Ym1   = (float*)alloc(sizeof(float) * (size_t)LM * SK);
  float* U0    = (float*)alloc(sizeof(float) * (size_t)NN * SK);
  float* U1    = (float*)alloc(sizeof(float) * (size_t)NN * SK);
  float* ev0   = (float*)alloc(sizeof(float) * SK);
  float* ev1   = (float*)alloc(sizeof(float) * SK);
  float* Ac    = (float*)alloc(sizeof(float) * (size_t)SK * NC);
  float* Bc    = (float*)alloc(sizeof(float) * (size_t)SK * NC);
  float* AAt   = (float*)alloc(sizeof(float) * SK * SK);
  float* BAt   = (float*)alloc(sizeof(float) * SK * SK);
  float* Dm    = (float*)alloc(sizeof(float) * SK * SK);
  float* Cxy   = (float*)alloc(sizeof(float) * SK * SK);
  float* Cyx   = (float*)alloc(sizeof(float) * SK * SK);
  float* P1    = (float*)alloc(sizeof(float) * SK * SK);
  float* Msg   = (float*)alloc(sizeof(float) * (size_t)SK * SK * SK);
  double* lpart= (double*)alloc(sizeof(double) * 192);
  unsigned* sy = (unsigned*)alloc(sizeof(unsigned) * 1024);

  double* Tas[2] = {Ta0, Ta1};
  double* Tbs[2] = {Tb0, Tb1};
  float* Yms[2] = {Ym0, Ym1};
  float* Qs2[2] = {Q0, Q1};
  float* Us[2] = {U0, U1};
  float* evs[2] = {ev0, ev1};

  // allow >64KB dynamic LDS for the cooperative kernel (idempotent)
  hipFuncSetAttribute((const void*)k_lanczos2,
                      hipFuncAttributeMaxDynamicSharedMemorySize, DYNLDS);

  // ---- kNN graph construction for both sides ----
  for (int s2 = 0; s2 < 2; s2++) {
    const float* f = feats[s2];
    int* idx = idxs[s2];
    k_sqnorm<<<NN, 256, 0, stream>>>(f, sq);
    for (int p2 = 0; p2 < 16; p2++) {
      k_d2panel<<<dim3(64, 4), 256, 0, stream>>>(f, sq, pan, p2 * 256);
      k_topk<<<256, 256, 0, stream>>>(pan, p2 * 256, idx, dkv);
    }
    k_partsum<<<64, 256, 0, stream>>>(dkv, part);
    k_sigma<<<1, 64, 0, stream>>>(part, scal);
    k_wexp<<<NN * KK / 256, 256, 0, stream>>>(dkv, scal, wv);
    hipMemsetAsync(cnt, 0, sizeof(int) * NN, stream);
    k_count<<<NN * KK / 256, 256, 0, stream>>>(idx, cnt);
    k_scan<<<1, 1024, 0, stream>>>(cnt, roffs[s2], rpos);
    hipMemsetAsync(hist, 0, sizeof(int) * 256 * NN, stream);
    k_hist<<<256, 256, 0, stream>>>(idx, hist);
    k_colscan<<<16, 256, 0, stream>>>(hist, roffs[s2], baseb);
    k_place2<<<256, 256, 0, stream>>>(idx, baseb, tsrc);
    k_deg<<<16, 256, 0, stream>>>(wv, roffs[s2], tsrc, deg);
    k_wadj2<<<16, 256, 0, stream>>>(wv, idx, roffs[s2], tsrc, deg,
                                    wadjrs[s2], wadjts[s2], tcols[s2]);
  }

  // ---- dual-side fused cooperative Lanczos (LDS slab + staged residual) ----
  hipMemsetAsync(sy, 0, sizeof(unsigned) * 1024, stream);
  {
    void* args[] = {(void*)&Q0, (void*)&Q1,
                    (void*)&ya0, (void*)&ya1, (void*)&yb0, (void*)&yb1,
                    (void*)&wadjrs[0], (void*)&idxs[0], (void*)&wadjts[0], (void*)&tcols[0], (void*)&roffs[0],
                    (void*)&wadjrs[1], (void*)&idxs[1], (void*)&wadjts[1], (void*)&tcols[1], (void*)&roffs[1],
                    (void*)&cv0, (void*)&cv1, (void*)&part,
                    (void*)&Ta0, (void*)&Tb0, (void*)&Ta1, (void*)&Tb1,
                    (void*)&sy};
    hipLaunchCooperativeKernel((const void*)k_lanczos2, dim3(256), dim3(1024), args, DYNLDS, stream);
  }

  // ---- per-side spectral finish ----
  for (int s2 = 0; s2 < 2; s2++) {
    k_bisect<<<1, 128, 0, stream>>>(Tas[s2], Tbs[s2], theta, evs[s2]);
    k_invit<<<1, 128, 0, stream>>>(Tas[s2], Tbs[s2], theta, dws, ews, fws, rws, Yms[s2]);
    k_mgsY<<<1, 256, 0, stream>>>(Yms[s2]);
    k_gemm_tn<<<dim3(NN / 64, SK / 64), 256, 0, stream>>>(Qs2[s2], Yms[s2], Us[s2], NN, SK, LM);
  }

  // ---- spectral coefficients + FM solves + losses ----
  k_gemm_tn<<<dim3(SK / 64, NC / 64), 256, 0, stream>>>(U0, feats[0], Ac, SK, NC, NN);
  k_gemm_tn<<<dim3(SK / 64, NC / 64), 256, 0, stream>>>(U1, feats[1], Bc, SK, NC, NN);
  k_smax<<<1, 128, 0, stream>>>(ev0, ev1, scal);

  k_gemm_nt<<<dim3(2, 2), 256, 0, stream>>>(Ac, Ac, AAt, SK, SK, NC);
  k_gemm_nt<<<dim3(2, 2), 256, 0, stream>>>(Bc, Ac, BAt, SK, SK, NC);
  k_mask<<<64, 256, 0, stream>>>(ev1, ev0, scal, Dm);
  k_cholsolve<<<SK, 128, 0, stream>>>(AAt, BAt, Dm, Msg, Cxy);
  k_gemm_nt<<<dim3(2, 2), 256, 0, stream>>>(Bc, Bc, AAt, SK, SK, NC);
  k_gemm_nt<<<dim3(2, 2), 256, 0, stream>>>(Ac, Bc, BAt, SK, SK, NC);
  k_mask<<<64, 256, 0, stream>>>(ev0, ev1, scal, Dm);
  k_cholsolve<<<SK, 128, 0, stream>>>(AAt, BAt, Dm, Msg, Cyx);

  k_gemm_nn<<<dim3(2, 2), 256, 0, stream>>>(Cxy, Cyx, P1, SK, SK, SK);
  k_frob_iden<<<32, 256, 0, stream>>>(P1, lpart, 0);
  k_gemm_nn<<<dim3(2, 2), 256, 0, stream>>>(Cyx, Cxy, P1, SK, SK, SK);
  k_frob_iden<<<32, 256, 0, stream>>>(P1, lpart, 1);
  k_gemm_tn<<<dim3(2, 2), 256, 0, stream>>>(Cxy, Cxy, P1, SK, SK, SK);
  k_frob_iden<<<32, 256, 0, stream>>>(P1, lpart, 2);
  k_gemm_tn<<<dim3(2, 2), 256, 0, stream>>>(Cyx, Cyx, P1, SK, SK, SK);
  k_frob_iden<<<32, 256, 0, stream>>>(P1, lpart, 3);
  k_lap<<<32, 256, 0, stream>>>(Cxy, ev0, ev1, lpart, 4);
  k_lap<<<32, 256, 0, stream>>>(Cyx, ev1, ev0, lpart, 5);
  k_writeout<<<1, 64, 0, stream>>>(lpart, (float*)d_out);
}

// Round 9
// 73356.903 us; speedup vs baseline: 11.0069x; 1.6746x over previous
//
#include <hip/hip_runtime.h>
#include <math.h>

#define NN 4096      // points
#define NC 768       // feature dim
#define KK 16        // knn k
#define SK 128       // spectral basis size
#define LM 1024      // Lanczos steps
#define LAMBDA_ 100.0f
// dynamic LDS for lanczos2: slab[LM][32] + ysh[NN] + cvsh[LM]
#define DYNLDS (LM * 32 * 4 + NN * 4 + LM * 4)
// dynamic LDS for cholinv: Ls[SK][SK+1] + Li[SK][SK+1]
#define CHOLLDS (2 * SK * (SK + 1) * 4)

typedef unsigned int u32;

__device__ __forceinline__ float hashf(u32 x) {
  x ^= x >> 16; x *= 0x7feb352dU; x ^= x >> 15; x *= 0x846ca68bU; x ^= x >> 16;
  return ((float)x) * (1.0f / 4294967296.0f);  // [0,1)
}

// ---- agent-scope (device-coherent) access helpers ----
__device__ __forceinline__ float agld(const float* p) {
  return __hip_atomic_load((float*)p, __ATOMIC_RELAXED, __HIP_MEMORY_SCOPE_AGENT);
}
__device__ __forceinline__ void agst(float* p, float v) {
  __hip_atomic_store(p, v, __ATOMIC_RELAXED, __HIP_MEMORY_SCOPE_AGENT);
}
__device__ __forceinline__ double agldd(const double* p) {
  return __hip_atomic_load((double*)p, __ATOMIC_RELAXED, __HIP_MEMORY_SCOPE_AGENT);
}
__device__ __forceinline__ void agstd(double* p, double v) {
  __hip_atomic_store(p, v, __ATOMIC_RELAXED, __HIP_MEMORY_SCOPE_AGENT);
}

// ---- per-side two-level tree barrier (128 blocks: 8 groups x 16) ----
__device__ __forceinline__ void gbar2(unsigned* syb, int lb, unsigned gph) {
  asm volatile("s_waitcnt vmcnt(0)" ::: "memory");
  __syncthreads();
  if (threadIdx.x == 0) {
    const int grp = lb >> 4, mem = lb & 15;
    unsigned* gc  = syb + grp * 16;
    unsigned* top = syb + 144;
    unsigned* fl  = syb + 256 + grp * 16;
    __hip_atomic_fetch_add(gc, 1u, __ATOMIC_RELEASE, __HIP_MEMORY_SCOPE_AGENT);
    if (mem == 0) {
      while (__hip_atomic_load(gc, __ATOMIC_RELAXED, __HIP_MEMORY_SCOPE_AGENT) < gph * 16u)
        __builtin_amdgcn_s_sleep(2);
      __hip_atomic_fetch_add(top, 1u, __ATOMIC_RELEASE, __HIP_MEMORY_SCOPE_AGENT);
      while (__hip_atomic_load(top, __ATOMIC_RELAXED, __HIP_MEMORY_SCOPE_AGENT) < gph * 8u)
        __builtin_amdgcn_s_sleep(2);
      __hip_atomic_store(fl, gph, __ATOMIC_RELEASE, __HIP_MEMORY_SCOPE_AGENT);
    } else {
      while (__hip_atomic_load(fl, __ATOMIC_RELAXED, __HIP_MEMORY_SCOPE_AGENT) < gph)
        __builtin_amdgcn_s_sleep(2);
    }
    __builtin_amdgcn_fence(__ATOMIC_ACQUIRE, "agent");
  }
  __syncthreads();
}

// ---------- row squared norms ----------
__global__ void k_sqnorm(const float* __restrict__ f, float* __restrict__ sq) {
  __shared__ float red[256];
  int i = blockIdx.x;
  float s = 0.f;
  for (int c = threadIdx.x; c < NC; c += 256) { float v = f[(size_t)i * NC + c]; s += v * v; }
  red[threadIdx.x] = s; __syncthreads();
  for (int o = 128; o > 0; o >>= 1) { if (threadIdx.x < o) red[threadIdx.x] += red[threadIdx.x + o]; __syncthreads(); }
  if (threadIdx.x == 0) sq[i] = red[0];
}

// ---------- d2 panel ----------
__global__ void __launch_bounds__(256) k_d2panel(const float* __restrict__ f, const float* __restrict__ sq,
                                                 float* __restrict__ pan, int i0) {
  __shared__ float As[16][65], Bs[16][65];
  int bj = blockIdx.x, bi = blockIdx.y;
  int row0 = i0 + bi * 64, col0 = bj * 64;
  int tx = threadIdx.x & 15, ty = threadIdx.x >> 4;
  float acc[4][4] = {};
  for (int k0 = 0; k0 < NC; k0 += 16) {
    for (int t2 = threadIdx.x; t2 < 1024; t2 += 256) {
      int kk = t2 & 15, rr = t2 >> 4;
      As[kk][rr] = f[(size_t)(row0 + rr) * NC + k0 + kk];
      Bs[kk][rr] = f[(size_t)(col0 + rr) * NC + k0 + kk];
    }
    __syncthreads();
#pragma unroll
    for (int kk = 0; kk < 16; kk++) {
      float av[4], bv[4];
#pragma unroll
      for (int a = 0; a < 4; a++) av[a] = As[kk][ty * 4 + a];
#pragma unroll
      for (int b = 0; b < 4; b++) bv[b] = Bs[kk][tx * 4 + b];
#pragma unroll
      for (int a = 0; a < 4; a++)
#pragma unroll
        for (int b = 0; b < 4; b++) acc[a][b] += av[a] * bv[b];
    }
    __syncthreads();
  }
#pragma unroll
  for (int a = 0; a < 4; a++) {
    int gr = row0 + ty * 4 + a;
    int pr = bi * 64 + ty * 4 + a;
    float sr = sq[gr];
#pragma unroll
    for (int b = 0; b < 4; b++) {
      int gc = col0 + tx * 4 + b;
      float v = sr + sq[gc] - 2.f * acc[a][b];
      v = fmaxf(v, 0.f);
      if (gr == gc) v += 1e10f;
      pan[(size_t)pr * NN + gc] = v;
    }
  }
}

// ---------- top-16 smallest per row ----------
__global__ void __launch_bounds__(256) k_topk(const float* __restrict__ pan, int i0,
                                              int* __restrict__ idx, float* __restrict__ dkv) {
  __shared__ float vals[NN];
  __shared__ float rv[256];
  __shared__ int ri[256];
  int r = blockIdx.x;
  const float* row = pan + (size_t)r * NN;
  for (int j = threadIdx.x; j < NN; j += 256) vals[j] = row[j];
  __syncthreads();
  for (int t3 = 0; t3 < KK; t3++) {
    float bv = 1e30f; int bi2 = NN;
    for (int j2 = threadIdx.x; j2 < NN; j2 += 256) {
      float v = vals[j2];
      if (v < bv || (v == bv && j2 < bi2)) { bv = v; bi2 = j2; }
    }
    rv[threadIdx.x] = bv; ri[threadIdx.x] = bi2;
    __syncthreads();
    for (int o = 128; o > 0; o >>= 1) {
      if (threadIdx.x < o) {
        float v2 = rv[threadIdx.x + o]; int i2 = ri[threadIdx.x + o];
        if (v2 < rv[threadIdx.x] || (v2 == rv[threadIdx.x] && i2 < ri[threadIdx.x])) {
          rv[threadIdx.x] = v2; ri[threadIdx.x] = i2;
        }
      }
      __syncthreads();
    }
    if (threadIdx.x == 0) {
      idx[(size_t)(i0 + r) * KK + t3] = ri[0];
      dkv[(size_t)(i0 + r) * KK + t3] = rv[0];
      vals[ri[0]] = 1e30f;
    }
    __syncthreads();
  }
}

// ---------- sigma2 ----------
__global__ void k_partsum(const float* __restrict__ dkv, double* __restrict__ part) {
  __shared__ double red[256];
  double s = 0.0;
  for (int t2 = blockIdx.x * 256 + threadIdx.x; t2 < NN * KK; t2 += 64 * 256) s += (double)dkv[t2];
  red[threadIdx.x] = s; __syncthreads();
  for (int o = 128; o > 0; o >>= 1) { if (threadIdx.x < o) red[threadIdx.x] += red[threadIdx.x + o]; __syncthreads(); }
  if (threadIdx.x == 0) part[blockIdx.x] = red[0];
}
__global__ void k_sigma(const double* __restrict__ part, double* __restrict__ scal) {
  __shared__ double red[64];
  red[threadIdx.x] = part[threadIdx.x]; __syncthreads();
  for (int o = 32; o > 0; o >>= 1) { if (threadIdx.x < o) red[threadIdx.x] += red[threadIdx.x + o]; __syncthreads(); }
  if (threadIdx.x == 0) scal[0] = red[0] / (double)(NN * KK) + 1e-12;
}

// ---------- gaussian weights ----------
__global__ void k_wexp(const float* __restrict__ dkv, const double* __restrict__ scal,
                       float* __restrict__ wv) {
  int t = blockIdx.x * 256 + threadIdx.x;
  if (t >= NN * KK) return;
  float inv2s = (float)(0.5 / scal[0]);
  wv[t] = expf(-dkv[t] * inv2s);
}

// ---------- deterministic CSR transpose: counting-sort ----------
__global__ void k_count(const int* __restrict__ idx, int* __restrict__ cnt) {
  int t = blockIdx.x * 256 + threadIdx.x;
  if (t < NN * KK) atomicAdd(&cnt[idx[t]], 1);
}

__global__ void __launch_bounds__(1024) k_scan(const int* __restrict__ cnt,
                                               int* __restrict__ roff, int* __restrict__ rpos) {
  __shared__ int buf[1024];
  int t = threadIdx.x;
  int v[4]; int s = 0;
#pragma unroll
  for (int u = 0; u < 4; u++) { v[u] = cnt[t * 4 + u]; s += v[u]; }
  buf[t] = s; __syncthreads();
  for (int o = 1; o < 1024; o <<= 1) {
    int x = (t >= o) ? buf[t - o] : 0;
    __syncthreads();
    buf[t] += x;
    __syncthreads();
  }
  int run = (t == 0) ? 0 : buf[t - 1];
#pragma unroll
  for (int u = 0; u < 4; u++) { roff[t * 4 + u] = run; rpos[t * 4 + u] = run; run += v[u]; }
  if (t == 1023) roff[NN] = run;
}

__global__ void k_hist(const int* __restrict__ idx, int* __restrict__ hist) {
  int e = blockIdx.x * 256 + threadIdx.x;
  atomicAdd(&hist[(e >> 8) * NN + idx[e]], 1);
}
__global__ void k_colscan(const int* __restrict__ hist, const int* __restrict__ roff,
                          int* __restrict__ baseb) {
  int j = blockIdx.x * 256 + threadIdx.x;
  if (j >= NN) return;
  int run = roff[j];
  for (int c = 0; c < 256; c++) { baseb[c * NN + j] = run; run += hist[c * NN + j]; }
}
__global__ void __launch_bounds__(256) k_place2(const int* __restrict__ idx,
                                                const int* __restrict__ baseb,
                                                int* __restrict__ tsrc) {
  __shared__ int ish[256];
  int c = blockIdx.x;
  int e = c * 256 + threadIdx.x;
  ish[threadIdx.x] = idx[e];
  __syncthreads();
  int j = ish[threadIdx.x];
  int rank = 0;
  for (int p2 = 0; p2 < threadIdx.x; p2++) rank += (ish[p2] == j) ? 1 : 0;
  tsrc[baseb[c * NN + j] + rank] = e;
}

// ---------- degrees ----------
__global__ void k_deg(const float* __restrict__ wv, const int* __restrict__ roff,
                      const int* __restrict__ tsrc, float* __restrict__ deg) {
  int i = blockIdx.x * 256 + threadIdx.x;
  if (i >= NN) return;
  float s = 0.f;
  for (int l = 0; l < KK; l++) s += wv[(size_t)i * KK + l];
  float s2 = 0.f;
  for (int e = roff[i]; e < roff[i + 1]; e++) s2 += wv[tsrc[e]];
  deg[i] = 0.5f * (s + s2);
}

// ---------- normalized adjacency ----------
__global__ void k_wadj2(const float* __restrict__ wv, const int* __restrict__ idx,
                        const int* __restrict__ roff, const int* __restrict__ tsrc,
                        const float* __restrict__ deg,
                        float* __restrict__ wadjr, float* __restrict__ wadjt,
                        int* __restrict__ tcol) {
  int i = blockIdx.x * 256 + threadIdx.x;
  if (i >= NN) return;
  float di = 1.0f / sqrtf(deg[i] + 1e-8f);
  for (int l = 0; l < KK; l++) {
    int j = idx[(size_t)i * KK + l];
    float dj = 1.0f / sqrtf(deg[j] + 1e-8f);
    wadjr[(size_t)i * KK + l] = 0.5f * wv[(size_t)i * KK + l] * di * dj;
  }
  for (int e = roff[i]; e < roff[i + 1]; e++) {
    int s = tsrc[e];
    int sn = s / KK;
    float dj = 1.0f / sqrtf(deg[sn] + 1e-8f);
    wadjt[e] = 0.5f * wv[s] * di * dj;
    tcol[e] = sn;
  }
}

// ---------- DUAL-SIDE fused cooperative Lanczos, LDS-cached slab ----------
__global__ void __launch_bounds__(1024) k_lanczos2(
    float* __restrict__ Q0, float* __restrict__ Q1,
    float* __restrict__ ya0, float* __restrict__ ya1,
    float* __restrict__ yb0, float* __restrict__ yb1,
    const float* __restrict__ wadjr0, const int* __restrict__ idx0,
    const float* __restrict__ wadjt0, const int* __restrict__ tcol0, const int* __restrict__ roff0,
    const float* __restrict__ wadjr1, const int* __restrict__ idx1,
    const float* __restrict__ wadjt1, const int* __restrict__ tcol1, const int* __restrict__ roff1,
    float* __restrict__ cv0, float* __restrict__ cv1, double* __restrict__ part,
    double* __restrict__ Ta0, double* __restrict__ Tb0,
    double* __restrict__ Ta1, double* __restrict__ Tb1,
    unsigned* __restrict__ sy) {
  const int b = blockIdx.x, t = threadIdx.x;
  const int s = b >> 7, lb = b & 127;
  const int n0 = lb * 32;
  const int lane = t & 63, wvid = t >> 6;  // 16 waves
  float* Qs = s ? Q1 : Q0;
  float* ybuf0 = s ? yb0 : ya0;
  float* ybuf1 = s ? yb1 : ya1;
  const float* wadjr = s ? wadjr1 : wadjr0;
  const int* idx = s ? idx1 : idx0;
  const float* wadjt = s ? wadjt1 : wadjt0;
  const int* tcol = s ? tcol1 : tcol0;
  const int* roff = s ? roff1 : roff0;
  float* cvs = s ? cv1 : cv0;
  double* ps = part + s * 128;
  double* Ta = s ? Ta1 : Ta0;
  double* Tb = s ? Tb1 : Tb0;
  unsigned* syb = sy + s * 512;
  u32 seed = 1234567u + (u32)s * 77777u;

  extern __shared__ char dynsh[];
  float* slabsh = (float*)dynsh;                      // [LM][32]
  float* ysh    = (float*)(dynsh + LM * 32 * 4);      // [NN]
  float* cvsh   = (float*)(dynsh + LM * 32 * 4 + NN * 4);  // [LM]
  __shared__ double pd[128];
  __shared__ double wl[16][8];
  __shared__ float fredu[32][33];
  __shared__ float r2loc[32];
  unsigned gph = 0;

  // init residual + norm partial
  if (t < 32) {
    int n = n0 + t;
    agst(&ybuf0[n], hashf((u32)n * 2246822519u + seed) - 0.5f);
  }
  __syncthreads();
  if (t == 0) {
    double ss = 0.0;
    for (int u = 0; u < 32; u++) { double v = (double)agld(&ybuf0[n0 + u]); ss += v * v; }
    agstd(&ps[lb], ss);
  }
  gbar2(syb, lb, ++gph);

  for (int it = 0; it < LM; it++) {
    float* r  = (it & 1) ? ybuf1 : ybuf0;
    float* r2 = (it & 1) ? ybuf0 : ybuf1;

    // ---- Phase A: stage r, norm, q-row write (+slab), SpMV from LDS ----
    {
      int b4 = t * 4;
      float a0 = agld(&r[b4]), a1 = agld(&r[b4 + 1]);
      float a2 = agld(&r[b4 + 2]), a3 = agld(&r[b4 + 3]);
      ysh[b4] = a0; ysh[b4 + 1] = a1; ysh[b4 + 2] = a2; ysh[b4 + 3] = a3;
    }
    if (t < 128) pd[t] = agldd(&ps[t]);
    __syncthreads();
    for (int o = 64; o > 0; o >>= 1) { if (t < o) pd[t] += pd[t + o]; __syncthreads(); }
    double nrm = sqrt(pd[0]);
    if (lb == 0 && t == 0 && it > 0) agstd(&Tb[it - 1], nrm);
    float inv = (float)(1.0 / (nrm > 1e-300 ? nrm : 1e-300));
    if (t < 32) {
      int n = n0 + t;
      float qv = ysh[n] * inv;
      agst(&Qs[(size_t)it * NN + n], qv);
      slabsh[it * 32 + t] = qv;
    }
#pragma unroll
    for (int rr = 0; rr < 2; rr++) {
      int n = n0 + wvid + rr * 16;       // 2 rows per wave
      int rb = roff[n], re = roff[n + 1];
      int L = 16 + (re - rb);
      float acc = 0.f;
      for (int i = lane; i < L; i += 64) {
        float w, qv;
        if (i < 16) { w = wadjr[(size_t)n * KK + i]; qv = ysh[idx[(size_t)n * KK + i]] * inv; }
        else        { int e = rb + i - 16; w = wadjt[e]; qv = ysh[tcol[e]] * inv; }
        acc += w * qv;
      }
      for (int o = 32; o > 0; o >>= 1) acc += __shfl_down(acc, o, 64);
      if (lane == 0) { agst(&r2[n], acc); r2loc[wvid + rr * 16] = acc; }
    }
    gbar2(syb, lb, ++gph);

    // ---- CGS2: two (dots, update) passes on r2 ----
#pragma unroll
    for (int pass = 0; pass < 2; pass++) {
      {
        int b4 = t * 4;
        float a0 = agld(&r2[b4]), a1 = agld(&r2[b4 + 1]);
        float a2 = agld(&r2[b4 + 2]), a3 = agld(&r2[b4 + 3]);
        ysh[b4] = a0; ysh[b4 + 1] = a1; ysh[b4 + 2] = a2; ysh[b4 + 3] = a3;
      }
      __syncthreads();
      // dots: rows j = lb + rsel*128 (block-exclusive, L2-resident)
      {
        float4 yv4 = *(const float4*)&ysh[t * 4];
        double sa[8];
#pragma unroll
        for (int rsel = 0; rsel < 8; rsel++) {
          int j = lb + rsel * 128;
          sa[rsel] = 0.0;
          if (j <= it) {
            float4 q4 = *(const float4*)&Qs[(size_t)j * NN + t * 4];
            double d = (double)q4.x * yv4.x; d += (double)q4.y * yv4.y;
            d += (double)q4.z * yv4.z; d += (double)q4.w * yv4.w;
            sa[rsel] = d;
          }
        }
#pragma unroll
        for (int rsel = 0; rsel < 8; rsel++) {
          int j = lb + rsel * 128;
          if (j <= it) {
            double sd = sa[rsel];
            for (int o = 32; o > 0; o >>= 1) sd += __shfl_down(sd, o, 64);
            if (lane == 0) wl[wvid][rsel] = sd;
          }
        }
        __syncthreads();
        if (t < 8) {
          int j = lb + t * 128;
          if (j <= it) {
            double tot = 0.0;
            for (int u = 0; u < 16; u++) tot += wl[u][t];
            agst(&cvs[j], (float)tot);
            if (pass == 0 && j == it) agstd(&Ta[it], tot);
          }
        }
        __syncthreads();
      }
      gbar2(syb, lb, ++gph);
      // update: r2[n0..n0+31] -= sum_j cvs[j]*slab[j][col]  (slab in LDS)
      {
        for (int j2s = t; j2s <= it; j2s += 1024) cvsh[j2s] = agld(&cvs[j2s]);
        __syncthreads();
        int i2 = t & 31, g = t >> 5;     // 32 cols x 32 j-groups
        float s0 = 0.f, s1 = 0.f, s2 = 0.f, s3 = 0.f;
        int j = g;
        for (; j + 96 <= it; j += 128) {
          s0 += cvsh[j]      * slabsh[j * 32 + i2];
          s1 += cvsh[j + 32] * slabsh[(j + 32) * 32 + i2];
          s2 += cvsh[j + 64] * slabsh[(j + 64) * 32 + i2];
          s3 += cvsh[j + 96] * slabsh[(j + 96) * 32 + i2];
        }
        for (; j <= it; j += 32) s0 += cvsh[j] * slabsh[j * 32 + i2];
        fredu[g][i2] = (s0 + s1) + (s2 + s3);
        __syncthreads();
        for (int o = 16; o > 0; o >>= 1) {
          if (g < o) fredu[g][i2] += fredu[g + o][i2];
          __syncthreads();
        }
        if (t < 32) {
          int n = n0 + t;
          float ny = r2loc[t] - fredu[0][t];
          agst(&r2[n], ny);
          r2loc[t] = ny;
        }
        __syncthreads();
        if (pass == 1 && t == 0) {
          double s2d = 0.0;
          for (int u = 0; u < 32; u++) { double v = (double)r2loc[u]; s2d += v * v; }
          agstd(&ps[lb], s2d);
        }
      }
      gbar2(syb, lb, ++gph);
    }
  }
}

// ---------- bisection (Ta/Tb^2 staged in LDS) ----------
__global__ void __launch_bounds__(128) k_bisect(const double* __restrict__ Ta, const double* __restrict__ Tb,
                                                double* __restrict__ theta, float* __restrict__ evL) {
  __shared__ double Tas[LM];
  __shared__ double Tb2[LM];
  int j = threadIdx.x;
  for (int k = j; k < LM; k += 128) {
    Tas[k] = Ta[k];
    double bq = (k > 0) ? Tb[k - 1] : 0.0;
    Tb2[k] = bq * bq;
  }
  __syncthreads();
  if (j >= SK) return;
  int tgt = LM - j;
  double lo = -2.0, hi = 2.0;
  for (int iter = 0; iter < 60; iter++) {
    double mid = 0.5 * (lo + hi);
    int cnt = 0; double q = 1.0;
    for (int k = 0; k < LM; k++) {
      q = Tas[k] - mid - Tb2[k] / q;
      if (q < 0.0) cnt++;
      if (fabs(q) < 1e-280) q = -1e-280;
    }
    if (cnt >= tgt) hi = mid; else lo = mid;
  }
  theta[j] = 0.5 * (lo + hi);
  evL[j] = (float)(1.0 - theta[j]);
}

// ---------- inverse iteration (Ta/Tb staged in LDS) ----------
__global__ void __launch_bounds__(128) k_invit(const double* __restrict__ Ta, const double* __restrict__ Tb,
                        const double* __restrict__ theta,
                        double* __restrict__ dws, double* __restrict__ ews,
                        double* __restrict__ fws, double* __restrict__ rws,
                        float* __restrict__ Ym) {
  __shared__ double Tas[LM];
  __shared__ double Tbs[LM];
  int j = threadIdx.x;
  for (int k = j; k < LM; k += 128) { Tas[k] = Ta[k]; Tbs[k] = Tb[k]; }
  __syncthreads();
  if (j >= SK) return;
  double sig = theta[j];
  for (int k = 0; k < LM; k++)
    rws[(size_t)k * SK + j] = (double)hashf((u32)k * 2654435761u + (u32)j * 40503u + 17u) - 0.5;
  for (int pass = 0; pass < 3; pass++) {
    double dk = Tas[0] - sig;
    double ek = Tbs[0];
    double fk = 0.0;
    double rk = rws[j];
    for (int k = 0; k < LM - 1; k++) {
      double bk = Tbs[k];
      double dn = Tas[k + 1] - sig;
      double en = (k + 2 < LM) ? Tbs[k + 1] : 0.0;
      double rn = rws[(size_t)(k + 1) * SK + j];
      double dd, ee, ff, dk2, ek2, rkeep, rnext;
      if (fabs(dk) >= fabs(bk)) {
        double dsafe = (fabs(dk) > 1e-300) ? dk : 1e-300;
        double m = bk / dsafe;
        dd = dsafe; ee = ek; ff = fk;
        dk2 = dn - m * ek;
        ek2 = en - m * fk;
        rkeep = rk;
        rnext = rn - m * rk;
      } else {
        double m = dk / bk;
        dd = bk; ee = dn; ff = en;
        dk2 = ek - m * dn;
        ek2 = fk - m * en;
        rkeep = rn;
        rnext = rk - m * rn;
      }
      dws[(size_t)k * SK + j] = dd;
      ews[(size_t)k * SK + j] = ee;
      fws[(size_t)k * SK + j] = ff;
      rws[(size_t)k * SK + j] = rkeep;
      rk = rnext; dk = dk2; ek = ek2; fk = 0.0;
    }
    if (fabs(dk) < 1e-300) dk = 1e-300;
    dws[(size_t)(LM - 1) * SK + j] = dk;
    ews[(size_t)(LM - 1) * SK + j] = 0.0;
    fws[(size_t)(LM - 1) * SK + j] = 0.0;
    rws[(size_t)(LM - 1) * SK + j] = rk;
    double y1 = 0.0, y2 = 0.0, nr = 0.0;
    for (int k = LM - 1; k >= 0; k--) {
      double dv = dws[(size_t)k * SK + j];
      double yk = (rws[(size_t)k * SK + j] - ews[(size_t)k * SK + j] * y1 - fws[(size_t)k * SK + j] * y2) / dv;
      rws[(size_t)k * SK + j] = yk;
      y2 = y1; y1 = yk;
      nr += yk * yk;
    }
    double inv = 1.0 / sqrt(nr > 1e-300 ? nr : 1e-300);
    for (int k = 0; k < LM; k++) rws[(size_t)k * SK + j] *= inv;
  }
  for (int k = 0; k < LM; k++) Ym[(size_t)k * SK + j] = (float)rws[(size_t)k * SK + j];
}

// ---------- Cholesky + lower-triangular inverse of SK x SK SPD matrix ----------
// S = L L^T; Linv = L^{-1} (row-major out). Column-parallel back-substitution.
__global__ void __launch_bounds__(128) k_cholinv(const float* __restrict__ S,
                                                 float* __restrict__ Linv) {
  extern __shared__ float csh[];
  float (*Ls)[SK + 1] = (float(*)[SK + 1])csh;
  float (*Li)[SK + 1] = (float(*)[SK + 1])(csh + SK * (SK + 1));
  int t = threadIdx.x;
  for (int e = t; e < SK * SK; e += 128) Ls[e / SK][e % SK] = S[e];
  __syncthreads();
  for (int k = 0; k < SK; k++) {
    if (t == 0) Ls[k][k] = sqrtf(fmaxf(Ls[k][k], 1e-20f));
    __syncthreads();
    float dk = Ls[k][k];
    for (int r = k + 1 + t; r < SK; r += 128) Ls[r][k] /= dk;
    __syncthreads();
    int rem = SK - k - 1;
    for (int e = t; e < rem * rem; e += 128) {
      int r = k + 1 + e / rem, c2 = k + 1 + e % rem;
      Ls[r][c2] -= Ls[r][k] * Ls[c2][k];
    }
    __syncthreads();
  }
  // thread t computes column t of L^{-1}
  {
    int c = t;
    for (int r = 0; r < c; r++) Li[r][c] = 0.f;
    Li[c][c] = 1.0f / Ls[c][c];
    for (int r = c + 1; r < SK; r++) {
      float sacc = 0.f;
      for (int k = c; k < r; k++) sacc += Ls[r][k] * Li[k][c];
      Li[r][c] = -sacc / Ls[r][r];
    }
  }
  __syncthreads();
  for (int e = t; e < SK * SK; e += 128) Linv[e] = Li[e / SK][e % SK];
}

// ---------- generic tiled GEMMs ----------
__global__ void __launch_bounds__(256) k_gemm_tn(const float* __restrict__ A, const float* __restrict__ B,
                                                 float* __restrict__ Cm, int M, int P, int Kd) {
  __shared__ float As[16][65], Bs[16][65];
  int bm = blockIdx.x * 64, bp = blockIdx.y * 64;
  int tx = threadIdx.x & 15, ty = threadIdx.x >> 4;
  float acc[4][4] = {};
  for (int k0 = 0; k0 < Kd; k0 += 16) {
    for (int t2 = threadIdx.x; t2 < 1024; t2 += 256) {
      int mm = t2 & 63, kk = t2 >> 6;
      As[kk][mm] = A[(size_t)(k0 + kk) * M + bm + mm];
      Bs[kk][mm] = B[(size_t)(k0 + kk) * P + bp + mm];
    }
    __syncthreads();
#pragma unroll
    for (int kk = 0; kk < 16; kk++) {
      float av[4], bv[4];
#pragma unroll
      for (int a = 0; a < 4; a++) av[a] = As[kk][ty * 4 + a];
#pragma unroll
      for (int b = 0; b < 4; b++) bv[b] = Bs[kk][tx * 4 + b];
#pragma unroll
      for (int a = 0; a < 4; a++)
#pragma unroll
        for (int b = 0; b < 4; b++) acc[a][b] += av[a] * bv[b];
    }
    __syncthreads();
  }
#pragma unroll
  for (int a = 0; a < 4; a++)
#pragma unroll
    for (int b = 0; b < 4; b++)
      Cm[(size_t)(bm + ty * 4 + a) * P + bp + tx * 4 + b] = acc[a][b];
}

__global__ void __launch_bounds__(256) k_gemm_nt(const float* __restrict__ A, const float* __restrict__ B,
                                                 float* __restrict__ Cm, int M, int P, int Kd) {
  __shared__ float As[16][65], Bs[16][65];
  int bm = blockIdx.x * 64, bp = blockIdx.y * 64;
  int tx = threadIdx.x & 15, ty = threadIdx.x >> 4;
  float acc[4][4] = {};
  for (int k0 = 0; k0 < Kd; k0 += 16) {
    for (int t2 = threadIdx.x; t2 < 1024; t2 += 256) {
      int kk = t2 & 15, mm = t2 >> 4;
      As[kk][mm] = A[(size_t)(bm + mm) * Kd + k0 + kk];
      Bs[kk][mm] = B[(size_t)(bp + mm) * Kd + k0 + kk];
    }
    __syncthreads();
#pragma unroll
    for (int kk = 0; kk < 16; kk++) {
      float av[4], bv[4];
#pragma unroll
      for (int a = 0; a < 4; a++) av[a] = As[kk][ty * 4 + a];
#pragma unroll
      for (int b = 0; b < 4; b++) bv[b] = Bs[kk][tx * 4 + b];
#pragma unroll
      for (int a = 0; a < 4; a++)
#pragma unroll
        for (int b = 0; b < 4; b++) acc[a][b] += av[a] * bv[b];
    }
    __syncthreads();
  }
#pragma unroll
  for (int a = 0; a < 4; a++)
#pragma unroll
    for (int b = 0; b < 4; b++)
      Cm[(size_t)(bm + ty * 4 + a) * P + bp + tx * 4 + b] = acc[a][b];
}

__global__ void __launch_bounds__(256) k_gemm_nn(const float* __restrict__ A, const float* __restrict__ B,
                                                 float* __restrict__ Cm, int M, int P, int Kd) {
  __shared__ float As[16][65], Bs[16][65];
  int bm = blockIdx.x * 64, bp = blockIdx.y * 64;
  int tx = threadIdx.x & 15, ty = threadIdx.x >> 4;
  float acc[4][4] = {};
  for (int k0 = 0; k0 < Kd; k0 += 16) {
    for (int t2 = threadIdx.x; t2 < 1024; t2 += 256) {
      int kk = t2 & 15, mm = t2 >> 4;
      As[kk][mm] = A[(size_t)(bm + mm) * Kd + k0 + kk];
    }
    for (int t2 = threadIdx.x; t2 < 1024; t2 += 256) {
      int mm = t2 & 63, kk = t2 >> 6;
      Bs[kk][mm] = B[(size_t)(k0 + kk) * P + bp + mm];
    }
    __syncthreads();
#pragma unroll
    for (int kk = 0; kk < 16; kk++) {
      float av[4], bv[4];
#pragma unroll
      for (int a = 0; a < 4; a++) av[a] = As[kk][ty * 4 + a];
#pragma unroll
      for (int b = 0; b < 4; b++) bv[b] = Bs[kk][tx * 4 + b];
#pragma unroll
      for (int a = 0; a < 4; a++)
#pragma unroll
        for (int b = 0; b < 4; b++) acc[a][b] += av[a] * bv[b];
    }
    __syncthreads();
  }
#pragma unroll
  for (int a = 0; a < 4; a++)
#pragma unroll
    for (int b = 0; b < 4; b++)
      Cm[(size_t)(bm + ty * 4 + a) * P + bp + tx * 4 + b] = acc[a][b];
}

// ---------- s = max(max ev_a, max ev_b) ----------
__global__ void k_smax(const float* __restrict__ ea, const float* __restrict__ eb, double* __restrict__ scal) {
  __shared__ float red[128];
  int t = threadIdx.x;
  red[t] = fmaxf(ea[t], eb[t]);
  __syncthreads();
  for (int o = 64; o > 0; o >>= 1) { if (t < o) red[t] = fmaxf(red[t], red[t + o]); __syncthreads(); }
  if (t == 0) scal[1] = (double)red[0];
}

// ---------- resolvent mask ----------
__global__ void k_mask(const float* __restrict__ evr, const float* __restrict__ evc,
                       const double* __restrict__ scal, float* __restrict__ Dm) {
  int t = blockIdx.x * 256 + threadIdx.x;
  if (t >= SK * SK) return;
  int i = t / SK, j = t % SK;
  float s = (float)scal[1];
  float g1 = sqrtf(fmaxf(evc[j] / s, 0.f));
  float g2 = sqrtf(fmaxf(evr[i] / s, 0.f));
  float a2 = g2 * g2 + 1.f, a1 = g1 * g1 + 1.f;
  float re = g2 / a2 - g1 / a1;
  float im = 1.f / a2 - 1.f / a1;
  Dm[t] = re * re + im * im;
}

// ---------- per-row Cholesky solve ----------
__global__ void __launch_bounds__(128) k_cholsolve(const float* __restrict__ AAt, const float* __restrict__ BAt,
                                                   const float* __restrict__ Dm, float* __restrict__ Msg,
                                                   float* __restrict__ Cout) {
  __shared__ float xs[SK];
  int i = blockIdx.x;
  float* Ms = Msg + (size_t)i * SK * SK;
  for (int t2 = threadIdx.x; t2 < SK * SK; t2 += 128) {
    int r = t2 / SK, c2 = t2 % SK;
    float v = AAt[t2];
    if (r == c2) v += LAMBDA_ * Dm[(size_t)i * SK + r];
    Ms[t2] = v;
  }
  if (threadIdx.x < SK) xs[threadIdx.x] = BAt[(size_t)i * SK + threadIdx.x];
  __syncthreads();
  for (int k = 0; k < SK; k++) {
    if (threadIdx.x == 0) Ms[k * SK + k] = sqrtf(fmaxf(Ms[k * SK + k], 1e-20f));
    __syncthreads();
    float dk = Ms[k * SK + k];
    for (int r = k + 1 + threadIdx.x; r < SK; r += 128) Ms[r * SK + k] /= dk;
    __syncthreads();
    int rem = SK - k - 1;
    for (int t2 = threadIdx.x; t2 < rem * rem; t2 += 128) {
      int r = k + 1 + t2 / rem, c2 = k + 1 + t2 % rem;
      Ms[r * SK + c2] -= Ms[r * SK + k] * Ms[c2 * SK + k];
    }
    __syncthreads();
  }
  for (int k = 0; k < SK; k++) {
    if (threadIdx.x == 0) xs[k] /= Ms[k * SK + k];
    __syncthreads();
    float xv = xs[k];
    for (int r = k + 1 + threadIdx.x; r < SK; r += 128) xs[r] -= Ms[r * SK + k] * xv;
    __syncthreads();
  }
  for (int k = SK - 1; k >= 0; k--) {
    if (threadIdx.x == 0) xs[k] /= Ms[k * SK + k];
    __syncthreads();
    float xv = xs[k];
    for (int r = threadIdx.x; r < k; r += 128) xs[r] -= Ms[k * SK + r] * xv;
    __syncthreads();
  }
  for (int t2 = threadIdx.x; t2 < SK; t2 += 128) Cout[(size_t)i * SK + t2] = xs[t2];
}

// ---------- loss partials (deterministic) ----------
__global__ void k_frob_iden(const float* __restrict__ Mat, double* __restrict__ lpart, int slot) {
  __shared__ double red[256];
  double s = 0.0;
  for (int t2 = blockIdx.x * 256 + threadIdx.x; t2 < SK * SK; t2 += 32 * 256) {
    float v = Mat[t2] - ((t2 / SK == t2 % SK) ? 1.f : 0.f);
    s += (double)v * (double)v;
  }
  red[threadIdx.x] = s; __syncthreads();
  for (int o = 128; o > 0; o >>= 1) { if (threadIdx.x < o) red[threadIdx.x] += red[threadIdx.x + o]; __syncthreads(); }
  if (threadIdx.x == 0) lpart[slot * 32 + blockIdx.x] = red[0];
}
__global__ void k_lap(const float* __restrict__ Cm, const float* __restrict__ evc,
                      const float* __restrict__ evr, double* __restrict__ lpart, int slot) {
  __shared__ double red[256];
  double s = 0.0;
  for (int t2 = blockIdx.x * 256 + threadIdx.x; t2 < SK * SK; t2 += 32 * 256) {
    int i = t2 / SK, j = t2 % SK;
    float v = Cm[t2] * (evc[j] - evr[i]);
    s += (double)v * (double)v;
  }
  red[threadIdx.x] = s; __syncthreads();
  for (int o = 128; o > 0; o >>= 1) { if (threadIdx.x < o) red[threadIdx.x] += red[threadIdx.x + o]; __syncthreads(); }
  if (threadIdx.x == 0) lpart[slot * 32 + blockIdx.x] = red[0];
}
__global__ void k_writeout(const double* __restrict__ lpart, float* __restrict__ out) {
  if (threadIdx.x == 0) {
    double b = 0.0, o = 0.0, l = 0.0;
    for (int s = 0; s < 64; s++) b += lpart[s];
    for (int s = 64; s < 128; s++) o += lpart[s];
    for (int s = 128; s < 192; s++) l += lpart[s];
    out[0] = (float)b; out[1] = (float)o; out[2] = (float)l;
  }
}

extern "C" void kernel_launch(void* const* d_in, const int* in_sizes, int n_in,
                              void* d_out, int out_size, void* d_ws, size_t ws_size,
                              hipStream_t stream) {
  const float* feats[2] = {(const float*)d_in[0], (const float*)d_in[1]};
  char* p = (char*)d_ws;
  auto alloc = [&](size_t bytes) -> void* {
    char* r = p;
    p += (bytes + 255) & ~(size_t)255;
    return (void*)r;
  };
  float* pan   = (float*)alloc(sizeof(float) * 256 * NN);
  float* sq    = (float*)alloc(sizeof(float) * NN);
  float* dkv   = (float*)alloc(sizeof(float) * (size_t)NN * KK);
  float* wv    = (float*)alloc(sizeof(float) * (size_t)NN * KK);
  int*   cnt   = (int*)alloc(sizeof(int) * NN);
  int*   rpos  = (int*)alloc(sizeof(int) * NN);
  int*   tsrc  = (int*)alloc(sizeof(int) * (size_t)NN * KK);
  float* deg   = (float*)alloc(sizeof(float) * NN);
  int*   hist  = (int*)alloc(sizeof(int) * 256 * NN);
  int*   baseb = (int*)alloc(sizeof(int) * 256 * NN);
  int*   idxs[2];  float* wadjrs[2]; float* wadjts[2]; int* tcols[2]; int* roffs[2];
  for (int s = 0; s < 2; s++) {
    idxs[s]   = (int*)alloc(sizeof(int) * (size_t)NN * KK);
    wadjrs[s] = (float*)alloc(sizeof(float) * (size_t)NN * KK);
    wadjts[s] = (float*)alloc(sizeof(float) * (size_t)NN * KK);
    tcols[s]  = (int*)alloc(sizeof(int) * (size_t)NN * KK);
    roffs[s]  = (int*)alloc(sizeof(int) * (NN + 1));
  }
  float* Q0    = (float*)alloc(sizeof(float) * (size_t)LM * NN);
  float* Q1    = (float*)alloc(sizeof(float) * (size_t)LM * NN);
  float* ya0   = (float*)alloc(sizeof(float) * NN);
  float* ya1   = (float*)alloc(sizeof(float) * NN);
  float* yb0   = (float*)alloc(sizeof(float) * NN);
  float* yb1   = (float*)alloc(sizeof(float) * NN);
  float* cv0   = (float*)alloc(sizeof(float) * LM);
  float* cv1   = (float*)alloc(sizeof(float) * LM);
  double* part = (double*)alloc(sizeof(double) * 256);
  double* scal = (double*)alloc(sizeof(double) * 8);
  double* Ta0  = (double*)alloc(sizeof(double) * LM);
  double* Tb0  = (double*)alloc(sizeof(double) * LM);
  double* Ta1  = (double*)alloc(sizeof(double) * LM);
  double* Tb1  = (double*)alloc(sizeof(double) * LM);
  double* theta= (double*)alloc(sizeof(double) * SK);
  double* dws  = (double*)alloc(sizeof(double) * (size_t)LM * SK);
  double* ews  = (double*)alloc(sizeof(double) * (size_t)LM * SK);
  double* fws  = (double*)alloc(sizeof(double) * (size_t)LM * SK);
  double* rws  = (double*)alloc(sizeof(double) * (size_t)LM * SK);
  float* Ym0   = (float*)alloc(sizeof(float) * (size_t)LM * SK);
  float* Ym1   = (float*)alloc(sizeof(float) * (size_t)LM * SK);
  float* Ym2   = (float*)alloc(sizeof(float) * (size_t)LM * SK);
  float* Sm    = (float*)alloc(sizeof(float) * SK * SK);
  float* Linv  = (float*)alloc(sizeof(float) * SK * SK);
  float* U0    = (float*)alloc(sizeof(float) * (size_t)NN * SK);
  float* U1    = (float*)alloc(sizeof(float) * (size_t)NN * SK);
  float* ev0   = (float*)alloc(sizeof(float) * SK);
  float* ev1   = (float*)alloc(sizeof(float) * SK);
  float* Ac    = (float*)alloc(sizeof(float) * (size_t)SK * NC);
  float* Bc    = (float*)alloc(sizeof(float) * (size_t)SK * NC);
  float* AAt   = (float*)alloc(sizeof(float) * SK * SK);
  float* BAt   = (float*)alloc(sizeof(float) * SK * SK);
  float* Dm    = (float*)alloc(sizeof(float) * SK * SK);
  float* Cxy   = (float*)alloc(sizeof(float) * SK * SK);
  float* Cyx   = (float*)alloc(sizeof(float) * SK * SK);
  float* P1    = (float*)alloc(sizeof(float) * SK * SK);
  float* Msg   = (float*)alloc(sizeof(float) * (size_t)SK * SK * SK);
  double* lpart= (double*)alloc(sizeof(double) * 192);
  unsigned* sy = (unsigned*)alloc(sizeof(unsigned) * 1024);

  double* Tas[2] = {Ta0, Ta1};
  double* Tbs[2] = {Tb0, Tb1};
  float* Yms[2] = {Ym0, Ym1};
  float* Qs2[2] = {Q0, Q1};
  float* Us[2] = {U0, U1};
  float* evs[2] = {ev0, ev1};

  hipFuncSetAttribute((const void*)k_lanczos2,
                      hipFuncAttributeMaxDynamicSharedMemorySize, DYNLDS);
  hipFuncSetAttribute((const void*)k_cholinv,
                      hipFuncAttributeMaxDynamicSharedMemorySize, CHOLLDS);

  // ---- kNN graph construction for both sides ----
  for (int s2 = 0; s2 < 2; s2++) {
    const float* f = feats[s2];
    int* idx = idxs[s2];
    k_sqnorm<<<NN, 256, 0, stream>>>(f, sq);
    for (int p2 = 0; p2 < 16; p2++) {
      k_d2panel<<<dim3(64, 4), 256, 0, stream>>>(f, sq, pan, p2 * 256);
      k_topk<<<256, 256, 0, stream>>>(pan, p2 * 256, idx, dkv);
    }
    k_partsum<<<64, 256, 0, stream>>>(dkv, part);
    k_sigma<<<1, 64, 0, stream>>>(part, scal);
    k_wexp<<<NN * KK / 256, 256, 0, stream>>>(dkv, scal, wv);
    hipMemsetAsync(cnt, 0, sizeof(int) * NN, stream);
    k_count<<<NN * KK / 256, 256, 0, stream>>>(idx, cnt);
    k_scan<<<1, 1024, 0, stream>>>(cnt, roffs[s2], rpos);
    hipMemsetAsync(hist, 0, sizeof(int) * 256 * NN, stream);
    k_hist<<<256, 256, 0, stream>>>(idx, hist);
    k_colscan<<<16, 256, 0, stream>>>(hist, roffs[s2], baseb);
    k_place2<<<256, 256, 0, stream>>>(idx, baseb, tsrc);
    k_deg<<<16, 256, 0, stream>>>(wv, roffs[s2], tsrc, deg);
    k_wadj2<<<16, 256, 0, stream>>>(wv, idx, roffs[s2], tsrc, deg,
                                    wadjrs[s2], wadjts[s2], tcols[s2]);
  }

  // ---- dual-side fused cooperative Lanczos ----
  hipMemsetAsync(sy, 0, sizeof(unsigned) * 1024, stream);
  {
    void* args[] = {(void*)&Q0, (void*)&Q1,
                    (void*)&ya0, (void*)&ya1, (void*)&yb0, (void*)&yb1,
                    (void*)&wadjrs[0], (void*)&idxs[0], (void*)&wadjts[0], (void*)&tcols[0], (void*)&roffs[0],
                    (void*)&wadjrs[1], (void*)&idxs[1], (void*)&wadjts[1], (void*)&tcols[1], (void*)&roffs[1],
                    (void*)&cv0, (void*)&cv1, (void*)&part,
                    (void*)&Ta0, (void*)&Tb0, (void*)&Ta1, (void*)&Tb1,
                    (void*)&sy};
    hipLaunchCooperativeKernel((const void*)k_lanczos2, dim3(256), dim3(1024), args, DYNLDS, stream);
  }

  // ---- per-side spectral finish (CholQR2 replaces MGS) ----
  for (int s2 = 0; s2 < 2; s2++) {
    k_bisect<<<1, 128, 0, stream>>>(Tas[s2], Tbs[s2], theta, evs[s2]);
    k_invit<<<1, 128, 0, stream>>>(Tas[s2], Tbs[s2], theta, dws, ews, fws, rws, Yms[s2]);
    // CholQR pass 1: Ym2 = Ym * inv(L)^T  with S = Ym^T Ym = L L^T
    k_gemm_tn<<<dim3(2, 2), 256, 0, stream>>>(Yms[s2], Yms[s2], Sm, SK, SK, LM);
    k_cholinv<<<1, 128, CHOLLDS, stream>>>(Sm, Linv);
    k_gemm_nt<<<dim3(LM / 64, 2), 256, 0, stream>>>(Yms[s2], Linv, Ym2, LM, SK, SK);
    // CholQR pass 2: Ym = Ym2 * inv(L2)^T
    k_gemm_tn<<<dim3(2, 2), 256, 0, stream>>>(Ym2, Ym2, Sm, SK, SK, LM);
    k_cholinv<<<1, 128, CHOLLDS, stream>>>(Sm, Linv);
    k_gemm_nt<<<dim3(LM / 64, 2), 256, 0, stream>>>(Ym2, Linv, Yms[s2], LM, SK, SK);
    // Ritz vectors
    k_gemm_tn<<<dim3(NN / 64, SK / 64), 256, 0, stream>>>(Qs2[s2], Yms[s2], Us[s2], NN, SK, LM);
  }

  // ---- spectral coefficients + FM solves + losses ----
  k_gemm_tn<<<dim3(SK / 64, NC / 64), 256, 0, stream>>>(U0, feats[0], Ac, SK, NC, NN);
  k_gemm_tn<<<dim3(SK / 64, NC / 64), 256, 0, stream>>>(U1, feats[1], Bc, SK, NC, NN);
  k_smax<<<1, 128, 0, stream>>>(ev0, ev1, scal);

  k_gemm_nt<<<dim3(2, 2), 256, 0, stream>>>(Ac, Ac, AAt, SK, SK, NC);
  k_gemm_nt<<<dim3(2, 2), 256, 0, stream>>>(Bc, Ac, BAt, SK, SK, NC);
  k_mask<<<64, 256, 0, stream>>>(ev1, ev0, scal, Dm);
  k_cholsolve<<<SK, 128, 0, stream>>>(AAt, BAt, Dm, Msg, Cxy);
  k_gemm_nt<<<dim3(2, 2), 256, 0, stream>>>(Bc, Bc, AAt, SK, SK, NC);
  k_gemm_nt<<<dim3(2, 2), 256, 0, stream>>>(Ac, Bc, BAt, SK, SK, NC);
  k_mask<<<64, 256, 0, stream>>>(ev0, ev1, scal, Dm);
  k_cholsolve<<<SK, 128, 0, stream>>>(AAt, BAt, Dm, Msg, Cyx);

  k_gemm_nn<<<dim3(2, 2), 256, 0, stream>>>(Cxy, Cyx, P1, SK, SK, SK);
  k_frob_iden<<<32, 256, 0, stream>>>(P1, lpart, 0);
  k_gemm_nn<<<dim3(2, 2), 256, 0, stream>>>(Cyx, Cxy, P1, SK, SK, SK);
  k_frob_iden<<<32, 256, 0, stream>>>(P1, lpart, 1);
  k_gemm_tn<<<dim3(2, 2), 256, 0, stream>>>(Cxy, Cxy, P1, SK, SK, SK);
  k_frob_iden<<<32, 256, 0, stream>>>(P1, lpart, 2);
  k_gemm_tn<<<dim3(2, 2), 256, 0, stream>>>(Cyx, Cyx, P1, SK, SK, SK);
  k_frob_iden<<<32, 256, 0, stream>>>(P1, lpart, 3);
  k_lap<<<32, 256, 0, stream>>>(Cxy, ev0, ev1, lpart, 4);
  k_lap<<<32, 256, 0, stream>>>(Cyx, ev1, ev0, lpart, 5);
  k_writeout<<<1, 64, 0, stream>>>(lpart, (float*)d_out);
}

// Round 10
// 54400.952 us; speedup vs baseline: 14.8422x; 1.3484x over previous
//
#include <hip/hip_runtime.h>
#include <math.h>

#define NN 4096      // points
#define NC 768       // feature dim
#define KK 16        // knn k
#define SK 128       // spectral basis size
#define LM 768       // Lanczos steps (6x oversampling of SK; was 1024)
#define NR (LM / 128) // dots rows per block
#define LAMBDA_ 100.0f
// dynamic LDS for lanczos2: slab[LM][32] + ysh[NN] + cvsh[LM]
#define DYNLDS (LM * 32 * 4 + NN * 4 + LM * 4)
// dynamic LDS for cholinv: Ls[SK][SK+1] + Li[SK][SK+1]
#define CHOLLDS (2 * SK * (SK + 1) * 4)

typedef unsigned int u32;

__device__ __forceinline__ float hashf(u32 x) {
  x ^= x >> 16; x *= 0x7feb352dU; x ^= x >> 15; x *= 0x846ca68bU; x ^= x >> 16;
  return ((float)x) * (1.0f / 4294967296.0f);  // [0,1)
}

// ---- agent-scope (device-coherent) access helpers ----
__device__ __forceinline__ float agld(const float* p) {
  return __hip_atomic_load((float*)p, __ATOMIC_RELAXED, __HIP_MEMORY_SCOPE_AGENT);
}
__device__ __forceinline__ void agst(float* p, float v) {
  __hip_atomic_store(p, v, __ATOMIC_RELAXED, __HIP_MEMORY_SCOPE_AGENT);
}
__device__ __forceinline__ double agldd(const double* p) {
  return __hip_atomic_load((double*)p, __ATOMIC_RELAXED, __HIP_MEMORY_SCOPE_AGENT);
}
__device__ __forceinline__ void agstd(double* p, double v) {
  __hip_atomic_store(p, v, __ATOMIC_RELAXED, __HIP_MEMORY_SCOPE_AGENT);
}

// ---- per-side two-level tree barrier (128 blocks: 8 groups x 16) ----
__device__ __forceinline__ void gbar2(unsigned* syb, int lb, unsigned gph) {
  asm volatile("s_waitcnt vmcnt(0)" ::: "memory");
  __syncthreads();
  if (threadIdx.x == 0) {
    const int grp = lb >> 4, mem = lb & 15;
    unsigned* gc  = syb + grp * 16;
    unsigned* top = syb + 144;
    unsigned* fl  = syb + 256 + grp * 16;
    __hip_atomic_fetch_add(gc, 1u, __ATOMIC_RELEASE, __HIP_MEMORY_SCOPE_AGENT);
    if (mem == 0) {
      while (__hip_atomic_load(gc, __ATOMIC_RELAXED, __HIP_MEMORY_SCOPE_AGENT) < gph * 16u)
        __builtin_amdgcn_s_sleep(2);
      __hip_atomic_fetch_add(top, 1u, __ATOMIC_RELEASE, __HIP_MEMORY_SCOPE_AGENT);
      while (__hip_atomic_load(top, __ATOMIC_RELAXED, __HIP_MEMORY_SCOPE_AGENT) < gph * 8u)
        __builtin_amdgcn_s_sleep(2);
      __hip_atomic_store(fl, gph, __ATOMIC_RELEASE, __HIP_MEMORY_SCOPE_AGENT);
    } else {
      while (__hip_atomic_load(fl, __ATOMIC_RELAXED, __HIP_MEMORY_SCOPE_AGENT) < gph)
        __builtin_amdgcn_s_sleep(2);
    }
    __builtin_amdgcn_fence(__ATOMIC_ACQUIRE, "agent");
  }
  __syncthreads();
}

// ---------- row squared norms ----------
__global__ void k_sqnorm(const float* __restrict__ f, float* __restrict__ sq) {
  __shared__ float red[256];
  int i = blockIdx.x;
  float s = 0.f;
  for (int c = threadIdx.x; c < NC; c += 256) { float v = f[(size_t)i * NC + c]; s += v * v; }
  red[threadIdx.x] = s; __syncthreads();
  for (int o = 128; o > 0; o >>= 1) { if (threadIdx.x < o) red[threadIdx.x] += red[threadIdx.x + o]; __syncthreads(); }
  if (threadIdx.x == 0) sq[i] = red[0];
}

// ---------- d2 panel ----------
__global__ void __launch_bounds__(256) k_d2panel(const float* __restrict__ f, const float* __restrict__ sq,
                                                 float* __restrict__ pan, int i0) {
  __shared__ float As[16][65], Bs[16][65];
  int bj = blockIdx.x, bi = blockIdx.y;
  int row0 = i0 + bi * 64, col0 = bj * 64;
  int tx = threadIdx.x & 15, ty = threadIdx.x >> 4;
  float acc[4][4] = {};
  for (int k0 = 0; k0 < NC; k0 += 16) {
    for (int t2 = threadIdx.x; t2 < 1024; t2 += 256) {
      int kk = t2 & 15, rr = t2 >> 4;
      As[kk][rr] = f[(size_t)(row0 + rr) * NC + k0 + kk];
      Bs[kk][rr] = f[(size_t)(col0 + rr) * NC + k0 + kk];
    }
    __syncthreads();
#pragma unroll
    for (int kk = 0; kk < 16; kk++) {
      float av[4], bv[4];
#pragma unroll
      for (int a = 0; a < 4; a++) av[a] = As[kk][ty * 4 + a];
#pragma unroll
      for (int b = 0; b < 4; b++) bv[b] = Bs[kk][tx * 4 + b];
#pragma unroll
      for (int a = 0; a < 4; a++)
#pragma unroll
        for (int b = 0; b < 4; b++) acc[a][b] += av[a] * bv[b];
    }
    __syncthreads();
  }
#pragma unroll
  for (int a = 0; a < 4; a++) {
    int gr = row0 + ty * 4 + a;
    int pr = bi * 64 + ty * 4 + a;
    float sr = sq[gr];
#pragma unroll
    for (int b = 0; b < 4; b++) {
      int gc = col0 + tx * 4 + b;
      float v = sr + sq[gc] - 2.f * acc[a][b];
      v = fmaxf(v, 0.f);
      if (gr == gc) v += 1e10f;
      pan[(size_t)pr * NN + gc] = v;
    }
  }
}

// ---------- top-16 smallest per row ----------
__global__ void __launch_bounds__(256) k_topk(const float* __restrict__ pan, int i0,
                                              int* __restrict__ idx, float* __restrict__ dkv) {
  __shared__ float vals[NN];
  __shared__ float rv[256];
  __shared__ int ri[256];
  int r = blockIdx.x;
  const float* row = pan + (size_t)r * NN;
  for (int j = threadIdx.x; j < NN; j += 256) vals[j] = row[j];
  __syncthreads();
  for (int t3 = 0; t3 < KK; t3++) {
    float bv = 1e30f; int bi2 = NN;
    for (int j2 = threadIdx.x; j2 < NN; j2 += 256) {
      float v = vals[j2];
      if (v < bv || (v == bv && j2 < bi2)) { bv = v; bi2 = j2; }
    }
    rv[threadIdx.x] = bv; ri[threadIdx.x] = bi2;
    __syncthreads();
    for (int o = 128; o > 0; o >>= 1) {
      if (threadIdx.x < o) {
        float v2 = rv[threadIdx.x + o]; int i2 = ri[threadIdx.x + o];
        if (v2 < rv[threadIdx.x] || (v2 == rv[threadIdx.x] && i2 < ri[threadIdx.x])) {
          rv[threadIdx.x] = v2; ri[threadIdx.x] = i2;
        }
      }
      __syncthreads();
    }
    if (threadIdx.x == 0) {
      idx[(size_t)(i0 + r) * KK + t3] = ri[0];
      dkv[(size_t)(i0 + r) * KK + t3] = rv[0];
      vals[ri[0]] = 1e30f;
    }
    __syncthreads();
  }
}

// ---------- sigma2 ----------
__global__ void k_partsum(const float* __restrict__ dkv, double* __restrict__ part) {
  __shared__ double red[256];
  double s = 0.0;
  for (int t2 = blockIdx.x * 256 + threadIdx.x; t2 < NN * KK; t2 += 64 * 256) s += (double)dkv[t2];
  red[threadIdx.x] = s; __syncthreads();
  for (int o = 128; o > 0; o >>= 1) { if (threadIdx.x < o) red[threadIdx.x] += red[threadIdx.x + o]; __syncthreads(); }
  if (threadIdx.x == 0) part[blockIdx.x] = red[0];
}
__global__ void k_sigma(const double* __restrict__ part, double* __restrict__ scal) {
  __shared__ double red[64];
  red[threadIdx.x] = part[threadIdx.x]; __syncthreads();
  for (int o = 32; o > 0; o >>= 1) { if (threadIdx.x < o) red[threadIdx.x] += red[threadIdx.x + o]; __syncthreads(); }
  if (threadIdx.x == 0) scal[0] = red[0] / (double)(NN * KK) + 1e-12;
}

// ---------- gaussian weights ----------
__global__ void k_wexp(const float* __restrict__ dkv, const double* __restrict__ scal,
                       float* __restrict__ wv) {
  int t = blockIdx.x * 256 + threadIdx.x;
  if (t >= NN * KK) return;
  float inv2s = (float)(0.5 / scal[0]);
  wv[t] = expf(-dkv[t] * inv2s);
}

// ---------- deterministic CSR transpose: counting-sort ----------
__global__ void k_count(const int* __restrict__ idx, int* __restrict__ cnt) {
  int t = blockIdx.x * 256 + threadIdx.x;
  if (t < NN * KK) atomicAdd(&cnt[idx[t]], 1);
}

__global__ void __launch_bounds__(1024) k_scan(const int* __restrict__ cnt,
                                               int* __restrict__ roff, int* __restrict__ rpos) {
  __shared__ int buf[1024];
  int t = threadIdx.x;
  int v[4]; int s = 0;
#pragma unroll
  for (int u = 0; u < 4; u++) { v[u] = cnt[t * 4 + u]; s += v[u]; }
  buf[t] = s; __syncthreads();
  for (int o = 1; o < 1024; o <<= 1) {
    int x = (t >= o) ? buf[t - o] : 0;
    __syncthreads();
    buf[t] += x;
    __syncthreads();
  }
  int run = (t == 0) ? 0 : buf[t - 1];
#pragma unroll
  for (int u = 0; u < 4; u++) { roff[t * 4 + u] = run; rpos[t * 4 + u] = run; run += v[u]; }
  if (t == 1023) roff[NN] = run;
}

__global__ void k_hist(const int* __restrict__ idx, int* __restrict__ hist) {
  int e = blockIdx.x * 256 + threadIdx.x;
  atomicAdd(&hist[(e >> 8) * NN + idx[e]], 1);
}
__global__ void k_colscan(const int* __restrict__ hist, const int* __restrict__ roff,
                          int* __restrict__ baseb) {
  int j = blockIdx.x * 256 + threadIdx.x;
  if (j >= NN) return;
  int run = roff[j];
  for (int c = 0; c < 256; c++) { baseb[c * NN + j] = run; run += hist[c * NN + j]; }
}
__global__ void __launch_bounds__(256) k_place2(const int* __restrict__ idx,
                                                const int* __restrict__ baseb,
                                                int* __restrict__ tsrc) {
  __shared__ int ish[256];
  int c = blockIdx.x;
  int e = c * 256 + threadIdx.x;
  ish[threadIdx.x] = idx[e];
  __syncthreads();
  int j = ish[threadIdx.x];
  int rank = 0;
  for (int p2 = 0; p2 < threadIdx.x; p2++) rank += (ish[p2] == j) ? 1 : 0;
  tsrc[baseb[c * NN + j] + rank] = e;
}

// ---------- degrees ----------
__global__ void k_deg(const float* __restrict__ wv, const int* __restrict__ roff,
                      const int* __restrict__ tsrc, float* __restrict__ deg) {
  int i = blockIdx.x * 256 + threadIdx.x;
  if (i >= NN) return;
  float s = 0.f;
  for (int l = 0; l < KK; l++) s += wv[(size_t)i * KK + l];
  float s2 = 0.f;
  for (int e = roff[i]; e < roff[i + 1]; e++) s2 += wv[tsrc[e]];
  deg[i] = 0.5f * (s + s2);
}

// ---------- normalized adjacency ----------
__global__ void k_wadj2(const float* __restrict__ wv, const int* __restrict__ idx,
                        const int* __restrict__ roff, const int* __restrict__ tsrc,
                        const float* __restrict__ deg,
                        float* __restrict__ wadjr, float* __restrict__ wadjt,
                        int* __restrict__ tcol) {
  int i = blockIdx.x * 256 + threadIdx.x;
  if (i >= NN) return;
  float di = 1.0f / sqrtf(deg[i] + 1e-8f);
  for (int l = 0; l < KK; l++) {
    int j = idx[(size_t)i * KK + l];
    float dj = 1.0f / sqrtf(deg[j] + 1e-8f);
    wadjr[(size_t)i * KK + l] = 0.5f * wv[(size_t)i * KK + l] * di * dj;
  }
  for (int e = roff[i]; e < roff[i + 1]; e++) {
    int s = tsrc[e];
    int sn = s / KK;
    float dj = 1.0f / sqrtf(deg[sn] + 1e-8f);
    wadjt[e] = 0.5f * wv[s] * di * dj;
    tcol[e] = sn;
  }
}

// ---------- DUAL-SIDE fused cooperative Lanczos, LDS-cached slab ----------
// 256 blocks x 1024 threads; side s = b>>7, 128 blocks/side, 32 rows/block.
// Latency-trimmed: single-wave norm reduce, register-direct CGS dot loads,
// 1-sync update combine. Fixed reduction orders -> deterministic.
__global__ void __launch_bounds__(1024) k_lanczos2(
    float* __restrict__ Q0, float* __restrict__ Q1,
    float* __restrict__ ya0, float* __restrict__ ya1,
    float* __restrict__ yb0, float* __restrict__ yb1,
    const float* __restrict__ wadjr0, const int* __restrict__ idx0,
    const float* __restrict__ wadjt0, const int* __restrict__ tcol0, const int* __restrict__ roff0,
    const float* __restrict__ wadjr1, const int* __restrict__ idx1,
    const float* __restrict__ wadjt1, const int* __restrict__ tcol1, const int* __restrict__ roff1,
    float* __restrict__ cv0, float* __restrict__ cv1, double* __restrict__ part,
    double* __restrict__ Ta0, double* __restrict__ Tb0,
    double* __restrict__ Ta1, double* __restrict__ Tb1,
    unsigned* __restrict__ sy) {
  const int b = blockIdx.x, t = threadIdx.x;
  const int s = b >> 7, lb = b & 127;
  const int n0 = lb * 32;
  const int lane = t & 63, wvid = t >> 6;  // 16 waves
  float* Qs = s ? Q1 : Q0;
  float* ybuf0 = s ? yb0 : ya0;
  float* ybuf1 = s ? yb1 : ya1;
  const float* wadjr = s ? wadjr1 : wadjr0;
  const int* idx = s ? idx1 : idx0;
  const float* wadjt = s ? wadjt1 : wadjt0;
  const int* tcol = s ? tcol1 : tcol0;
  const int* roff = s ? roff1 : roff0;
  float* cvs = s ? cv1 : cv0;
  double* ps = part + s * 128;
  double* Ta = s ? Ta1 : Ta0;
  double* Tb = s ? Tb1 : Tb0;
  unsigned* syb = sy + s * 512;
  u32 seed = 1234567u + (u32)s * 77777u;

  extern __shared__ char dynsh[];
  float* slabsh = (float*)dynsh;                      // [LM][32]
  float* ysh    = (float*)(dynsh + LM * 32 * 4);      // [NN]
  float* cvsh   = (float*)(dynsh + LM * 32 * 4 + NN * 4);  // [LM]
  __shared__ double pd[2];
  __shared__ double wl[16][NR];
  __shared__ float fredu[32][33];
  __shared__ float r2loc[32];
  unsigned gph = 0;

  // init residual + norm partial
  if (t < 32) {
    int n = n0 + t;
    agst(&ybuf0[n], hashf((u32)n * 2246822519u + seed) - 0.5f);
  }
  __syncthreads();
  if (t == 0) {
    double ss = 0.0;
    for (int u = 0; u < 32; u++) { double v = (double)agld(&ybuf0[n0 + u]); ss += v * v; }
    agstd(&ps[lb], ss);
  }
  gbar2(syb, lb, ++gph);

  for (int it = 0; it < LM; it++) {
    float* r  = (it & 1) ? ybuf1 : ybuf0;
    float* r2 = (it & 1) ? ybuf0 : ybuf1;

    // ---- Phase A: stage r, single-wave norm, q-row write (+slab), SpMV ----
    {
      int b4 = t * 4;
      float a0 = agld(&r[b4]), a1 = agld(&r[b4 + 1]);
      float a2 = agld(&r[b4 + 2]), a3 = agld(&r[b4 + 3]);
      ysh[b4] = a0; ysh[b4 + 1] = a1; ysh[b4 + 2] = a2; ysh[b4 + 3] = a3;
    }
    if (t < 64) {
      double v = agldd(&ps[t]) + agldd(&ps[t + 64]);
      for (int o = 32; o > 0; o >>= 1) v += __shfl_down(v, o, 64);
      if (t == 0) pd[0] = v;
    }
    __syncthreads();
    double nrm = sqrt(pd[0]);
    if (lb == 0 && t == 0 && it > 0) agstd(&Tb[it - 1], nrm);
    float inv = (float)(1.0 / (nrm > 1e-300 ? nrm : 1e-300));
    if (t < 32) {
      int n = n0 + t;
      float qv = ysh[n] * inv;
      agst(&Qs[(size_t)it * NN + n], qv);
      slabsh[it * 32 + t] = qv;
    }
#pragma unroll
    for (int rr = 0; rr < 2; rr++) {
      int n = n0 + wvid + rr * 16;       // 2 rows per wave
      int rb = roff[n], re = roff[n + 1];
      int L = 16 + (re - rb);
      float acc = 0.f;
      for (int i = lane; i < L; i += 64) {
        float w, qv;
        if (i < 16) { w = wadjr[(size_t)n * KK + i]; qv = ysh[idx[(size_t)n * KK + i]] * inv; }
        else        { int e = rb + i - 16; w = wadjt[e]; qv = ysh[tcol[e]] * inv; }
        acc += w * qv;
      }
      for (int o = 32; o > 0; o >>= 1) acc += __shfl_down(acc, o, 64);
      if (lane == 0) { agst(&r2[n], acc); r2loc[wvid + rr * 16] = acc; }
    }
    gbar2(syb, lb, ++gph);

    // ---- CGS2: two (dots, update) passes on r2 ----
#pragma unroll
    for (int pass = 0; pass < 2; pass++) {
      // dots: register-direct loads (each thread only needs its own 4 values)
      {
        float4 yv4;
        int b4 = t * 4;
        yv4.x = agld(&r2[b4]); yv4.y = agld(&r2[b4 + 1]);
        yv4.z = agld(&r2[b4 + 2]); yv4.w = agld(&r2[b4 + 3]);
        double sa[NR];
#pragma unroll
        for (int rsel = 0; rsel < NR; rsel++) {
          int j = lb + rsel * 128;
          sa[rsel] = 0.0;
          if (j <= it) {
            float4 q4 = *(const float4*)&Qs[(size_t)j * NN + t * 4];
            double d = (double)q4.x * yv4.x; d += (double)q4.y * yv4.y;
            d += (double)q4.z * yv4.z; d += (double)q4.w * yv4.w;
            sa[rsel] = d;
          }
        }
#pragma unroll
        for (int rsel = 0; rsel < NR; rsel++) {
          int j = lb + rsel * 128;
          if (j <= it) {
            double sd = sa[rsel];
            for (int o = 32; o > 0; o >>= 1) sd += __shfl_down(sd, o, 64);
            if (lane == 0) wl[wvid][rsel] = sd;
          }
        }
        __syncthreads();
        if (t < NR) {
          int j = lb + t * 128;
          if (j <= it) {
            double tot = 0.0;
            for (int u = 0; u < 16; u++) tot += wl[u][t];
            agst(&cvs[j], (float)tot);
            if (pass == 0 && j == it) agstd(&Ta[it], tot);
          }
        }
        __syncthreads();
      }
      gbar2(syb, lb, ++gph);
      // update: r2[n0..n0+31] -= sum_j cvs[j]*slab[j][col]  (slab in LDS)
      {
        for (int j2s = t; j2s <= it; j2s += 1024) cvsh[j2s] = agld(&cvs[j2s]);
        __syncthreads();
        int i2 = t & 31, g = t >> 5;     // 32 cols x 32 j-groups
        float s0 = 0.f, s1 = 0.f, s2 = 0.f, s3 = 0.f;
        int j = g;
        for (; j + 96 <= it; j += 128) {
          s0 += cvsh[j]      * slabsh[j * 32 + i2];
          s1 += cvsh[j + 32] * slabsh[(j + 32) * 32 + i2];
          s2 += cvsh[j + 64] * slabsh[(j + 64) * 32 + i2];
          s3 += cvsh[j + 96] * slabsh[(j + 96) * 32 + i2];
        }
        for (; j <= it; j += 32) s0 += cvsh[j] * slabsh[j * 32 + i2];
        fredu[g][i2] = (s0 + s1) + (s2 + s3);
        __syncthreads();
        if (t < 32) {
          float acc2 = 0.f;
          for (int g2 = 0; g2 < 32; g2++) acc2 += fredu[g2][t];
          float ny = r2loc[t] - acc2;
          agst(&r2[n0 + t], ny);
          r2loc[t] = ny;
        }
        __syncthreads();
        if (pass == 1 && t == 0) {
          double s2d = 0.0;
          for (int u = 0; u < 32; u++) { double v = (double)r2loc[u]; s2d += v * v; }
          agstd(&ps[lb], s2d);
        }
      }
      gbar2(syb, lb, ++gph);
    }
  }
}

// ---------- bisection (Ta/Tb^2 staged in LDS) ----------
__global__ void __launch_bounds__(128) k_bisect(const double* __restrict__ Ta, const double* __restrict__ Tb,
                                                double* __restrict__ theta, float* __restrict__ evL) {
  __shared__ double Tas[LM];
  __shared__ double Tb2[LM];
  int j = threadIdx.x;
  for (int k = j; k < LM; k += 128) {
    Tas[k] = Ta[k];
    double bq = (k > 0) ? Tb[k - 1] : 0.0;
    Tb2[k] = bq * bq;
  }
  __syncthreads();
  if (j >= SK) return;
  int tgt = LM - j;
  double lo = -2.0, hi = 2.0;
  for (int iter = 0; iter < 60; iter++) {
    double mid = 0.5 * (lo + hi);
    int cnt = 0; double q = 1.0;
    for (int k = 0; k < LM; k++) {
      q = Tas[k] - mid - Tb2[k] / q;
      if (q < 0.0) cnt++;
      if (fabs(q) < 1e-280) q = -1e-280;
    }
    if (cnt >= tgt) hi = mid; else lo = mid;
  }
  theta[j] = 0.5 * (lo + hi);
  evL[j] = (float)(1.0 - theta[j]);
}

// ---------- inverse iteration (Ta/Tb staged in LDS) ----------
__global__ void __launch_bounds__(128) k_invit(const double* __restrict__ Ta, const double* __restrict__ Tb,
                        const double* __restrict__ theta,
                        double* __restrict__ dws, double* __restrict__ ews,
                        double* __restrict__ fws, double* __restrict__ rws,
                        float* __restrict__ Ym) {
  __shared__ double Tas[LM];
  __shared__ double Tbs[LM];
  int j = threadIdx.x;
  for (int k = j; k < LM; k += 128) { Tas[k] = Ta[k]; Tbs[k] = Tb[k]; }
  __syncthreads();
  if (j >= SK) return;
  double sig = theta[j];
  for (int k = 0; k < LM; k++)
    rws[(size_t)k * SK + j] = (double)hashf((u32)k * 2654435761u + (u32)j * 40503u + 17u) - 0.5;
  for (int pass = 0; pass < 3; pass++) {
    double dk = Tas[0] - sig;
    double ek = Tbs[0];
    double fk = 0.0;
    double rk = rws[j];
    for (int k = 0; k < LM - 1; k++) {
      double bk = Tbs[k];
      double dn = Tas[k + 1] - sig;
      double en = (k + 2 < LM) ? Tbs[k + 1] : 0.0;
      double rn = rws[(size_t)(k + 1) * SK + j];
      double dd, ee, ff, dk2, ek2, rkeep, rnext;
      if (fabs(dk) >= fabs(bk)) {
        double dsafe = (fabs(dk) > 1e-300) ? dk : 1e-300;
        double m = bk / dsafe;
        dd = dsafe; ee = ek; ff = fk;
        dk2 = dn - m * ek;
        ek2 = en - m * fk;
        rkeep = rk;
        rnext = rn - m * rk;
      } else {
        double m = dk / bk;
        dd = bk; ee = dn; ff = en;
        dk2 = ek - m * dn;
        ek2 = fk - m * en;
        rkeep = rn;
        rnext = rk - m * rn;
      }
      dws[(size_t)k * SK + j] = dd;
      ews[(size_t)k * SK + j] = ee;
      fws[(size_t)k * SK + j] = ff;
      rws[(size_t)k * SK + j] = rkeep;
      rk = rnext; dk = dk2; ek = ek2; fk = 0.0;
    }
    if (fabs(dk) < 1e-300) dk = 1e-300;
    dws[(size_t)(LM - 1) * SK + j] = dk;
    ews[(size_t)(LM - 1) * SK + j] = 0.0;
    fws[(size_t)(LM - 1) * SK + j] = 0.0;
    rws[(size_t)(LM - 1) * SK + j] = rk;
    double y1 = 0.0, y2 = 0.0, nr = 0.0;
    for (int k = LM - 1; k >= 0; k--) {
      double dv = dws[(size_t)k * SK + j];
      double yk = (rws[(size_t)k * SK + j] - ews[(size_t)k * SK + j] * y1 - fws[(size_t)k * SK + j] * y2) / dv;
      rws[(size_t)k * SK + j] = yk;
      y2 = y1; y1 = yk;
      nr += yk * yk;
    }
    double inv = 1.0 / sqrt(nr > 1e-300 ? nr : 1e-300);
    for (int k = 0; k < LM; k++) rws[(size_t)k * SK + j] *= inv;
  }
  for (int k = 0; k < LM; k++) Ym[(size_t)k * SK + j] = (float)rws[(size_t)k * SK + j];
}

// ---------- Cholesky + lower-triangular inverse of SK x SK SPD matrix ----------
__global__ void __launch_bounds__(128) k_cholinv(const float* __restrict__ S,
                                                 float* __restrict__ Linv) {
  extern __shared__ float csh[];
  float (*Ls)[SK + 1] = (float(*)[SK + 1])csh;
  float (*Li)[SK + 1] = (float(*)[SK + 1])(csh + SK * (SK + 1));
  int t = threadIdx.x;
  for (int e = t; e < SK * SK; e += 128) Ls[e / SK][e % SK] = S[e];
  __syncthreads();
  for (int k = 0; k < SK; k++) {
    if (t == 0) Ls[k][k] = sqrtf(fmaxf(Ls[k][k], 1e-20f));
    __syncthreads();
    float dk = Ls[k][k];
    for (int r = k + 1 + t; r < SK; r += 128) Ls[r][k] /= dk;
    __syncthreads();
    int rem = SK - k - 1;
    for (int e = t; e < rem * rem; e += 128) {
      int r = k + 1 + e / rem, c2 = k + 1 + e % rem;
      Ls[r][c2] -= Ls[r][k] * Ls[c2][k];
    }
    __syncthreads();
  }
  {
    int c = t;
    for (int r = 0; r < c; r++) Li[r][c] = 0.f;
    Li[c][c] = 1.0f / Ls[c][c];
    for (int r = c + 1; r < SK; r++) {
      float sacc = 0.f;
      for (int k = c; k < r; k++) sacc += Ls[r][k] * Li[k][c];
      Li[r][c] = -sacc / Ls[r][r];
    }
  }
  __syncthreads();
  for (int e = t; e < SK * SK; e += 128) Linv[e] = Li[e / SK][e % SK];
}

// ---------- generic tiled GEMMs ----------
__global__ void __launch_bounds__(256) k_gemm_tn(const float* __restrict__ A, const float* __restrict__ B,
                                                 float* __restrict__ Cm, int M, int P, int Kd) {
  __shared__ float As[16][65], Bs[16][65];
  int bm = blockIdx.x * 64, bp = blockIdx.y * 64;
  int tx = threadIdx.x & 15, ty = threadIdx.x >> 4;
  float acc[4][4] = {};
  for (int k0 = 0; k0 < Kd; k0 += 16) {
    for (int t2 = threadIdx.x; t2 < 1024; t2 += 256) {
      int mm = t2 & 63, kk = t2 >> 6;
      As[kk][mm] = A[(size_t)(k0 + kk) * M + bm + mm];
      Bs[kk][mm] = B[(size_t)(k0 + kk) * P + bp + mm];
    }
    __syncthreads();
#pragma unroll
    for (int kk = 0; kk < 16; kk++) {
      float av[4], bv[4];
#pragma unroll
      for (int a = 0; a < 4; a++) av[a] = As[kk][ty * 4 + a];
#pragma unroll
      for (int b = 0; b < 4; b++) bv[b] = Bs[kk][tx * 4 + b];
#pragma unroll
      for (int a = 0; a < 4; a++)
#pragma unroll
        for (int b = 0; b < 4; b++) acc[a][b] += av[a] * bv[b];
    }
    __syncthreads();
  }
#pragma unroll
  for (int a = 0; a < 4; a++)
#pragma unroll
    for (int b = 0; b < 4; b++)
      Cm[(size_t)(bm + ty * 4 + a) * P + bp + tx * 4 + b] = acc[a][b];
}

__global__ void __launch_bounds__(256) k_gemm_nt(const float* __restrict__ A, const float* __restrict__ B,
                                                 float* __restrict__ Cm, int M, int P, int Kd) {
  __shared__ float As[16][65], Bs[16][65];
  int bm = blockIdx.x * 64, bp = blockIdx.y * 64;
  int tx = threadIdx.x & 15, ty = threadIdx.x >> 4;
  float acc[4][4] = {};
  for (int k0 = 0; k0 < Kd; k0 += 16) {
    for (int t2 = threadIdx.x; t2 < 1024; t2 += 256) {
      int kk = t2 & 15, mm = t2 >> 4;
      As[kk][mm] = A[(size_t)(bm + mm) * Kd + k0 + kk];
      Bs[kk][mm] = B[(size_t)(bp + mm) * Kd + k0 + kk];
    }
    __syncthreads();
#pragma unroll
    for (int kk = 0; kk < 16; kk++) {
      float av[4], bv[4];
#pragma unroll
      for (int a = 0; a < 4; a++) av[a] = As[kk][ty * 4 + a];
#pragma unroll
      for (int b = 0; b < 4; b++) bv[b] = Bs[kk][tx * 4 + b];
#pragma unroll
      for (int a = 0; a < 4; a++)
#pragma unroll
        for (int b = 0; b < 4; b++) acc[a][b] += av[a] * bv[b];
    }
    __syncthreads();
  }
#pragma unroll
  for (int a = 0; a < 4; a++)
#pragma unroll
    for (int b = 0; b < 4; b++)
      Cm[(size_t)(bm + ty * 4 + a) * P + bp + tx * 4 + b] = acc[a][b];
}

__global__ void __launch_bounds__(256) k_gemm_nn(const float* __restrict__ A, const float* __restrict__ B,
                                                 float* __restrict__ Cm, int M, int P, int Kd) {
  __shared__ float As[16][65], Bs[16][65];
  int bm = blockIdx.x * 64, bp = blockIdx.y * 64;
  int tx = threadIdx.x & 15, ty = threadIdx.x >> 4;
  float acc[4][4] = {};
  for (int k0 = 0; k0 < Kd; k0 += 16) {
    for (int t2 = threadIdx.x; t2 < 1024; t2 += 256) {
      int kk = t2 & 15, mm = t2 >> 4;
      As[kk][mm] = A[(size_t)(bm + mm) * Kd + k0 + kk];
    }
    for (int t2 = threadIdx.x; t2 < 1024; t2 += 256) {
      int mm = t2 & 63, kk = t2 >> 6;
      Bs[kk][mm] = B[(size_t)(k0 + kk) * P + bp + mm];
    }
    __syncthreads();
#pragma unroll
    for (int kk = 0; kk < 16; kk++) {
      float av[4], bv[4];
#pragma unroll
      for (int a = 0; a < 4; a++) av[a] = As[kk][ty * 4 + a];
#pragma unroll
      for (int b = 0; b < 4; b++) bv[b] = Bs[kk][tx * 4 + b];
#pragma unroll
      for (int a = 0; a < 4; a++)
#pragma unroll
        for (int b = 0; b < 4; b++) acc[a][b] += av[a] * bv[b];
    }
    __syncthreads();
  }
#pragma unroll
  for (int a = 0; a < 4; a++)
#pragma unroll
    for (int b = 0; b < 4; b++)
      Cm[(size_t)(bm + ty * 4 + a) * P + bp + tx * 4 + b] = acc[a][b];
}

// ---------- s = max(max ev_a, max ev_b) ----------
__global__ void k_smax(const float* __restrict__ ea, const float* __restrict__ eb, double* __restrict__ scal) {
  __shared__ float red[128];
  int t = threadIdx.x;
  red[t] = fmaxf(ea[t], eb[t]);
  __syncthreads();
  for (int o = 64; o > 0; o >>= 1) { if (t < o) red[t] = fmaxf(red[t], red[t + o]); __syncthreads(); }
  if (t == 0) scal[1] = (double)red[0];
}

// ---------- resolvent mask ----------
__global__ void k_mask(const float* __restrict__ evr, const float* __restrict__ evc,
                       const double* __restrict__ scal, float* __restrict__ Dm) {
  int t = blockIdx.x * 256 + threadIdx.x;
  if (t >= SK * SK) return;
  int i = t / SK, j = t % SK;
  float s = (float)scal[1];
  float g1 = sqrtf(fmaxf(evc[j] / s, 0.f));
  float g2 = sqrtf(fmaxf(evr[i] / s, 0.f));
  float a2 = g2 * g2 + 1.f, a1 = g1 * g1 + 1.f;
  float re = g2 / a2 - g1 / a1;
  float im = 1.f / a2 - 1.f / a1;
  Dm[t] = re * re + im * im;
}

// ---------- per-row Cholesky solve ----------
__global__ void __launch_bounds__(128) k_cholsolve(const float* __restrict__ AAt, const float* __restrict__ BAt,
                                                   const float* __restrict__ Dm, float* __restrict__ Msg,
                                                   float* __restrict__ Cout) {
  __shared__ float xs[SK];
  int i = blockIdx.x;
  float* Ms = Msg + (size_t)i * SK * SK;
  for (int t2 = threadIdx.x; t2 < SK * SK; t2 += 128) {
    int r = t2 / SK, c2 = t2 % SK;
    float v = AAt[t2];
    if (r == c2) v += LAMBDA_ * Dm[(size_t)i * SK + r];
    Ms[t2] = v;
  }
  if (threadIdx.x < SK) xs[threadIdx.x] = BAt[(size_t)i * SK + threadIdx.x];
  __syncthreads();
  for (int k = 0; k < SK; k++) {
    if (threadIdx.x == 0) Ms[k * SK + k] = sqrtf(fmaxf(Ms[k * SK + k], 1e-20f));
    __syncthreads();
    float dk = Ms[k * SK + k];
    for (int r = k + 1 + threadIdx.x; r < SK; r += 128) Ms[r * SK + k] /= dk;
    __syncthreads();
    int rem = SK - k - 1;
    for (int t2 = threadIdx.x; t2 < rem * rem; t2 += 128) {
      int r = k + 1 + t2 / rem, c2 = k + 1 + t2 % rem;
      Ms[r * SK + c2] -= Ms[r * SK + k] * Ms[c2 * SK + k];
    }
    __syncthreads();
  }
  for (int k = 0; k < SK; k++) {
    if (threadIdx.x == 0) xs[k] /= Ms[k * SK + k];
    __syncthreads();
    float xv = xs[k];
    for (int r = k + 1 + threadIdx.x; r < SK; r += 128) xs[r] -= Ms[r * SK + k] * xv;
    __syncthreads();
  }
  for (int k = SK - 1; k >= 0; k--) {
    if (threadIdx.x == 0) xs[k] /= Ms[k * SK + k];
    __syncthreads();
    float xv = xs[k];
    for (int r = threadIdx.x; r < k; r += 128) xs[r] -= Ms[k * SK + r] * xv;
    __syncthreads();
  }
  for (int t2 = threadIdx.x; t2 < SK; t2 += 128) Cout[(size_t)i * SK + t2] = xs[t2];
}

// ---------- loss partials (deterministic) ----------
__global__ void k_frob_iden(const float* __restrict__ Mat, double* __restrict__ lpart, int slot) {
  __shared__ double red[256];
  double s = 0.0;
  for (int t2 = blockIdx.x * 256 + threadIdx.x; t2 < SK * SK; t2 += 32 * 256) {
    float v = Mat[t2] - ((t2 / SK == t2 % SK) ? 1.f : 0.f);
    s += (double)v * (double)v;
  }
  red[threadIdx.x] = s; __syncthreads();
  for (int o = 128; o > 0; o >>= 1) { if (threadIdx.x < o) red[threadIdx.x] += red[threadIdx.x + o]; __syncthreads(); }
  if (threadIdx.x == 0) lpart[slot * 32 + blockIdx.x] = red[0];
}
__global__ void k_lap(const float* __restrict__ Cm, const float* __restrict__ evc,
                      const float* __restrict__ evr, double* __restrict__ lpart, int slot) {
  __shared__ double red[256];
  double s = 0.0;
  for (int t2 = blockIdx.x * 256 + threadIdx.x; t2 < SK * SK; t2 += 32 * 256) {
    int i = t2 / SK, j = t2 % SK;
    float v = Cm[t2] * (evc[j] - evr[i]);
    s += (double)v * (double)v;
  }
  red[threadIdx.x] = s; __syncthreads();
  for (int o = 128; o > 0; o >>= 1) { if (threadIdx.x < o) red[threadIdx.x] += red[threadIdx.x + o]; __syncthreads(); }
  if (threadIdx.x == 0) lpart[slot * 32 + blockIdx.x] = red[0];
}
__global__ void k_writeout(const double* __restrict__ lpart, float* __restrict__ out) {
  if (threadIdx.x == 0) {
    double b = 0.0, o = 0.0, l = 0.0;
    for (int s = 0; s < 64; s++) b += lpart[s];
    for (int s = 64; s < 128; s++) o += lpart[s];
    for (int s = 128; s < 192; s++) l += lpart[s];
    out[0] = (float)b; out[1] = (float)o; out[2] = (float)l;
  }
}

extern "C" void kernel_launch(void* const* d_in, const int* in_sizes, int n_in,
                              void* d_out, int out_size, void* d_ws, size_t ws_size,
                              hipStream_t stream) {
  const float* feats[2] = {(const float*)d_in[0], (const float*)d_in[1]};
  char* p = (char*)d_ws;
  auto alloc = [&](size_t bytes) -> void* {
    char* r = p;
    p += (bytes + 255) & ~(size_t)255;
    return (void*)r;
  };
  float* pan   = (float*)alloc(sizeof(float) * 256 * NN);
  float* sq    = (float*)alloc(sizeof(float) * NN);
  float* dkv   = (float*)alloc(sizeof(float) * (size_t)NN * KK);
  float* wv    = (float*)alloc(sizeof(float) * (size_t)NN * KK);
  int*   cnt   = (int*)alloc(sizeof(int) * NN);
  int*   rpos  = (int*)alloc(sizeof(int) * NN);
  int*   tsrc  = (int*)alloc(sizeof(int) * (size_t)NN * KK);
  float* deg   = (float*)alloc(sizeof(float) * NN);
  int*   hist  = (int*)alloc(sizeof(int) * 256 * NN);
  int*   baseb = (int*)alloc(sizeof(int) * 256 * NN);
  int*   idxs[2];  float* wadjrs[2]; float* wadjts[2]; int* tcols[2]; int* roffs[2];
  for (int s = 0; s < 2; s++) {
    idxs[s]   = (int*)alloc(sizeof(int) * (size_t)NN * KK);
    wadjrs[s] = (float*)alloc(sizeof(float) * (size_t)NN * KK);
    wadjts[s] = (float*)alloc(sizeof(float) * (size_t)NN * KK);
    tcols[s]  = (int*)alloc(sizeof(int) * (size_t)NN * KK);
    roffs[s]  = (int*)alloc(sizeof(int) * (NN + 1));
  }
  float* Q0    = (float*)alloc(sizeof(float) * (size_t)LM * NN);
  float* Q1    = (float*)alloc(sizeof(float) * (size_t)LM * NN);
  float* ya0   = (float*)alloc(sizeof(float) * NN);
  float* ya1   = (float*)alloc(sizeof(float) * NN);
  float* yb0   = (float*)alloc(sizeof(float) * NN);
  float* yb1   = (float*)alloc(sizeof(float) * NN);
  float* cv0   = (float*)alloc(sizeof(float) * LM);
  float* cv1   = (float*)alloc(sizeof(float) * LM);
  double* part = (double*)alloc(sizeof(double) * 256);
  double* scal = (double*)alloc(sizeof(double) * 8);
  double* Ta0  = (double*)alloc(sizeof(double) * LM);
  double* Tb0  = (double*)alloc(sizeof(double) * LM);
  double* Ta1  = (double*)alloc(sizeof(double) * LM);
  double* Tb1  = (double*)alloc(sizeof(double) * LM);
  double* theta= (double*)alloc(sizeof(double) * SK);
  double* dws  = (double*)alloc(sizeof(double) * (size_t)LM * SK);
  double* ews  = (double*)alloc(sizeof(double) * (size_t)LM * SK);
  double* fws  = (double*)alloc(sizeof(double) * (size_t)LM * SK);
  double* rws  = (double*)alloc(sizeof(double) * (size_t)LM * SK);
  float* Ym0   = (float*)alloc(sizeof(float) * (size_t)LM * SK);
  float* Ym1   = (float*)alloc(sizeof(float) * (size_t)LM * SK);
  float* Ym2   = (float*)alloc(sizeof(float) * (size_t)LM * SK);
  float* Sm    = (float*)alloc(sizeof(float) * SK * SK);
  float* Linv  = (float*)alloc(sizeof(float) * SK * SK);
  float* U0    = (float*)alloc(sizeof(float) * (size_t)NN * SK);
  float* U1    = (float*)alloc(sizeof(float) * (size_t)NN * SK);
  float* ev0   = (float*)alloc(sizeof(float) * SK);
  float* ev1   = (float*)alloc(sizeof(float) * SK);
  float* Ac    = (float*)alloc(sizeof(float) * (size_t)SK * NC);
  float* Bc    = (float*)alloc(sizeof(float) * (size_t)SK * NC);
  float* AAt   = (float*)alloc(sizeof(float) * SK * SK);
  float* BAt   = (float*)alloc(sizeof(float) * SK * SK);
  float* Dm    = (float*)alloc(sizeof(float) * SK * SK);
  float* Cxy   = (float*)alloc(sizeof(float) * SK * SK);
  float* Cyx   = (float*)alloc(sizeof(float) * SK * SK);
  float* P1    = (float*)alloc(sizeof(float) * SK * SK);
  float* Msg   = (float*)alloc(sizeof(float) * (size_t)SK * SK * SK);
  double* lpart= (double*)alloc(sizeof(double) * 192);
  unsigned* sy = (unsigned*)alloc(sizeof(unsigned) * 1024);

  double* Tas[2] = {Ta0, Ta1};
  double* Tbs[2] = {Tb0, Tb1};
  float* Yms[2] = {Ym0, Ym1};
  float* Qs2[2] = {Q0, Q1};
  float* Us[2] = {U0, U1};
  float* evs[2] = {ev0, ev1};

  hipFuncSetAttribute((const void*)k_lanczos2,
                      hipFuncAttributeMaxDynamicSharedMemorySize, DYNLDS);
  hipFuncSetAttribute((const void*)k_cholinv,
                      hipFuncAttributeMaxDynamicSharedMemorySize, CHOLLDS);

  // ---- kNN graph construction for both sides ----
  for (int s2 = 0; s2 < 2; s2++) {
    const float* f = feats[s2];
    int* idx = idxs[s2];
    k_sqnorm<<<NN, 256, 0, stream>>>(f, sq);
    for (int p2 = 0; p2 < 16; p2++) {
      k_d2panel<<<dim3(64, 4), 256, 0, stream>>>(f, sq, pan, p2 * 256);
      k_topk<<<256, 256, 0, stream>>>(pan, p2 * 256, idx, dkv);
    }
    k_partsum<<<64, 256, 0, stream>>>(dkv, part);
    k_sigma<<<1, 64, 0, stream>>>(part, scal);
    k_wexp<<<NN * KK / 256, 256, 0, stream>>>(dkv, scal, wv);
    hipMemsetAsync(cnt, 0, sizeof(int) * NN, stream);
    k_count<<<NN * KK / 256, 256, 0, stream>>>(idx, cnt);
    k_scan<<<1, 1024, 0, stream>>>(cnt, roffs[s2], rpos);
    hipMemsetAsync(hist, 0, sizeof(int) * 256 * NN, stream);
    k_hist<<<256, 256, 0, stream>>>(idx, hist);
    k_colscan<<<16, 256, 0, stream>>>(hist, roffs[s2], baseb);
    k_place2<<<256, 256, 0, stream>>>(idx, baseb, tsrc);
    k_deg<<<16, 256, 0, stream>>>(wv, roffs[s2], tsrc, deg);
    k_wadj2<<<16, 256, 0, stream>>>(wv, idx, roffs[s2], tsrc, deg,
                                    wadjrs[s2], wadjts[s2], tcols[s2]);
  }

  // ---- dual-side fused cooperative Lanczos ----
  hipMemsetAsync(sy, 0, sizeof(unsigned) * 1024, stream);
  {
    void* args[] = {(void*)&Q0, (void*)&Q1,
                    (void*)&ya0, (void*)&ya1, (void*)&yb0, (void*)&yb1,
                    (void*)&wadjrs[0], (void*)&idxs[0], (void*)&wadjts[0], (void*)&tcols[0], (void*)&roffs[0],
                    (void*)&wadjrs[1], (void*)&idxs[1], (void*)&wadjts[1], (void*)&tcols[1], (void*)&roffs[1],
                    (void*)&cv0, (void*)&cv1, (void*)&part,
                    (void*)&Ta0, (void*)&Tb0, (void*)&Ta1, (void*)&Tb1,
                    (void*)&sy};
    hipLaunchCooperativeKernel((const void*)k_lanczos2, dim3(256), dim3(1024), args, DYNLDS, stream);
  }

  // ---- per-side spectral finish (CholQR2) ----
  for (int s2 = 0; s2 < 2; s2++) {
    k_bisect<<<1, 128, 0, stream>>>(Tas[s2], Tbs[s2], theta, evs[s2]);
    k_invit<<<1, 128, 0, stream>>>(Tas[s2], Tbs[s2], theta, dws, ews, fws, rws, Yms[s2]);
    k_gemm_tn<<<dim3(2, 2), 256, 0, stream>>>(Yms[s2], Yms[s2], Sm, SK, SK, LM);
    k_cholinv<<<1, 128, CHOLLDS, stream>>>(Sm, Linv);
    k_gemm_nt<<<dim3(LM / 64, 2), 256, 0, stream>>>(Yms[s2], Linv, Ym2, LM, SK, SK);
    k_gemm_tn<<<dim3(2, 2), 256, 0, stream>>>(Ym2, Ym2, Sm, SK, SK, LM);
    k_cholinv<<<1, 128, CHOLLDS, stream>>>(Sm, Linv);
    k_gemm_nt<<<dim3(LM / 64, 2), 256, 0, stream>>>(Ym2, Linv, Yms[s2], LM, SK, SK);
    k_gemm_tn<<<dim3(NN / 64, SK / 64), 256, 0, stream>>>(Qs2[s2], Yms[s2], Us[s2], NN, SK, LM);
  }

  // ---- spectral coefficients + FM solves + losses ----
  k_gemm_tn<<<dim3(SK / 64, NC / 64), 256, 0, stream>>>(U0, feats[0], Ac, SK, NC, NN);
  k_gemm_tn<<<dim3(SK / 64, NC / 64), 256, 0, stream>>>(U1, feats[1], Bc, SK, NC, NN);
  k_smax<<<1, 128, 0, stream>>>(ev0, ev1, scal);

  k_gemm_nt<<<dim3(2, 2), 256, 0, stream>>>(Ac, Ac, AAt, SK, SK, NC);
  k_gemm_nt<<<dim3(2, 2), 256, 0, stream>>>(Bc, Ac, BAt, SK, SK, NC);
  k_mask<<<64, 256, 0, stream>>>(ev1, ev0, scal, Dm);
  k_cholsolve<<<SK, 128, 0, stream>>>(AAt, BAt, Dm, Msg, Cxy);
  k_gemm_nt<<<dim3(2, 2), 256, 0, stream>>>(Bc, Bc, AAt, SK, SK, NC);
  k_gemm_nt<<<dim3(2, 2), 256, 0, stream>>>(Ac, Bc, BAt, SK, SK, NC);
  k_mask<<<64, 256, 0, stream>>>(ev0, ev1, scal, Dm);
  k_cholsolve<<<SK, 128, 0, stream>>>(AAt, BAt, Dm, Msg, Cyx);

  k_gemm_nn<<<dim3(2, 2), 256, 0, stream>>>(Cxy, Cyx, P1, SK, SK, SK);
  k_frob_iden<<<32, 256, 0, stream>>>(P1, lpart, 0);
  k_gemm_nn<<<dim3(2, 2), 256, 0, stream>>>(Cyx, Cxy, P1, SK, SK, SK);
  k_frob_iden<<<32, 256, 0, stream>>>(P1, lpart, 1);
  k_gemm_tn<<<dim3(2, 2), 256, 0, stream>>>(Cxy, Cxy, P1, SK, SK, SK);
  k_frob_iden<<<32, 256, 0, stream>>>(P1, lpart, 2);
  k_gemm_tn<<<dim3(2, 2), 256, 0, stream>>>(Cyx, Cyx, P1, SK, SK, SK);
  k_frob_iden<<<32, 256, 0, stream>>>(P1, lpart, 3);
  k_lap<<<32, 256, 0, stream>>>(Cxy, ev0, ev1, lpart, 4);
  k_lap<<<32, 256, 0, stream>>>(Cyx, ev1, ev0, lpart, 5);
  k_writeout<<<1, 64, 0, stream>>>(lpart, (float*)d_out);
}

// Round 11
// 41240.292 us; speedup vs baseline: 19.5786x; 1.3191x over previous
//
#include <hip/hip_runtime.h>
#include <math.h>

#define NN 4096      // points
#define NC 768       // feature dim
#define KK 16        // knn k
#define SK 128       // spectral basis size
#define LM 768       // Lanczos steps (6x oversampling of SK)
#define NR (LM / 128) // dots rows per block
#define LAMBDA_ 100.0f
// dynamic LDS for lanczos2: slab[LM][32] + ysh[NN] + cvsh[LM]
#define DYNLDS (LM * 32 * 4 + NN * 4 + LM * 4)
// dynamic LDS for cholinv: Ls[SK][SK+1] + Li[SK][SK+1]
#define CHOLLDS (2 * SK * (SK + 1) * 4)

typedef unsigned int u32;

__device__ __forceinline__ float hashf(u32 x) {
  x ^= x >> 16; x *= 0x7feb352dU; x ^= x >> 15; x *= 0x846ca68bU; x ^= x >> 16;
  return ((float)x) * (1.0f / 4294967296.0f);  // [0,1)
}

// ---- agent-scope (device-coherent) access helpers ----
__device__ __forceinline__ float agld(const float* p) {
  return __hip_atomic_load((float*)p, __ATOMIC_RELAXED, __HIP_MEMORY_SCOPE_AGENT);
}
__device__ __forceinline__ void agst(float* p, float v) {
  __hip_atomic_store(p, v, __ATOMIC_RELAXED, __HIP_MEMORY_SCOPE_AGENT);
}
__device__ __forceinline__ double agldd(const double* p) {
  return __hip_atomic_load((double*)p, __ATOMIC_RELAXED, __HIP_MEMORY_SCOPE_AGENT);
}
__device__ __forceinline__ void agstd(double* p, double v) {
  __hip_atomic_store(p, v, __ATOMIC_RELAXED, __HIP_MEMORY_SCOPE_AGENT);
}

// ---- per-side two-level tree barrier (128 blocks: 8 groups x 16) ----
__device__ __forceinline__ void gbar2(unsigned* syb, int lb, unsigned gph) {
  asm volatile("s_waitcnt vmcnt(0)" ::: "memory");
  __syncthreads();
  if (threadIdx.x == 0) {
    const int grp = lb >> 4, mem = lb & 15;
    unsigned* gc  = syb + grp * 16;
    unsigned* top = syb + 144;
    unsigned* fl  = syb + 256 + grp * 16;
    __hip_atomic_fetch_add(gc, 1u, __ATOMIC_RELEASE, __HIP_MEMORY_SCOPE_AGENT);
    if (mem == 0) {
      while (__hip_atomic_load(gc, __ATOMIC_RELAXED, __HIP_MEMORY_SCOPE_AGENT) < gph * 16u)
        __builtin_amdgcn_s_sleep(2);
      __hip_atomic_fetch_add(top, 1u, __ATOMIC_RELEASE, __HIP_MEMORY_SCOPE_AGENT);
      while (__hip_atomic_load(top, __ATOMIC_RELAXED, __HIP_MEMORY_SCOPE_AGENT) < gph * 8u)
        __builtin_amdgcn_s_sleep(2);
      __hip_atomic_store(fl, gph, __ATOMIC_RELEASE, __HIP_MEMORY_SCOPE_AGENT);
    } else {
      while (__hip_atomic_load(fl, __ATOMIC_RELAXED, __HIP_MEMORY_SCOPE_AGENT) < gph)
        __builtin_amdgcn_s_sleep(2);
    }
    __builtin_amdgcn_fence(__ATOMIC_ACQUIRE, "agent");
  }
  __syncthreads();
}

// ---------- row squared norms ----------
__global__ void k_sqnorm(const float* __restrict__ f, float* __restrict__ sq) {
  __shared__ float red[256];
  int i = blockIdx.x;
  float s = 0.f;
  for (int c = threadIdx.x; c < NC; c += 256) { float v = f[(size_t)i * NC + c]; s += v * v; }
  red[threadIdx.x] = s; __syncthreads();
  for (int o = 128; o > 0; o >>= 1) { if (threadIdx.x < o) red[threadIdx.x] += red[threadIdx.x + o]; __syncthreads(); }
  if (threadIdx.x == 0) sq[i] = red[0];
}

// ---------- d2 panel ----------
__global__ void __launch_bounds__(256) k_d2panel(const float* __restrict__ f, const float* __restrict__ sq,
                                                 float* __restrict__ pan, int i0) {
  __shared__ float As[16][65], Bs[16][65];
  int bj = blockIdx.x, bi = blockIdx.y;
  int row0 = i0 + bi * 64, col0 = bj * 64;
  int tx = threadIdx.x & 15, ty = threadIdx.x >> 4;
  float acc[4][4] = {};
  for (int k0 = 0; k0 < NC; k0 += 16) {
    for (int t2 = threadIdx.x; t2 < 1024; t2 += 256) {
      int kk = t2 & 15, rr = t2 >> 4;
      As[kk][rr] = f[(size_t)(row0 + rr) * NC + k0 + kk];
      Bs[kk][rr] = f[(size_t)(col0 + rr) * NC + k0 + kk];
    }
    __syncthreads();
#pragma unroll
    for (int kk = 0; kk < 16; kk++) {
      float av[4], bv[4];
#pragma unroll
      for (int a = 0; a < 4; a++) av[a] = As[kk][ty * 4 + a];
#pragma unroll
      for (int b = 0; b < 4; b++) bv[b] = Bs[kk][tx * 4 + b];
#pragma unroll
      for (int a = 0; a < 4; a++)
#pragma unroll
        for (int b = 0; b < 4; b++) acc[a][b] += av[a] * bv[b];
    }
    __syncthreads();
  }
#pragma unroll
  for (int a = 0; a < 4; a++) {
    int gr = row0 + ty * 4 + a;
    int pr = bi * 64 + ty * 4 + a;
    float sr = sq[gr];
#pragma unroll
    for (int b = 0; b < 4; b++) {
      int gc = col0 + tx * 4 + b;
      float v = sr + sq[gc] - 2.f * acc[a][b];
      v = fmaxf(v, 0.f);
      if (gr == gc) v += 1e10f;
      pan[(size_t)pr * NN + gc] = v;
    }
  }
}

// ---------- top-16 smallest per row ----------
__global__ void __launch_bounds__(256) k_topk(const float* __restrict__ pan, int i0,
                                              int* __restrict__ idx, float* __restrict__ dkv) {
  __shared__ float vals[NN];
  __shared__ float rv[256];
  __shared__ int ri[256];
  int r = blockIdx.x;
  const float* row = pan + (size_t)r * NN;
  for (int j = threadIdx.x; j < NN; j += 256) vals[j] = row[j];
  __syncthreads();
  for (int t3 = 0; t3 < KK; t3++) {
    float bv = 1e30f; int bi2 = NN;
    for (int j2 = threadIdx.x; j2 < NN; j2 += 256) {
      float v = vals[j2];
      if (v < bv || (v == bv && j2 < bi2)) { bv = v; bi2 = j2; }
    }
    rv[threadIdx.x] = bv; ri[threadIdx.x] = bi2;
    __syncthreads();
    for (int o = 128; o > 0; o >>= 1) {
      if (threadIdx.x < o) {
        float v2 = rv[threadIdx.x + o]; int i2 = ri[threadIdx.x + o];
        if (v2 < rv[threadIdx.x] || (v2 == rv[threadIdx.x] && i2 < ri[threadIdx.x])) {
          rv[threadIdx.x] = v2; ri[threadIdx.x] = i2;
        }
      }
      __syncthreads();
    }
    if (threadIdx.x == 0) {
      idx[(size_t)(i0 + r) * KK + t3] = ri[0];
      dkv[(size_t)(i0 + r) * KK + t3] = rv[0];
      vals[ri[0]] = 1e30f;
    }
    __syncthreads();
  }
}

// ---------- sigma2 ----------
__global__ void k_partsum(const float* __restrict__ dkv, double* __restrict__ part) {
  __shared__ double red[256];
  double s = 0.0;
  for (int t2 = blockIdx.x * 256 + threadIdx.x; t2 < NN * KK; t2 += 64 * 256) s += (double)dkv[t2];
  red[threadIdx.x] = s; __syncthreads();
  for (int o = 128; o > 0; o >>= 1) { if (threadIdx.x < o) red[threadIdx.x] += red[threadIdx.x + o]; __syncthreads(); }
  if (threadIdx.x == 0) part[blockIdx.x] = red[0];
}
__global__ void k_sigma(const double* __restrict__ part, double* __restrict__ scal) {
  __shared__ double red[64];
  red[threadIdx.x] = part[threadIdx.x]; __syncthreads();
  for (int o = 32; o > 0; o >>= 1) { if (threadIdx.x < o) red[threadIdx.x] += red[threadIdx.x + o]; __syncthreads(); }
  if (threadIdx.x == 0) scal[0] = red[0] / (double)(NN * KK) + 1e-12;
}

// ---------- gaussian weights ----------
__global__ void k_wexp(const float* __restrict__ dkv, const double* __restrict__ scal,
                       float* __restrict__ wv) {
  int t = blockIdx.x * 256 + threadIdx.x;
  if (t >= NN * KK) return;
  float inv2s = (float)(0.5 / scal[0]);
  wv[t] = expf(-dkv[t] * inv2s);
}

// ---------- deterministic CSR transpose: counting-sort ----------
__global__ void k_count(const int* __restrict__ idx, int* __restrict__ cnt) {
  int t = blockIdx.x * 256 + threadIdx.x;
  if (t < NN * KK) atomicAdd(&cnt[idx[t]], 1);
}

__global__ void __launch_bounds__(1024) k_scan(const int* __restrict__ cnt,
                                               int* __restrict__ roff, int* __restrict__ rpos) {
  __shared__ int buf[1024];
  int t = threadIdx.x;
  int v[4]; int s = 0;
#pragma unroll
  for (int u = 0; u < 4; u++) { v[u] = cnt[t * 4 + u]; s += v[u]; }
  buf[t] = s; __syncthreads();
  for (int o = 1; o < 1024; o <<= 1) {
    int x = (t >= o) ? buf[t - o] : 0;
    __syncthreads();
    buf[t] += x;
    __syncthreads();
  }
  int run = (t == 0) ? 0 : buf[t - 1];
#pragma unroll
  for (int u = 0; u < 4; u++) { roff[t * 4 + u] = run; rpos[t * 4 + u] = run; run += v[u]; }
  if (t == 1023) roff[NN] = run;
}

__global__ void k_hist(const int* __restrict__ idx, int* __restrict__ hist) {
  int e = blockIdx.x * 256 + threadIdx.x;
  atomicAdd(&hist[(e >> 8) * NN + idx[e]], 1);
}
__global__ void k_colscan(const int* __restrict__ hist, const int* __restrict__ roff,
                          int* __restrict__ baseb) {
  int j = blockIdx.x * 256 + threadIdx.x;
  if (j >= NN) return;
  int run = roff[j];
  for (int c = 0; c < 256; c++) { baseb[c * NN + j] = run; run += hist[c * NN + j]; }
}
__global__ void __launch_bounds__(256) k_place2(const int* __restrict__ idx,
                                                const int* __restrict__ baseb,
                                                int* __restrict__ tsrc) {
  __shared__ int ish[256];
  int c = blockIdx.x;
  int e = c * 256 + threadIdx.x;
  ish[threadIdx.x] = idx[e];
  __syncthreads();
  int j = ish[threadIdx.x];
  int rank = 0;
  for (int p2 = 0; p2 < threadIdx.x; p2++) rank += (ish[p2] == j) ? 1 : 0;
  tsrc[baseb[c * NN + j] + rank] = e;
}

// ---------- degrees ----------
__global__ void k_deg(const float* __restrict__ wv, const int* __restrict__ roff,
                      const int* __restrict__ tsrc, float* __restrict__ deg) {
  int i = blockIdx.x * 256 + threadIdx.x;
  if (i >= NN) return;
  float s = 0.f;
  for (int l = 0; l < KK; l++) s += wv[(size_t)i * KK + l];
  float s2 = 0.f;
  for (int e = roff[i]; e < roff[i + 1]; e++) s2 += wv[tsrc[e]];
  deg[i] = 0.5f * (s + s2);
}

// ---------- normalized adjacency ----------
__global__ void k_wadj2(const float* __restrict__ wv, const int* __restrict__ idx,
                        const int* __restrict__ roff, const int* __restrict__ tsrc,
                        const float* __restrict__ deg,
                        float* __restrict__ wadjr, float* __restrict__ wadjt,
                        int* __restrict__ tcol) {
  int i = blockIdx.x * 256 + threadIdx.x;
  if (i >= NN) return;
  float di = 1.0f / sqrtf(deg[i] + 1e-8f);
  for (int l = 0; l < KK; l++) {
    int j = idx[(size_t)i * KK + l];
    float dj = 1.0f / sqrtf(deg[j] + 1e-8f);
    wadjr[(size_t)i * KK + l] = 0.5f * wv[(size_t)i * KK + l] * di * dj;
  }
  for (int e = roff[i]; e < roff[i + 1]; e++) {
    int s = tsrc[e];
    int sn = s / KK;
    float dj = 1.0f / sqrtf(deg[sn] + 1e-8f);
    wadjt[e] = 0.5f * wv[s] * di * dj;
    tcol[e] = sn;
  }
}

// ---------- DUAL-SIDE fused cooperative Lanczos, CGS1 (3 barriers/iter) ----------
// 256 blocks x 1024 threads; side s = b>>7, 128 blocks/side, 32 rows/block.
// Full reorthogonalization with ONE classical-GS pass per iteration (textbook
// full-reorth Lanczos); components removed are O(eps)-sized each step.
__global__ void __launch_bounds__(1024) k_lanczos2(
    float* __restrict__ Q0, float* __restrict__ Q1,
    float* __restrict__ ya0, float* __restrict__ ya1,
    float* __restrict__ yb0, float* __restrict__ yb1,
    const float* __restrict__ wadjr0, const int* __restrict__ idx0,
    const float* __restrict__ wadjt0, const int* __restrict__ tcol0, const int* __restrict__ roff0,
    const float* __restrict__ wadjr1, const int* __restrict__ idx1,
    const float* __restrict__ wadjt1, const int* __restrict__ tcol1, const int* __restrict__ roff1,
    float* __restrict__ cv0, float* __restrict__ cv1, double* __restrict__ part,
    double* __restrict__ Ta0, double* __restrict__ Tb0,
    double* __restrict__ Ta1, double* __restrict__ Tb1,
    unsigned* __restrict__ sy) {
  const int b = blockIdx.x, t = threadIdx.x;
  const int s = b >> 7, lb = b & 127;
  const int n0 = lb * 32;
  const int lane = t & 63, wvid = t >> 6;  // 16 waves
  float* Qs = s ? Q1 : Q0;
  float* ybuf0 = s ? yb0 : ya0;
  float* ybuf1 = s ? yb1 : ya1;
  const float* wadjr = s ? wadjr1 : wadjr0;
  const int* idx = s ? idx1 : idx0;
  const float* wadjt = s ? wadjt1 : wadjt0;
  const int* tcol = s ? tcol1 : tcol0;
  const int* roff = s ? roff1 : roff0;
  float* cvs = s ? cv1 : cv0;
  double* ps = part + s * 128;
  double* Ta = s ? Ta1 : Ta0;
  double* Tb = s ? Tb1 : Tb0;
  unsigned* syb = sy + s * 512;
  u32 seed = 1234567u + (u32)s * 77777u;

  extern __shared__ char dynsh[];
  float* slabsh = (float*)dynsh;                      // [LM][32]
  float* ysh    = (float*)(dynsh + LM * 32 * 4);      // [NN]
  float* cvsh   = (float*)(dynsh + LM * 32 * 4 + NN * 4);  // [LM]
  __shared__ double pd[2];
  __shared__ double wl[16][NR];
  __shared__ float fredu[32][33];
  __shared__ float r2loc[32];
  unsigned gph = 0;

  // init residual + norm partial
  if (t < 32) {
    int n = n0 + t;
    agst(&ybuf0[n], hashf((u32)n * 2246822519u + seed) - 0.5f);
  }
  __syncthreads();
  if (t == 0) {
    double ss = 0.0;
    for (int u = 0; u < 32; u++) { double v = (double)agld(&ybuf0[n0 + u]); ss += v * v; }
    agstd(&ps[lb], ss);
  }
  gbar2(syb, lb, ++gph);

  for (int it = 0; it < LM; it++) {
    float* r  = (it & 1) ? ybuf1 : ybuf0;
    float* r2 = (it & 1) ? ybuf0 : ybuf1;

    // ---- Phase A: stage r, single-wave norm, q-row write (+slab), SpMV ----
    {
      int b4 = t * 4;
      float a0 = agld(&r[b4]), a1 = agld(&r[b4 + 1]);
      float a2 = agld(&r[b4 + 2]), a3 = agld(&r[b4 + 3]);
      ysh[b4] = a0; ysh[b4 + 1] = a1; ysh[b4 + 2] = a2; ysh[b4 + 3] = a3;
    }
    if (t < 64) {
      double v = agldd(&ps[t]) + agldd(&ps[t + 64]);
      for (int o = 32; o > 0; o >>= 1) v += __shfl_down(v, o, 64);
      if (t == 0) pd[0] = v;
    }
    __syncthreads();
    double nrm = sqrt(pd[0]);
    if (lb == 0 && t == 0 && it > 0) agstd(&Tb[it - 1], nrm);
    float inv = (float)(1.0 / (nrm > 1e-300 ? nrm : 1e-300));
    if (t < 32) {
      int n = n0 + t;
      float qv = ysh[n] * inv;
      agst(&Qs[(size_t)it * NN + n], qv);
      slabsh[it * 32 + t] = qv;
    }
#pragma unroll
    for (int rr = 0; rr < 2; rr++) {
      int n = n0 + wvid + rr * 16;       // 2 rows per wave
      int rb = roff[n], re = roff[n + 1];
      int L = 16 + (re - rb);
      float acc = 0.f;
      for (int i = lane; i < L; i += 64) {
        float w, qv;
        if (i < 16) { w = wadjr[(size_t)n * KK + i]; qv = ysh[idx[(size_t)n * KK + i]] * inv; }
        else        { int e = rb + i - 16; w = wadjt[e]; qv = ysh[tcol[e]] * inv; }
        acc += w * qv;
      }
      for (int o = 32; o > 0; o >>= 1) acc += __shfl_down(acc, o, 64);
      if (lane == 0) { agst(&r2[n], acc); r2loc[wvid + rr * 16] = acc; }
    }
    gbar2(syb, lb, ++gph);

    // ---- Phase B: dots (single CGS pass), register-direct loads ----
    {
      float4 yv4;
      int b4 = t * 4;
      yv4.x = agld(&r2[b4]); yv4.y = agld(&r2[b4 + 1]);
      yv4.z = agld(&r2[b4 + 2]); yv4.w = agld(&r2[b4 + 3]);
      double sa[NR];
#pragma unroll
      for (int rsel = 0; rsel < NR; rsel++) {
        int j = lb + rsel * 128;
        sa[rsel] = 0.0;
        if (j <= it) {
          float4 q4 = *(const float4*)&Qs[(size_t)j * NN + t * 4];
          double d = (double)q4.x * yv4.x; d += (double)q4.y * yv4.y;
          d += (double)q4.z * yv4.z; d += (double)q4.w * yv4.w;
          sa[rsel] = d;
        }
      }
#pragma unroll
      for (int rsel = 0; rsel < NR; rsel++) {
        int j = lb + rsel * 128;
        if (j <= it) {
          double sd = sa[rsel];
          for (int o = 32; o > 0; o >>= 1) sd += __shfl_down(sd, o, 64);
          if (lane == 0) wl[wvid][rsel] = sd;
        }
      }
      __syncthreads();
      if (t < NR) {
        int j = lb + t * 128;
        if (j <= it) {
          double tot = 0.0;
          for (int u = 0; u < 16; u++) tot += wl[u][t];
          agst(&cvs[j], (float)tot);
          if (j == it) agstd(&Ta[it], tot);
        }
      }
      __syncthreads();
    }
    gbar2(syb, lb, ++gph);

    // ---- Phase C: update + next norm partial ----
    {
      for (int j2s = t; j2s <= it; j2s += 1024) cvsh[j2s] = agld(&cvs[j2s]);
      __syncthreads();
      int i2 = t & 31, g = t >> 5;     // 32 cols x 32 j-groups
      float s0 = 0.f, s1 = 0.f, s2 = 0.f, s3 = 0.f;
      int j = g;
      for (; j + 96 <= it; j += 128) {
        s0 += cvsh[j]      * slabsh[j * 32 + i2];
        s1 += cvsh[j + 32] * slabsh[(j + 32) * 32 + i2];
        s2 += cvsh[j + 64] * slabsh[(j + 64) * 32 + i2];
        s3 += cvsh[j + 96] * slabsh[(j + 96) * 32 + i2];
      }
      for (; j <= it; j += 32) s0 += cvsh[j] * slabsh[j * 32 + i2];
      fredu[g][i2] = (s0 + s1) + (s2 + s3);
      __syncthreads();
      if (t < 32) {
        float acc2 = 0.f;
        for (int g2 = 0; g2 < 32; g2++) acc2 += fredu[g2][t];
        float ny = r2loc[t] - acc2;
        agst(&r2[n0 + t], ny);
        r2loc[t] = ny;
      }
      __syncthreads();
      if (t == 0) {
        double s2d = 0.0;
        for (int u = 0; u < 32; u++) { double v = (double)r2loc[u]; s2d += v * v; }
        agstd(&ps[lb], s2d);
      }
    }
    gbar2(syb, lb, ++gph);
  }
}

// ---------- bisection (Ta/Tb^2 staged in LDS) ----------
__global__ void __launch_bounds__(128) k_bisect(const double* __restrict__ Ta, const double* __restrict__ Tb,
                                                double* __restrict__ theta, float* __restrict__ evL) {
  __shared__ double Tas[LM];
  __shared__ double Tb2[LM];
  int j = threadIdx.x;
  for (int k = j; k < LM; k += 128) {
    Tas[k] = Ta[k];
    double bq = (k > 0) ? Tb[k - 1] : 0.0;
    Tb2[k] = bq * bq;
  }
  __syncthreads();
  if (j >= SK) return;
  int tgt = LM - j;
  double lo = -2.0, hi = 2.0;
  for (int iter = 0; iter < 60; iter++) {
    double mid = 0.5 * (lo + hi);
    int cnt = 0; double q = 1.0;
    for (int k = 0; k < LM; k++) {
      q = Tas[k] - mid - Tb2[k] / q;
      if (q < 0.0) cnt++;
      if (fabs(q) < 1e-280) q = -1e-280;
    }
    if (cnt >= tgt) hi = mid; else lo = mid;
  }
  theta[j] = 0.5 * (lo + hi);
  evL[j] = (float)(1.0 - theta[j]);
}

// ---------- inverse iteration (Ta/Tb staged in LDS) ----------
__global__ void __launch_bounds__(128) k_invit(const double* __restrict__ Ta, const double* __restrict__ Tb,
                        const double* __restrict__ theta,
                        double* __restrict__ dws, double* __restrict__ ews,
                        double* __restrict__ fws, double* __restrict__ rws,
                        float* __restrict__ Ym) {
  __shared__ double Tas[LM];
  __shared__ double Tbs[LM];
  int j = threadIdx.x;
  for (int k = j; k < LM; k += 128) { Tas[k] = Ta[k]; Tbs[k] = Tb[k]; }
  __syncthreads();
  if (j >= SK) return;
  double sig = theta[j];
  for (int k = 0; k < LM; k++)
    rws[(size_t)k * SK + j] = (double)hashf((u32)k * 2654435761u + (u32)j * 40503u + 17u) - 0.5;
  for (int pass = 0; pass < 3; pass++) {
    double dk = Tas[0] - sig;
    double ek = Tbs[0];
    double fk = 0.0;
    double rk = rws[j];
    for (int k = 0; k < LM - 1; k++) {
      double bk = Tbs[k];
      double dn = Tas[k + 1] - sig;
      double en = (k + 2 < LM) ? Tbs[k + 1] : 0.0;
      double rn = rws[(size_t)(k + 1) * SK + j];
      double dd, ee, ff, dk2, ek2, rkeep, rnext;
      if (fabs(dk) >= fabs(bk)) {
        double dsafe = (fabs(dk) > 1e-300) ? dk : 1e-300;
        double m = bk / dsafe;
        dd = dsafe; ee = ek; ff = fk;
        dk2 = dn - m * ek;
        ek2 = en - m * fk;
        rkeep = rk;
        rnext = rn - m * rk;
      } else {
        double m = dk / bk;
        dd = bk; ee = dn; ff = en;
        dk2 = ek - m * dn;
        ek2 = fk - m * en;
        rkeep = rn;
        rnext = rk - m * rn;
      }
      dws[(size_t)k * SK + j] = dd;
      ews[(size_t)k * SK + j] = ee;
      fws[(size_t)k * SK + j] = ff;
      rws[(size_t)k * SK + j] = rkeep;
      rk = rnext; dk = dk2; ek = ek2; fk = 0.0;
    }
    if (fabs(dk) < 1e-300) dk = 1e-300;
    dws[(size_t)(LM - 1) * SK + j] = dk;
    ews[(size_t)(LM - 1) * SK + j] = 0.0;
    fws[(size_t)(LM - 1) * SK + j] = 0.0;
    rws[(size_t)(LM - 1) * SK + j] = rk;
    double y1 = 0.0, y2 = 0.0, nr = 0.0;
    for (int k = LM - 1; k >= 0; k--) {
      double dv = dws[(size_t)k * SK + j];
      double yk = (rws[(size_t)k * SK + j] - ews[(size_t)k * SK + j] * y1 - fws[(size_t)k * SK + j] * y2) / dv;
      rws[(size_t)k * SK + j] = yk;
      y2 = y1; y1 = yk;
      nr += yk * yk;
    }
    double inv = 1.0 / sqrt(nr > 1e-300 ? nr : 1e-300);
    for (int k = 0; k < LM; k++) rws[(size_t)k * SK + j] *= inv;
  }
  for (int k = 0; k < LM; k++) Ym[(size_t)k * SK + j] = (float)rws[(size_t)k * SK + j];
}

// ---------- Cholesky + lower-triangular inverse of SK x SK SPD matrix ----------
__global__ void __launch_bounds__(128) k_cholinv(const float* __restrict__ S,
                                                 float* __restrict__ Linv) {
  extern __shared__ float csh[];
  float (*Ls)[SK + 1] = (float(*)[SK + 1])csh;
  float (*Li)[SK + 1] = (float(*)[SK + 1])(csh + SK * (SK + 1));
  int t = threadIdx.x;
  for (int e = t; e < SK * SK; e += 128) Ls[e / SK][e % SK] = S[e];
  __syncthreads();
  for (int k = 0; k < SK; k++) {
    if (t == 0) Ls[k][k] = sqrtf(fmaxf(Ls[k][k], 1e-20f));
    __syncthreads();
    float dk = Ls[k][k];
    for (int r = k + 1 + t; r < SK; r += 128) Ls[r][k] /= dk;
    __syncthreads();
    int rem = SK - k - 1;
    for (int e = t; e < rem * rem; e += 128) {
      int r = k + 1 + e / rem, c2 = k + 1 + e % rem;
      Ls[r][c2] -= Ls[r][k] * Ls[c2][k];
    }
    __syncthreads();
  }
  {
    int c = t;
    for (int r = 0; r < c; r++) Li[r][c] = 0.f;
    Li[c][c] = 1.0f / Ls[c][c];
    for (int r = c + 1; r < SK; r++) {
      float sacc = 0.f;
      for (int k = c; k < r; k++) sacc += Ls[r][k] * Li[k][c];
      Li[r][c] = -sacc / Ls[r][r];
    }
  }
  __syncthreads();
  for (int e = t; e < SK * SK; e += 128) Linv[e] = Li[e / SK][e % SK];
}

// ---------- generic tiled GEMMs ----------
__global__ void __launch_bounds__(256) k_gemm_tn(const float* __restrict__ A, const float* __restrict__ B,
                                                 float* __restrict__ Cm, int M, int P, int Kd) {
  __shared__ float As[16][65], Bs[16][65];
  int bm = blockIdx.x * 64, bp = blockIdx.y * 64;
  int tx = threadIdx.x & 15, ty = threadIdx.x >> 4;
  float acc[4][4] = {};
  for (int k0 = 0; k0 < Kd; k0 += 16) {
    for (int t2 = threadIdx.x; t2 < 1024; t2 += 256) {
      int mm = t2 & 63, kk = t2 >> 6;
      As[kk][mm] = A[(size_t)(k0 + kk) * M + bm + mm];
      Bs[kk][mm] = B[(size_t)(k0 + kk) * P + bp + mm];
    }
    __syncthreads();
#pragma unroll
    for (int kk = 0; kk < 16; kk++) {
      float av[4], bv[4];
#pragma unroll
      for (int a = 0; a < 4; a++) av[a] = As[kk][ty * 4 + a];
#pragma unroll
      for (int b = 0; b < 4; b++) bv[b] = Bs[kk][tx * 4 + b];
#pragma unroll
      for (int a = 0; a < 4; a++)
#pragma unroll
        for (int b = 0; b < 4; b++) acc[a][b] += av[a] * bv[b];
    }
    __syncthreads();
  }
#pragma unroll
  for (int a = 0; a < 4; a++)
#pragma unroll
    for (int b = 0; b < 4; b++)
      Cm[(size_t)(bm + ty * 4 + a) * P + bp + tx * 4 + b] = acc[a][b];
}

__global__ void __launch_bounds__(256) k_gemm_nt(const float* __restrict__ A, const float* __restrict__ B,
                                                 float* __restrict__ Cm, int M, int P, int Kd) {
  __shared__ float As[16][65], Bs[16][65];
  int bm = blockIdx.x * 64, bp = blockIdx.y * 64;
  int tx = threadIdx.x & 15, ty = threadIdx.x >> 4;
  float acc[4][4] = {};
  for (int k0 = 0; k0 < Kd; k0 += 16) {
    for (int t2 = threadIdx.x; t2 < 1024; t2 += 256) {
      int kk = t2 & 15, mm = t2 >> 4;
      As[kk][mm] = A[(size_t)(bm + mm) * Kd + k0 + kk];
      Bs[kk][mm] = B[(size_t)(bp + mm) * Kd + k0 + kk];
    }
    __syncthreads();
#pragma unroll
    for (int kk = 0; kk < 16; kk++) {
      float av[4], bv[4];
#pragma unroll
      for (int a = 0; a < 4; a++) av[a] = As[kk][ty * 4 + a];
#pragma unroll
      for (int b = 0; b < 4; b++) bv[b] = Bs[kk][tx * 4 + b];
#pragma unroll
      for (int a = 0; a < 4; a++)
#pragma unroll
        for (int b = 0; b < 4; b++) acc[a][b] += av[a] * bv[b];
    }
    __syncthreads();
  }
#pragma unroll
  for (int a = 0; a < 4; a++)
#pragma unroll
    for (int b = 0; b < 4; b++)
      Cm[(size_t)(bm + ty * 4 + a) * P + bp + tx * 4 + b] = acc[a][b];
}

__global__ void __launch_bounds__(256) k_gemm_nn(const float* __restrict__ A, const float* __restrict__ B,
                                                 float* __restrict__ Cm, int M, int P, int Kd) {
  __shared__ float As[16][65], Bs[16][65];
  int bm = blockIdx.x * 64, bp = blockIdx.y * 64;
  int tx = threadIdx.x & 15, ty = threadIdx.x >> 4;
  float acc[4][4] = {};
  for (int k0 = 0; k0 < Kd; k0 += 16) {
    for (int t2 = threadIdx.x; t2 < 1024; t2 += 256) {
      int kk = t2 & 15, mm = t2 >> 4;
      As[kk][mm] = A[(size_t)(bm + mm) * Kd + k0 + kk];
    }
    for (int t2 = threadIdx.x; t2 < 1024; t2 += 256) {
      int mm = t2 & 63, kk = t2 >> 6;
      Bs[kk][mm] = B[(size_t)(k0 + kk) * P + bp + mm];
    }
    __syncthreads();
#pragma unroll
    for (int kk = 0; kk < 16; kk++) {
      float av[4], bv[4];
#pragma unroll
      for (int a = 0; a < 4; a++) av[a] = As[kk][ty * 4 + a];
#pragma unroll
      for (int b = 0; b < 4; b++) bv[b] = Bs[kk][tx * 4 + b];
#pragma unroll
      for (int a = 0; a < 4; a++)
#pragma unroll
        for (int b = 0; b < 4; b++) acc[a][b] += av[a] * bv[b];
    }
    __syncthreads();
  }
#pragma unroll
  for (int a = 0; a < 4; a++)
#pragma unroll
    for (int b = 0; b < 4; b++)
      Cm[(size_t)(bm + ty * 4 + a) * P + bp + tx * 4 + b] = acc[a][b];
}

// ---------- s = max(max ev_a, max ev_b) ----------
__global__ void k_smax(const float* __restrict__ ea, const float* __restrict__ eb, double* __restrict__ scal) {
  __shared__ float red[128];
  int t = threadIdx.x;
  red[t] = fmaxf(ea[t], eb[t]);
  __syncthreads();
  for (int o = 64; o > 0; o >>= 1) { if (t < o) red[t] = fmaxf(red[t], red[t + o]); __syncthreads(); }
  if (t == 0) scal[1] = (double)red[0];
}

// ---------- resolvent mask ----------
__global__ void k_mask(const float* __restrict__ evr, const float* __restrict__ evc,
                       const double* __restrict__ scal, float* __restrict__ Dm) {
  int t = blockIdx.x * 256 + threadIdx.x;
  if (t >= SK * SK) return;
  int i = t / SK, j = t % SK;
  float s = (float)scal[1];
  float g1 = sqrtf(fmaxf(evc[j] / s, 0.f));
  float g2 = sqrtf(fmaxf(evr[i] / s, 0.f));
  float a2 = g2 * g2 + 1.f, a1 = g1 * g1 + 1.f;
  float re = g2 / a2 - g1 / a1;
  float im = 1.f / a2 - 1.f / a1;
  Dm[t] = re * re + im * im;
}

// ---------- per-row Cholesky solve ----------
__global__ void __launch_bounds__(128) k_cholsolve(const float* __restrict__ AAt, const float* __restrict__ BAt,
                                                   const float* __restrict__ Dm, float* __restrict__ Msg,
                                                   float* __restrict__ Cout) {
  __shared__ float xs[SK];
  int i = blockIdx.x;
  float* Ms = Msg + (size_t)i * SK * SK;
  for (int t2 = threadIdx.x; t2 < SK * SK; t2 += 128) {
    int r = t2 / SK, c2 = t2 % SK;
    float v = AAt[t2];
    if (r == c2) v += LAMBDA_ * Dm[(size_t)i * SK + r];
    Ms[t2] = v;
  }
  if (threadIdx.x < SK) xs[threadIdx.x] = BAt[(size_t)i * SK + threadIdx.x];
  __syncthreads();
  for (int k = 0; k < SK; k++) {
    if (threadIdx.x == 0) Ms[k * SK + k] = sqrtf(fmaxf(Ms[k * SK + k], 1e-20f));
    __syncthreads();
    float dk = Ms[k * SK + k];
    for (int r = k + 1 + threadIdx.x; r < SK; r += 128) Ms[r * SK + k] /= dk;
    __syncthreads();
    int rem = SK - k - 1;
    for (int t2 = threadIdx.x; t2 < rem * rem; t2 += 128) {
      int r = k + 1 + t2 / rem, c2 = k + 1 + t2 % rem;
      Ms[r * SK + c2] -= Ms[r * SK + k] * Ms[c2 * SK + k];
    }
    __syncthreads();
  }
  for (int k = 0; k < SK; k++) {
    if (threadIdx.x == 0) xs[k] /= Ms[k * SK + k];
    __syncthreads();
    float xv = xs[k];
    for (int r = k + 1 + threadIdx.x; r < SK; r += 128) xs[r] -= Ms[r * SK + k] * xv;
    __syncthreads();
  }
  for (int k = SK - 1; k >= 0; k--) {
    if (threadIdx.x == 0) xs[k] /= Ms[k * SK + k];
    __syncthreads();
    float xv = xs[k];
    for (int r = threadIdx.x; r < k; r += 128) xs[r] -= Ms[k * SK + r] * xv;
    __syncthreads();
  }
  for (int t2 = threadIdx.x; t2 < SK; t2 += 128) Cout[(size_t)i * SK + t2] = xs[t2];
}

// ---------- loss partials (deterministic) ----------
__global__ void k_frob_iden(const float* __restrict__ Mat, double* __restrict__ lpart, int slot) {
  __shared__ double red[256];
  double s = 0.0;
  for (int t2 = blockIdx.x * 256 + threadIdx.x; t2 < SK * SK; t2 += 32 * 256) {
    float v = Mat[t2] - ((t2 / SK == t2 % SK) ? 1.f : 0.f);
    s += (double)v * (double)v;
  }
  red[threadIdx.x] = s; __syncthreads();
  for (int o = 128; o > 0; o >>= 1) { if (threadIdx.x < o) red[threadIdx.x] += red[threadIdx.x + o]; __syncthreads(); }
  if (threadIdx.x == 0) lpart[slot * 32 + blockIdx.x] = red[0];
}
__global__ void k_lap(const float* __restrict__ Cm, const float* __restrict__ evc,
                      const float* __restrict__ evr, double* __restrict__ lpart, int slot) {
  __shared__ double red[256];
  double s = 0.0;
  for (int t2 = blockIdx.x * 256 + threadIdx.x; t2 < SK * SK; t2 += 32 * 256) {
    int i = t2 / SK, j = t2 % SK;
    float v = Cm[t2] * (evc[j] - evr[i]);
    s += (double)v * (double)v;
  }
  red[threadIdx.x] = s; __syncthreads();
  for (int o = 128; o > 0; o >>= 1) { if (threadIdx.x < o) red[threadIdx.x] += red[threadIdx.x + o]; __syncthreads(); }
  if (threadIdx.x == 0) lpart[slot * 32 + blockIdx.x] = red[0];
}
__global__ void k_writeout(const double* __restrict__ lpart, float* __restrict__ out) {
  if (threadIdx.x == 0) {
    double b = 0.0, o = 0.0, l = 0.0;
    for (int s = 0; s < 64; s++) b += lpart[s];
    for (int s = 64; s < 128; s++) o += lpart[s];
    for (int s = 128; s < 192; s++) l += lpart[s];
    out[0] = (float)b; out[1] = (float)o; out[2] = (float)l;
  }
}

extern "C" void kernel_launch(void* const* d_in, const int* in_sizes, int n_in,
                              void* d_out, int out_size, void* d_ws, size_t ws_size,
                              hipStream_t stream) {
  const float* feats[2] = {(const float*)d_in[0], (const float*)d_in[1]};
  char* p = (char*)d_ws;
  auto alloc = [&](size_t bytes) -> void* {
    char* r = p;
    p += (bytes + 255) & ~(size_t)255;
    return (void*)r;
  };
  float* pan   = (float*)alloc(sizeof(float) * 256 * NN);
  float* sq    = (float*)alloc(sizeof(float) * NN);
  float* dkv   = (float*)alloc(sizeof(float) * (size_t)NN * KK);
  float* wv    = (float*)alloc(sizeof(float) * (size_t)NN * KK);
  int*   cnt   = (int*)alloc(sizeof(int) * NN);
  int*   rpos  = (int*)alloc(sizeof(int) * NN);
  int*   tsrc  = (int*)alloc(sizeof(int) * (size_t)NN * KK);
  float* deg   = (float*)alloc(sizeof(float) * NN);
  int*   hist  = (int*)alloc(sizeof(int) * 256 * NN);
  int*   baseb = (int*)alloc(sizeof(int) * 256 * NN);
  int*   idxs[2];  float* wadjrs[2]; float* wadjts[2]; int* tcols[2]; int* roffs[2];
  for (int s = 0; s < 2; s++) {
    idxs[s]   = (int*)alloc(sizeof(int) * (size_t)NN * KK);
    wadjrs[s] = (float*)alloc(sizeof(float) * (size_t)NN * KK);
    wadjts[s] = (float*)alloc(sizeof(float) * (size_t)NN * KK);
    tcols[s]  = (int*)alloc(sizeof(int) * (size_t)NN * KK);
    roffs[s]  = (int*)alloc(sizeof(int) * (NN + 1));
  }
  float* Q0    = (float*)alloc(sizeof(float) * (size_t)LM * NN);
  float* Q1    = (float*)alloc(sizeof(float) * (size_t)LM * NN);
  float* ya0   = (float*)alloc(sizeof(float) * NN);
  float* ya1   = (float*)alloc(sizeof(float) * NN);
  float* yb0   = (float*)alloc(sizeof(float) * NN);
  float* yb1   = (float*)alloc(sizeof(float) * NN);
  float* cv0   = (float*)alloc(sizeof(float) * LM);
  float* cv1   = (float*)alloc(sizeof(float) * LM);
  double* part = (double*)alloc(sizeof(double) * 256);
  double* scal = (double*)alloc(sizeof(double) * 8);
  double* Ta0  = (double*)alloc(sizeof(double) * LM);
  double* Tb0  = (double*)alloc(sizeof(double) * LM);
  double* Ta1  = (double*)alloc(sizeof(double) * LM);
  double* Tb1  = (double*)alloc(sizeof(double) * LM);
  double* theta= (double*)alloc(sizeof(double) * SK);
  double* dws  = (double*)alloc(sizeof(double) * (size_t)LM * SK);
  double* ews  = (double*)alloc(sizeof(double) * (size_t)LM * SK);
  double* fws  = (double*)alloc(sizeof(double) * (size_t)LM * SK);
  double* rws  = (double*)alloc(sizeof(double) * (size_t)LM * SK);
  float* Ym0   = (float*)alloc(sizeof(float) * (size_t)LM * SK);
  float* Ym1   = (float*)alloc(sizeof(float) * (size_t)LM * SK);
  float* Ym2   = (float*)alloc(sizeof(float) * (size_t)LM * SK);
  float* Sm    = (float*)alloc(sizeof(float) * SK * SK);
  float* Linv  = (float*)alloc(sizeof(float) * SK * SK);
  float* U0    = (float*)alloc(sizeof(float) * (size_t)NN * SK);
  float* U1    = (float*)alloc(sizeof(float) * (size_t)NN * SK);
  float* ev0   = (float*)alloc(sizeof(float) * SK);
  float* ev1   = (float*)alloc(sizeof(float) * SK);
  float* Ac    = (float*)alloc(sizeof(float) * (size_t)SK * NC);
  float* Bc    = (float*)alloc(sizeof(float) * (size_t)SK * NC);
  float* AAt   = (float*)alloc(sizeof(float) * SK * SK);
  float* BAt   = (float*)alloc(sizeof(float) * SK * SK);
  float* Dm    = (float*)alloc(sizeof(float) * SK * SK);
  float* Cxy   = (float*)alloc(sizeof(float) * SK * SK);
  float* Cyx   = (float*)alloc(sizeof(float) * SK * SK);
  float* P1    = (float*)alloc(sizeof(float) * SK * SK);
  float* Msg   = (float*)alloc(sizeof(float) * (size_t)SK * SK * SK);
  double* lpart= (double*)alloc(sizeof(double) * 192);
  unsigned* sy = (unsigned*)alloc(sizeof(unsigned) * 1024);

  double* Tas[2] = {Ta0, Ta1};
  double* Tbs[2] = {Tb0, Tb1};
  float* Yms[2] = {Ym0, Ym1};
  float* Qs2[2] = {Q0, Q1};
  float* Us[2] = {U0, U1};
  float* evs[2] = {ev0, ev1};

  hipFuncSetAttribute((const void*)k_lanczos2,
                      hipFuncAttributeMaxDynamicSharedMemorySize, DYNLDS);
  hipFuncSetAttribute((const void*)k_cholinv,
                      hipFuncAttributeMaxDynamicSharedMemorySize, CHOLLDS);

  // ---- kNN graph construction for both sides ----
  for (int s2 = 0; s2 < 2; s2++) {
    const float* f = feats[s2];
    int* idx = idxs[s2];
    k_sqnorm<<<NN, 256, 0, stream>>>(f, sq);
    for (int p2 = 0; p2 < 16; p2++) {
      k_d2panel<<<dim3(64, 4), 256, 0, stream>>>(f, sq, pan, p2 * 256);
      k_topk<<<256, 256, 0, stream>>>(pan, p2 * 256, idx, dkv);
    }
    k_partsum<<<64, 256, 0, stream>>>(dkv, part);
    k_sigma<<<1, 64, 0, stream>>>(part, scal);
    k_wexp<<<NN * KK / 256, 256, 0, stream>>>(dkv, scal, wv);
    hipMemsetAsync(cnt, 0, sizeof(int) * NN, stream);
    k_count<<<NN * KK / 256, 256, 0, stream>>>(idx, cnt);
    k_scan<<<1, 1024, 0, stream>>>(cnt, roffs[s2], rpos);
    hipMemsetAsync(hist, 0, sizeof(int) * 256 * NN, stream);
    k_hist<<<256, 256, 0, stream>>>(idx, hist);
    k_colscan<<<16, 256, 0, stream>>>(hist, roffs[s2], baseb);
    k_place2<<<256, 256, 0, stream>>>(idx, baseb, tsrc);
    k_deg<<<16, 256, 0, stream>>>(wv, roffs[s2], tsrc, deg);
    k_wadj2<<<16, 256, 0, stream>>>(wv, idx, roffs[s2], tsrc, deg,
                                    wadjrs[s2], wadjts[s2], tcols[s2]);
  }

  // ---- dual-side fused cooperative Lanczos (CGS1) ----
  hipMemsetAsync(sy, 0, sizeof(unsigned) * 1024, stream);
  {
    void* args[] = {(void*)&Q0, (void*)&Q1,
                    (void*)&ya0, (void*)&ya1, (void*)&yb0, (void*)&yb1,
                    (void*)&wadjrs[0], (void*)&idxs[0], (void*)&wadjts[0], (void*)&tcols[0], (void*)&roffs[0],
                    (void*)&wadjrs[1], (void*)&idxs[1], (void*)&wadjts[1], (void*)&tcols[1], (void*)&roffs[1],
                    (void*)&cv0, (void*)&cv1, (void*)&part,
                    (void*)&Ta0, (void*)&Tb0, (void*)&Ta1, (void*)&Tb1,
                    (void*)&sy};
    hipLaunchCooperativeKernel((const void*)k_lanczos2, dim3(256), dim3(1024), args, DYNLDS, stream);
  }

  // ---- per-side spectral finish (CholQR2) ----
  for (int s2 = 0; s2 < 2; s2++) {
    k_bisect<<<1, 128, 0, stream>>>(Tas[s2], Tbs[s2], theta, evs[s2]);
    k_invit<<<1, 128, 0, stream>>>(Tas[s2], Tbs[s2], theta, dws, ews, fws, rws, Yms[s2]);
    k_gemm_tn<<<dim3(2, 2), 256, 0, stream>>>(Yms[s2], Yms[s2], Sm, SK, SK, LM);
    k_cholinv<<<1, 128, CHOLLDS, stream>>>(Sm, Linv);
    k_gemm_nt<<<dim3(LM / 64, 2), 256, 0, stream>>>(Yms[s2], Linv, Ym2, LM, SK, SK);
    k_gemm_tn<<<dim3(2, 2), 256, 0, stream>>>(Ym2, Ym2, Sm, SK, SK, LM);
    k_cholinv<<<1, 128, CHOLLDS, stream>>>(Sm, Linv);
    k_gemm_nt<<<dim3(LM / 64, 2), 256, 0, stream>>>(Ym2, Linv, Yms[s2], LM, SK, SK);
    k_gemm_tn<<<dim3(NN / 64, SK / 64), 256, 0, stream>>>(Qs2[s2], Yms[s2], Us[s2], NN, SK, LM);
  }

  // ---- spectral coefficients + FM solves + losses ----
  k_gemm_tn<<<dim3(SK / 64, NC / 64), 256, 0, stream>>>(U0, feats[0], Ac, SK, NC, NN);
  k_gemm_tn<<<dim3(SK / 64, NC / 64), 256, 0, stream>>>(U1, feats[1], Bc, SK, NC, NN);
  k_smax<<<1, 128, 0, stream>>>(ev0, ev1, scal);

  k_gemm_nt<<<dim3(2, 2), 256, 0, stream>>>(Ac, Ac, AAt, SK, SK, NC);
  k_gemm_nt<<<dim3(2, 2), 256, 0, stream>>>(Bc, Ac, BAt, SK, SK, NC);
  k_mask<<<64, 256, 0, stream>>>(ev1, ev0, scal, Dm);
  k_cholsolve<<<SK, 128, 0, stream>>>(AAt, BAt, Dm, Msg, Cxy);
  k_gemm_nt<<<dim3(2, 2), 256, 0, stream>>>(Bc, Bc, AAt, SK, SK, NC);
  k_gemm_nt<<<dim3(2, 2), 256, 0, stream>>>(Ac, Bc, BAt, SK, SK, NC);
  k_mask<<<64, 256, 0, stream>>>(ev0, ev1, scal, Dm);
  k_cholsolve<<<SK, 128, 0, stream>>>(AAt, BAt, Dm, Msg, Cyx);

  k_gemm_nn<<<dim3(2, 2), 256, 0, stream>>>(Cxy, Cyx, P1, SK, SK, SK);
  k_frob_iden<<<32, 256, 0, stream>>>(P1, lpart, 0);
  k_gemm_nn<<<dim3(2, 2), 256, 0, stream>>>(Cyx, Cxy, P1, SK, SK, SK);
  k_frob_iden<<<32, 256, 0, stream>>>(P1, lpart, 1);
  k_gemm_tn<<<dim3(2, 2), 256, 0, stream>>>(Cxy, Cxy, P1, SK, SK, SK);
  k_frob_iden<<<32, 256, 0, stream>>>(P1, lpart, 2);
  k_gemm_tn<<<dim3(2, 2), 256, 0, stream>>>(Cyx, Cyx, P1, SK, SK, SK);
  k_frob_iden<<<32, 256, 0, stream>>>(P1, lpart, 3);
  k_lap<<<32, 256, 0, stream>>>(Cxy, ev0, ev1, lpart, 4);
  k_lap<<<32, 256, 0, stream>>>(Cyx, ev1, ev0, lpart, 5);
  k_writeout<<<1, 64, 0, stream>>>(lpart, (float*)d_out);
}

// Round 12
// 35521.149 us; speedup vs baseline: 22.7309x; 1.1610x over previous
//
#include <hip/hip_runtime.h>
#include <math.h>

#define NN 4096      // points
#define NC 768       // feature dim
#define KK 16        // knn k
#define SK 128       // spectral basis size
#define LM 768       // Lanczos steps (6x oversampling of SK)
#define NR (LM / 128) // dots rows per block
#define LAMBDA_ 100.0f
// dynamic LDS for lanczos2: slab[LM][32] + ysh[NN] + cvsh[LM]
#define DYNLDS (LM * 32 * 4 + NN * 4 + LM * 4)
// dynamic LDS for cholinv: Ls[SK][SK+1] + Li[SK][SK+1]
#define CHOLLDS (2 * SK * (SK + 1) * 4)
// dynamic LDS for cholsolve: Ms[SK][SK+1]
#define CHSLDS (SK * (SK + 1) * 4)

typedef unsigned int u32;

__device__ __forceinline__ float hashf(u32 x) {
  x ^= x >> 16; x *= 0x7feb352dU; x ^= x >> 15; x *= 0x846ca68bU; x ^= x >> 16;
  return ((float)x) * (1.0f / 4294967296.0f);  // [0,1)
}

// ---- agent-scope (device-coherent) access helpers ----
__device__ __forceinline__ float agld(const float* p) {
  return __hip_atomic_load((float*)p, __ATOMIC_RELAXED, __HIP_MEMORY_SCOPE_AGENT);
}
__device__ __forceinline__ void agst(float* p, float v) {
  __hip_atomic_store(p, v, __ATOMIC_RELAXED, __HIP_MEMORY_SCOPE_AGENT);
}
__device__ __forceinline__ double agldd(const double* p) {
  return __hip_atomic_load((double*)p, __ATOMIC_RELAXED, __HIP_MEMORY_SCOPE_AGENT);
}
__device__ __forceinline__ void agstd(double* p, double v) {
  __hip_atomic_store(p, v, __ATOMIC_RELAXED, __HIP_MEMORY_SCOPE_AGENT);
}

// ---- per-side two-level tree barrier (128 blocks: 8 groups x 16) ----
__device__ __forceinline__ void gbar2(unsigned* syb, int lb, unsigned gph) {
  asm volatile("s_waitcnt vmcnt(0)" ::: "memory");
  __syncthreads();
  if (threadIdx.x == 0) {
    const int grp = lb >> 4, mem = lb & 15;
    unsigned* gc  = syb + grp * 16;
    unsigned* top = syb + 144;
    unsigned* fl  = syb + 256 + grp * 16;
    __hip_atomic_fetch_add(gc, 1u, __ATOMIC_RELEASE, __HIP_MEMORY_SCOPE_AGENT);
    if (mem == 0) {
      while (__hip_atomic_load(gc, __ATOMIC_RELAXED, __HIP_MEMORY_SCOPE_AGENT) < gph * 16u)
        __builtin_amdgcn_s_sleep(1);
      __hip_atomic_fetch_add(top, 1u, __ATOMIC_RELEASE, __HIP_MEMORY_SCOPE_AGENT);
      while (__hip_atomic_load(top, __ATOMIC_RELAXED, __HIP_MEMORY_SCOPE_AGENT) < gph * 8u)
        __builtin_amdgcn_s_sleep(1);
      __hip_atomic_store(fl, gph, __ATOMIC_RELEASE, __HIP_MEMORY_SCOPE_AGENT);
    } else {
      while (__hip_atomic_load(fl, __ATOMIC_RELAXED, __HIP_MEMORY_SCOPE_AGENT) < gph)
        __builtin_amdgcn_s_sleep(1);
    }
    __builtin_amdgcn_fence(__ATOMIC_ACQUIRE, "agent");
  }
  __syncthreads();
}

// ---------- row squared norms ----------
__global__ void k_sqnorm(const float* __restrict__ f, float* __restrict__ sq) {
  __shared__ float red[256];
  int i = blockIdx.x;
  float s = 0.f;
  for (int c = threadIdx.x; c < NC; c += 256) { float v = f[(size_t)i * NC + c]; s += v * v; }
  red[threadIdx.x] = s; __syncthreads();
  for (int o = 128; o > 0; o >>= 1) { if (threadIdx.x < o) red[threadIdx.x] += red[threadIdx.x + o]; __syncthreads(); }
  if (threadIdx.x == 0) sq[i] = red[0];
}

// ---------- d2 panel ----------
__global__ void __launch_bounds__(256) k_d2panel(const float* __restrict__ f, const float* __restrict__ sq,
                                                 float* __restrict__ pan, int i0) {
  __shared__ float As[16][65], Bs[16][65];
  int bj = blockIdx.x, bi = blockIdx.y;
  int row0 = i0 + bi * 64, col0 = bj * 64;
  int tx = threadIdx.x & 15, ty = threadIdx.x >> 4;
  float acc[4][4] = {};
  for (int k0 = 0; k0 < NC; k0 += 16) {
    for (int t2 = threadIdx.x; t2 < 1024; t2 += 256) {
      int kk = t2 & 15, rr = t2 >> 4;
      As[kk][rr] = f[(size_t)(row0 + rr) * NC + k0 + kk];
      Bs[kk][rr] = f[(size_t)(col0 + rr) * NC + k0 + kk];
    }
    __syncthreads();
#pragma unroll
    for (int kk = 0; kk < 16; kk++) {
      float av[4], bv[4];
#pragma unroll
      for (int a = 0; a < 4; a++) av[a] = As[kk][ty * 4 + a];
#pragma unroll
      for (int b = 0; b < 4; b++) bv[b] = Bs[kk][tx * 4 + b];
#pragma unroll
      for (int a = 0; a < 4; a++)
#pragma unroll
        for (int b = 0; b < 4; b++) acc[a][b] += av[a] * bv[b];
    }
    __syncthreads();
  }
#pragma unroll
  for (int a = 0; a < 4; a++) {
    int gr = row0 + ty * 4 + a;
    int pr = bi * 64 + ty * 4 + a;
    float sr = sq[gr];
#pragma unroll
    for (int b = 0; b < 4; b++) {
      int gc = col0 + tx * 4 + b;
      float v = sr + sq[gc] - 2.f * acc[a][b];
      v = fmaxf(v, 0.f);
      if (gr == gc) v += 1e10f;
      pan[(size_t)pr * NN + gc] = v;
    }
  }
}

// ---------- top-16 smallest per row ----------
__global__ void __launch_bounds__(256) k_topk(const float* __restrict__ pan, int i0,
                                              int* __restrict__ idx, float* __restrict__ dkv) {
  __shared__ float vals[NN];
  __shared__ float rv[256];
  __shared__ int ri[256];
  int r = blockIdx.x;
  const float* row = pan + (size_t)r * NN;
  for (int j = threadIdx.x; j < NN; j += 256) vals[j] = row[j];
  __syncthreads();
  for (int t3 = 0; t3 < KK; t3++) {
    float bv = 1e30f; int bi2 = NN;
    for (int j2 = threadIdx.x; j2 < NN; j2 += 256) {
      float v = vals[j2];
      if (v < bv || (v == bv && j2 < bi2)) { bv = v; bi2 = j2; }
    }
    rv[threadIdx.x] = bv; ri[threadIdx.x] = bi2;
    __syncthreads();
    for (int o = 128; o > 0; o >>= 1) {
      if (threadIdx.x < o) {
        float v2 = rv[threadIdx.x + o]; int i2 = ri[threadIdx.x + o];
        if (v2 < rv[threadIdx.x] || (v2 == rv[threadIdx.x] && i2 < ri[threadIdx.x])) {
          rv[threadIdx.x] = v2; ri[threadIdx.x] = i2;
        }
      }
      __syncthreads();
    }
    if (threadIdx.x == 0) {
      idx[(size_t)(i0 + r) * KK + t3] = ri[0];
      dkv[(size_t)(i0 + r) * KK + t3] = rv[0];
      vals[ri[0]] = 1e30f;
    }
    __syncthreads();
  }
}

// ---------- sigma2 ----------
__global__ void k_partsum(const float* __restrict__ dkv, double* __restrict__ part) {
  __shared__ double red[256];
  double s = 0.0;
  for (int t2 = blockIdx.x * 256 + threadIdx.x; t2 < NN * KK; t2 += 64 * 256) s += (double)dkv[t2];
  red[threadIdx.x] = s; __syncthreads();
  for (int o = 128; o > 0; o >>= 1) { if (threadIdx.x < o) red[threadIdx.x] += red[threadIdx.x + o]; __syncthreads(); }
  if (threadIdx.x == 0) part[blockIdx.x] = red[0];
}
__global__ void k_sigma(const double* __restrict__ part, double* __restrict__ scal) {
  __shared__ double red[64];
  red[threadIdx.x] = part[threadIdx.x]; __syncthreads();
  for (int o = 32; o > 0; o >>= 1) { if (threadIdx.x < o) red[threadIdx.x] += red[threadIdx.x + o]; __syncthreads(); }
  if (threadIdx.x == 0) scal[0] = red[0] / (double)(NN * KK) + 1e-12;
}

// ---------- gaussian weights ----------
__global__ void k_wexp(const float* __restrict__ dkv, const double* __restrict__ scal,
                       float* __restrict__ wv) {
  int t = blockIdx.x * 256 + threadIdx.x;
  if (t >= NN * KK) return;
  float inv2s = (float)(0.5 / scal[0]);
  wv[t] = expf(-dkv[t] * inv2s);
}

// ---------- deterministic CSR transpose: counting-sort ----------
__global__ void k_count(const int* __restrict__ idx, int* __restrict__ cnt) {
  int t = blockIdx.x * 256 + threadIdx.x;
  if (t < NN * KK) atomicAdd(&cnt[idx[t]], 1);
}

__global__ void __launch_bounds__(1024) k_scan(const int* __restrict__ cnt,
                                               int* __restrict__ roff, int* __restrict__ rpos) {
  __shared__ int buf[1024];
  int t = threadIdx.x;
  int v[4]; int s = 0;
#pragma unroll
  for (int u = 0; u < 4; u++) { v[u] = cnt[t * 4 + u]; s += v[u]; }
  buf[t] = s; __syncthreads();
  for (int o = 1; o < 1024; o <<= 1) {
    int x = (t >= o) ? buf[t - o] : 0;
    __syncthreads();
    buf[t] += x;
    __syncthreads();
  }
  int run = (t == 0) ? 0 : buf[t - 1];
#pragma unroll
  for (int u = 0; u < 4; u++) { roff[t * 4 + u] = run; rpos[t * 4 + u] = run; run += v[u]; }
  if (t == 1023) roff[NN] = run;
}

__global__ void k_hist(const int* __restrict__ idx, int* __restrict__ hist) {
  int e = blockIdx.x * 256 + threadIdx.x;
  atomicAdd(&hist[(e >> 8) * NN + idx[e]], 1);
}
__global__ void k_colscan(const int* __restrict__ hist, const int* __restrict__ roff,
                          int* __restrict__ baseb) {
  int j = blockIdx.x * 256 + threadIdx.x;
  if (j >= NN) return;
  int run = roff[j];
  for (int c = 0; c < 256; c++) { baseb[c * NN + j] = run; run += hist[c * NN + j]; }
}
__global__ void __launch_bounds__(256) k_place2(const int* __restrict__ idx,
                                                const int* __restrict__ baseb,
                                                int* __restrict__ tsrc) {
  __shared__ int ish[256];
  int c = blockIdx.x;
  int e = c * 256 + threadIdx.x;
  ish[threadIdx.x] = idx[e];
  __syncthreads();
  int j = ish[threadIdx.x];
  int rank = 0;
  for (int p2 = 0; p2 < threadIdx.x; p2++) rank += (ish[p2] == j) ? 1 : 0;
  tsrc[baseb[c * NN + j] + rank] = e;
}

// ---------- degrees ----------
__global__ void k_deg(const float* __restrict__ wv, const int* __restrict__ roff,
                      const int* __restrict__ tsrc, float* __restrict__ deg) {
  int i = blockIdx.x * 256 + threadIdx.x;
  if (i >= NN) return;
  float s = 0.f;
  for (int l = 0; l < KK; l++) s += wv[(size_t)i * KK + l];
  float s2 = 0.f;
  for (int e = roff[i]; e < roff[i + 1]; e++) s2 += wv[tsrc[e]];
  deg[i] = 0.5f * (s + s2);
}

// ---------- normalized adjacency ----------
__global__ void k_wadj2(const float* __restrict__ wv, const int* __restrict__ idx,
                        const int* __restrict__ roff, const int* __restrict__ tsrc,
                        const float* __restrict__ deg,
                        float* __restrict__ wadjr, float* __restrict__ wadjt,
                        int* __restrict__ tcol) {
  int i = blockIdx.x * 256 + threadIdx.x;
  if (i >= NN) return;
  float di = 1.0f / sqrtf(deg[i] + 1e-8f);
  for (int l = 0; l < KK; l++) {
    int j = idx[(size_t)i * KK + l];
    float dj = 1.0f / sqrtf(deg[j] + 1e-8f);
    wadjr[(size_t)i * KK + l] = 0.5f * wv[(size_t)i * KK + l] * di * dj;
  }
  for (int e = roff[i]; e < roff[i + 1]; e++) {
    int s = tsrc[e];
    int sn = s / KK;
    float dj = 1.0f / sqrtf(deg[sn] + 1e-8f);
    wadjt[e] = 0.5f * wv[s] * di * dj;
    tcol[e] = sn;
  }
}

// ---------- DUAL-SIDE fused cooperative Lanczos, CGS1 (3 barriers/iter) ----------
__global__ void __launch_bounds__(1024) k_lanczos2(
    float* __restrict__ Q0, float* __restrict__ Q1,
    float* __restrict__ ya0, float* __restrict__ ya1,
    float* __restrict__ yb0, float* __restrict__ yb1,
    const float* __restrict__ wadjr0, const int* __restrict__ idx0,
    const float* __restrict__ wadjt0, const int* __restrict__ tcol0, const int* __restrict__ roff0,
    const float* __restrict__ wadjr1, const int* __restrict__ idx1,
    const float* __restrict__ wadjt1, const int* __restrict__ tcol1, const int* __restrict__ roff1,
    float* __restrict__ cv0, float* __restrict__ cv1, double* __restrict__ part,
    double* __restrict__ Ta0, double* __restrict__ Tb0,
    double* __restrict__ Ta1, double* __restrict__ Tb1,
    unsigned* __restrict__ sy) {
  const int b = blockIdx.x, t = threadIdx.x;
  const int s = b >> 7, lb = b & 127;
  const int n0 = lb * 32;
  const int lane = t & 63, wvid = t >> 6;  // 16 waves
  float* Qs = s ? Q1 : Q0;
  float* ybuf0 = s ? yb0 : ya0;
  float* ybuf1 = s ? yb1 : ya1;
  const float* wadjr = s ? wadjr1 : wadjr0;
  const int* idx = s ? idx1 : idx0;
  const float* wadjt = s ? wadjt1 : wadjt0;
  const int* tcol = s ? tcol1 : tcol0;
  const int* roff = s ? roff1 : roff0;
  float* cvs = s ? cv1 : cv0;
  double* ps = part + s * 128;
  double* Ta = s ? Ta1 : Ta0;
  double* Tb = s ? Tb1 : Tb0;
  unsigned* syb = sy + s * 512;
  u32 seed = 1234567u + (u32)s * 77777u;

  extern __shared__ char dynsh[];
  float* slabsh = (float*)dynsh;                      // [LM][32]
  float* ysh    = (float*)(dynsh + LM * 32 * 4);      // [NN]
  float* cvsh   = (float*)(dynsh + LM * 32 * 4 + NN * 4);  // [LM]
  __shared__ double pd[2];
  __shared__ double wl[16][NR];
  __shared__ float fredu[32][33];
  __shared__ float r2loc[32];
  unsigned gph = 0;

  // init residual + norm partial
  if (t < 32) {
    int n = n0 + t;
    agst(&ybuf0[n], hashf((u32)n * 2246822519u + seed) - 0.5f);
  }
  __syncthreads();
  if (t == 0) {
    double ss = 0.0;
    for (int u = 0; u < 32; u++) { double v = (double)agld(&ybuf0[n0 + u]); ss += v * v; }
    agstd(&ps[lb], ss);
  }
  gbar2(syb, lb, ++gph);

  for (int it = 0; it < LM; it++) {
    float* r  = (it & 1) ? ybuf1 : ybuf0;
    float* r2 = (it & 1) ? ybuf0 : ybuf1;

    // ---- Phase A: stage r, single-wave norm, q-row write (+slab), SpMV ----
    {
      int b4 = t * 4;
      float a0 = agld(&r[b4]), a1 = agld(&r[b4 + 1]);
      float a2 = agld(&r[b4 + 2]), a3 = agld(&r[b4 + 3]);
      ysh[b4] = a0; ysh[b4 + 1] = a1; ysh[b4 + 2] = a2; ysh[b4 + 3] = a3;
    }
    if (t < 64) {
      double v = agldd(&ps[t]) + agldd(&ps[t + 64]);
      for (int o = 32; o > 0; o >>= 1) v += __shfl_down(v, o, 64);
      if (t == 0) pd[0] = v;
    }
    __syncthreads();
    double nrm = sqrt(pd[0]);
    if (lb == 0 && t == 0 && it > 0) agstd(&Tb[it - 1], nrm);
    float inv = (float)(1.0 / (nrm > 1e-300 ? nrm : 1e-300));
    if (t < 32) {
      int n = n0 + t;
      float qv = ysh[n] * inv;
      agst(&Qs[(size_t)it * NN + n], qv);
      slabsh[it * 32 + t] = qv;
    }
#pragma unroll
    for (int rr = 0; rr < 2; rr++) {
      int n = n0 + wvid + rr * 16;       // 2 rows per wave
      int rb = roff[n], re = roff[n + 1];
      int L = 16 + (re - rb);
      float acc = 0.f;
      for (int i = lane; i < L; i += 64) {
        float w, qv;
        if (i < 16) { w = wadjr[(size_t)n * KK + i]; qv = ysh[idx[(size_t)n * KK + i]] * inv; }
        else        { int e = rb + i - 16; w = wadjt[e]; qv = ysh[tcol[e]] * inv; }
        acc += w * qv;
      }
      for (int o = 32; o > 0; o >>= 1) acc += __shfl_down(acc, o, 64);
      if (lane == 0) { agst(&r2[n], acc); r2loc[wvid + rr * 16] = acc; }
    }
    gbar2(syb, lb, ++gph);

    // ---- Phase B: dots (single CGS pass), register-direct loads ----
    {
      float4 yv4;
      int b4 = t * 4;
      yv4.x = agld(&r2[b4]); yv4.y = agld(&r2[b4 + 1]);
      yv4.z = agld(&r2[b4 + 2]); yv4.w = agld(&r2[b4 + 3]);
      double sa[NR];
#pragma unroll
      for (int rsel = 0; rsel < NR; rsel++) {
        int j = lb + rsel * 128;
        sa[rsel] = 0.0;
        if (j <= it) {
          float4 q4 = *(const float4*)&Qs[(size_t)j * NN + t * 4];
          double d = (double)q4.x * yv4.x; d += (double)q4.y * yv4.y;
          d += (double)q4.z * yv4.z; d += (double)q4.w * yv4.w;
          sa[rsel] = d;
        }
      }
#pragma unroll
      for (int rsel = 0; rsel < NR; rsel++) {
        int j = lb + rsel * 128;
        if (j <= it) {
          double sd = sa[rsel];
          for (int o = 32; o > 0; o >>= 1) sd += __shfl_down(sd, o, 64);
          if (lane == 0) wl[wvid][rsel] = sd;
        }
      }
      __syncthreads();
      if (t < NR) {
        int j = lb + t * 128;
        if (j <= it) {
          double tot = 0.0;
          for (int u = 0; u < 16; u++) tot += wl[u][t];
          agst(&cvs[j], (float)tot);
          if (j == it) agstd(&Ta[it], tot);
        }
      }
      __syncthreads();
    }
    gbar2(syb, lb, ++gph);

    // ---- Phase C: update + next norm partial ----
    {
      for (int j2s = t; j2s <= it; j2s += 1024) cvsh[j2s] = agld(&cvs[j2s]);
      __syncthreads();
      int i2 = t & 31, g = t >> 5;     // 32 cols x 32 j-groups
      float s0 = 0.f, s1 = 0.f, s2 = 0.f, s3 = 0.f;
      int j = g;
      for (; j + 96 <= it; j += 128) {
        s0 += cvsh[j]      * slabsh[j * 32 + i2];
        s1 += cvsh[j + 32] * slabsh[(j + 32) * 32 + i2];
        s2 += cvsh[j + 64] * slabsh[(j + 64) * 32 + i2];
        s3 += cvsh[j + 96] * slabsh[(j + 96) * 32 + i2];
      }
      for (; j <= it; j += 32) s0 += cvsh[j] * slabsh[j * 32 + i2];
      fredu[g][i2] = (s0 + s1) + (s2 + s3);
      __syncthreads();
      if (t < 32) {
        float acc2 = 0.f;
        for (int g2 = 0; g2 < 32; g2++) acc2 += fredu[g2][t];
        float ny = r2loc[t] - acc2;
        agst(&r2[n0 + t], ny);
        r2loc[t] = ny;
      }
      __syncthreads();
      if (t == 0) {
        double s2d = 0.0;
        for (int u = 0; u < 32; u++) { double v = (double)r2loc[u]; s2d += v * v; }
        agstd(&ps[lb], s2d);
      }
    }
    gbar2(syb, lb, ++gph);
  }
}

// ---------- bisection, both sides batched (grid=2) ----------
__global__ void __launch_bounds__(128) k_bisect2(const double* __restrict__ Ta0, const double* __restrict__ Tb0,
                                                 const double* __restrict__ Ta1, const double* __restrict__ Tb1,
                                                 double* __restrict__ theta0, double* __restrict__ theta1,
                                                 float* __restrict__ ev0, float* __restrict__ ev1) {
  __shared__ double Tas[LM];
  __shared__ double Tb2[LM];
  int side = blockIdx.x;
  const double* Ta = side ? Ta1 : Ta0;
  const double* Tb = side ? Tb1 : Tb0;
  double* theta = side ? theta1 : theta0;
  float* evL = side ? ev1 : ev0;
  int j = threadIdx.x;
  for (int k = j; k < LM; k += 128) {
    Tas[k] = Ta[k];
    double bq = (k > 0) ? Tb[k - 1] : 0.0;
    Tb2[k] = bq * bq;
  }
  __syncthreads();
  if (j >= SK) return;
  int tgt = LM - j;
  double lo = -2.0, hi = 2.0;
  for (int iter = 0; iter < 50; iter++) {
    double mid = 0.5 * (lo + hi);
    int cnt = 0; double q = 1.0;
    for (int k = 0; k < LM; k++) {
      q = Tas[k] - mid - Tb2[k] / q;
      if (q < 0.0) cnt++;
      if (fabs(q) < 1e-280) q = -1e-280;
    }
    if (cnt >= tgt) hi = mid; else lo = mid;
  }
  theta[j] = 0.5 * (lo + hi);
  evL[j] = (float)(1.0 - theta[j]);
}

// ---------- inverse iteration, 1 pass, both sides batched (grid=2) ----------
__global__ void __launch_bounds__(128) k_invit2(const double* __restrict__ Ta0, const double* __restrict__ Tb0,
                        const double* __restrict__ Ta1, const double* __restrict__ Tb1,
                        const double* __restrict__ theta0, const double* __restrict__ theta1,
                        double* __restrict__ dws, double* __restrict__ ews,
                        double* __restrict__ fws, double* __restrict__ rws,
                        float* __restrict__ Ym0, float* __restrict__ Ym1) {
  __shared__ double Tas[LM];
  __shared__ double Tbs[LM];
  int side = blockIdx.x;
  const double* Ta = side ? Ta1 : Ta0;
  const double* Tb = side ? Tb1 : Tb0;
  const double* theta = side ? theta1 : theta0;
  float* Ym = side ? Ym1 : Ym0;
  size_t off = (size_t)side * LM * SK;
  double* dw = dws + off; double* ew = ews + off;
  double* fw = fws + off; double* rw = rws + off;
  int j = threadIdx.x;
  for (int k = j; k < LM; k += 128) { Tas[k] = Ta[k]; Tbs[k] = Tb[k]; }
  __syncthreads();
  if (j >= SK) return;
  double sig = theta[j];
  for (int k = 0; k < LM; k++)
    rw[(size_t)k * SK + j] = (double)hashf((u32)k * 2654435761u + (u32)j * 40503u + 17u) - 0.5;
  // single inverse-iteration pass (shifts accurate to ~1e-13 -> one solve suffices;
  // within-cluster mixing handled by CholQR2 + Ritz projection downstream)
  {
    double dk = Tas[0] - sig;
    double ek = Tbs[0];
    double fk = 0.0;
    double rk = rw[j];
    for (int k = 0; k < LM - 1; k++) {
      double bk = Tbs[k];
      double dn = Tas[k + 1] - sig;
      double en = (k + 2 < LM) ? Tbs[k + 1] : 0.0;
      double rn = rw[(size_t)(k + 1) * SK + j];
      double dd, ee, ff, dk2, ek2, rkeep, rnext;
      if (fabs(dk) >= fabs(bk)) {
        double dsafe = (fabs(dk) > 1e-300) ? dk : 1e-300;
        double m = bk / dsafe;
        dd = dsafe; ee = ek; ff = fk;
        dk2 = dn - m * ek;
        ek2 = en - m * fk;
        rkeep = rk;
        rnext = rn - m * rk;
      } else {
        double m = dk / bk;
        dd = bk; ee = dn; ff = en;
        dk2 = ek - m * dn;
        ek2 = fk - m * en;
        rkeep = rn;
        rnext = rk - m * rn;
      }
      dw[(size_t)k * SK + j] = dd;
      ew[(size_t)k * SK + j] = ee;
      fw[(size_t)k * SK + j] = ff;
      rw[(size_t)k * SK + j] = rkeep;
      rk = rnext; dk = dk2; ek = ek2; fk = 0.0;
    }
    if (fabs(dk) < 1e-300) dk = 1e-300;
    dw[(size_t)(LM - 1) * SK + j] = dk;
    ew[(size_t)(LM - 1) * SK + j] = 0.0;
    fw[(size_t)(LM - 1) * SK + j] = 0.0;
    rw[(size_t)(LM - 1) * SK + j] = rk;
    double y1 = 0.0, y2 = 0.0, nr = 0.0;
    for (int k = LM - 1; k >= 0; k--) {
      double dv = dw[(size_t)k * SK + j];
      double yk = (rw[(size_t)k * SK + j] - ew[(size_t)k * SK + j] * y1 - fw[(size_t)k * SK + j] * y2) / dv;
      rw[(size_t)k * SK + j] = yk;
      y2 = y1; y1 = yk;
      nr += yk * yk;
    }
    double inv = 1.0 / sqrt(nr > 1e-300 ? nr : 1e-300);
    for (int k = 0; k < LM; k++) Ym[(size_t)k * SK + j] = (float)(rw[(size_t)k * SK + j] * inv);
  }
}

// ---------- Cholesky + lower-triangular inverse of SK x SK SPD matrix ----------
__global__ void __launch_bounds__(128) k_cholinv(const float* __restrict__ S,
                                                 float* __restrict__ Linv) {
  extern __shared__ float csh[];
  float (*Ls)[SK + 1] = (float(*)[SK + 1])csh;
  float (*Li)[SK + 1] = (float(*)[SK + 1])(csh + SK * (SK + 1));
  int t = threadIdx.x;
  for (int e = t; e < SK * SK; e += 128) Ls[e / SK][e % SK] = S[e];
  __syncthreads();
  for (int k = 0; k < SK; k++) {
    if (t == 0) Ls[k][k] = sqrtf(fmaxf(Ls[k][k], 1e-20f));
    __syncthreads();
    float dk = Ls[k][k];
    for (int r = k + 1 + t; r < SK; r += 128) Ls[r][k] /= dk;
    __syncthreads();
    int rem = SK - k - 1;
    for (int e = t; e < rem * rem; e += 128) {
      int r = k + 1 + e / rem, c2 = k + 1 + e % rem;
      Ls[r][c2] -= Ls[r][k] * Ls[c2][k];
    }
    __syncthreads();
  }
  {
    int c = t;
    for (int r = 0; r < c; r++) Li[r][c] = 0.f;
    Li[c][c] = 1.0f / Ls[c][c];
    for (int r = c + 1; r < SK; r++) {
      float sacc = 0.f;
      for (int k = c; k < r; k++) sacc += Ls[r][k] * Li[k][c];
      Li[r][c] = -sacc / Ls[r][r];
    }
  }
  __syncthreads();
  for (int e = t; e < SK * SK; e += 128) Linv[e] = Li[e / SK][e % SK];
}

// ---------- generic tiled GEMMs ----------
__global__ void __launch_bounds__(256) k_gemm_tn(const float* __restrict__ A, const float* __restrict__ B,
                                                 float* __restrict__ Cm, int M, int P, int Kd) {
  __shared__ float As[16][65], Bs[16][65];
  int bm = blockIdx.x * 64, bp = blockIdx.y * 64;
  int tx = threadIdx.x & 15, ty = threadIdx.x >> 4;
  float acc[4][4] = {};
  for (int k0 = 0; k0 < Kd; k0 += 16) {
    for (int t2 = threadIdx.x; t2 < 1024; t2 += 256) {
      int mm = t2 & 63, kk = t2 >> 6;
      As[kk][mm] = A[(size_t)(k0 + kk) * M + bm + mm];
      Bs[kk][mm] = B[(size_t)(k0 + kk) * P + bp + mm];
    }
    __syncthreads();
#pragma unroll
    for (int kk = 0; kk < 16; kk++) {
      float av[4], bv[4];
#pragma unroll
      for (int a = 0; a < 4; a++) av[a] = As[kk][ty * 4 + a];
#pragma unroll
      for (int b = 0; b < 4; b++) bv[b] = Bs[kk][tx * 4 + b];
#pragma unroll
      for (int a = 0; a < 4; a++)
#pragma unroll
        for (int b = 0; b < 4; b++) acc[a][b] += av[a] * bv[b];
    }
    __syncthreads();
  }
#pragma unroll
  for (int a = 0; a < 4; a++)
#pragma unroll
    for (int b = 0; b < 4; b++)
      Cm[(size_t)(bm + ty * 4 + a) * P + bp + tx * 4 + b] = acc[a][b];
}

__global__ void __launch_bounds__(256) k_gemm_nt(const float* __restrict__ A, const float* __restrict__ B,
                                                 float* __restrict__ Cm, int M, int P, int Kd) {
  __shared__ float As[16][65], Bs[16][65];
  int bm = blockIdx.x * 64, bp = blockIdx.y * 64;
  int tx = threadIdx.x & 15, ty = threadIdx.x >> 4;
  float acc[4][4] = {};
  for (int k0 = 0; k0 < Kd; k0 += 16) {
    for (int t2 = threadIdx.x; t2 < 1024; t2 += 256) {
      int kk = t2 & 15, mm = t2 >> 4;
      As[kk][mm] = A[(size_t)(bm + mm) * Kd + k0 + kk];
      Bs[kk][mm] = B[(size_t)(bp + mm) * Kd + k0 + kk];
    }
    __syncthreads();
#pragma unroll
    for (int kk = 0; kk < 16; kk++) {
      float av[4], bv[4];
#pragma unroll
      for (int a = 0; a < 4; a++) av[a] = As[kk][ty * 4 + a];
#pragma unroll
      for (int b = 0; b < 4; b++) bv[b] = Bs[kk][tx * 4 + b];
#pragma unroll
      for (int a = 0; a < 4; a++)
#pragma unroll
        for (int b = 0; b < 4; b++) acc[a][b] += av[a] * bv[b];
    }
    __syncthreads();
  }
#pragma unroll
  for (int a = 0; a < 4; a++)
#pragma unroll
    for (int b = 0; b < 4; b++)
      Cm[(size_t)(bm + ty * 4 + a) * P + bp + tx * 4 + b] = acc[a][b];
}

__global__ void __launch_bounds__(256) k_gemm_nn(const float* __restrict__ A, const float* __restrict__ B,
                                                 float* __restrict__ Cm, int M, int P, int Kd) {
  __shared__ float As[16][65], Bs[16][65];
  int bm = blockIdx.x * 64, bp = blockIdx.y * 64;
  int tx = threadIdx.x & 15, ty = threadIdx.x >> 4;
  float acc[4][4] = {};
  for (int k0 = 0; k0 < Kd; k0 += 16) {
    for (int t2 = threadIdx.x; t2 < 1024; t2 += 256) {
      int kk = t2 & 15, mm = t2 >> 4;
      As[kk][mm] = A[(size_t)(bm + mm) * Kd + k0 + kk];
    }
    for (int t2 = threadIdx.x; t2 < 1024; t2 += 256) {
      int mm = t2 & 63, kk = t2 >> 6;
      Bs[kk][mm] = B[(size_t)(k0 + kk) * P + bp + mm];
    }
    __syncthreads();
#pragma unroll
    for (int kk = 0; kk < 16; kk++) {
      float av[4], bv[4];
#pragma unroll
      for (int a = 0; a < 4; a++) av[a] = As[kk][ty * 4 + a];
#pragma unroll
      for (int b = 0; b < 4; b++) bv[b] = Bs[kk][tx * 4 + b];
#pragma unroll
      for (int a = 0; a < 4; a++)
#pragma unroll
        for (int b = 0; b < 4; b++) acc[a][b] += av[a] * bv[b];
    }
    __syncthreads();
  }
#pragma unroll
  for (int a = 0; a < 4; a++)
#pragma unroll
    for (int b = 0; b < 4; b++)
      Cm[(size_t)(bm + ty * 4 + a) * P + bp + tx * 4 + b] = acc[a][b];
}

// ---------- s = max(max ev_a, max ev_b) ----------
__global__ void k_smax(const float* __restrict__ ea, const float* __restrict__ eb, double* __restrict__ scal) {
  __shared__ float red[128];
  int t = threadIdx.x;
  red[t] = fmaxf(ea[t], eb[t]);
  __syncthreads();
  for (int o = 64; o > 0; o >>= 1) { if (t < o) red[t] = fmaxf(red[t], red[t + o]); __syncthreads(); }
  if (t == 0) scal[1] = (double)red[0];
}

// ---------- resolvent mask ----------
__global__ void k_mask(const float* __restrict__ evr, const float* __restrict__ evc,
                       const double* __restrict__ scal, float* __restrict__ Dm) {
  int t = blockIdx.x * 256 + threadIdx.x;
  if (t >= SK * SK) return;
  int i = t / SK, j = t % SK;
  float s = (float)scal[1];
  float g1 = sqrtf(fmaxf(evc[j] / s, 0.f));
  float g2 = sqrtf(fmaxf(evr[i] / s, 0.f));
  float a2 = g2 * g2 + 1.f, a1 = g1 * g1 + 1.f;
  float re = g2 / a2 - g1 / a1;
  float im = 1.f / a2 - 1.f / a1;
  Dm[t] = re * re + im * im;
}

// ---------- per-row Cholesky solve (factor matrix in padded LDS) ----------
__global__ void __launch_bounds__(128) k_cholsolve(const float* __restrict__ AAt, const float* __restrict__ BAt,
                                                   const float* __restrict__ Dm,
                                                   float* __restrict__ Cout) {
  extern __shared__ float Msh[];   // [SK][SK+1]
  __shared__ float xs[SK];
  int i = blockIdx.x;
  const int LD = SK + 1;
  for (int t2 = threadIdx.x; t2 < SK * SK; t2 += 128) {
    int r = t2 / SK, c2 = t2 % SK;
    float v = AAt[t2];
    if (r == c2) v += LAMBDA_ * Dm[(size_t)i * SK + r];
    Msh[r * LD + c2] = v;
  }
  if (threadIdx.x < SK) xs[threadIdx.x] = BAt[(size_t)i * SK + threadIdx.x];
  __syncthreads();
  for (int k = 0; k < SK; k++) {
    if (threadIdx.x == 0) Msh[k * LD + k] = sqrtf(fmaxf(Msh[k * LD + k], 1e-20f));
    __syncthreads();
    float dk = Msh[k * LD + k];
    for (int r = k + 1 + threadIdx.x; r < SK; r += 128) Msh[r * LD + k] /= dk;
    __syncthreads();
    int rem = SK - k - 1;
    for (int t2 = threadIdx.x; t2 < rem * rem; t2 += 128) {
      int r = k + 1 + t2 / rem, c2 = k + 1 + t2 % rem;
      Msh[r * LD + c2] -= Msh[r * LD + k] * Msh[c2 * LD + k];
    }
    __syncthreads();
  }
  for (int k = 0; k < SK; k++) {
    if (threadIdx.x == 0) xs[k] /= Msh[k * LD + k];
    __syncthreads();
    float xv = xs[k];
    for (int r = k + 1 + threadIdx.x; r < SK; r += 128) xs[r] -= Msh[r * LD + k] * xv;
    __syncthreads();
  }
  for (int k = SK - 1; k >= 0; k--) {
    if (threadIdx.x == 0) xs[k] /= Msh[k * LD + k];
    __syncthreads();
    float xv = xs[k];
    for (int r = threadIdx.x; r < k; r += 128) xs[r] -= Msh[k * LD + r] * xv;
    __syncthreads();
  }
  for (int t2 = threadIdx.x; t2 < SK; t2 += 128) Cout[(size_t)i * SK + t2] = xs[t2];
}

// ---------- loss partials (deterministic) ----------
__global__ void k_frob_iden(const float* __restrict__ Mat, double* __restrict__ lpart, int slot) {
  __shared__ double red[256];
  double s = 0.0;
  for (int t2 = blockIdx.x * 256 + threadIdx.x; t2 < SK * SK; t2 += 32 * 256) {
    float v = Mat[t2] - ((t2 / SK == t2 % SK) ? 1.f : 0.f);
    s += (double)v * (double)v;
  }
  red[threadIdx.x] = s; __syncthreads();
  for (int o = 128; o > 0; o >>= 1) { if (threadIdx.x < o) red[threadIdx.x] += red[threadIdx.x + o]; __syncthreads(); }
  if (threadIdx.x == 0) lpart[slot * 32 + blockIdx.x] = red[0];
}
__global__ void k_lap(const float* __restrict__ Cm, const float* __restrict__ evc,
                      const float* __restrict__ evr, double* __restrict__ lpart, int slot) {
  __shared__ double red[256];
  double s = 0.0;
  for (int t2 = blockIdx.x * 256 + threadIdx.x; t2 < SK * SK; t2 += 32 * 256) {
    int i = t2 / SK, j = t2 % SK;
    float v = Cm[t2] * (evc[j] - evr[i]);
    s += (double)v * (double)v;
  }
  red[threadIdx.x] = s; __syncthreads();
  for (int o = 128; o > 0; o >>= 1) { if (threadIdx.x < o) red[threadIdx.x] += red[threadIdx.x + o]; __syncthreads(); }
  if (threadIdx.x == 0) lpart[slot * 32 + blockIdx.x] = red[0];
}
__global__ void k_writeout(const double* __restrict__ lpart, float* __restrict__ out) {
  if (threadIdx.x == 0) {
    double b = 0.0, o = 0.0, l = 0.0;
    for (int s = 0; s < 64; s++) b += lpart[s];
    for (int s = 64; s < 128; s++) o += lpart[s];
    for (int s = 128; s < 192; s++) l += lpart[s];
    out[0] = (float)b; out[1] = (float)o; out[2] = (float)l;
  }
}

extern "C" void kernel_launch(void* const* d_in, const int* in_sizes, int n_in,
                              void* d_out, int out_size, void* d_ws, size_t ws_size,
                              hipStream_t stream) {
  const float* feats[2] = {(const float*)d_in[0], (const float*)d_in[1]};
  char* p = (char*)d_ws;
  auto alloc = [&](size_t bytes) -> void* {
    char* r = p;
    p += (bytes + 255) & ~(size_t)255;
    return (void*)r;
  };
  float* pan   = (float*)alloc(sizeof(float) * 256 * NN);
  float* sq    = (float*)alloc(sizeof(float) * NN);
  float* dkv   = (float*)alloc(sizeof(float) * (size_t)NN * KK);
  float* wv    = (float*)alloc(sizeof(float) * (size_t)NN * KK);
  int*   cnt   = (int*)alloc(sizeof(int) * NN);
  int*   rpos  = (int*)alloc(sizeof(int) * NN);
  int*   tsrc  = (int*)alloc(sizeof(int) * (size_t)NN * KK);
  float* deg   = (float*)alloc(sizeof(float) * NN);
  int*   hist  = (int*)alloc(sizeof(int) * 256 * NN);
  int*   baseb = (int*)alloc(sizeof(int) * 256 * NN);
  int*   idxs[2];  float* wadjrs[2]; float* wadjts[2]; int* tcols[2]; int* roffs[2];
  for (int s = 0; s < 2; s++) {
    idxs[s]   = (int*)alloc(sizeof(int) * (size_t)NN * KK);
    wadjrs[s] = (float*)alloc(sizeof(float) * (size_t)NN * KK);
    wadjts[s] = (float*)alloc(sizeof(float) * (size_t)NN * KK);
    tcols[s]  = (int*)alloc(sizeof(int) * (size_t)NN * KK);
    roffs[s]  = (int*)alloc(sizeof(int) * (NN + 1));
  }
  float* Q0    = (float*)alloc(sizeof(float) * (size_t)LM * NN);
  float* Q1    = (float*)alloc(sizeof(float) * (size_t)LM * NN);
  float* ya0   = (float*)alloc(sizeof(float) * NN);
  float* ya1   = (float*)alloc(sizeof(float) * NN);
  float* yb0   = (float*)alloc(sizeof(float) * NN);
  float* yb1   = (float*)alloc(sizeof(float) * NN);
  float* cv0   = (float*)alloc(sizeof(float) * LM);
  float* cv1   = (float*)alloc(sizeof(float) * LM);
  double* part = (double*)alloc(sizeof(double) * 256);
  double* scal = (double*)alloc(sizeof(double) * 8);
  double* Ta0  = (double*)alloc(sizeof(double) * LM);
  double* Tb0  = (double*)alloc(sizeof(double) * LM);
  double* Ta1  = (double*)alloc(sizeof(double) * LM);
  double* Tb1  = (double*)alloc(sizeof(double) * LM);
  double* theta0 = (double*)alloc(sizeof(double) * SK);
  double* theta1 = (double*)alloc(sizeof(double) * SK);
  double* dws  = (double*)alloc(sizeof(double) * 2 * (size_t)LM * SK);
  double* ews  = (double*)alloc(sizeof(double) * 2 * (size_t)LM * SK);
  double* fws  = (double*)alloc(sizeof(double) * 2 * (size_t)LM * SK);
  double* rws  = (double*)alloc(sizeof(double) * 2 * (size_t)LM * SK);
  float* Ym0   = (float*)alloc(sizeof(float) * (size_t)LM * SK);
  float* Ym1   = (float*)alloc(sizeof(float) * (size_t)LM * SK);
  float* Ym2   = (float*)alloc(sizeof(float) * (size_t)LM * SK);
  float* Sm    = (float*)alloc(sizeof(float) * SK * SK);
  float* Linv  = (float*)alloc(sizeof(float) * SK * SK);
  float* U0    = (float*)alloc(sizeof(float) * (size_t)NN * SK);
  float* U1    = (float*)alloc(sizeof(float) * (size_t)NN * SK);
  float* ev0   = (float*)alloc(sizeof(float) * SK);
  float* ev1   = (float*)alloc(sizeof(float) * SK);
  float* Ac    = (float*)alloc(sizeof(float) * (size_t)SK * NC);
  float* Bc    = (float*)alloc(sizeof(float) * (size_t)SK * NC);
  float* AAt   = (float*)alloc(sizeof(float) * SK * SK);
  float* BAt   = (float*)alloc(sizeof(float) * SK * SK);
  float* Dm    = (float*)alloc(sizeof(float) * SK * SK);
  float* Cxy   = (float*)alloc(sizeof(float) * SK * SK);
  float* Cyx   = (float*)alloc(sizeof(float) * SK * SK);
  float* P1    = (float*)alloc(sizeof(float) * SK * SK);
  double* lpart= (double*)alloc(sizeof(double) * 192);
  unsigned* sy = (unsigned*)alloc(sizeof(unsigned) * 1024);

  float* Yms[2] = {Ym0, Ym1};
  float* Qs2[2] = {Q0, Q1};
  float* Us[2] = {U0, U1};

  hipFuncSetAttribute((const void*)k_lanczos2,
                      hipFuncAttributeMaxDynamicSharedMemorySize, DYNLDS);
  hipFuncSetAttribute((const void*)k_cholinv,
                      hipFuncAttributeMaxDynamicSharedMemorySize, CHOLLDS);
  hipFuncSetAttribute((const void*)k_cholsolve,
                      hipFuncAttributeMaxDynamicSharedMemorySize, CHSLDS);

  // ---- kNN graph construction for both sides ----
  for (int s2 = 0; s2 < 2; s2++) {
    const float* f = feats[s2];
    int* idx = idxs[s2];
    k_sqnorm<<<NN, 256, 0, stream>>>(f, sq);
    for (int p2 = 0; p2 < 16; p2++) {
      k_d2panel<<<dim3(64, 4), 256, 0, stream>>>(f, sq, pan, p2 * 256);
      k_topk<<<256, 256, 0, stream>>>(pan, p2 * 256, idx, dkv);
    }
    k_partsum<<<64, 256, 0, stream>>>(dkv, part);
    k_sigma<<<1, 64, 0, stream>>>(part, scal);
    k_wexp<<<NN * KK / 256, 256, 0, stream>>>(dkv, scal, wv);
    hipMemsetAsync(cnt, 0, sizeof(int) * NN, stream);
    k_count<<<NN * KK / 256, 256, 0, stream>>>(idx, cnt);
    k_scan<<<1, 1024, 0, stream>>>(cnt, roffs[s2], rpos);
    hipMemsetAsync(hist, 0, sizeof(int) * 256 * NN, stream);
    k_hist<<<256, 256, 0, stream>>>(idx, hist);
    k_colscan<<<16, 256, 0, stream>>>(hist, roffs[s2], baseb);
    k_place2<<<256, 256, 0, stream>>>(idx, baseb, tsrc);
    k_deg<<<16, 256, 0, stream>>>(wv, roffs[s2], tsrc, deg);
    k_wadj2<<<16, 256, 0, stream>>>(wv, idx, roffs[s2], tsrc, deg,
                                    wadjrs[s2], wadjts[s2], tcols[s2]);
  }

  // ---- dual-side fused cooperative Lanczos (CGS1) ----
  hipMemsetAsync(sy, 0, sizeof(unsigned) * 1024, stream);
  {
    void* args[] = {(void*)&Q0, (void*)&Q1,
                    (void*)&ya0, (void*)&ya1, (void*)&yb0, (void*)&yb1,
                    (void*)&wadjrs[0], (void*)&idxs[0], (void*)&wadjts[0], (void*)&tcols[0], (void*)&roffs[0],
                    (void*)&wadjrs[1], (void*)&idxs[1], (void*)&wadjts[1], (void*)&tcols[1], (void*)&roffs[1],
                    (void*)&cv0, (void*)&cv1, (void*)&part,
                    (void*)&Ta0, (void*)&Tb0, (void*)&Ta1, (void*)&Tb1,
                    (void*)&sy};
    hipLaunchCooperativeKernel((const void*)k_lanczos2, dim3(256), dim3(1024), args, DYNLDS, stream);
  }

  // ---- spectral finish: batched bisect + 1-pass invit, then per-side CholQR2 ----
  k_bisect2<<<2, 128, 0, stream>>>(Ta0, Tb0, Ta1, Tb1, theta0, theta1, ev0, ev1);
  k_invit2<<<2, 128, 0, stream>>>(Ta0, Tb0, Ta1, Tb1, theta0, theta1,
                                  dws, ews, fws, rws, Ym0, Ym1);
  for (int s2 = 0; s2 < 2; s2++) {
    k_gemm_tn<<<dim3(2, 2), 256, 0, stream>>>(Yms[s2], Yms[s2], Sm, SK, SK, LM);
    k_cholinv<<<1, 128, CHOLLDS, stream>>>(Sm, Linv);
    k_gemm_nt<<<dim3(LM / 64, 2), 256, 0, stream>>>(Yms[s2], Linv, Ym2, LM, SK, SK);
    k_gemm_tn<<<dim3(2, 2), 256, 0, stream>>>(Ym2, Ym2, Sm, SK, SK, LM);
    k_cholinv<<<1, 128, CHOLLDS, stream>>>(Sm, Linv);
    k_gemm_nt<<<dim3(LM / 64, 2), 256, 0, stream>>>(Ym2, Linv, Yms[s2], LM, SK, SK);
    k_gemm_tn<<<dim3(NN / 64, SK / 64), 256, 0, stream>>>(Qs2[s2], Yms[s2], Us[s2], NN, SK, LM);
  }

  // ---- spectral coefficients + FM solves + losses ----
  k_gemm_tn<<<dim3(SK / 64, NC / 64), 256, 0, stream>>>(U0, feats[0], Ac, SK, NC, NN);
  k_gemm_tn<<<dim3(SK / 64, NC / 64), 256, 0, stream>>>(U1, feats[1], Bc, SK, NC, NN);
  k_smax<<<1, 128, 0, stream>>>(ev0, ev1, scal);

  k_gemm_nt<<<dim3(2, 2), 256, 0, stream>>>(Ac, Ac, AAt, SK, SK, NC);
  k_gemm_nt<<<dim3(2, 2), 256, 0, stream>>>(Bc, Ac, BAt, SK, SK, NC);
  k_mask<<<64, 256, 0, stream>>>(ev1, ev0, scal, Dm);
  k_cholsolve<<<SK, 128, CHSLDS, stream>>>(AAt, BAt, Dm, Cxy);
  k_gemm_nt<<<dim3(2, 2), 256, 0, stream>>>(Bc, Bc, AAt, SK, SK, NC);
  k_gemm_nt<<<dim3(2, 2), 256, 0, stream>>>(Ac, Bc, BAt, SK, SK, NC);
  k_mask<<<64, 256, 0, stream>>>(ev0, ev1, scal, Dm);
  k_cholsolve<<<SK, 128, CHSLDS, stream>>>(AAt, BAt, Dm, Cyx);

  k_gemm_nn<<<dim3(2, 2), 256, 0, stream>>>(Cxy, Cyx, P1, SK, SK, SK);
  k_frob_iden<<<32, 256, 0, stream>>>(P1, lpart, 0);
  k_gemm_nn<<<dim3(2, 2), 256, 0, stream>>>(Cyx, Cxy, P1, SK, SK, SK);
  k_frob_iden<<<32, 256, 0, stream>>>(P1, lpart, 1);
  k_gemm_tn<<<dim3(2, 2), 256, 0, stream>>>(Cxy, Cxy, P1, SK, SK, SK);
  k_frob_iden<<<32, 256, 0, stream>>>(P1, lpart, 2);
  k_gemm_tn<<<dim3(2, 2), 256, 0, stream>>>(Cyx, Cyx, P1, SK, SK, SK);
  k_frob_iden<<<32, 256, 0, stream>>>(P1, lpart, 3);
  k_lap<<<32, 256, 0, stream>>>(Cxy, ev0, ev1, lpart, 4);
  k_lap<<<32, 256, 0, stream>>>(Cyx, ev1, ev0, lpart, 5);
  k_writeout<<<1, 64, 0, stream>>>(lpart, (float*)d_out);
}

// Round 13
// 29506.763 us; speedup vs baseline: 27.3642x; 1.2038x over previous
//
#include <hip/hip_runtime.h>
#include <math.h>

#define NN 4096      // points
#define NC 768       // feature dim
#define KK 16        // knn k
#define SK 128       // spectral basis size
#define LM 640       // Lanczos steps (5x oversampling of SK)
#define NR (LM / 128) // dots rows per block
#define LAMBDA_ 100.0f
// dynamic LDS for lanczos2: slab[LM][32] + ysh[NN] + cvsh[LM]
#define DYNLDS (LM * 32 * 4 + NN * 4 + LM * 4)
// dynamic LDS for cholinv: Ls[SK][SK+1] + Li[SK][SK+1]
#define CHOLLDS (2 * SK * (SK + 1) * 4)
// dynamic LDS for cholsolve: Ms[SK][SK+1]
#define CHSLDS (SK * (SK + 1) * 4)

typedef unsigned int u32;

__device__ __forceinline__ float hashf(u32 x) {
  x ^= x >> 16; x *= 0x7feb352dU; x ^= x >> 15; x *= 0x846ca68bU; x ^= x >> 16;
  return ((float)x) * (1.0f / 4294967296.0f);  // [0,1)
}

// ---- agent-scope (device-coherent) access helpers ----
__device__ __forceinline__ float agld(const float* p) {
  return __hip_atomic_load((float*)p, __ATOMIC_RELAXED, __HIP_MEMORY_SCOPE_AGENT);
}
__device__ __forceinline__ void agst(float* p, float v) {
  __hip_atomic_store(p, v, __ATOMIC_RELAXED, __HIP_MEMORY_SCOPE_AGENT);
}
__device__ __forceinline__ double agldd(const double* p) {
  return __hip_atomic_load((double*)p, __ATOMIC_RELAXED, __HIP_MEMORY_SCOPE_AGENT);
}
__device__ __forceinline__ void agstd(double* p, double v) {
  __hip_atomic_store(p, v, __ATOMIC_RELAXED, __HIP_MEMORY_SCOPE_AGENT);
}

// ---- per-side two-level tree barrier (128 blocks: 8 groups x 16) ----
__device__ __forceinline__ void gbar2(unsigned* syb, int lb, unsigned gph) {
  asm volatile("s_waitcnt vmcnt(0)" ::: "memory");
  __syncthreads();
  if (threadIdx.x == 0) {
    const int grp = lb >> 4, mem = lb & 15;
    unsigned* gc  = syb + grp * 16;
    unsigned* top = syb + 144;
    unsigned* fl  = syb + 256 + grp * 16;
    __hip_atomic_fetch_add(gc, 1u, __ATOMIC_RELEASE, __HIP_MEMORY_SCOPE_AGENT);
    if (mem == 0) {
      while (__hip_atomic_load(gc, __ATOMIC_RELAXED, __HIP_MEMORY_SCOPE_AGENT) < gph * 16u)
        __builtin_amdgcn_s_sleep(1);
      __hip_atomic_fetch_add(top, 1u, __ATOMIC_RELEASE, __HIP_MEMORY_SCOPE_AGENT);
      while (__hip_atomic_load(top, __ATOMIC_RELAXED, __HIP_MEMORY_SCOPE_AGENT) < gph * 8u)
        __builtin_amdgcn_s_sleep(1);
      __hip_atomic_store(fl, gph, __ATOMIC_RELEASE, __HIP_MEMORY_SCOPE_AGENT);
    } else {
      while (__hip_atomic_load(fl, __ATOMIC_RELAXED, __HIP_MEMORY_SCOPE_AGENT) < gph)
        __builtin_amdgcn_s_sleep(1);
    }
    __builtin_amdgcn_fence(__ATOMIC_ACQUIRE, "agent");
  }
  __syncthreads();
}

// ---------- row squared norms (both sides batched via blockIdx.y) ----------
__global__ void k_sqnorm2(const float* __restrict__ f0, const float* __restrict__ f1,
                          float* __restrict__ sq0, float* __restrict__ sq1) {
  __shared__ float red[256];
  const float* f = blockIdx.y ? f1 : f0;
  float* sq = blockIdx.y ? sq1 : sq0;
  int i = blockIdx.x;
  float s = 0.f;
  for (int c = threadIdx.x; c < NC; c += 256) { float v = f[(size_t)i * NC + c]; s += v * v; }
  red[threadIdx.x] = s; __syncthreads();
  for (int o = 128; o > 0; o >>= 1) { if (threadIdx.x < o) red[threadIdx.x] += red[threadIdx.x + o]; __syncthreads(); }
  if (threadIdx.x == 0) sq[i] = red[0];
}

// ---------- d2 panel (both sides batched via blockIdx.z) ----------
__global__ void __launch_bounds__(256) k_d2panel2(const float* __restrict__ f0, const float* __restrict__ f1,
                                                  const float* __restrict__ sq0, const float* __restrict__ sq1,
                                                  float* __restrict__ pan0, float* __restrict__ pan1, int i0) {
  __shared__ float As[16][65], Bs[16][65];
  const float* f = blockIdx.z ? f1 : f0;
  const float* sq = blockIdx.z ? sq1 : sq0;
  float* pan = blockIdx.z ? pan1 : pan0;
  int bj = blockIdx.x, bi = blockIdx.y;
  int row0 = i0 + bi * 64, col0 = bj * 64;
  int tx = threadIdx.x & 15, ty = threadIdx.x >> 4;
  float acc[4][4] = {};
  for (int k0 = 0; k0 < NC; k0 += 16) {
    for (int t2 = threadIdx.x; t2 < 1024; t2 += 256) {
      int kk = t2 & 15, rr = t2 >> 4;
      As[kk][rr] = f[(size_t)(row0 + rr) * NC + k0 + kk];
      Bs[kk][rr] = f[(size_t)(col0 + rr) * NC + k0 + kk];
    }
    __syncthreads();
#pragma unroll
    for (int kk = 0; kk < 16; kk++) {
      float av[4], bv[4];
#pragma unroll
      for (int a = 0; a < 4; a++) av[a] = As[kk][ty * 4 + a];
#pragma unroll
      for (int b = 0; b < 4; b++) bv[b] = Bs[kk][tx * 4 + b];
#pragma unroll
      for (int a = 0; a < 4; a++)
#pragma unroll
        for (int b = 0; b < 4; b++) acc[a][b] += av[a] * bv[b];
    }
    __syncthreads();
  }
#pragma unroll
  for (int a = 0; a < 4; a++) {
    int gr = row0 + ty * 4 + a;
    int pr = bi * 64 + ty * 4 + a;
    float sr = sq[gr];
#pragma unroll
    for (int b = 0; b < 4; b++) {
      int gc = col0 + tx * 4 + b;
      float v = sr + sq[gc] - 2.f * acc[a][b];
      v = fmaxf(v, 0.f);
      if (gr == gc) v += 1e10f;
      pan[(size_t)pr * NN + gc] = v;
    }
  }
}

// ---------- top-16 smallest per row (both sides batched via blockIdx.z) ----------
__global__ void __launch_bounds__(256) k_topk2(const float* __restrict__ pan0, const float* __restrict__ pan1,
                                               int i0,
                                               int* __restrict__ idx0, int* __restrict__ idx1,
                                               float* __restrict__ dkv0, float* __restrict__ dkv1) {
  __shared__ float vals[NN];
  __shared__ float rv[256];
  __shared__ int ri[256];
  const float* pan = blockIdx.z ? pan1 : pan0;
  int* idx = blockIdx.z ? idx1 : idx0;
  float* dkv = blockIdx.z ? dkv1 : dkv0;
  int r = blockIdx.x;
  const float* row = pan + (size_t)r * NN;
  for (int j = threadIdx.x; j < NN; j += 256) vals[j] = row[j];
  __syncthreads();
  for (int t3 = 0; t3 < KK; t3++) {
    float bv = 1e30f; int bi2 = NN;
    for (int j2 = threadIdx.x; j2 < NN; j2 += 256) {
      float v = vals[j2];
      if (v < bv || (v == bv && j2 < bi2)) { bv = v; bi2 = j2; }
    }
    rv[threadIdx.x] = bv; ri[threadIdx.x] = bi2;
    __syncthreads();
    for (int o = 128; o > 0; o >>= 1) {
      if (threadIdx.x < o) {
        float v2 = rv[threadIdx.x + o]; int i2 = ri[threadIdx.x + o];
        if (v2 < rv[threadIdx.x] || (v2 == rv[threadIdx.x] && i2 < ri[threadIdx.x])) {
          rv[threadIdx.x] = v2; ri[threadIdx.x] = i2;
        }
      }
      __syncthreads();
    }
    if (threadIdx.x == 0) {
      idx[(size_t)(i0 + r) * KK + t3] = ri[0];
      dkv[(size_t)(i0 + r) * KK + t3] = rv[0];
      vals[ri[0]] = 1e30f;
    }
    __syncthreads();
  }
}

// ---------- sigma2 ----------
__global__ void k_partsum(const float* __restrict__ dkv, double* __restrict__ part) {
  __shared__ double red[256];
  double s = 0.0;
  for (int t2 = blockIdx.x * 256 + threadIdx.x; t2 < NN * KK; t2 += 64 * 256) s += (double)dkv[t2];
  red[threadIdx.x] = s; __syncthreads();
  for (int o = 128; o > 0; o >>= 1) { if (threadIdx.x < o) red[threadIdx.x] += red[threadIdx.x + o]; __syncthreads(); }
  if (threadIdx.x == 0) part[blockIdx.x] = red[0];
}
__global__ void k_sigma(const double* __restrict__ part, double* __restrict__ scal) {
  __shared__ double red[64];
  red[threadIdx.x] = part[threadIdx.x]; __syncthreads();
  for (int o = 32; o > 0; o >>= 1) { if (threadIdx.x < o) red[threadIdx.x] += red[threadIdx.x + o]; __syncthreads(); }
  if (threadIdx.x == 0) scal[0] = red[0] / (double)(NN * KK) + 1e-12;
}

// ---------- gaussian weights ----------
__global__ void k_wexp(const float* __restrict__ dkv, const double* __restrict__ scal,
                       float* __restrict__ wv) {
  int t = blockIdx.x * 256 + threadIdx.x;
  if (t >= NN * KK) return;
  float inv2s = (float)(0.5 / scal[0]);
  wv[t] = expf(-dkv[t] * inv2s);
}

// ---------- deterministic CSR transpose: counting-sort ----------
__global__ void k_count(const int* __restrict__ idx, int* __restrict__ cnt) {
  int t = blockIdx.x * 256 + threadIdx.x;
  if (t < NN * KK) atomicAdd(&cnt[idx[t]], 1);
}

__global__ void __launch_bounds__(1024) k_scan(const int* __restrict__ cnt,
                                               int* __restrict__ roff, int* __restrict__ rpos) {
  __shared__ int buf[1024];
  int t = threadIdx.x;
  int v[4]; int s = 0;
#pragma unroll
  for (int u = 0; u < 4; u++) { v[u] = cnt[t * 4 + u]; s += v[u]; }
  buf[t] = s; __syncthreads();
  for (int o = 1; o < 1024; o <<= 1) {
    int x = (t >= o) ? buf[t - o] : 0;
    __syncthreads();
    buf[t] += x;
    __syncthreads();
  }
  int run = (t == 0) ? 0 : buf[t - 1];
#pragma unroll
  for (int u = 0; u < 4; u++) { roff[t * 4 + u] = run; rpos[t * 4 + u] = run; run += v[u]; }
  if (t == 1023) roff[NN] = run;
}

__global__ void k_hist(const int* __restrict__ idx, int* __restrict__ hist) {
  int e = blockIdx.x * 256 + threadIdx.x;
  atomicAdd(&hist[(e >> 8) * NN + idx[e]], 1);
}
__global__ void k_colscan(const int* __restrict__ hist, const int* __restrict__ roff,
                          int* __restrict__ baseb) {
  int j = blockIdx.x * 256 + threadIdx.x;
  if (j >= NN) return;
  int run = roff[j];
  for (int c = 0; c < 256; c++) { baseb[c * NN + j] = run; run += hist[c * NN + j]; }
}
__global__ void __launch_bounds__(256) k_place2(const int* __restrict__ idx,
                                                const int* __restrict__ baseb,
                                                int* __restrict__ tsrc) {
  __shared__ int ish[256];
  int c = blockIdx.x;
  int e = c * 256 + threadIdx.x;
  ish[threadIdx.x] = idx[e];
  __syncthreads();
  int j = ish[threadIdx.x];
  int rank = 0;
  for (int p2 = 0; p2 < threadIdx.x; p2++) rank += (ish[p2] == j) ? 1 : 0;
  tsrc[baseb[c * NN + j] + rank] = e;
}

// ---------- degrees ----------
__global__ void k_deg(const float* __restrict__ wv, const int* __restrict__ roff,
                      const int* __restrict__ tsrc, float* __restrict__ deg) {
  int i = blockIdx.x * 256 + threadIdx.x;
  if (i >= NN) return;
  float s = 0.f;
  for (int l = 0; l < KK; l++) s += wv[(size_t)i * KK + l];
  float s2 = 0.f;
  for (int e = roff[i]; e < roff[i + 1]; e++) s2 += wv[tsrc[e]];
  deg[i] = 0.5f * (s + s2);
}

// ---------- normalized adjacency ----------
__global__ void k_wadj2(const float* __restrict__ wv, const int* __restrict__ idx,
                        const int* __restrict__ roff, const int* __restrict__ tsrc,
                        const float* __restrict__ deg,
                        float* __restrict__ wadjr, float* __restrict__ wadjt,
                        int* __restrict__ tcol) {
  int i = blockIdx.x * 256 + threadIdx.x;
  if (i >= NN) return;
  float di = 1.0f / sqrtf(deg[i] + 1e-8f);
  for (int l = 0; l < KK; l++) {
    int j = idx[(size_t)i * KK + l];
    float dj = 1.0f / sqrtf(deg[j] + 1e-8f);
    wadjr[(size_t)i * KK + l] = 0.5f * wv[(size_t)i * KK + l] * di * dj;
  }
  for (int e = roff[i]; e < roff[i + 1]; e++) {
    int s = tsrc[e];
    int sn = s / KK;
    float dj = 1.0f / sqrtf(deg[sn] + 1e-8f);
    wadjt[e] = 0.5f * wv[s] * di * dj;
    tcol[e] = sn;
  }
}

// ---------- DUAL-SIDE fused cooperative Lanczos, CGS1 (3 barriers/iter) ----------
__global__ void __launch_bounds__(1024) k_lanczos2(
    float* __restrict__ Q0, float* __restrict__ Q1,
    float* __restrict__ ya0, float* __restrict__ ya1,
    float* __restrict__ yb0, float* __restrict__ yb1,
    const float* __restrict__ wadjr0, const int* __restrict__ idx0,
    const float* __restrict__ wadjt0, const int* __restrict__ tcol0, const int* __restrict__ roff0,
    const float* __restrict__ wadjr1, const int* __restrict__ idx1,
    const float* __restrict__ wadjt1, const int* __restrict__ tcol1, const int* __restrict__ roff1,
    float* __restrict__ cv0, float* __restrict__ cv1, double* __restrict__ part,
    double* __restrict__ Ta0, double* __restrict__ Tb0,
    double* __restrict__ Ta1, double* __restrict__ Tb1,
    unsigned* __restrict__ sy) {
  const int b = blockIdx.x, t = threadIdx.x;
  const int s = b >> 7, lb = b & 127;
  const int n0 = lb * 32;
  const int lane = t & 63, wvid = t >> 6;  // 16 waves
  float* Qs = s ? Q1 : Q0;
  float* ybuf0 = s ? yb0 : ya0;
  float* ybuf1 = s ? yb1 : ya1;
  const float* wadjr = s ? wadjr1 : wadjr0;
  const int* idx = s ? idx1 : idx0;
  const float* wadjt = s ? wadjt1 : wadjt0;
  const int* tcol = s ? tcol1 : tcol0;
  const int* roff = s ? roff1 : roff0;
  float* cvs = s ? cv1 : cv0;
  double* ps = part + s * 128;
  double* Ta = s ? Ta1 : Ta0;
  double* Tb = s ? Tb1 : Tb0;
  unsigned* syb = sy + s * 512;
  u32 seed = 1234567u + (u32)s * 77777u;

  extern __shared__ char dynsh[];
  float* slabsh = (float*)dynsh;                      // [LM][32]
  float* ysh    = (float*)(dynsh + LM * 32 * 4);      // [NN]
  float* cvsh   = (float*)(dynsh + LM * 32 * 4 + NN * 4);  // [LM]
  __shared__ double pd[2];
  __shared__ double wl[16][NR];
  __shared__ float fredu[32][33];
  __shared__ float r2loc[32];
  unsigned gph = 0;

  // init residual + norm partial
  if (t < 32) {
    int n = n0 + t;
    agst(&ybuf0[n], hashf((u32)n * 2246822519u + seed) - 0.5f);
  }
  __syncthreads();
  if (t == 0) {
    double ss = 0.0;
    for (int u = 0; u < 32; u++) { double v = (double)agld(&ybuf0[n0 + u]); ss += v * v; }
    agstd(&ps[lb], ss);
  }
  gbar2(syb, lb, ++gph);

  for (int it = 0; it < LM; it++) {
    float* r  = (it & 1) ? ybuf1 : ybuf0;
    float* r2 = (it & 1) ? ybuf0 : ybuf1;

    // ---- Phase A: stage r, single-wave norm, q-row write (+slab), SpMV ----
    {
      int b4 = t * 4;
      float a0 = agld(&r[b4]), a1 = agld(&r[b4 + 1]);
      float a2 = agld(&r[b4 + 2]), a3 = agld(&r[b4 + 3]);
      ysh[b4] = a0; ysh[b4 + 1] = a1; ysh[b4 + 2] = a2; ysh[b4 + 3] = a3;
    }
    if (t < 64) {
      double v = agldd(&ps[t]) + agldd(&ps[t + 64]);
      for (int o = 32; o > 0; o >>= 1) v += __shfl_down(v, o, 64);
      if (t == 0) pd[0] = v;
    }
    __syncthreads();
    double nrm = sqrt(pd[0]);
    if (lb == 0 && t == 0 && it > 0) agstd(&Tb[it - 1], nrm);
    float inv = (float)(1.0 / (nrm > 1e-300 ? nrm : 1e-300));
    if (t < 32) {
      int n = n0 + t;
      float qv = ysh[n] * inv;
      agst(&Qs[(size_t)it * NN + n], qv);
      slabsh[it * 32 + t] = qv;
    }
#pragma unroll
    for (int rr = 0; rr < 2; rr++) {
      int n = n0 + wvid + rr * 16;       // 2 rows per wave
      int rb = roff[n], re = roff[n + 1];
      int L = 16 + (re - rb);
      float acc = 0.f;
      for (int i = lane; i < L; i += 64) {
        float w, qv;
        if (i < 16) { w = wadjr[(size_t)n * KK + i]; qv = ysh[idx[(size_t)n * KK + i]] * inv; }
        else        { int e = rb + i - 16; w = wadjt[e]; qv = ysh[tcol[e]] * inv; }
        acc += w * qv;
      }
      for (int o = 32; o > 0; o >>= 1) acc += __shfl_down(acc, o, 64);
      if (lane == 0) { agst(&r2[n], acc); r2loc[wvid + rr * 16] = acc; }
    }
    gbar2(syb, lb, ++gph);

    // ---- Phase B: dots (single CGS pass), register-direct loads ----
    {
      float4 yv4;
      int b4 = t * 4;
      yv4.x = agld(&r2[b4]); yv4.y = agld(&r2[b4 + 1]);
      yv4.z = agld(&r2[b4 + 2]); yv4.w = agld(&r2[b4 + 3]);
      double sa[NR];
#pragma unroll
      for (int rsel = 0; rsel < NR; rsel++) {
        int j = lb + rsel * 128;
        sa[rsel] = 0.0;
        if (j <= it) {
          float4 q4 = *(const float4*)&Qs[(size_t)j * NN + t * 4];
          double d = (double)q4.x * yv4.x; d += (double)q4.y * yv4.y;
          d += (double)q4.z * yv4.z; d += (double)q4.w * yv4.w;
          sa[rsel] = d;
        }
      }
#pragma unroll
      for (int rsel = 0; rsel < NR; rsel++) {
        int j = lb + rsel * 128;
        if (j <= it) {
          double sd = sa[rsel];
          for (int o = 32; o > 0; o >>= 1) sd += __shfl_down(sd, o, 64);
          if (lane == 0) wl[wvid][rsel] = sd;
        }
      }
      __syncthreads();
      if (t < NR) {
        int j = lb + t * 128;
        if (j <= it) {
          double tot = 0.0;
          for (int u = 0; u < 16; u++) tot += wl[u][t];
          agst(&cvs[j], (float)tot);
          if (j == it) agstd(&Ta[it], tot);
        }
      }
      __syncthreads();
    }
    gbar2(syb, lb, ++gph);

    // ---- Phase C: update + next norm partial ----
    {
      for (int j2s = t; j2s <= it; j2s += 1024) cvsh[j2s] = agld(&cvs[j2s]);
      __syncthreads();
      int i2 = t & 31, g = t >> 5;     // 32 cols x 32 j-groups
      float s0 = 0.f, s1 = 0.f, s2 = 0.f, s3 = 0.f;
      int j = g;
      for (; j + 96 <= it; j += 128) {
        s0 += cvsh[j]      * slabsh[j * 32 + i2];
        s1 += cvsh[j + 32] * slabsh[(j + 32) * 32 + i2];
        s2 += cvsh[j + 64] * slabsh[(j + 64) * 32 + i2];
        s3 += cvsh[j + 96] * slabsh[(j + 96) * 32 + i2];
      }
      for (; j <= it; j += 32) s0 += cvsh[j] * slabsh[j * 32 + i2];
      fredu[g][i2] = (s0 + s1) + (s2 + s3);
      __syncthreads();
      if (t < 32) {
        float acc2 = 0.f;
        for (int g2 = 0; g2 < 32; g2++) acc2 += fredu[g2][t];
        float ny = r2loc[t] - acc2;
        agst(&r2[n0 + t], ny);
        r2loc[t] = ny;
      }
      __syncthreads();
      if (t == 0) {
        double s2d = 0.0;
        for (int u = 0; u < 32; u++) { double v = (double)r2loc[u]; s2d += v * v; }
        agstd(&ps[lb], s2d);
      }
    }
    gbar2(syb, lb, ++gph);
  }
}

// ---------- bisection, both sides batched (grid=2) ----------
__global__ void __launch_bounds__(128) k_bisect2(const double* __restrict__ Ta0, const double* __restrict__ Tb0,
                                                 const double* __restrict__ Ta1, const double* __restrict__ Tb1,
                                                 double* __restrict__ theta0, double* __restrict__ theta1,
                                                 float* __restrict__ ev0, float* __restrict__ ev1) {
  __shared__ double Tas[LM];
  __shared__ double Tb2[LM];
  int side = blockIdx.x;
  const double* Ta = side ? Ta1 : Ta0;
  const double* Tb = side ? Tb1 : Tb0;
  double* theta = side ? theta1 : theta0;
  float* evL = side ? ev1 : ev0;
  int j = threadIdx.x;
  for (int k = j; k < LM; k += 128) {
    Tas[k] = Ta[k];
    double bq = (k > 0) ? Tb[k - 1] : 0.0;
    Tb2[k] = bq * bq;
  }
  __syncthreads();
  if (j >= SK) return;
  int tgt = LM - j;
  double lo = -2.0, hi = 2.0;
  for (int iter = 0; iter < 50; iter++) {
    double mid = 0.5 * (lo + hi);
    int cnt = 0; double q = 1.0;
    for (int k = 0; k < LM; k++) {
      q = Tas[k] - mid - Tb2[k] / q;
      if (q < 0.0) cnt++;
      if (fabs(q) < 1e-280) q = -1e-280;
    }
    if (cnt >= tgt) hi = mid; else lo = mid;
  }
  theta[j] = 0.5 * (lo + hi);
  evL[j] = (float)(1.0 - theta[j]);
}

// ---------- inverse iteration, 1 pass, both sides batched (grid=2) ----------
__global__ void __launch_bounds__(128) k_invit2(const double* __restrict__ Ta0, const double* __restrict__ Tb0,
                        const double* __restrict__ Ta1, const double* __restrict__ Tb1,
                        const double* __restrict__ theta0, const double* __restrict__ theta1,
                        double* __restrict__ dws, double* __restrict__ ews,
                        double* __restrict__ fws, double* __restrict__ rws,
                        float* __restrict__ Ym0, float* __restrict__ Ym1) {
  __shared__ double Tas[LM];
  __shared__ double Tbs[LM];
  int side = blockIdx.x;
  const double* Ta = side ? Ta1 : Ta0;
  const double* Tb = side ? Tb1 : Tb0;
  const double* theta = side ? theta1 : theta0;
  float* Ym = side ? Ym1 : Ym0;
  size_t off = (size_t)side * LM * SK;
  double* dw = dws + off; double* ew = ews + off;
  double* fw = fws + off; double* rw = rws + off;
  int j = threadIdx.x;
  for (int k = j; k < LM; k += 128) { Tas[k] = Ta[k]; Tbs[k] = Tb[k]; }
  __syncthreads();
  if (j >= SK) return;
  double sig = theta[j];
  for (int k = 0; k < LM; k++)
    rw[(size_t)k * SK + j] = (double)hashf((u32)k * 2654435761u + (u32)j * 40503u + 17u) - 0.5;
  {
    double dk = Tas[0] - sig;
    double ek = Tbs[0];
    double fk = 0.0;
    double rk = rw[j];
    for (int k = 0; k < LM - 1; k++) {
      double bk = Tbs[k];
      double dn = Tas[k + 1] - sig;
      double en = (k + 2 < LM) ? Tbs[k + 1] : 0.0;
      double rn = rw[(size_t)(k + 1) * SK + j];
      double dd, ee, ff, dk2, ek2, rkeep, rnext;
      if (fabs(dk) >= fabs(bk)) {
        double dsafe = (fabs(dk) > 1e-300) ? dk : 1e-300;
        double m = bk / dsafe;
        dd = dsafe; ee = ek; ff = fk;
        dk2 = dn - m * ek;
        ek2 = en - m * fk;
        rkeep = rk;
        rnext = rn - m * rk;
      } else {
        double m = dk / bk;
        dd = bk; ee = dn; ff = en;
        dk2 = ek - m * dn;
        ek2 = fk - m * en;
        rkeep = rn;
        rnext = rk - m * rn;
      }
      dw[(size_t)k * SK + j] = dd;
      ew[(size_t)k * SK + j] = ee;
      fw[(size_t)k * SK + j] = ff;
      rw[(size_t)k * SK + j] = rkeep;
      rk = rnext; dk = dk2; ek = ek2; fk = 0.0;
    }
    if (fabs(dk) < 1e-300) dk = 1e-300;
    dw[(size_t)(LM - 1) * SK + j] = dk;
    ew[(size_t)(LM - 1) * SK + j] = 0.0;
    fw[(size_t)(LM - 1) * SK + j] = 0.0;
    rw[(size_t)(LM - 1) * SK + j] = rk;
    double y1 = 0.0, y2 = 0.0, nr = 0.0;
    for (int k = LM - 1; k >= 0; k--) {
      double dv = dw[(size_t)k * SK + j];
      double yk = (rw[(size_t)k * SK + j] - ew[(size_t)k * SK + j] * y1 - fw[(size_t)k * SK + j] * y2) / dv;
      rw[(size_t)k * SK + j] = yk;
      y2 = y1; y1 = yk;
      nr += yk * yk;
    }
    double inv = 1.0 / sqrt(nr > 1e-300 ? nr : 1e-300);
    for (int k = 0; k < LM; k++) Ym[(size_t)k * SK + j] = (float)(rw[(size_t)k * SK + j] * inv);
  }
}

// ---------- Cholesky + lower-triangular inverse of SK x SK SPD matrix ----------
__global__ void __launch_bounds__(128) k_cholinv(const float* __restrict__ S,
                                                 float* __restrict__ Linv) {
  extern __shared__ float csh[];
  float (*Ls)[SK + 1] = (float(*)[SK + 1])csh;
  float (*Li)[SK + 1] = (float(*)[SK + 1])(csh + SK * (SK + 1));
  int t = threadIdx.x;
  for (int e = t; e < SK * SK; e += 128) Ls[e / SK][e % SK] = S[e];
  __syncthreads();
  for (int k = 0; k < SK; k++) {
    if (t == 0) Ls[k][k] = sqrtf(fmaxf(Ls[k][k], 1e-20f));
    __syncthreads();
    float dk = Ls[k][k];
    for (int r = k + 1 + t; r < SK; r += 128) Ls[r][k] /= dk;
    __syncthreads();
    int rem = SK - k - 1;
    for (int e = t; e < rem * rem; e += 128) {
      int r = k + 1 + e / rem, c2 = k + 1 + e % rem;
      Ls[r][c2] -= Ls[r][k] * Ls[c2][k];
    }
    __syncthreads();
  }
  {
    int c = t;
    for (int r = 0; r < c; r++) Li[r][c] = 0.f;
    Li[c][c] = 1.0f / Ls[c][c];
    for (int r = c + 1; r < SK; r++) {
      float sacc = 0.f;
      for (int k = c; k < r; k++) sacc += Ls[r][k] * Li[k][c];
      Li[r][c] = -sacc / Ls[r][r];
    }
  }
  __syncthreads();
  for (int e = t; e < SK * SK; e += 128) Linv[e] = Li[e / SK][e % SK];
}

// ---------- generic tiled GEMMs ----------
__global__ void __launch_bounds__(256) k_gemm_tn(const float* __restrict__ A, const float* __restrict__ B,
                                                 float* __restrict__ Cm, int M, int P, int Kd) {
  __shared__ float As[16][65], Bs[16][65];
  int bm = blockIdx.x * 64, bp = blockIdx.y * 64;
  int tx = threadIdx.x & 15, ty = threadIdx.x >> 4;
  float acc[4][4] = {};
  for (int k0 = 0; k0 < Kd; k0 += 16) {
    for (int t2 = threadIdx.x; t2 < 1024; t2 += 256) {
      int mm = t2 & 63, kk = t2 >> 6;
      As[kk][mm] = A[(size_t)(k0 + kk) * M + bm + mm];
      Bs[kk][mm] = B[(size_t)(k0 + kk) * P + bp + mm];
    }
    __syncthreads();
#pragma unroll
    for (int kk = 0; kk < 16; kk++) {
      float av[4], bv[4];
#pragma unroll
      for (int a = 0; a < 4; a++) av[a] = As[kk][ty * 4 + a];
#pragma unroll
      for (int b = 0; b < 4; b++) bv[b] = Bs[kk][tx * 4 + b];
#pragma unroll
      for (int a = 0; a < 4; a++)
#pragma unroll
        for (int b = 0; b < 4; b++) acc[a][b] += av[a] * bv[b];
    }
    __syncthreads();
  }
#pragma unroll
  for (int a = 0; a < 4; a++)
#pragma unroll
    for (int b = 0; b < 4; b++)
      Cm[(size_t)(bm + ty * 4 + a) * P + bp + tx * 4 + b] = acc[a][b];
}

__global__ void __launch_bounds__(256) k_gemm_nt(const float* __restrict__ A, const float* __restrict__ B,
                                                 float* __restrict__ Cm, int M, int P, int Kd) {
  __shared__ float As[16][65], Bs[16][65];
  int bm = blockIdx.x * 64, bp = blockIdx.y * 64;
  int tx = threadIdx.x & 15, ty = threadIdx.x >> 4;
  float acc[4][4] = {};
  for (int k0 = 0; k0 < Kd; k0 += 16) {
    for (int t2 = threadIdx.x; t2 < 1024; t2 += 256) {
      int kk = t2 & 15, mm = t2 >> 4;
      As[kk][mm] = A[(size_t)(bm + mm) * Kd + k0 + kk];
      Bs[kk][mm] = B[(size_t)(bp + mm) * Kd + k0 + kk];
    }
    __syncthreads();
#pragma unroll
    for (int kk = 0; kk < 16; kk++) {
      float av[4], bv[4];
#pragma unroll
      for (int a = 0; a < 4; a++) av[a] = As[kk][ty * 4 + a];
#pragma unroll
      for (int b = 0; b < 4; b++) bv[b] = Bs[kk][tx * 4 + b];
#pragma unroll
      for (int a = 0; a < 4; a++)
#pragma unroll
        for (int b = 0; b < 4; b++) acc[a][b] += av[a] * bv[b];
    }
    __syncthreads();
  }
#pragma unroll
  for (int a = 0; a < 4; a++)
#pragma unroll
    for (int b = 0; b < 4; b++)
      Cm[(size_t)(bm + ty * 4 + a) * P + bp + tx * 4 + b] = acc[a][b];
}

__global__ void __launch_bounds__(256) k_gemm_nn(const float* __restrict__ A, const float* __restrict__ B,
                                                 float* __restrict__ Cm, int M, int P, int Kd) {
  __shared__ float As[16][65], Bs[16][65];
  int bm = blockIdx.x * 64, bp = blockIdx.y * 64;
  int tx = threadIdx.x & 15, ty = threadIdx.x >> 4;
  float acc[4][4] = {};
  for (int k0 = 0; k0 < Kd; k0 += 16) {
    for (int t2 = threadIdx.x; t2 < 1024; t2 += 256) {
      int kk = t2 & 15, mm = t2 >> 4;
      As[kk][mm] = A[(size_t)(bm + mm) * Kd + k0 + kk];
    }
    for (int t2 = threadIdx.x; t2 < 1024; t2 += 256) {
      int mm = t2 & 63, kk = t2 >> 6;
      Bs[kk][mm] = B[(size_t)(k0 + kk) * P + bp + mm];
    }
    __syncthreads();
#pragma unroll
    for (int kk = 0; kk < 16; kk++) {
      float av[4], bv[4];
#pragma unroll
      for (int a = 0; a < 4; a++) av[a] = As[kk][ty * 4 + a];
#pragma unroll
      for (int b = 0; b < 4; b++) bv[b] = Bs[kk][tx * 4 + b];
#pragma unroll
      for (int a = 0; a < 4; a++)
#pragma unroll
        for (int b = 0; b < 4; b++) acc[a][b] += av[a] * bv[b];
    }
    __syncthreads();
  }
#pragma unroll
  for (int a = 0; a < 4; a++)
#pragma unroll
    for (int b = 0; b < 4; b++)
      Cm[(size_t)(bm + ty * 4 + a) * P + bp + tx * 4 + b] = acc[a][b];
}

// ---------- s = max(max ev_a, max ev_b) ----------
__global__ void k_smax(const float* __restrict__ ea, const float* __restrict__ eb, double* __restrict__ scal) {
  __shared__ float red[128];
  int t = threadIdx.x;
  red[t] = fmaxf(ea[t], eb[t]);
  __syncthreads();
  for (int o = 64; o > 0; o >>= 1) { if (t < o) red[t] = fmaxf(red[t], red[t + o]); __syncthreads(); }
  if (t == 0) scal[1] = (double)red[0];
}

// ---------- resolvent mask ----------
__global__ void k_mask(const float* __restrict__ evr, const float* __restrict__ evc,
                       const double* __restrict__ scal, float* __restrict__ Dm) {
  int t = blockIdx.x * 256 + threadIdx.x;
  if (t >= SK * SK) return;
  int i = t / SK, j = t % SK;
  float s = (float)scal[1];
  float g1 = sqrtf(fmaxf(evc[j] / s, 0.f));
  float g2 = sqrtf(fmaxf(evr[i] / s, 0.f));
  float a2 = g2 * g2 + 1.f, a1 = g1 * g1 + 1.f;
  float re = g2 / a2 - g1 / a1;
  float im = 1.f / a2 - 1.f / a1;
  Dm[t] = re * re + im * im;
}

// ---------- per-row Cholesky solve (factor matrix in padded LDS) ----------
__global__ void __launch_bounds__(128) k_cholsolve(const float* __restrict__ AAt, const float* __restrict__ BAt,
                                                   const float* __restrict__ Dm,
                                                   float* __restrict__ Cout) {
  extern __shared__ float Msh[];   // [SK][SK+1]
  __shared__ float xs[SK];
  int i = blockIdx.x;
  const int LD = SK + 1;
  for (int t2 = threadIdx.x; t2 < SK * SK; t2 += 128) {
    int r = t2 / SK, c2 = t2 % SK;
    float v = AAt[t2];
    if (r == c2) v += LAMBDA_ * Dm[(size_t)i * SK + r];
    Msh[r * LD + c2] = v;
  }
  if (threadIdx.x < SK) xs[threadIdx.x] = BAt[(size_t)i * SK + threadIdx.x];
  __syncthreads();
  for (int k = 0; k < SK; k++) {
    if (threadIdx.x == 0) Msh[k * LD + k] = sqrtf(fmaxf(Msh[k * LD + k], 1e-20f));
    __syncthreads();
    float dk = Msh[k * LD + k];
    for (int r = k + 1 + threadIdx.x; r < SK; r += 128) Msh[r * LD + k] /= dk;
    __syncthreads();
    int rem = SK - k - 1;
    for (int t2 = threadIdx.x; t2 < rem * rem; t2 += 128) {
      int r = k + 1 + t2 / rem, c2 = k + 1 + t2 % rem;
      Msh[r * LD + c2] -= Msh[r * LD + k] * Msh[c2 * LD + k];
    }
    __syncthreads();
  }
  for (int k = 0; k < SK; k++) {
    if (threadIdx.x == 0) xs[k] /= Msh[k * LD + k];
    __syncthreads();
    float xv = xs[k];
    for (int r = k + 1 + threadIdx.x; r < SK; r += 128) xs[r] -= Msh[r * LD + k] * xv;
    __syncthreads();
  }
  for (int k = SK - 1; k >= 0; k--) {
    if (threadIdx.x == 0) xs[k] /= Msh[k * LD + k];
    __syncthreads();
    float xv = xs[k];
    for (int r = threadIdx.x; r < k; r += 128) xs[r] -= Msh[k * LD + r] * xv;
    __syncthreads();
  }
  for (int t2 = threadIdx.x; t2 < SK; t2 += 128) Cout[(size_t)i * SK + t2] = xs[t2];
}

// ---------- loss partials (deterministic) ----------
__global__ void k_frob_iden(const float* __restrict__ Mat, double* __restrict__ lpart, int slot) {
  __shared__ double red[256];
  double s = 0.0;
  for (int t2 = blockIdx.x * 256 + threadIdx.x; t2 < SK * SK; t2 += 32 * 256) {
    float v = Mat[t2] - ((t2 / SK == t2 % SK) ? 1.f : 0.f);
    s += (double)v * (double)v;
  }
  red[threadIdx.x] = s; __syncthreads();
  for (int o = 128; o > 0; o >>= 1) { if (threadIdx.x < o) red[threadIdx.x] += red[threadIdx.x + o]; __syncthreads(); }
  if (threadIdx.x == 0) lpart[slot * 32 + blockIdx.x] = red[0];
}
__global__ void k_lap(const float* __restrict__ Cm, const float* __restrict__ evc,
                      const float* __restrict__ evr, double* __restrict__ lpart, int slot) {
  __shared__ double red[256];
  double s = 0.0;
  for (int t2 = blockIdx.x * 256 + threadIdx.x; t2 < SK * SK; t2 += 32 * 256) {
    int i = t2 / SK, j = t2 % SK;
    float v = Cm[t2] * (evc[j] - evr[i]);
    s += (double)v * (double)v;
  }
  red[threadIdx.x] = s; __syncthreads();
  for (int o = 128; o > 0; o >>= 1) { if (threadIdx.x < o) red[threadIdx.x] += red[threadIdx.x + o]; __syncthreads(); }
  if (threadIdx.x == 0) lpart[slot * 32 + blockIdx.x] = red[0];
}
__global__ void k_writeout(const double* __restrict__ lpart, float* __restrict__ out) {
  if (threadIdx.x == 0) {
    double b = 0.0, o = 0.0, l = 0.0;
    for (int s = 0; s < 64; s++) b += lpart[s];
    for (int s = 64; s < 128; s++) o += lpart[s];
    for (int s = 128; s < 192; s++) l += lpart[s];
    out[0] = (float)b; out[1] = (float)o; out[2] = (float)l;
  }
}

extern "C" void kernel_launch(void* const* d_in, const int* in_sizes, int n_in,
                              void* d_out, int out_size, void* d_ws, size_t ws_size,
                              hipStream_t stream) {
  const float* feats[2] = {(const float*)d_in[0], (const float*)d_in[1]};
  char* p = (char*)d_ws;
  auto alloc = [&](size_t bytes) -> void* {
    char* r = p;
    p += (bytes + 255) & ~(size_t)255;
    return (void*)r;
  };
  float* pan0  = (float*)alloc(sizeof(float) * 256 * NN);
  float* pan1  = (float*)alloc(sizeof(float) * 256 * NN);
  float* sq0   = (float*)alloc(sizeof(float) * NN);
  float* sq1   = (float*)alloc(sizeof(float) * NN);
  float* dkv0  = (float*)alloc(sizeof(float) * (size_t)NN * KK);
  float* dkv1  = (float*)alloc(sizeof(float) * (size_t)NN * KK);
  float* wv    = (float*)alloc(sizeof(float) * (size_t)NN * KK);
  int*   cnt   = (int*)alloc(sizeof(int) * NN);
  int*   rpos  = (int*)alloc(sizeof(int) * NN);
  int*   tsrc  = (int*)alloc(sizeof(int) * (size_t)NN * KK);
  float* deg   = (float*)alloc(sizeof(float) * NN);
  int*   hist  = (int*)alloc(sizeof(int) * 256 * NN);
  int*   baseb = (int*)alloc(sizeof(int) * 256 * NN);
  int*   idxs[2];  float* wadjrs[2]; float* wadjts[2]; int* tcols[2]; int* roffs[2];
  for (int s = 0; s < 2; s++) {
    idxs[s]   = (int*)alloc(sizeof(int) * (size_t)NN * KK);
    wadjrs[s] = (float*)alloc(sizeof(float) * (size_t)NN * KK);
    wadjts[s] = (float*)alloc(sizeof(float) * (size_t)NN * KK);
    tcols[s]  = (int*)alloc(sizeof(int) * (size_t)NN * KK);
    roffs[s]  = (int*)alloc(sizeof(int) * (NN + 1));
  }
  float* Q0    = (float*)alloc(sizeof(float) * (size_t)LM * NN);
  float* Q1    = (float*)alloc(sizeof(float) * (size_t)LM * NN);
  float* ya0   = (float*)alloc(sizeof(float) * NN);
  float* ya1   = (float*)alloc(sizeof(float) * NN);
  float* yb0   = (float*)alloc(sizeof(float) * NN);
  float* yb1   = (float*)alloc(sizeof(float) * NN);
  float* cv0   = (float*)alloc(sizeof(float) * LM);
  float* cv1   = (float*)alloc(sizeof(float) * LM);
  double* part = (double*)alloc(sizeof(double) * 256);
  double* scal0= (double*)alloc(sizeof(double) * 8);
  double* scal1= (double*)alloc(sizeof(double) * 8);
  double* Ta0  = (double*)alloc(sizeof(double) * LM);
  double* Tb0  = (double*)alloc(sizeof(double) * LM);
  double* Ta1  = (double*)alloc(sizeof(double) * LM);
  double* Tb1  = (double*)alloc(sizeof(double) * LM);
  double* theta0 = (double*)alloc(sizeof(double) * SK);
  double* theta1 = (double*)alloc(sizeof(double) * SK);
  double* dws  = (double*)alloc(sizeof(double) * 2 * (size_t)LM * SK);
  double* ews  = (double*)alloc(sizeof(double) * 2 * (size_t)LM * SK);
  double* fws  = (double*)alloc(sizeof(double) * 2 * (size_t)LM * SK);
  double* rws  = (double*)alloc(sizeof(double) * 2 * (size_t)LM * SK);
  float* Ym0   = (float*)alloc(sizeof(float) * (size_t)LM * SK);
  float* Ym1   = (float*)alloc(sizeof(float) * (size_t)LM * SK);
  float* Ym2   = (float*)alloc(sizeof(float) * (size_t)LM * SK);
  float* Sm    = (float*)alloc(sizeof(float) * SK * SK);
  float* Linv  = (float*)alloc(sizeof(float) * SK * SK);
  float* U0    = (float*)alloc(sizeof(float) * (size_t)NN * SK);
  float* U1    = (float*)alloc(sizeof(float) * (size_t)NN * SK);
  float* ev0   = (float*)alloc(sizeof(float) * SK);
  float* ev1   = (float*)alloc(sizeof(float) * SK);
  float* Ac    = (float*)alloc(sizeof(float) * (size_t)SK * NC);
  float* Bc    = (float*)alloc(sizeof(float) * (size_t)SK * NC);
  float* AAt   = (float*)alloc(sizeof(float) * SK * SK);
  float* BAt   = (float*)alloc(sizeof(float) * SK * SK);
  float* Dm    = (float*)alloc(sizeof(float) * SK * SK);
  float* Cxy   = (float*)alloc(sizeof(float) * SK * SK);
  float* Cyx   = (float*)alloc(sizeof(float) * SK * SK);
  float* P1    = (float*)alloc(sizeof(float) * SK * SK);
  double* lpart= (double*)alloc(sizeof(double) * 192);
  unsigned* sy = (unsigned*)alloc(sizeof(unsigned) * 1024);

  float* Yms[2] = {Ym0, Ym1};
  float* Qs2[2] = {Q0, Q1};
  float* Us[2] = {U0, U1};
  float* dkvs[2] = {dkv0, dkv1};
  double* scals[2] = {scal0, scal1};

  hipFuncSetAttribute((const void*)k_lanczos2,
                      hipFuncAttributeMaxDynamicSharedMemorySize, DYNLDS);
  hipFuncSetAttribute((const void*)k_cholinv,
                      hipFuncAttributeMaxDynamicSharedMemorySize, CHOLLDS);
  hipFuncSetAttribute((const void*)k_cholsolve,
                      hipFuncAttributeMaxDynamicSharedMemorySize, CHSLDS);

  // ---- kNN distance + top-k: both sides batched per panel ----
  k_sqnorm2<<<dim3(NN, 2), 256, 0, stream>>>(feats[0], feats[1], sq0, sq1);
  for (int p2 = 0; p2 < 16; p2++) {
    k_d2panel2<<<dim3(64, 4, 2), 256, 0, stream>>>(feats[0], feats[1], sq0, sq1, pan0, pan1, p2 * 256);
    k_topk2<<<dim3(256, 1, 2), 256, 0, stream>>>(pan0, pan1, p2 * 256,
                                                 idxs[0], idxs[1], dkv0, dkv1);
  }
  // ---- per-side graph finish (tiny kernels) ----
  for (int s2 = 0; s2 < 2; s2++) {
    int* idx = idxs[s2];
    float* dkv = dkvs[s2];
    k_partsum<<<64, 256, 0, stream>>>(dkv, part);
    k_sigma<<<1, 64, 0, stream>>>(part, scals[s2]);
    k_wexp<<<NN * KK / 256, 256, 0, stream>>>(dkv, scals[s2], wv);
    hipMemsetAsync(cnt, 0, sizeof(int) * NN, stream);
    k_count<<<NN * KK / 256, 256, 0, stream>>>(idx, cnt);
    k_scan<<<1, 1024, 0, stream>>>(cnt, roffs[s2], rpos);
    hipMemsetAsync(hist, 0, sizeof(int) * 256 * NN, stream);
    k_hist<<<256, 256, 0, stream>>>(idx, hist);
    k_colscan<<<16, 256, 0, stream>>>(hist, roffs[s2], baseb);
    k_place2<<<256, 256, 0, stream>>>(idx, baseb, tsrc);
    k_deg<<<16, 256, 0, stream>>>(wv, roffs[s2], tsrc, deg);
    k_wadj2<<<16, 256, 0, stream>>>(wv, idx, roffs[s2], tsrc, deg,
                                    wadjrs[s2], wadjts[s2], tcols[s2]);
  }

  // ---- dual-side fused cooperative Lanczos (CGS1) ----
  hipMemsetAsync(sy, 0, sizeof(unsigned) * 1024, stream);
  {
    void* args[] = {(void*)&Q0, (void*)&Q1,
                    (void*)&ya0, (void*)&ya1, (void*)&yb0, (void*)&yb1,
                    (void*)&wadjrs[0], (void*)&idxs[0], (void*)&wadjts[0], (void*)&tcols[0], (void*)&roffs[0],
                    (void*)&wadjrs[1], (void*)&idxs[1], (void*)&wadjts[1], (void*)&tcols[1], (void*)&roffs[1],
                    (void*)&cv0, (void*)&cv1, (void*)&part,
                    (void*)&Ta0, (void*)&Tb0, (void*)&Ta1, (void*)&Tb1,
                    (void*)&sy};
    hipLaunchCooperativeKernel((const void*)k_lanczos2, dim3(256), dim3(1024), args, DYNLDS, stream);
  }

  // ---- spectral finish: batched bisect + 1-pass invit, then per-side CholQR2 ----
  k_bisect2<<<2, 128, 0, stream>>>(Ta0, Tb0, Ta1, Tb1, theta0, theta1, ev0, ev1);
  k_invit2<<<2, 128, 0, stream>>>(Ta0, Tb0, Ta1, Tb1, theta0, theta1,
                                  dws, ews, fws, rws, Ym0, Ym1);
  for (int s2 = 0; s2 < 2; s2++) {
    k_gemm_tn<<<dim3(2, 2), 256, 0, stream>>>(Yms[s2], Yms[s2], Sm, SK, SK, LM);
    k_cholinv<<<1, 128, CHOLLDS, stream>>>(Sm, Linv);
    k_gemm_nt<<<dim3(LM / 64, 2), 256, 0, stream>>>(Yms[s2], Linv, Ym2, LM, SK, SK);
    k_gemm_tn<<<dim3(2, 2), 256, 0, stream>>>(Ym2, Ym2, Sm, SK, SK, LM);
    k_cholinv<<<1, 128, CHOLLDS, stream>>>(Sm, Linv);
    k_gemm_nt<<<dim3(LM / 64, 2), 256, 0, stream>>>(Ym2, Linv, Yms[s2], LM, SK, SK);
    k_gemm_tn<<<dim3(NN / 64, SK / 64), 256, 0, stream>>>(Qs2[s2], Yms[s2], Us[s2], NN, SK, LM);
  }

  // ---- spectral coefficients + FM solves + losses ----
  k_gemm_tn<<<dim3(SK / 64, NC / 64), 256, 0, stream>>>(U0, feats[0], Ac, SK, NC, NN);
  k_gemm_tn<<<dim3(SK / 64, NC / 64), 256, 0, stream>>>(U1, feats[1], Bc, SK, NC, NN);
  k_smax<<<1, 128, 0, stream>>>(ev0, ev1, scal0);

  k_gemm_nt<<<dim3(2, 2), 256, 0, stream>>>(Ac, Ac, AAt, SK, SK, NC);
  k_gemm_nt<<<dim3(2, 2), 256, 0, stream>>>(Bc, Ac, BAt, SK, SK, NC);
  k_mask<<<64, 256, 0, stream>>>(ev1, ev0, scal0, Dm);
  k_cholsolve<<<SK, 128, CHSLDS, stream>>>(AAt, BAt, Dm, Cxy);
  k_gemm_nt<<<dim3(2, 2), 256, 0, stream>>>(Bc, Bc, AAt, SK, SK, NC);
  k_gemm_nt<<<dim3(2, 2), 256, 0, stream>>>(Ac, Bc, BAt, SK, SK, NC);
  k_mask<<<64, 256, 0, stream>>>(ev0, ev1, scal0, Dm);
  k_cholsolve<<<SK, 128, CHSLDS, stream>>>(AAt, BAt, Dm, Cyx);

  k_gemm_nn<<<dim3(2, 2), 256, 0, stream>>>(Cxy, Cyx, P1, SK, SK, SK);
  k_frob_iden<<<32, 256, 0, stream>>>(P1, lpart, 0);
  k_gemm_nn<<<dim3(2, 2), 256, 0, stream>>>(Cyx, Cxy, P1, SK, SK, SK);
  k_frob_iden<<<32, 256, 0, stream>>>(P1, lpart, 1);
  k_gemm_tn<<<dim3(2, 2), 256, 0, stream>>>(Cxy, Cxy, P1, SK, SK, SK);
  k_frob_iden<<<32, 256, 0, stream>>>(P1, lpart, 2);
  k_gemm_tn<<<dim3(2, 2), 256, 0, stream>>>(Cyx, Cyx, P1, SK, SK, SK);
  k_frob_iden<<<32, 256, 0, stream>>>(P1, lpart, 3);
  k_lap<<<32, 256, 0, stream>>>(Cxy, ev0, ev1, lpart, 4);
  k_lap<<<32, 256, 0, stream>>>(Cyx, ev1, ev0, lpart, 5);
  k_writeout<<<1, 64, 0, stream>>>(lpart, (float*)d_out);
}